// Round 4
// baseline (84537.732 us; speedup 1.0000x reference)
//
#include <hip/hip_runtime.h>
#include <hip/hip_bf16.h>

#define DEVI __device__ __forceinline__

DEVI float sigm(float x){ return 1.f/(1.f+expf(-x)); }

// ---------------- transpose: out[b][c][r] = in[b][r][c] ----------------
__global__ void k_transpose(const float* __restrict__ in, float* __restrict__ out, int R, int C){
  int b = blockIdx.y;
  long n = (long)R*C;
  long i = (long)blockIdx.x*256 + threadIdx.x;
  if (i < n){
    int r = (int)(i / C), c = (int)(i % C);
    out[(long)b*n + (long)c*R + r] = in[(long)b*n + i];
  }
}

// ---------------- embedding gathers (D=200) ----------------
__global__ void k_gather(const float* __restrict__ emb, const int* __restrict__ tok, float* __restrict__ out){
  int row = blockIdx.x; int c = threadIdx.x;
  if (c < 200) out[(long)row*200 + c] = emb[(long)tok[row]*200 + c];
}
__global__ void k_gather_sel(const float* __restrict__ emb, const int* __restrict__ tok, const int* __restrict__ sel, float* __restrict__ out){
  int t = blockIdx.x, b = blockIdx.y; int c = threadIdx.x;
  if (c < 200){
    int tk = tok[(long)sel[b]*50 + t];
    out[((long)b*50 + t)*200 + c] = emb[(long)tk*200 + c];
  }
}

// ---------------- fp32 GEMM 128x128 tile, 8x8 micro: C = A(M,K) @ W(N,K)^T + bias ----------------
__global__ __launch_bounds__(256) void k_gemm128(
    const float* __restrict__ A, const float* __restrict__ W,
    const float* __restrict__ bias, float* __restrict__ C,
    int M, int N, int K, long sA, long sW, long sC, long sBias)
{
  int bz = blockIdx.z;
  A += (long)bz*sA; W += (long)bz*sW; C += (long)bz*sC;
  if (bias) bias += (long)bz*sBias;
  int n0 = blockIdx.x*128, m0 = blockIdx.y*128;
  __shared__ float As[16][132];
  __shared__ float Bs[16][132];
  int tid = threadIdx.x;
  int tx = tid & 15, ty = tid >> 4;
  float acc[8][8] = {};
  const bool k4 = ((K & 3) == 0);
  for (int k0 = 0; k0 < K; k0 += 16){
    #pragma unroll
    for (int half = 0; half < 2; half++){
      int s = tid + half*256;
      int r = s >> 2;
      int kq = (s & 3) << 2;
      int k = k0 + kq;
      int m = m0 + r;
      float4 va = make_float4(0.f,0.f,0.f,0.f);
      if (m < M){
        if (k4 && k + 3 < K) va = *(const float4*)&A[(long)m*K + k];
        else {
          float* pv = (float*)&va;
          #pragma unroll
          for (int u=0; u<4; u++) if (k+u < K) pv[u] = A[(long)m*K + k + u];
        }
      }
      As[kq+0][r]=va.x; As[kq+1][r]=va.y; As[kq+2][r]=va.z; As[kq+3][r]=va.w;
      int n = n0 + r;
      float4 vb = make_float4(0.f,0.f,0.f,0.f);
      if (n < N){
        if (k4 && k + 3 < K) vb = *(const float4*)&W[(long)n*K + k];
        else {
          float* pv = (float*)&vb;
          #pragma unroll
          for (int u=0; u<4; u++) if (k+u < K) pv[u] = W[(long)n*K + k + u];
        }
      }
      Bs[kq+0][r]=vb.x; Bs[kq+1][r]=vb.y; Bs[kq+2][r]=vb.z; Bs[kq+3][r]=vb.w;
    }
    __syncthreads();
    #pragma unroll
    for (int kk=0;kk<16;kk++){
      float a[8], b[8];
      *(float4*)&a[0] = *(const float4*)&As[kk][ty*8];
      *(float4*)&a[4] = *(const float4*)&As[kk][ty*8+4];
      *(float4*)&b[0] = *(const float4*)&Bs[kk][tx*8];
      *(float4*)&b[4] = *(const float4*)&Bs[kk][tx*8+4];
      #pragma unroll
      for (int i=0;i<8;i++)
        #pragma unroll
        for (int j=0;j<8;j++)
          acc[i][j] += a[i]*b[j];
    }
    __syncthreads();
  }
  #pragma unroll
  for (int i=0;i<8;i++){
    int m = m0 + ty*8 + i;
    if (m >= M) continue;
    #pragma unroll
    for (int j=0;j<8;j++){
      int n = n0 + tx*8 + j;
      if (n < N) C[(long)m*N + n] = acc[i][j] + (bias ? bias[n] : 0.f);
    }
  }
}

// ---------------- small GRU (h=150, 3h=450), 1 wg per (item,dir) ----------------
__global__ __launch_bounds__(512) void k_gru_small(
    const float* __restrict__ xs, long xsDir,
    const float* __restrict__ Wt, const float* __restrict__ bhh,
    float* __restrict__ y, int yld,
    float* __restrict__ meanOut, int meanld,
    int T)
{
  int item = blockIdx.x, dir = blockIdx.y;
  const float* xsd = xs + (long)dir*xsDir + (long)item*T*450;
  const float* Wtd = Wt + (long)dir*150*450;
  int tid = threadIdx.x;
  float bh = (tid < 450) ? bhh[(long)dir*450 + tid] : 0.f;
  __shared__ float hs[152];
  __shared__ float gs[456];
  if (tid < 150) hs[tid] = 0.f;
  float hsum = 0.f;
  __syncthreads();
  for (int t=0;t<T;t++){
    int tt = dir ? (T-1-t) : t;
    if (tid < 450){
      float g = bh;
      const float* wp = Wtd + tid;
      #pragma unroll 5
      for (int k=0;k<150;k++) g += hs[k] * wp[(long)k*450];
      gs[tid] = g;
    }
    __syncthreads();
    if (tid < 150){
      const float* xr = xsd + (long)tt*450;
      float r = sigm(xr[tid]     + gs[tid]);
      float z = sigm(xr[150+tid] + gs[150+tid]);
      float nn = tanhf(xr[300+tid] + r*gs[300+tid]);
      float h = (1.f-z)*nn + z*hs[tid];
      hs[tid] = h;
      hsum += h;
      if (y) y[((long)item*T + tt)*yld + dir*150 + tid] = h;
    }
    __syncthreads();
  }
  if (meanOut && tid < 150)
    meanOut[(long)item*meanld + dir*150 + tid] = hsum / (float)T;
}

// ---------------- persistent big GRU: all T steps in one launch ----------------
// Decomp: wid -> (dir, bb in {0,1} of 16 batch, cb of 10 h-cols). 256 threads.
// Per step: stage h slice [16][H] + 30 weight rows to LDS; thread (i=row 0..29, bp=0..7)
// computes gate dots for 2 batch items; 160 threads do the GRU update.
// Cross-wg sync: device-scope global barrier (counter+step flag) per step.
template<int H, int HPAD, int KT, int NPH, int LDW, int NCB>
__global__ __launch_bounds__(256) void k_gru_persist(
    const float* __restrict__ xs, long xsDir,
    const float* __restrict__ Whh, const float* __restrict__ bhh,
    float* hA, float* hB,
    float* __restrict__ ysum, int ysld,
    int T, int* bar, int nwg)
{
  constexpr int H3 = 3*H;
  constexpr int KP = KT*NPH;          // padded k extent (>= H, zeros beyond)
  int wid = blockIdx.x;
  int dir = wid / (2*NCB);
  int rem = wid % (2*NCB);
  int bb  = rem / NCB;
  int cb  = rem % NCB;
  int c0  = cb*10;
  int tid = threadIdx.x;

  const float* xsd = xs + (long)dir*xsDir;
  const float* Wd  = Whh + (long)dir*(long)H*H3;   // [3H][H] row-major
  const float* bhd = bhh + (long)dir*H3;

  __shared__ float hs[16*HPAD];
  __shared__ float Wl[30*LDW];
  __shared__ float gl[30*16];

  int i  = tid >> 3;        // 0..31 (rows; 30 used)
  int bp = tid & 7;         // 0..7
  bool alive = (i < 30);
  int gg = i/10, ci = i%10;
  long grow = (long)gg*H + c0 + ci;
  float bias = alive ? bhd[grow] : 0.f;

  int uci = tid % 10, ubl = tid / 10;  // update mapping (tid<160)
  int uc = c0 + uci;
  int ub = bb*16 + ubl;
  float ysacc = 0.f;

  for (int t=0; t<T; t++){
    const float* hp = ((t & 1) ? hB : hA) + (long)dir*32*H;
    float*       hn = ((t & 1) ? hA : hB) + (long)dir*32*H;
    int tt = dir ? (T-1-t) : t;

    // stage h slice (zeros in k-pad region)
    for (int u = tid; u < 16*(KP/2); u += 256){
      int bl = u / (KP/2), jq = u % (KP/2);
      int k = jq*2;
      float2 v = make_float2(0.f, 0.f);
      if (k + 2 <= H) v = *(const float2*)&hp[(long)(bb*16+bl)*H + k];
      *(float2*)&hs[bl*HPAD + k] = v;
    }

    float acc0 = bias, acc1 = bias;
    #pragma unroll
    for (int ph = 0; ph < NPH; ph++){
      int k0 = ph*KT;
      __syncthreads();
      for (int u = tid; u < 30*KT; u += 256){
        int r = u / KT, k = k0 + u % KT;
        Wl[r*LDW + (u%KT)] = (k < H) ? Wd[((long)(r/10)*H + c0 + r%10)*H + k] : 0.f;
      }
      __syncthreads();
      if (alive){
        const float* wr = &Wl[i*LDW];
        const float* h0 = &hs[(2*bp)*HPAD + k0];
        const float* h1 = &hs[(2*bp+1)*HPAD + k0];
        #pragma unroll 4
        for (int jq = 0; jq < KT; jq += 4){
          float4 w = *(const float4*)&wr[jq];
          float4 a = *(const float4*)&h0[jq];
          float4 b = *(const float4*)&h1[jq];
          acc0 += w.x*a.x + w.y*a.y + w.z*a.z + w.w*a.w;
          acc1 += w.x*b.x + w.y*b.y + w.z*b.z + w.w*b.w;
        }
      }
    }
    if (alive){ gl[i*16 + 2*bp] = acc0; gl[i*16 + 2*bp + 1] = acc1; }
    __syncthreads();
    if (tid < 160){
      const float* xr = xsd + ((long)ub*T + tt)*H3;
      float r  = sigm(xr[uc]     + gl[(uci)*16    + ubl]);
      float z  = sigm(xr[H+uc]   + gl[(10+uci)*16 + ubl]);
      float nn = tanhf(xr[2*H+uc] + r*gl[(20+uci)*16 + ubl]);
      float hv = hs[ubl*HPAD + uc];
      float hne = (1.f-z)*nn + z*hv;
      hn[(long)ub*H + uc] = hne;
      ysacc += hne;
    }
    // ---- global barrier ----
    __threadfence();
    __syncthreads();
    if (tid == 0){
      if (__hip_atomic_fetch_add(&bar[0], 1, __ATOMIC_ACQ_REL, __HIP_MEMORY_SCOPE_AGENT) == nwg-1){
        __hip_atomic_store(&bar[0], 0, __ATOMIC_RELAXED, __HIP_MEMORY_SCOPE_AGENT);
        __hip_atomic_store(&bar[1], t+1, __ATOMIC_RELEASE, __HIP_MEMORY_SCOPE_AGENT);
      } else {
        while (__hip_atomic_load(&bar[1], __ATOMIC_ACQUIRE, __HIP_MEMORY_SCOPE_AGENT) < t+1)
          __builtin_amdgcn_s_sleep(2);
      }
    }
    __syncthreads();
    __threadfence();
  }
  if (tid < 160)
    ysum[(long)ub*ysld + dir*H + uc] = ysacc;
}

// ---------------- graph decomposition layer (D=300, K=8) ----------------
__global__ __launch_bounds__(256) void k_graphdecomp(
   const float* __restrict__ labIn, float* __restrict__ labOut,
   const int* __restrict__ nb, const int* __restrict__ nbm, int N)
{
  int n = blockIdx.x; if (n >= N) return;
  int tid = threadIdx.x;
  __shared__ float ln[300];
  __shared__ float red[12];
  for (int d=tid; d<300; d+=256) ln[d] = labIn[(long)n*300+d];
  float deg = 0.f;
  for (int k=0;k<8;k++) deg += (float)nbm[n*8+k];
  float invdeg = 1.f / fmaxf(deg, 1.f);
  float acc0 = 0.f, acc1 = 0.f;
  __syncthreads();
  for (int k=0;k<8;k++){
    int j = nb[n*8+k];
    float mk = (float)nbm[n*8+k];
    const float* lj = labIn + (long)j*300;
    float p1=0.f, p2=0.f;
    for (int d=tid; d<300; d+=256){ float v = lj[d]; p1 += ln[d]*v; p2 += v*v; }
    for (int o=32;o>0;o>>=1){ p1 += __shfl_down(p1,o); p2 += __shfl_down(p2,o); }
    __syncthreads();
    int w = tid>>6, lane = tid&63;
    if (lane==0){ red[w]=p1; red[4+w]=p2; }
    __syncthreads();
    float x1 = red[0]+red[1]+red[2]+red[3];
    float x2 = red[4]+red[5]+red[6]+red[7];
    float coef = (x1 / (x2 + 1e-10f)) * mk * invdeg;
    acc0 += coef * lj[tid];
    if (tid + 256 < 300) acc1 += coef * lj[tid+256];
    __syncthreads();
  }
  bool pos = deg > 0.f;
  labOut[(long)n*300 + tid]                       = pos ? (ln[tid]     - acc0) : ln[tid];
  if (tid+256 < 300) labOut[(long)n*300 + tid+256] = pos ? (ln[tid+256] - acc1) : ln[tid+256];
}

// ---------------- copy ----------------
__global__ void k_copy(const float* __restrict__ src, float* __restrict__ dst, long n){
  long i = (long)blockIdx.x*256+threadIdx.x; if (i<n) dst[i]=src[i];
}

// ---------------- code_wise reductions ----------------
__global__ void k_cw_rowmax(const float* __restrict__ S, float* __restrict__ Mv){
  const int ofs[4]={0,119,238,341};
  const int wid[4]={119,119,103,103};
  int s = blockIdx.y; int row = blockIdx.x*256+threadIdx.x;
  if (row < 16384){
    const float* p = S + (long)row*444 + ofs[s];
    float m = -3.4e38f;
    int w = wid[s];
    for (int n=0;n<w;n++) m = fmaxf(m, p[n]);
    Mv[(long)s*16384+row] = m;
  }
}
__global__ void k_cw_softmax(const float* __restrict__ Mv, float* __restrict__ att){
  int b=blockIdx.x, s=blockIdx.y, tid=threadIdx.x;
  const float* src = Mv + (long)s*16384 + (long)b*512;
  __shared__ float red[256];
  float v0 = src[tid], v1 = src[tid+256];
  red[tid] = fmaxf(v0,v1); __syncthreads();
  for (int o=128;o>0;o>>=1){ if (tid<o) red[tid]=fmaxf(red[tid],red[tid+o]); __syncthreads(); }
  float m = red[0]; __syncthreads();
  float e0=expf(v0-m), e1=expf(v1-m);
  red[tid]=e0+e1; __syncthreads();
  for (int o=128;o>0;o>>=1){ if (tid<o) red[tid]+=red[tid+o]; __syncthreads(); }
  float inv = 1.f/red[0];
  float* dst = att + ((long)s*32 + b)*512;
  dst[tid]=e0*inv; dst[tid+256]=e1*inv;
}
__global__ void k_cw_out(const float* __restrict__ att, const float* __restrict__ DH, float* __restrict__ outp){
  int b=blockIdx.x, s=blockIdx.y, tid=threadIdx.x;
  __shared__ float a[512];
  for (int i=tid;i<512;i+=256) a[i]=att[((long)s*32+b)*512+i];
  __syncthreads();
  for (int d=tid; d<300; d+=256){
    float acc=0.f;
    for (int t=0;t<512;t++) acc += a[t]*DH[((long)b*512+t)*300+d];
    outp[((long)s*32+b)*300+d]=acc;
  }
}

// ---------------- masked softmax over l=50 (in place) ----------------
__global__ void k_masksm(float* __restrict__ att, long nrows){
  long row = (long)blockIdx.x*256 + threadIdx.x;
  if (row >= nrows) return;
  float* p = att + row*50;
  float m = -INFINITY;
  for (int l=0;l<50;l++){ float a = p[l]; if (a != 0.f && a > m) m = a; }
  if (m == -INFINITY){ for (int l=0;l<50;l++) p[l] = 0.f; return; }
  float s = 0.f;
  for (int l=0;l<50;l++){ float a = p[l]; float e = (a==0.f) ? 0.f : expf(a-m); p[l]=e; s+=e; }
  float inv = 1.f/s;
  for (int l=0;l<50;l++) p[l] *= inv;
}

// ---------------- fact separation combine (rows of 300), 1 wave per row ----------------
// NOTE: no __restrict__ — call 2 intentionally aliases simOut=scen, diffOut=circ.
__global__ void k_factsep(const float* circ, const float* scen,
                          float* simOut, float* diffOut, long nrows)
{
  int lane = threadIdx.x & 63;
  long row = (long)blockIdx.x*4 + (threadIdx.x >> 6);
  if (row >= nrows) return;
  const float* c = circ + row*300;
  const float* s = scen + row*300;
  float x3=0.f, x4=0.f;
  for (int d=lane; d<300; d+=64){ float sv=s[d]; x3 += c[d]*sv; x4 += sv*sv; }
  for (int o=32;o>0;o>>=1){ x3 += __shfl_down(x3,o); x4 += __shfl_down(x4,o); }
  x3 = __shfl(x3,0); x4 = __shfl(x4,0);
  float coef = x3 / (x4 + 1e-10f);
  for (int d=lane; d<300; d+=64){
    float sv = s[d]; float cv = c[d];
    float sim = coef*sv;
    simOut[row*300+d] = sim;
    diffOut[row*300+d] = cv - sim;
  }
}

// ---------------- assemblers ----------------
__global__ void k_factart(const float* __restrict__ DH, const float* __restrict__ dha,
                          const float* __restrict__ adc, const float* __restrict__ db,
                          float* __restrict__ out)
{
  long row = blockIdx.x; int b = (int)(row >> 9);
  for (int c=threadIdx.x; c<1200; c+=256){
    float v;
    if (c < 300) v = DH[row*300 + c];
    else if (c < 600) v = dha[(long)b*300 + (c-300)];
    else if (c < 900) v = adc[row*300 + (c-600)];
    else v = db[(long)b*300 + (c-900)];
    out[row*1200 + c] = v;
  }
}
__global__ void k_termcat(const float* __restrict__ DH, const float* __restrict__ ssc,
                          const float* __restrict__ dsc, float* __restrict__ out){
  long row = blockIdx.x;
  for (int c=threadIdx.x; c<900; c+=256){
    float v = (c<300) ? DH[row*300+c] : (c<600 ? ssc[row*300+(c-300)] : dsc[row*300+(c-600)]);
    out[row*900+c] = v;
  }
}

// ---------------- classifier: logits -> fp32 out, optional argmax ----------------
__global__ __launch_bounds__(256) void k_classify(
    const float* __restrict__ s0, const float* __restrict__ s1, const float* __restrict__ s2,
    int L, int Kf, float scale,
    const float* __restrict__ W, const float* __restrict__ bias, int N,
    float* __restrict__ out, int* __restrict__ amax)
{
  int b = blockIdx.x; int tid = threadIdx.x;
  __shared__ float feat[1200];
  __shared__ float logit[128];
  for (int i=tid; i<Kf; i+=256){
    int seg = i / L, c = i % L;
    const float* s = (seg==0) ? s0 : (seg==1 ? s1 : s2);
    feat[i] = s[(long)b*L + c] * scale;
  }
  __syncthreads();
  for (int n=tid; n<N; n+=256){
    float acc = bias[n];
    const float* w = W + (long)n*Kf;
    for (int k=0;k<Kf;k++) acc += feat[k]*w[k];
    out[(long)b*N + n] = acc;
    logit[n] = acc;
  }
  __syncthreads();
  if (amax && tid==0){
    float best = logit[0]; int bi=0;
    for (int n=1;n<N;n++) if (logit[n] > best){ best=logit[n]; bi=n; }
    amax[b] = bi;
  }
}

static inline int cdiv(long a, long b){ return (int)((a + b - 1)/b); }

extern "C" void kernel_launch(void* const* d_in, const int* in_sizes, int n_in,
                              void* d_out, int out_size, void* d_ws, size_t ws_size,
                              hipStream_t stream)
{
  (void)in_sizes; (void)n_in; (void)out_size;
  const float* emb     = (const float*)d_in[0];
  const float* encWih  = (const float*)d_in[1];
  const float* encWhh  = (const float*)d_in[2];
  const float* encbih  = (const float*)d_in[3];
  const float* encbhh  = (const float*)d_in[4];
  const float* cchWih  = (const float*)d_in[5];
  const float* cchWhh  = (const float*)d_in[6];
  const float* cchbih  = (const float*)d_in[7];
  const float* cchbhh  = (const float*)d_in[8];
  const float* termWih = (const float*)d_in[9];
  const float* termWhh = (const float*)d_in[10];
  const float* termbih = (const float*)d_in[11];
  const float* termbhh = (const float*)d_in[12];
  const float* artWih  = (const float*)d_in[13];
  const float* artWhh  = (const float*)d_in[14];
  const float* artbih  = (const float*)d_in[15];
  const float* artbhh  = (const float*)d_in[16];
  const float* Wc      = (const float*)d_in[17];
  const float* bc      = (const float*)d_in[18];
  const float* Wa      = (const float*)d_in[19];
  const float* ba      = (const float*)d_in[20];
  const float* Wt_     = (const float*)d_in[21];
  const float* bt_     = (const float*)d_in[22];
  const int* docs    = (const int*)d_in[23];
  const int* chtok   = (const int*)d_in[24];
  const int* artok   = (const int*)d_in[25];
  const int* chnb    = (const int*)d_in[26];
  const int* chnbm   = (const int*)d_in[27];
  const int* arnb    = (const int*)d_in[28];
  const int* arnbm   = (const int*)d_in[29];
  const int* vchtok  = (const int*)d_in[30];
  const int* vartok  = (const int*)d_in[31];
  float* ob = (float*)d_out;
  float* ws = (float*)d_ws;

  // -------- workspace layout (float elements) --------
  constexpr long O_WTENC = 0;                       // 2*150*450
  constexpr long O_WTCCH = O_WTENC + 135000;        // 2*150*450
  constexpr long O_WTART = O_WTCCH + 135000;        // (spare)
  constexpr long O_WTTERM= O_WTART + 2160000;       // (spare)
  constexpr long O_DH    = O_WTTERM + 1215000;      // 16384*300
  constexpr long O_DMEAN = O_DH + 4915200;          // 32*300
  constexpr long O_CHM   = O_DMEAN + 9600;          // 119*300
  constexpr long O_ARM   = O_CHM + 35700;           // 103*300
  constexpr long O_LAB   = O_ARM + 30900;           // 444*300
  constexpr long O_GDT   = O_LAB + 133200;          // 119*300 (also barrier ints later)
  constexpr long O_CWM   = O_GDT + 35700;           // 4*16384
  constexpr long O_CWA   = O_CWM + 65536;           // 4*32*512
  constexpr long O_CWO   = O_CWA + 65536;           // 4*32*300
  constexpr long O_CP    = O_CWO + 38400;           // 64 ints
  constexpr long O_VCH   = O_CP + 64;               // 32*50*300
  constexpr long O_VCHT  = O_VCH + 480000;          // 32*300*50
  constexpr long O_ATT   = O_VCHT + 480000;         // 32*512*50
  constexpr long O_SCEN  = O_ATT + 819200;          // 16384*300
  constexpr long O_ADC   = O_SCEN + 4915200;        // 16384*300
  constexpr long O_SEC   = O_ADC + 4915200;         // 16384*300
  constexpr long O_HBUF  = O_SEC + 4915200;         // h ping-pong 2*38400
  constexpr long O_YSUM  = O_HBUF + 76800;          // 32*1200
  constexpr long O_GATH  = O_YSUM + 38400;          // 16384*200
  constexpr long O_XSS   = O_GATH + 3276800;        // 2*6592*450
  constexpr long O_PF    = O_XSS + 5932800;         // 16384*1200
  constexpr long O_XB    = O_PF + 19660800;         // 2*16384*1800
  constexpr long TOTAL   = O_XB + 58982400;         // ~454 MB
  if (ws_size < (size_t)TOTAL * 4) return;

  float* WT_ENC = ws + O_WTENC;
  float* WT_CCH = ws + O_WTCCH;
  float* DH     = ws + O_DH;
  float* DMEAN  = ws + O_DMEAN;
  float* CHM    = ws + O_CHM;
  float* ARM    = ws + O_ARM;
  float* LAB    = ws + O_LAB;
  float* GDT    = ws + O_GDT;
  float* CWM    = ws + O_CWM;
  float* CWA    = ws + O_CWA;
  float* CWO    = ws + O_CWO;
  int*   CP     = (int*)(ws + O_CP);
  int*   AP     = CP + 32;
  float* VCH    = ws + O_VCH;
  float* VCHT   = ws + O_VCHT;
  float* ATT    = ws + O_ATT;
  float* SCEN   = ws + O_SCEN;
  float* ADC    = ws + O_ADC;
  float* SEC    = ws + O_SEC;
  float* HBUF   = ws + O_HBUF;
  float* YSUM   = ws + O_YSUM;
  float* GATH   = ws + O_GATH;
  float* XSS    = ws + O_XSS;
  float* PF     = ws + O_PF;
  float* XB     = ws + O_XB;
  int*   BAR    = (int*)GDT;   // GDT region is free after graph decomposition

  // -------- transpose small Whh --------
  k_transpose<<<dim3(cdiv(450L*150,256),2),256,0,stream>>>(encWhh, WT_ENC, 450,150);
  k_transpose<<<dim3(cdiv(450L*150,256),2),256,0,stream>>>(cchWhh, WT_CCH, 450,150);

  // -------- charge token encoder (encch), mean only --------
  k_gather<<<3808,256,0,stream>>>(emb, chtok, GATH);
  k_gemm128<<<dim3(4,cdiv(3808,128),2),256,0,stream>>>(GATH, cchWih, cchbih, XSS,
      3808,450,200, 0, 450L*200, 3808L*450, 450);
  k_gru_small<<<dim3(119,2),512,0,stream>>>(XSS, 3808L*450, WT_CCH, cchbhh,
      nullptr,0, CHM,300, 32);

  // -------- article token encoder (encch), mean only --------
  k_gather<<<6592,256,0,stream>>>(emb, artok, GATH);
  k_gemm128<<<dim3(4,cdiv(6592,128),2),256,0,stream>>>(GATH, cchWih, cchbih, XSS,
      6592,450,200, 0, 450L*200, 6592L*450, 450);
  k_gru_small<<<dim3(103,2),512,0,stream>>>(XSS, 6592L*450, WT_CCH, cchbhh,
      nullptr,0, ARM,300, 64);

  // -------- originals + graph decomposition into label-cat --------
  k_copy<<<cdiv(35700,256),256,0,stream>>>(CHM, LAB + 119L*300, 35700);
  k_copy<<<cdiv(30900,256),256,0,stream>>>(ARM, LAB + 341L*300, 30900);
  k_graphdecomp<<<119,256,0,stream>>>(CHM, GDT, chnb, chnbm, 119);
  k_graphdecomp<<<119,256,0,stream>>>(GDT, LAB, chnb, chnbm, 119);
  k_graphdecomp<<<103,256,0,stream>>>(ARM, GDT, arnb, arnbm, 103);
  k_graphdecomp<<<103,256,0,stream>>>(GDT, LAB + 238L*300, arnb, arnbm, 103);

  // -------- document encoder (enc) -> d_hidden + doc_mean --------
  k_gather<<<16384,256,0,stream>>>(emb, docs, GATH);
  k_gemm128<<<dim3(4,128,2),256,0,stream>>>(GATH, encWih, encbih, PF,
      16384,450,200, 0, 450L*200, 16384L*450, 450);
  k_gru_small<<<dim3(32,2),512,0,stream>>>(PF, 16384L*450, WT_ENC, encbhh,
      DH,300, DMEAN,300, 512);

  // -------- code_wise (4 label sets at once) --------
  k_gemm128<<<dim3(4,128,1),256,0,stream>>>(DH, LAB, nullptr, PF,
      16384,444,300, 0,0,0, 0);
  k_cw_rowmax<<<dim3(64,4),256,0,stream>>>(PF, CWM);
  k_cw_softmax<<<dim3(32,4),256,0,stream>>>(CWM, CWA);
  k_cw_out<<<dim3(32,4),256,0,stream>>>(CWA, DH, CWO);

  // -------- charge classifier + argmax --------
  k_classify<<<32,256,0,stream>>>(DMEAN, CWO, CWO + 32L*300,
      300, 900, 1.f, Wc, bc, 119, ob, CP);

  // -------- verdict-charge GRU (enc) --------
  k_gather_sel<<<dim3(50,32),256,0,stream>>>(emb, vchtok, CP, GATH);
  k_gemm128<<<dim3(4,13,2),256,0,stream>>>(GATH, encWih, encbih, XSS,
      1600,450,200, 0, 450L*200, 1600L*450, 450);
  k_gru_small<<<dim3(32,2),512,0,stream>>>(XSS, 1600L*450, WT_ENC, encbhh,
      VCH,300, nullptr,0, 50);

  // -------- fact separation 1 (vch vs d_hidden) --------
  k_gemm128<<<dim3(1,4,32),256,0,stream>>>(DH, VCH, nullptr, ATT,
      512,50,300, 512L*300, 50L*300, 512L*50, 0);
  k_masksm<<<64,256,0,stream>>>(ATT, 16384);
  k_transpose<<<dim3(cdiv(15000,256),32),256,0,stream>>>(VCH, VCHT, 50, 300);
  k_gemm128<<<dim3(3,4,32),256,0,stream>>>(ATT, VCHT, nullptr, SCEN,
      512,300,50, 512L*50, 300L*50, 512L*300, 0);
  k_factsep<<<4096,256,0,stream>>>(DH, SCEN, ADC, SEC, 16384);

  // -------- fact_article + art bigru (persistent) --------
  k_factart<<<16384,256,0,stream>>>(DH, CWO + 2L*32*300, ADC, CWO + 3L*32*300, PF);
  k_gemm128<<<dim3(cdiv(1800,128),128,2),256,0,stream>>>(PF, artWih, artbih, XB,
      16384,1800,1200, 0, 1800L*1200, 16384L*1800, 1800);
  hipMemsetAsync(BAR, 0, 4*sizeof(int), stream);
  hipMemsetAsync(HBUF, 0, 38400*sizeof(float), stream);
  // art: H=600, HPAD=604, KT=120, NPH=5, LDW=132, NCB=60 -> 240 wgs
  k_gru_persist<600,604,120,5,132,60><<<240,256,0,stream>>>(
      XB, 16384L*1800, artWhh, artbhh, HBUF, HBUF+38400, YSUM, 1200, 512, BAR, 240);
  k_classify<<<32,256,0,stream>>>(YSUM, nullptr, nullptr,
      1200, 1200, 1.f/512.f, Wa, ba, 103, ob + 3808, AP);

  // -------- verdict-article GRU (enc) --------
  k_gather_sel<<<dim3(50,32),256,0,stream>>>(emb, vartok, AP, GATH);
  k_gemm128<<<dim3(4,13,2),256,0,stream>>>(GATH, encWih, encbih, XSS,
      1600,450,200, 0, 450L*200, 1600L*450, 450);
  k_gru_small<<<dim3(32,2),512,0,stream>>>(XSS, 1600L*450, WT_ENC, encbhh,
      VCH,300, nullptr,0, 50);

  // -------- fact separation 2 (var vs sec); ssc->SCEN, dsc->SEC in place --------
  k_gemm128<<<dim3(1,4,32),256,0,stream>>>(SEC, VCH, nullptr, ATT,
      512,50,300, 512L*300, 50L*300, 512L*50, 0);
  k_masksm<<<64,256,0,stream>>>(ATT, 16384);
  k_transpose<<<dim3(cdiv(15000,256),32),256,0,stream>>>(VCH, VCHT, 50, 300);
  k_gemm128<<<dim3(3,4,32),256,0,stream>>>(ATT, VCHT, nullptr, SCEN,
      512,300,50, 512L*50, 300L*50, 512L*300, 0);
  k_factsep<<<4096,256,0,stream>>>(SEC, SCEN, SCEN, SEC, 16384);

  // -------- term bigru (persistent) --------
  k_termcat<<<16384,256,0,stream>>>(DH, SCEN, SEC, PF);
  k_gemm128<<<dim3(cdiv(1350,128),128,2),256,0,stream>>>(PF, termWih, termbih, XB,
      16384,1350,900, 0, 1350L*900, 16384L*1350, 1350);
  hipMemsetAsync(BAR, 0, 4*sizeof(int), stream);
  hipMemsetAsync(HBUF, 0, 38400*sizeof(float), stream);
  // term: H=450, HPAD=460, KT=152 (k-pad 456), NPH=3, LDW=164, NCB=45 -> 180 wgs
  k_gru_persist<450,460,152,3,164,45><<<180,256,0,stream>>>(
      XB, 16384L*1350, termWhh, termbhh, HBUF, HBUF+38400, YSUM, 900, 512, BAR, 180);
  k_classify<<<32,256,0,stream>>>(YSUM, nullptr, nullptr,
      900, 900, 1.f/512.f, Wt_, bt_, 11, ob + 7104, nullptr);
}

// Round 5
// 67996.686 us; speedup vs baseline: 1.2433x; 1.2433x over previous
//
#include <hip/hip_runtime.h>
#include <hip/hip_bf16.h>

#define DEVI __device__ __forceinline__

DEVI float sigm(float x){ return 1.f/(1.f+expf(-x)); }

// ---------------- transpose: out[b][c][r] = in[b][r][c] ----------------
__global__ void k_transpose(const float* __restrict__ in, float* __restrict__ out, int R, int C){
  int b = blockIdx.y;
  long n = (long)R*C;
  long i = (long)blockIdx.x*256 + threadIdx.x;
  if (i < n){
    int r = (int)(i / C), c = (int)(i % C);
    out[(long)b*n + (long)c*R + r] = in[(long)b*n + i];
  }
}

// ---------------- embedding gathers (D=200) ----------------
__global__ void k_gather(const float* __restrict__ emb, const int* __restrict__ tok, float* __restrict__ out){
  int row = blockIdx.x; int c = threadIdx.x;
  if (c < 200) out[(long)row*200 + c] = emb[(long)tok[row]*200 + c];
}
__global__ void k_gather_sel(const float* __restrict__ emb, const int* __restrict__ tok, const int* __restrict__ sel, float* __restrict__ out){
  int t = blockIdx.x, b = blockIdx.y; int c = threadIdx.x;
  if (c < 200){
    int tk = tok[(long)sel[b]*50 + t];
    out[((long)b*50 + t)*200 + c] = emb[(long)tk*200 + c];
  }
}

// ---------------- fp32 GEMM 128x128 tile, 8x8 micro: C = A(M,K) @ W(N,K)^T + bias ----------------
__global__ __launch_bounds__(256) void k_gemm128(
    const float* __restrict__ A, const float* __restrict__ W,
    const float* __restrict__ bias, float* __restrict__ C,
    int M, int N, int K, long sA, long sW, long sC, long sBias)
{
  int bz = blockIdx.z;
  A += (long)bz*sA; W += (long)bz*sW; C += (long)bz*sC;
  if (bias) bias += (long)bz*sBias;
  int n0 = blockIdx.x*128, m0 = blockIdx.y*128;
  __shared__ float As[16][132];
  __shared__ float Bs[16][132];
  int tid = threadIdx.x;
  int tx = tid & 15, ty = tid >> 4;
  float acc[8][8] = {};
  const bool k4 = ((K & 3) == 0);
  for (int k0 = 0; k0 < K; k0 += 16){
    #pragma unroll
    for (int half = 0; half < 2; half++){
      int s = tid + half*256;
      int r = s >> 2;
      int kq = (s & 3) << 2;
      int k = k0 + kq;
      int m = m0 + r;
      float4 va = make_float4(0.f,0.f,0.f,0.f);
      if (m < M){
        if (k4 && k + 3 < K) va = *(const float4*)&A[(long)m*K + k];
        else {
          float* pv = (float*)&va;
          #pragma unroll
          for (int u=0; u<4; u++) if (k+u < K) pv[u] = A[(long)m*K + k + u];
        }
      }
      As[kq+0][r]=va.x; As[kq+1][r]=va.y; As[kq+2][r]=va.z; As[kq+3][r]=va.w;
      int n = n0 + r;
      float4 vb = make_float4(0.f,0.f,0.f,0.f);
      if (n < N){
        if (k4 && k + 3 < K) vb = *(const float4*)&W[(long)n*K + k];
        else {
          float* pv = (float*)&vb;
          #pragma unroll
          for (int u=0; u<4; u++) if (k+u < K) pv[u] = W[(long)n*K + k + u];
        }
      }
      Bs[kq+0][r]=vb.x; Bs[kq+1][r]=vb.y; Bs[kq+2][r]=vb.z; Bs[kq+3][r]=vb.w;
    }
    __syncthreads();
    #pragma unroll
    for (int kk=0;kk<16;kk++){
      float a[8], b[8];
      *(float4*)&a[0] = *(const float4*)&As[kk][ty*8];
      *(float4*)&a[4] = *(const float4*)&As[kk][ty*8+4];
      *(float4*)&b[0] = *(const float4*)&Bs[kk][tx*8];
      *(float4*)&b[4] = *(const float4*)&Bs[kk][tx*8+4];
      #pragma unroll
      for (int i=0;i<8;i++)
        #pragma unroll
        for (int j=0;j<8;j++)
          acc[i][j] += a[i]*b[j];
    }
    __syncthreads();
  }
  #pragma unroll
  for (int i=0;i<8;i++){
    int m = m0 + ty*8 + i;
    if (m >= M) continue;
    #pragma unroll
    for (int j=0;j<8;j++){
      int n = n0 + tx*8 + j;
      if (n < N) C[(long)m*N + n] = acc[i][j] + (bias ? bias[n] : 0.f);
    }
  }
}

// ---------------- small GRU (h=150, 3h=450), 1 wg per (item,dir) ----------------
__global__ __launch_bounds__(512) void k_gru_small(
    const float* __restrict__ xs, long xsDir,
    const float* __restrict__ Wt, const float* __restrict__ bhh,
    float* __restrict__ y, int yld,
    float* __restrict__ meanOut, int meanld,
    int T)
{
  int item = blockIdx.x, dir = blockIdx.y;
  const float* xsd = xs + (long)dir*xsDir + (long)item*T*450;
  const float* Wtd = Wt + (long)dir*150*450;
  int tid = threadIdx.x;
  float bh = (tid < 450) ? bhh[(long)dir*450 + tid] : 0.f;
  __shared__ float hs[152];
  __shared__ float gs[456];
  if (tid < 150) hs[tid] = 0.f;
  float hsum = 0.f;
  __syncthreads();
  for (int t=0;t<T;t++){
    int tt = dir ? (T-1-t) : t;
    if (tid < 450){
      float g = bh;
      const float* wp = Wtd + tid;
      #pragma unroll 5
      for (int k=0;k<150;k++) g += hs[k] * wp[(long)k*450];
      gs[tid] = g;
    }
    __syncthreads();
    if (tid < 150){
      const float* xr = xsd + (long)tt*450;
      float r = sigm(xr[tid]     + gs[tid]);
      float z = sigm(xr[150+tid] + gs[150+tid]);
      float nn = tanhf(xr[300+tid] + r*gs[300+tid]);
      float h = (1.f-z)*nn + z*hs[tid];
      hs[tid] = h;
      hsum += h;
      if (y) y[((long)item*T + tt)*yld + dir*150 + tid] = h;
    }
    __syncthreads();
  }
  if (meanOut && tid < 150)
    meanOut[(long)item*meanld + dir*150 + tid] = hsum / (float)T;
}

// ---------------- persistent big GRU, weights LDS-resident, flag barrier ----------------
// wid -> (dir, bb of 16 items, cb of 10 h-cols). 256 threads, 1 wg/CU (LDS-bound).
// Weights (30 gate rows x KP) loaded to LDS ONCE. Per step: stage 16xH h-slice,
// register-blocked gate GEMM (R=3 rows, I=4 items, 6-way k-split), LDS k-reduce,
// GRU update, then contention-free global barrier: parallel flag stores + wg0
// scan + 8-line go broadcast (no atomic RMW).
#define GDOT(AC, W, A) AC += W.x*A.x + W.y*A.y + W.z*A.z + W.w*A.w;
template<int H, int KP, int LDW, int HPAD, int KL, int NCB>
__global__ __launch_bounds__(256) void k_gru_persist(
    const float* __restrict__ xs, long xsDir,
    const float* __restrict__ Whh, const float* __restrict__ bhh,
    float* hA, float* hB,
    float* __restrict__ ysum, int ysld,
    int T, int* flags, int* go, int nwg)
{
  constexpr int H3 = 3*H;
  int wid = blockIdx.x;
  int dir = wid / (2*NCB);
  int rem = wid % (2*NCB);
  int bb  = rem / NCB;
  int cb  = rem % NCB;
  int c0  = cb*10;
  int tid = threadIdx.x;

  const float* xsd = xs + (long)dir*xsDir;
  const float* Wd  = Whh + (long)dir*(long)H*H3;   // [3H][H] row-major
  const float* bhd = bhh + (long)dir*H3;

  __shared__ float hs[16*HPAD];
  __shared__ float Wl[30*LDW];
  __shared__ float blds[32];
  __shared__ float gl[30*16];
  __shared__ float part[240*12];

  // ---- load this wg's 30 gate-row weights into LDS ONCE ----
  for (int u = tid; u < 30*KP; u += 256){
    int r = u / KP, k = u % KP;
    long row = (long)(r/10)*H + c0 + (r%10);
    Wl[r*LDW + k] = (k < H) ? Wd[row*H + k] : 0.f;
  }
  if (tid < 30) blds[tid] = bhd[(long)(tid/10)*H + c0 + (tid%10)];

  // compute mapping: tid = ks*40 + rg*4 + ig  (ks 0..5, rg 0..9, ig 0..3)
  int ks = tid / 40;
  int rem2 = tid % 40;
  int rg = rem2 / 4;
  int ig = rem2 % 4;
  bool alive = (tid < 240);
  int r0 = rg*3;
  int it0 = ig*4;
  int kbase = ks*KL;

  // update mapping (tid<160): item uit, col uci
  int uit = tid / 10, uci = tid % 10;
  int uc = c0 + uci;
  int ub = bb*16 + uit;
  float ysacc = 0.f;

  __syncthreads();

  for (int t=0; t<T; t++){
    const float* hp = ((t & 1) ? hB : hA) + (long)dir*32*H;
    float*       hn = ((t & 1) ? hA : hB) + (long)dir*32*H;
    int tt = dir ? (T-1-t) : t;

    // ---- stage h slice [16][H] (zero k-pad) ----
    for (int u = tid; u < 16*(KP/4); u += 256){
      int bl = u / (KP/4);
      int k = (u % (KP/4))*4;
      const float* src = &hp[(long)(bb*16+bl)*H + k];
      float4 v;
      if (k + 4 <= H) v = *(const float4*)src;
      else {
        float* pv = (float*)&v;
        #pragma unroll
        for (int q=0;q<4;q++) pv[q] = (k+q < H) ? src[q] : 0.f;
      }
      *(float4*)&hs[bl*HPAD + k] = v;
    }
    __syncthreads();

    // ---- gate GEMM partials: 3 rows x 4 items x KL ----
    if (alive){
      float acc[3][4];
      #pragma unroll
      for (int a=0;a<3;a++)
        #pragma unroll
        for (int b=0;b<4;b++) acc[a][b] = 0.f;
      const float* wr0 = &Wl[(r0+0)*LDW + kbase];
      const float* wr1 = &Wl[(r0+1)*LDW + kbase];
      const float* wr2 = &Wl[(r0+2)*LDW + kbase];
      const float* h0  = &hs[(it0+0)*HPAD + kbase];
      const float* h1  = &hs[(it0+1)*HPAD + kbase];
      const float* h2  = &hs[(it0+2)*HPAD + kbase];
      const float* h3  = &hs[(it0+3)*HPAD + kbase];
      for (int jq = 0; jq < KL; jq += 4){
        float4 w0 = *(const float4*)&wr0[jq];
        float4 w1 = *(const float4*)&wr1[jq];
        float4 w2 = *(const float4*)&wr2[jq];
        float4 a0 = *(const float4*)&h0[jq];
        float4 a1 = *(const float4*)&h1[jq];
        float4 a2 = *(const float4*)&h2[jq];
        float4 a3 = *(const float4*)&h3[jq];
        GDOT(acc[0][0], w0, a0) GDOT(acc[0][1], w0, a1) GDOT(acc[0][2], w0, a2) GDOT(acc[0][3], w0, a3)
        GDOT(acc[1][0], w1, a0) GDOT(acc[1][1], w1, a1) GDOT(acc[1][2], w1, a2) GDOT(acc[1][3], w1, a3)
        GDOT(acc[2][0], w2, a0) GDOT(acc[2][1], w2, a1) GDOT(acc[2][2], w2, a2) GDOT(acc[2][3], w2, a3)
      }
      #pragma unroll
      for (int a=0;a<3;a++)
        *(float4*)&part[tid*12 + a*4] = make_float4(acc[a][0],acc[a][1],acc[a][2],acc[a][3]);
    }
    __syncthreads();

    // ---- k-reduce 6 partials -> gl[30][16] ----
    if (alive){
      #pragma unroll
      for (int vv=0; vv<2; vv++){
        int v = tid + vv*240;               // 0..479
        int row = v >> 4, item = v & 15;
        int base = ((row/3)*4 + (item>>2))*12 + (row%3)*4 + (item&3);
        float sum = blds[row];
        #pragma unroll
        for (int s=0; s<6; s++) sum += part[s*480 + base];
        gl[row*16 + item] = sum;
      }
    }
    __syncthreads();

    // ---- GRU update ----
    if (tid < 160){
      const float* xr = xsd + ((long)ub*T + tt)*H3;
      float r  = sigm(xr[uc]      + gl[(uci)*16    + uit]);
      float z  = sigm(xr[H+uc]    + gl[(10+uci)*16 + uit]);
      float nn = tanhf(xr[2*H+uc] + r*gl[(20+uci)*16 + uit]);
      float hv = hs[uit*HPAD + uc];
      float hne = (1.f-z)*nn + z*hv;
      hn[(long)ub*H + uc] = hne;
      ysacc += hne;
    }
    __threadfence();
    __syncthreads();

    // ---- contention-free global barrier (skip after last step) ----
    if (t+1 < T){
      if (wid == 0){
        if (tid == 0)
          __hip_atomic_store(&flags[0], t+1, __ATOMIC_RELEASE, __HIP_MEMORY_SCOPE_AGENT);
        if (tid < nwg){
          while (__hip_atomic_load(&flags[tid], __ATOMIC_ACQUIRE, __HIP_MEMORY_SCOPE_AGENT) < t+1)
            __builtin_amdgcn_s_sleep(8);
        }
        __syncthreads();
        if (tid < 8)
          __hip_atomic_store(&go[tid*32], t+1, __ATOMIC_RELEASE, __HIP_MEMORY_SCOPE_AGENT);
      } else {
        if (tid == 0){
          __hip_atomic_store(&flags[wid], t+1, __ATOMIC_RELEASE, __HIP_MEMORY_SCOPE_AGENT);
          while (__hip_atomic_load(&go[(wid & 7)*32], __ATOMIC_ACQUIRE, __HIP_MEMORY_SCOPE_AGENT) < t+1)
            __builtin_amdgcn_s_sleep(8);
        }
        __syncthreads();
      }
      __threadfence();
    }
  }
  if (tid < 160)
    ysum[(long)ub*ysld + dir*H + uc] = ysacc;
}

// ---------------- graph decomposition layer (D=300, K=8) ----------------
__global__ __launch_bounds__(256) void k_graphdecomp(
   const float* __restrict__ labIn, float* __restrict__ labOut,
   const int* __restrict__ nb, const int* __restrict__ nbm, int N)
{
  int n = blockIdx.x; if (n >= N) return;
  int tid = threadIdx.x;
  __shared__ float ln[300];
  __shared__ float red[12];
  for (int d=tid; d<300; d+=256) ln[d] = labIn[(long)n*300+d];
  float deg = 0.f;
  for (int k=0;k<8;k++) deg += (float)nbm[n*8+k];
  float invdeg = 1.f / fmaxf(deg, 1.f);
  float acc0 = 0.f, acc1 = 0.f;
  __syncthreads();
  for (int k=0;k<8;k++){
    int j = nb[n*8+k];
    float mk = (float)nbm[n*8+k];
    const float* lj = labIn + (long)j*300;
    float p1=0.f, p2=0.f;
    for (int d=tid; d<300; d+=256){ float v = lj[d]; p1 += ln[d]*v; p2 += v*v; }
    for (int o=32;o>0;o>>=1){ p1 += __shfl_down(p1,o); p2 += __shfl_down(p2,o); }
    __syncthreads();
    int w = tid>>6, lane = tid&63;
    if (lane==0){ red[w]=p1; red[4+w]=p2; }
    __syncthreads();
    float x1 = red[0]+red[1]+red[2]+red[3];
    float x2 = red[4]+red[5]+red[6]+red[7];
    float coef = (x1 / (x2 + 1e-10f)) * mk * invdeg;
    acc0 += coef * lj[tid];
    if (tid + 256 < 300) acc1 += coef * lj[tid+256];
    __syncthreads();
  }
  bool pos = deg > 0.f;
  labOut[(long)n*300 + tid]                       = pos ? (ln[tid]     - acc0) : ln[tid];
  if (tid+256 < 300) labOut[(long)n*300 + tid+256] = pos ? (ln[tid+256] - acc1) : ln[tid+256];
}

// ---------------- copy ----------------
__global__ void k_copy(const float* __restrict__ src, float* __restrict__ dst, long n){
  long i = (long)blockIdx.x*256+threadIdx.x; if (i<n) dst[i]=src[i];
}

// ---------------- code_wise reductions ----------------
__global__ void k_cw_rowmax(const float* __restrict__ S, float* __restrict__ Mv){
  const int ofs[4]={0,119,238,341};
  const int wid[4]={119,119,103,103};
  int s = blockIdx.y; int row = blockIdx.x*256+threadIdx.x;
  if (row < 16384){
    const float* p = S + (long)row*444 + ofs[s];
    float m = -3.4e38f;
    int w = wid[s];
    for (int n=0;n<w;n++) m = fmaxf(m, p[n]);
    Mv[(long)s*16384+row] = m;
  }
}
__global__ void k_cw_softmax(const float* __restrict__ Mv, float* __restrict__ att){
  int b=blockIdx.x, s=blockIdx.y, tid=threadIdx.x;
  const float* src = Mv + (long)s*16384 + (long)b*512;
  __shared__ float red[256];
  float v0 = src[tid], v1 = src[tid+256];
  red[tid] = fmaxf(v0,v1); __syncthreads();
  for (int o=128;o>0;o>>=1){ if (tid<o) red[tid]=fmaxf(red[tid],red[tid+o]); __syncthreads(); }
  float m = red[0]; __syncthreads();
  float e0=expf(v0-m), e1=expf(v1-m);
  red[tid]=e0+e1; __syncthreads();
  for (int o=128;o>0;o>>=1){ if (tid<o) red[tid]+=red[tid+o]; __syncthreads(); }
  float inv = 1.f/red[0];
  float* dst = att + ((long)s*32 + b)*512;
  dst[tid]=e0*inv; dst[tid+256]=e1*inv;
}
__global__ void k_cw_out(const float* __restrict__ att, const float* __restrict__ DH, float* __restrict__ outp){
  int b=blockIdx.x, s=blockIdx.y, tid=threadIdx.x;
  __shared__ float a[512];
  for (int i=tid;i<512;i+=256) a[i]=att[((long)s*32+b)*512+i];
  __syncthreads();
  for (int d=tid; d<300; d+=256){
    float acc=0.f;
    for (int t=0;t<512;t++) acc += a[t]*DH[((long)b*512+t)*300+d];
    outp[((long)s*32+b)*300+d]=acc;
  }
}

// ---------------- masked softmax over l=50 (in place) ----------------
__global__ void k_masksm(float* __restrict__ att, long nrows){
  long row = (long)blockIdx.x*256 + threadIdx.x;
  if (row >= nrows) return;
  float* p = att + row*50;
  float m = -INFINITY;
  for (int l=0;l<50;l++){ float a = p[l]; if (a != 0.f && a > m) m = a; }
  if (m == -INFINITY){ for (int l=0;l<50;l++) p[l] = 0.f; return; }
  float s = 0.f;
  for (int l=0;l<50;l++){ float a = p[l]; float e = (a==0.f) ? 0.f : expf(a-m); p[l]=e; s+=e; }
  float inv = 1.f/s;
  for (int l=0;l<50;l++) p[l] *= inv;
}

// ---------------- fact separation combine (rows of 300), 1 wave per row ----------------
// NOTE: no __restrict__ — call 2 intentionally aliases simOut=scen, diffOut=circ.
__global__ void k_factsep(const float* circ, const float* scen,
                          float* simOut, float* diffOut, long nrows)
{
  int lane = threadIdx.x & 63;
  long row = (long)blockIdx.x*4 + (threadIdx.x >> 6);
  if (row >= nrows) return;
  const float* c = circ + row*300;
  const float* s = scen + row*300;
  float x3=0.f, x4=0.f;
  for (int d=lane; d<300; d+=64){ float sv=s[d]; x3 += c[d]*sv; x4 += sv*sv; }
  for (int o=32;o>0;o>>=1){ x3 += __shfl_down(x3,o); x4 += __shfl_down(x4,o); }
  x3 = __shfl(x3,0); x4 = __shfl(x4,0);
  float coef = x3 / (x4 + 1e-10f);
  for (int d=lane; d<300; d+=64){
    float sv = s[d]; float cv = c[d];
    float sim = coef*sv;
    simOut[row*300+d] = sim;
    diffOut[row*300+d] = cv - sim;
  }
}

// ---------------- assemblers ----------------
__global__ void k_factart(const float* __restrict__ DH, const float* __restrict__ dha,
                          const float* __restrict__ adc, const float* __restrict__ db,
                          float* __restrict__ out)
{
  long row = blockIdx.x; int b = (int)(row >> 9);
  for (int c=threadIdx.x; c<1200; c+=256){
    float v;
    if (c < 300) v = DH[row*300 + c];
    else if (c < 600) v = dha[(long)b*300 + (c-300)];
    else if (c < 900) v = adc[row*300 + (c-600)];
    else v = db[(long)b*300 + (c-900)];
    out[row*1200 + c] = v;
  }
}
__global__ void k_termcat(const float* __restrict__ DH, const float* __restrict__ ssc,
                          const float* __restrict__ dsc, float* __restrict__ out){
  long row = blockIdx.x;
  for (int c=threadIdx.x; c<900; c+=256){
    float v = (c<300) ? DH[row*300+c] : (c<600 ? ssc[row*300+(c-300)] : dsc[row*300+(c-600)]);
    out[row*900+c] = v;
  }
}

// ---------------- classifier: logits -> fp32 out, optional argmax ----------------
__global__ __launch_bounds__(256) void k_classify(
    const float* __restrict__ s0, const float* __restrict__ s1, const float* __restrict__ s2,
    int L, int Kf, float scale,
    const float* __restrict__ W, const float* __restrict__ bias, int N,
    float* __restrict__ out, int* __restrict__ amax)
{
  int b = blockIdx.x; int tid = threadIdx.x;
  __shared__ float feat[1200];
  __shared__ float logit[128];
  for (int i=tid; i<Kf; i+=256){
    int seg = i / L, c = i % L;
    const float* s = (seg==0) ? s0 : (seg==1 ? s1 : s2);
    feat[i] = s[(long)b*L + c] * scale;
  }
  __syncthreads();
  for (int n=tid; n<N; n+=256){
    float acc = bias[n];
    const float* w = W + (long)n*Kf;
    for (int k=0;k<Kf;k++) acc += feat[k]*w[k];
    out[(long)b*N + n] = acc;
    logit[n] = acc;
  }
  __syncthreads();
  if (amax && tid==0){
    float best = logit[0]; int bi=0;
    for (int n=1;n<N;n++) if (logit[n] > best){ best=logit[n]; bi=n; }
    amax[b] = bi;
  }
}

static inline int cdiv(long a, long b){ return (int)((a + b - 1)/b); }

extern "C" void kernel_launch(void* const* d_in, const int* in_sizes, int n_in,
                              void* d_out, int out_size, void* d_ws, size_t ws_size,
                              hipStream_t stream)
{
  (void)in_sizes; (void)n_in; (void)out_size;
  const float* emb     = (const float*)d_in[0];
  const float* encWih  = (const float*)d_in[1];
  const float* encWhh  = (const float*)d_in[2];
  const float* encbih  = (const float*)d_in[3];
  const float* encbhh  = (const float*)d_in[4];
  const float* cchWih  = (const float*)d_in[5];
  const float* cchWhh  = (const float*)d_in[6];
  const float* cchbih  = (const float*)d_in[7];
  const float* cchbhh  = (const float*)d_in[8];
  const float* termWih = (const float*)d_in[9];
  const float* termWhh = (const float*)d_in[10];
  const float* termbih = (const float*)d_in[11];
  const float* termbhh = (const float*)d_in[12];
  const float* artWih  = (const float*)d_in[13];
  const float* artWhh  = (const float*)d_in[14];
  const float* artbih  = (const float*)d_in[15];
  const float* artbhh  = (const float*)d_in[16];
  const float* Wc      = (const float*)d_in[17];
  const float* bc      = (const float*)d_in[18];
  const float* Wa      = (const float*)d_in[19];
  const float* ba      = (const float*)d_in[20];
  const float* Wt_     = (const float*)d_in[21];
  const float* bt_     = (const float*)d_in[22];
  const int* docs    = (const int*)d_in[23];
  const int* chtok   = (const int*)d_in[24];
  const int* artok   = (const int*)d_in[25];
  const int* chnb    = (const int*)d_in[26];
  const int* chnbm   = (const int*)d_in[27];
  const int* arnb    = (const int*)d_in[28];
  const int* arnbm   = (const int*)d_in[29];
  const int* vchtok  = (const int*)d_in[30];
  const int* vartok  = (const int*)d_in[31];
  float* ob = (float*)d_out;
  float* ws = (float*)d_ws;

  // -------- workspace layout (float elements) --------
  constexpr long O_WTENC = 0;                       // 2*150*450
  constexpr long O_WTCCH = O_WTENC + 135000;        // 2*150*450
  constexpr long O_WTART = O_WTCCH + 135000;        // (spare)
  constexpr long O_WTTERM= O_WTART + 2160000;       // (spare)
  constexpr long O_DH    = O_WTTERM + 1215000;      // 16384*300
  constexpr long O_DMEAN = O_DH + 4915200;          // 32*300
  constexpr long O_CHM   = O_DMEAN + 9600;          // 119*300
  constexpr long O_ARM   = O_CHM + 35700;           // 103*300
  constexpr long O_LAB   = O_ARM + 30900;           // 444*300
  constexpr long O_GDT   = O_LAB + 133200;          // 119*300 (barrier ints after decomp)
  constexpr long O_CWM   = O_GDT + 35700;           // 4*16384
  constexpr long O_CWA   = O_CWM + 65536;           // 4*32*512
  constexpr long O_CWO   = O_CWA + 65536;           // 4*32*300
  constexpr long O_CP    = O_CWO + 38400;           // 64 ints
  constexpr long O_VCH   = O_CP + 64;               // 32*50*300
  constexpr long O_VCHT  = O_VCH + 480000;          // 32*300*50
  constexpr long O_ATT   = O_VCHT + 480000;         // 32*512*50
  constexpr long O_SCEN  = O_ATT + 819200;          // 16384*300
  constexpr long O_ADC   = O_SCEN + 4915200;        // 16384*300
  constexpr long O_SEC   = O_ADC + 4915200;         // 16384*300
  constexpr long O_HBUF  = O_SEC + 4915200;         // h ping-pong 2*38400
  constexpr long O_YSUM  = O_HBUF + 76800;          // 32*1200
  constexpr long O_GATH  = O_YSUM + 38400;          // 16384*200
  constexpr long O_XSS   = O_GATH + 3276800;        // 2*6592*450
  constexpr long O_PF    = O_XSS + 5932800;         // 16384*1200
  constexpr long O_XB    = O_PF + 19660800;         // 2*16384*1800
  constexpr long TOTAL   = O_XB + 58982400;         // ~454 MB
  if (ws_size < (size_t)TOTAL * 4) return;

  float* WT_ENC = ws + O_WTENC;
  float* WT_CCH = ws + O_WTCCH;
  float* DH     = ws + O_DH;
  float* DMEAN  = ws + O_DMEAN;
  float* CHM    = ws + O_CHM;
  float* ARM    = ws + O_ARM;
  float* LAB    = ws + O_LAB;
  float* GDT    = ws + O_GDT;
  float* CWM    = ws + O_CWM;
  float* CWA    = ws + O_CWA;
  float* CWO    = ws + O_CWO;
  int*   CP     = (int*)(ws + O_CP);
  int*   AP     = CP + 32;
  float* VCH    = ws + O_VCH;
  float* VCHT   = ws + O_VCHT;
  float* ATT    = ws + O_ATT;
  float* SCEN   = ws + O_SCEN;
  float* ADC    = ws + O_ADC;
  float* SEC    = ws + O_SEC;
  float* HBUF   = ws + O_HBUF;
  float* YSUM   = ws + O_YSUM;
  float* GATH   = ws + O_GATH;
  float* XSS    = ws + O_XSS;
  float* PF     = ws + O_PF;
  float* XB     = ws + O_XB;
  int*   FLAGS  = (int*)GDT;       // free after graph decomposition
  int*   GO     = FLAGS + 256;     // 8 lines spaced by 32 ints

  // -------- transpose small Whh --------
  k_transpose<<<dim3(cdiv(450L*150,256),2),256,0,stream>>>(encWhh, WT_ENC, 450,150);
  k_transpose<<<dim3(cdiv(450L*150,256),2),256,0,stream>>>(cchWhh, WT_CCH, 450,150);

  // -------- charge token encoder (encch), mean only --------
  k_gather<<<3808,256,0,stream>>>(emb, chtok, GATH);
  k_gemm128<<<dim3(4,cdiv(3808,128),2),256,0,stream>>>(GATH, cchWih, cchbih, XSS,
      3808,450,200, 0, 450L*200, 3808L*450, 450);
  k_gru_small<<<dim3(119,2),512,0,stream>>>(XSS, 3808L*450, WT_CCH, cchbhh,
      nullptr,0, CHM,300, 32);

  // -------- article token encoder (encch), mean only --------
  k_gather<<<6592,256,0,stream>>>(emb, artok, GATH);
  k_gemm128<<<dim3(4,cdiv(6592,128),2),256,0,stream>>>(GATH, cchWih, cchbih, XSS,
      6592,450,200, 0, 450L*200, 6592L*450, 450);
  k_gru_small<<<dim3(103,2),512,0,stream>>>(XSS, 6592L*450, WT_CCH, cchbhh,
      nullptr,0, ARM,300, 64);

  // -------- originals + graph decomposition into label-cat --------
  k_copy<<<cdiv(35700,256),256,0,stream>>>(CHM, LAB + 119L*300, 35700);
  k_copy<<<cdiv(30900,256),256,0,stream>>>(ARM, LAB + 341L*300, 30900);
  k_graphdecomp<<<119,256,0,stream>>>(CHM, GDT, chnb, chnbm, 119);
  k_graphdecomp<<<119,256,0,stream>>>(GDT, LAB, chnb, chnbm, 119);
  k_graphdecomp<<<103,256,0,stream>>>(ARM, GDT, arnb, arnbm, 103);
  k_graphdecomp<<<103,256,0,stream>>>(GDT, LAB + 238L*300, arnb, arnbm, 103);

  // -------- document encoder (enc) -> d_hidden + doc_mean --------
  k_gather<<<16384,256,0,stream>>>(emb, docs, GATH);
  k_gemm128<<<dim3(4,128,2),256,0,stream>>>(GATH, encWih, encbih, PF,
      16384,450,200, 0, 450L*200, 16384L*450, 450);
  k_gru_small<<<dim3(32,2),512,0,stream>>>(PF, 16384L*450, WT_ENC, encbhh,
      DH,300, DMEAN,300, 512);

  // -------- code_wise (4 label sets at once) --------
  k_gemm128<<<dim3(4,128,1),256,0,stream>>>(DH, LAB, nullptr, PF,
      16384,444,300, 0,0,0, 0);
  k_cw_rowmax<<<dim3(64,4),256,0,stream>>>(PF, CWM);
  k_cw_softmax<<<dim3(32,4),256,0,stream>>>(CWM, CWA);
  k_cw_out<<<dim3(32,4),256,0,stream>>>(CWA, DH, CWO);

  // -------- charge classifier + argmax --------
  k_classify<<<32,256,0,stream>>>(DMEAN, CWO, CWO + 32L*300,
      300, 900, 1.f, Wc, bc, 119, ob, CP);

  // -------- verdict-charge GRU (enc) --------
  k_gather_sel<<<dim3(50,32),256,0,stream>>>(emb, vchtok, CP, GATH);
  k_gemm128<<<dim3(4,13,2),256,0,stream>>>(GATH, encWih, encbih, XSS,
      1600,450,200, 0, 450L*200, 1600L*450, 450);
  k_gru_small<<<dim3(32,2),512,0,stream>>>(XSS, 1600L*450, WT_ENC, encbhh,
      VCH,300, nullptr,0, 50);

  // -------- fact separation 1 (vch vs d_hidden) --------
  k_gemm128<<<dim3(1,4,32),256,0,stream>>>(DH, VCH, nullptr, ATT,
      512,50,300, 512L*300, 50L*300, 512L*50, 0);
  k_masksm<<<64,256,0,stream>>>(ATT, 16384);
  k_transpose<<<dim3(cdiv(15000,256),32),256,0,stream>>>(VCH, VCHT, 50, 300);
  k_gemm128<<<dim3(3,4,32),256,0,stream>>>(ATT, VCHT, nullptr, SCEN,
      512,300,50, 512L*50, 300L*50, 512L*300, 0);
  k_factsep<<<4096,256,0,stream>>>(DH, SCEN, ADC, SEC, 16384);

  // -------- fact_article + art bigru (persistent, flag barrier) --------
  k_factart<<<16384,256,0,stream>>>(DH, CWO + 2L*32*300, ADC, CWO + 3L*32*300, PF);
  k_gemm128<<<dim3(cdiv(1800,128),128,2),256,0,stream>>>(PF, artWih, artbih, XB,
      16384,1800,1200, 0, 1800L*1200, 16384L*1800, 1800);
  hipMemsetAsync(FLAGS, 0, 512*sizeof(int), stream);
  hipMemsetAsync(HBUF, 0, 38400*sizeof(float), stream);
  // art: H=600, KP=600, LDW=604, HPAD=604, KL=100, NCB=60 -> 240 wgs
  k_gru_persist<600,600,604,604,100,60><<<240,256,0,stream>>>(
      XB, 16384L*1800, artWhh, artbhh, HBUF, HBUF+38400, YSUM, 1200, 512, FLAGS, GO, 240);
  k_classify<<<32,256,0,stream>>>(YSUM, nullptr, nullptr,
      1200, 1200, 1.f/512.f, Wa, ba, 103, ob + 3808, AP);

  // -------- verdict-article GRU (enc) --------
  k_gather_sel<<<dim3(50,32),256,0,stream>>>(emb, vartok, AP, GATH);
  k_gemm128<<<dim3(4,13,2),256,0,stream>>>(GATH, encWih, encbih, XSS,
      1600,450,200, 0, 450L*200, 1600L*450, 450);
  k_gru_small<<<dim3(32,2),512,0,stream>>>(XSS, 1600L*450, WT_ENC, encbhh,
      VCH,300, nullptr,0, 50);

  // -------- fact separation 2 (var vs sec); ssc->SCEN, dsc->SEC in place --------
  k_gemm128<<<dim3(1,4,32),256,0,stream>>>(SEC, VCH, nullptr, ATT,
      512,50,300, 512L*300, 50L*300, 512L*50, 0);
  k_masksm<<<64,256,0,stream>>>(ATT, 16384);
  k_transpose<<<dim3(cdiv(15000,256),32),256,0,stream>>>(VCH, VCHT, 50, 300);
  k_gemm128<<<dim3(3,4,32),256,0,stream>>>(ATT, VCHT, nullptr, SCEN,
      512,300,50, 512L*50, 300L*50, 512L*300, 0);
  k_factsep<<<4096,256,0,stream>>>(SEC, SCEN, SCEN, SEC, 16384);

  // -------- term bigru (persistent, flag barrier) --------
  k_termcat<<<16384,256,0,stream>>>(DH, SCEN, SEC, PF);
  k_gemm128<<<dim3(cdiv(1350,128),128,2),256,0,stream>>>(PF, termWih, termbih, XB,
      16384,1350,900, 0, 1350L*900, 16384L*1350, 1350);
  hipMemsetAsync(FLAGS, 0, 512*sizeof(int), stream);
  hipMemsetAsync(HBUF, 0, 38400*sizeof(float), stream);
  // term: H=450, KP=456, LDW=460, HPAD=460, KL=76, NCB=45 -> 180 wgs
  k_gru_persist<450,456,460,460,76,45><<<180,256,0,stream>>>(
      XB, 16384L*1350, termWhh, termbhh, HBUF, HBUF+38400, YSUM, 900, 512, FLAGS, GO, 180);
  k_classify<<<32,256,0,stream>>>(YSUM, nullptr, nullptr,
      900, 900, 1.f/512.f, Wt_, bt_, 11, ob + 7104, nullptr);
}

// Round 6
// 23119.035 us; speedup vs baseline: 3.6566x; 2.9412x over previous
//
#include <hip/hip_runtime.h>
#include <hip/hip_bf16.h>

#define DEVI __device__ __forceinline__

DEVI float sigm(float x){ return 1.f/(1.f+expf(-x)); }

// ---------------- transpose: out[b][c][r] = in[b][r][c] ----------------
__global__ void k_transpose(const float* __restrict__ in, float* __restrict__ out, int R, int C){
  int b = blockIdx.y;
  long n = (long)R*C;
  long i = (long)blockIdx.x*256 + threadIdx.x;
  if (i < n){
    int r = (int)(i / C), c = (int)(i % C);
    out[(long)b*n + (long)c*R + r] = in[(long)b*n + i];
  }
}

// ---------------- embedding gathers (D=200) ----------------
__global__ void k_gather(const float* __restrict__ emb, const int* __restrict__ tok, float* __restrict__ out){
  int row = blockIdx.x; int c = threadIdx.x;
  if (c < 200) out[(long)row*200 + c] = emb[(long)tok[row]*200 + c];
}
__global__ void k_gather_sel(const float* __restrict__ emb, const int* __restrict__ tok, const int* __restrict__ sel, float* __restrict__ out){
  int t = blockIdx.x, b = blockIdx.y; int c = threadIdx.x;
  if (c < 200){
    int tk = tok[(long)sel[b]*50 + t];
    out[((long)b*50 + t)*200 + c] = emb[(long)tk*200 + c];
  }
}

// ---------------- fp32 GEMM 128x128 tile, 8x8 micro: C = A(M,K) @ W(N,K)^T + bias ----------------
__global__ __launch_bounds__(256) void k_gemm128(
    const float* __restrict__ A, const float* __restrict__ W,
    const float* __restrict__ bias, float* __restrict__ C,
    int M, int N, int K, long sA, long sW, long sC, long sBias)
{
  int bz = blockIdx.z;
  A += (long)bz*sA; W += (long)bz*sW; C += (long)bz*sC;
  if (bias) bias += (long)bz*sBias;
  int n0 = blockIdx.x*128, m0 = blockIdx.y*128;
  __shared__ float As[16][132];
  __shared__ float Bs[16][132];
  int tid = threadIdx.x;
  int tx = tid & 15, ty = tid >> 4;
  float acc[8][8] = {};
  const bool k4 = ((K & 3) == 0);
  for (int k0 = 0; k0 < K; k0 += 16){
    #pragma unroll
    for (int half = 0; half < 2; half++){
      int s = tid + half*256;
      int r = s >> 2;
      int kq = (s & 3) << 2;
      int k = k0 + kq;
      int m = m0 + r;
      float4 va = make_float4(0.f,0.f,0.f,0.f);
      if (m < M){
        if (k4 && k + 3 < K) va = *(const float4*)&A[(long)m*K + k];
        else {
          float* pv = (float*)&va;
          #pragma unroll
          for (int u=0; u<4; u++) if (k+u < K) pv[u] = A[(long)m*K + k + u];
        }
      }
      As[kq+0][r]=va.x; As[kq+1][r]=va.y; As[kq+2][r]=va.z; As[kq+3][r]=va.w;
      int n = n0 + r;
      float4 vb = make_float4(0.f,0.f,0.f,0.f);
      if (n < N){
        if (k4 && k + 3 < K) vb = *(const float4*)&W[(long)n*K + k];
        else {
          float* pv = (float*)&vb;
          #pragma unroll
          for (int u=0; u<4; u++) if (k+u < K) pv[u] = W[(long)n*K + k + u];
        }
      }
      Bs[kq+0][r]=vb.x; Bs[kq+1][r]=vb.y; Bs[kq+2][r]=vb.z; Bs[kq+3][r]=vb.w;
    }
    __syncthreads();
    #pragma unroll
    for (int kk=0;kk<16;kk++){
      float a[8], b[8];
      *(float4*)&a[0] = *(const float4*)&As[kk][ty*8];
      *(float4*)&a[4] = *(const float4*)&As[kk][ty*8+4];
      *(float4*)&b[0] = *(const float4*)&Bs[kk][tx*8];
      *(float4*)&b[4] = *(const float4*)&Bs[kk][tx*8+4];
      #pragma unroll
      for (int i=0;i<8;i++)
        #pragma unroll
        for (int j=0;j<8;j++)
          acc[i][j] += a[i]*b[j];
    }
    __syncthreads();
  }
  #pragma unroll
  for (int i=0;i<8;i++){
    int m = m0 + ty*8 + i;
    if (m >= M) continue;
    #pragma unroll
    for (int j=0;j<8;j++){
      int n = n0 + tx*8 + j;
      if (n < N) C[(long)m*N + n] = acc[i][j] + (bias ? bias[n] : 0.f);
    }
  }
}

// ---------------- small GRU (h=150, 3h=450), 1 wg per (item,dir) ----------------
__global__ __launch_bounds__(512) void k_gru_small(
    const float* __restrict__ xs, long xsDir,
    const float* __restrict__ Wt, const float* __restrict__ bhh,
    float* __restrict__ y, int yld,
    float* __restrict__ meanOut, int meanld,
    int T)
{
  int item = blockIdx.x, dir = blockIdx.y;
  const float* xsd = xs + (long)dir*xsDir + (long)item*T*450;
  const float* Wtd = Wt + (long)dir*150*450;
  int tid = threadIdx.x;
  float bh = (tid < 450) ? bhh[(long)dir*450 + tid] : 0.f;
  __shared__ float hs[152];
  __shared__ float gs[456];
  if (tid < 150) hs[tid] = 0.f;
  float hsum = 0.f;
  __syncthreads();
  for (int t=0;t<T;t++){
    int tt = dir ? (T-1-t) : t;
    if (tid < 450){
      float g = bh;
      const float* wp = Wtd + tid;
      #pragma unroll 5
      for (int k=0;k<150;k++) g += hs[k] * wp[(long)k*450];
      gs[tid] = g;
    }
    __syncthreads();
    if (tid < 150){
      const float* xr = xsd + (long)tt*450;
      float r = sigm(xr[tid]     + gs[tid]);
      float z = sigm(xr[150+tid] + gs[150+tid]);
      float nn = tanhf(xr[300+tid] + r*gs[300+tid]);
      float h = (1.f-z)*nn + z*hs[tid];
      hs[tid] = h;
      hsum += h;
      if (y) y[((long)item*T + tt)*yld + dir*150 + tid] = h;
    }
    __syncthreads();
  }
  if (meanOut && tid < 150)
    meanOut[(long)item*meanld + dir*150 + tid] = hsum / (float)T;
}

// ---------------- persistent big GRU, fence-free relaxed-atomic exchange ----------------
// wid -> (dir, bb of 16 items, cb of 10 h-cols). Weights LDS-resident (loaded once).
// Cross-wg h exchange: RELAXED agent-scope atomics (sc1 write-through/uncached) -> no
// buffer_wbl2/buffer_inv cache maintenance. Ordering: __syncthreads drains vmcnt(0)
// before the flag store. Barrier: per-(dir,bb) quadrant (NCB wgs), symmetric flag poll,
// monotonic values (no reset).
#define GDOT(AC, W, A) AC += W.x*A.x + W.y*A.y + W.z*A.z + W.w*A.w;
template<int H, int KP, int LDW, int HPAD, int KL, int NCB>
__global__ __launch_bounds__(256) void k_gru_persist(
    const float* __restrict__ xs, long xsDir,
    const float* __restrict__ Whh, const float* __restrict__ bhh,
    float* hA, float* hB,
    float* __restrict__ ysum, int ysld,
    int T, int* flags)
{
  constexpr int H3 = 3*H;
  int wid = blockIdx.x;
  int dir = wid / (2*NCB);
  int rem = wid % (2*NCB);
  int bb  = rem / NCB;
  int cb  = rem % NCB;
  int qbase = (dir*2 + bb)*64;
  int c0  = cb*10;
  int tid = threadIdx.x;

  const float* xsd = xs + (long)dir*xsDir;
  const float* Wd  = Whh + (long)dir*(long)H*H3;   // [3H][H] row-major
  const float* bhd = bhh + (long)dir*H3;

  __shared__ float hs[16*HPAD];
  __shared__ float Wl[30*LDW];
  __shared__ float blds[32];
  __shared__ float gl[30*16];
  __shared__ float part[240*12];

  // ---- load this wg's 30 gate-row weights into LDS ONCE ----
  for (int u = tid; u < 30*KP; u += 256){
    int r = u / KP, k = u % KP;
    long row = (long)(r/10)*H + c0 + (r%10);
    Wl[r*LDW + k] = (k < H) ? Wd[row*H + k] : 0.f;
  }
  if (tid < 30) blds[tid] = bhd[(long)(tid/10)*H + (c0 + tid%10)];

  // compute mapping: tid = ks*40 + rg*4 + ig  (ks 0..5, rg 0..9, ig 0..3)
  int ks = tid / 40;
  int rem2 = tid % 40;
  int rg = rem2 / 4;
  int ig = rem2 % 4;
  bool alive = (tid < 240);
  int r0 = rg*3;
  int it0 = ig*4;
  int kbase = ks*KL;

  // update mapping (tid<160): item uit, col uci
  int uit = tid / 10, uci = tid % 10;
  int uc = c0 + uci;
  int ub = bb*16 + uit;
  float ysacc = 0.f;

  __syncthreads();

  for (int t=0; t<T; t++){
    float* hp = ((t & 1) ? hB : hA) + (long)dir*32*H;
    float* hn = ((t & 1) ? hA : hB) + (long)dir*32*H;
    int tt = dir ? (T-1-t) : t;

    // ---- stage h slice [16][H] via relaxed agent atomics (uncached, coherent) ----
    #pragma unroll 8
    for (int u = tid; u < 16*KP; u += 256){
      int bl = u / KP, k = u % KP;
      float v = 0.f;
      if (k < H)
        v = __hip_atomic_load(&hp[(long)(bb*16+bl)*H + k], __ATOMIC_RELAXED, __HIP_MEMORY_SCOPE_AGENT);
      hs[bl*HPAD + k] = v;
    }
    // ---- prefetch this step's x values (independent of h) ----
    float xv0 = 0.f, xv1 = 0.f, xv2 = 0.f;
    if (tid < 160){
      const float* xr = xsd + ((long)ub*T + tt)*H3;
      xv0 = xr[uc]; xv1 = xr[H+uc]; xv2 = xr[2*H+uc];
    }
    __syncthreads();

    // ---- gate GEMM partials: 3 rows x 4 items x KL ----
    if (alive){
      float acc[3][4];
      #pragma unroll
      for (int a=0;a<3;a++)
        #pragma unroll
        for (int b=0;b<4;b++) acc[a][b] = 0.f;
      const float* wr0 = &Wl[(r0+0)*LDW + kbase];
      const float* wr1 = &Wl[(r0+1)*LDW + kbase];
      const float* wr2 = &Wl[(r0+2)*LDW + kbase];
      const float* h0  = &hs[(it0+0)*HPAD + kbase];
      const float* h1  = &hs[(it0+1)*HPAD + kbase];
      const float* h2  = &hs[(it0+2)*HPAD + kbase];
      const float* h3  = &hs[(it0+3)*HPAD + kbase];
      for (int jq = 0; jq < KL; jq += 4){
        float4 w0 = *(const float4*)&wr0[jq];
        float4 w1 = *(const float4*)&wr1[jq];
        float4 w2 = *(const float4*)&wr2[jq];
        float4 a0 = *(const float4*)&h0[jq];
        float4 a1 = *(const float4*)&h1[jq];
        float4 a2 = *(const float4*)&h2[jq];
        float4 a3 = *(const float4*)&h3[jq];
        GDOT(acc[0][0], w0, a0) GDOT(acc[0][1], w0, a1) GDOT(acc[0][2], w0, a2) GDOT(acc[0][3], w0, a3)
        GDOT(acc[1][0], w1, a0) GDOT(acc[1][1], w1, a1) GDOT(acc[1][2], w1, a2) GDOT(acc[1][3], w1, a3)
        GDOT(acc[2][0], w2, a0) GDOT(acc[2][1], w2, a1) GDOT(acc[2][2], w2, a2) GDOT(acc[2][3], w2, a3)
      }
      #pragma unroll
      for (int a=0;a<3;a++)
        *(float4*)&part[tid*12 + a*4] = make_float4(acc[a][0],acc[a][1],acc[a][2],acc[a][3]);
    }
    __syncthreads();

    // ---- k-reduce 6 partials -> gl[30][16] ----
    if (alive){
      #pragma unroll
      for (int vv=0; vv<2; vv++){
        int v = tid + vv*240;               // 0..479
        int row = v >> 4, item = v & 15;
        int base = ((row/3)*4 + (item>>2))*12 + (row%3)*4 + (item&3);
        float sum = blds[row];
        #pragma unroll
        for (int s=0; s<6; s++) sum += part[s*480 + base];
        gl[row*16 + item] = sum;
      }
    }
    __syncthreads();

    // ---- GRU update; h stores are write-through relaxed atomics ----
    if (tid < 160){
      float r  = sigm(xv0 + gl[(uci)*16    + uit]);
      float z  = sigm(xv1 + gl[(10+uci)*16 + uit]);
      float nn = tanhf(xv2 + r*gl[(20+uci)*16 + uit]);
      float hv = hs[uit*HPAD + uc];
      float hne = (1.f-z)*nn + z*hv;
      __hip_atomic_store(&hn[(long)ub*H + uc], hne, __ATOMIC_RELAXED, __HIP_MEMORY_SCOPE_AGENT);
      ysacc += hne;
    }
    __syncthreads();   // drains vmcnt(0): hn write-through stores are globally visible

    // ---- quadrant barrier: symmetric flag poll, monotonic, no fences ----
    if (t+1 < T){
      if (tid == 0)
        __hip_atomic_store(&flags[qbase + cb], t+1, __ATOMIC_RELAXED, __HIP_MEMORY_SCOPE_AGENT);
      if (tid < NCB){
        while (__hip_atomic_load(&flags[qbase + tid], __ATOMIC_RELAXED, __HIP_MEMORY_SCOPE_AGENT) < t+1)
          __builtin_amdgcn_s_sleep(2);
      }
      __syncthreads();
    }
  }
  if (tid < 160)
    ysum[(long)ub*ysld + dir*H + uc] = ysacc;
}

// ---------------- graph decomposition layer (D=300, K=8) ----------------
__global__ __launch_bounds__(256) void k_graphdecomp(
   const float* __restrict__ labIn, float* __restrict__ labOut,
   const int* __restrict__ nb, const int* __restrict__ nbm, int N)
{
  int n = blockIdx.x; if (n >= N) return;
  int tid = threadIdx.x;
  __shared__ float ln[300];
  __shared__ float red[12];
  for (int d=tid; d<300; d+=256) ln[d] = labIn[(long)n*300+d];
  float deg = 0.f;
  for (int k=0;k<8;k++) deg += (float)nbm[n*8+k];
  float invdeg = 1.f / fmaxf(deg, 1.f);
  float acc0 = 0.f, acc1 = 0.f;
  __syncthreads();
  for (int k=0;k<8;k++){
    int j = nb[n*8+k];
    float mk = (float)nbm[n*8+k];
    const float* lj = labIn + (long)j*300;
    float p1=0.f, p2=0.f;
    for (int d=tid; d<300; d+=256){ float v = lj[d]; p1 += ln[d]*v; p2 += v*v; }
    for (int o=32;o>0;o>>=1){ p1 += __shfl_down(p1,o); p2 += __shfl_down(p2,o); }
    __syncthreads();
    int w = tid>>6, lane = tid&63;
    if (lane==0){ red[w]=p1; red[4+w]=p2; }
    __syncthreads();
    float x1 = red[0]+red[1]+red[2]+red[3];
    float x2 = red[4]+red[5]+red[6]+red[7];
    float coef = (x1 / (x2 + 1e-10f)) * mk * invdeg;
    acc0 += coef * lj[tid];
    if (tid + 256 < 300) acc1 += coef * lj[tid+256];
    __syncthreads();
  }
  bool pos = deg > 0.f;
  labOut[(long)n*300 + tid]                       = pos ? (ln[tid]     - acc0) : ln[tid];
  if (tid+256 < 300) labOut[(long)n*300 + tid+256] = pos ? (ln[tid+256] - acc1) : ln[tid+256];
}

// ---------------- copy ----------------
__global__ void k_copy(const float* __restrict__ src, float* __restrict__ dst, long n){
  long i = (long)blockIdx.x*256+threadIdx.x; if (i<n) dst[i]=src[i];
}

// ---------------- code_wise reductions ----------------
__global__ void k_cw_rowmax(const float* __restrict__ S, float* __restrict__ Mv){
  const int ofs[4]={0,119,238,341};
  const int wid[4]={119,119,103,103};
  int s = blockIdx.y; int row = blockIdx.x*256+threadIdx.x;
  if (row < 16384){
    const float* p = S + (long)row*444 + ofs[s];
    float m = -3.4e38f;
    int w = wid[s];
    for (int n=0;n<w;n++) m = fmaxf(m, p[n]);
    Mv[(long)s*16384+row] = m;
  }
}
__global__ void k_cw_softmax(const float* __restrict__ Mv, float* __restrict__ att){
  int b=blockIdx.x, s=blockIdx.y, tid=threadIdx.x;
  const float* src = Mv + (long)s*16384 + (long)b*512;
  __shared__ float red[256];
  float v0 = src[tid], v1 = src[tid+256];
  red[tid] = fmaxf(v0,v1); __syncthreads();
  for (int o=128;o>0;o>>=1){ if (tid<o) red[tid]=fmaxf(red[tid],red[tid+o]); __syncthreads(); }
  float m = red[0]; __syncthreads();
  float e0=expf(v0-m), e1=expf(v1-m);
  red[tid]=e0+e1; __syncthreads();
  for (int o=128;o>0;o>>=1){ if (tid<o) red[tid]+=red[tid+o]; __syncthreads(); }
  float inv = 1.f/red[0];
  float* dst = att + ((long)s*32 + b)*512;
  dst[tid]=e0*inv; dst[tid+256]=e1*inv;
}
__global__ void k_cw_out(const float* __restrict__ att, const float* __restrict__ DH, float* __restrict__ outp){
  int b=blockIdx.x, s=blockIdx.y, tid=threadIdx.x;
  __shared__ float a[512];
  for (int i=tid;i<512;i+=256) a[i]=att[((long)s*32+b)*512+i];
  __syncthreads();
  for (int d=tid; d<300; d+=256){
    float acc=0.f;
    for (int t=0;t<512;t++) acc += a[t]*DH[((long)b*512+t)*300+d];
    outp[((long)s*32+b)*300+d]=acc;
  }
}

// ---------------- masked softmax over l=50 (in place) ----------------
__global__ void k_masksm(float* __restrict__ att, long nrows){
  long row = (long)blockIdx.x*256 + threadIdx.x;
  if (row >= nrows) return;
  float* p = att + row*50;
  float m = -INFINITY;
  for (int l=0;l<50;l++){ float a = p[l]; if (a != 0.f && a > m) m = a; }
  if (m == -INFINITY){ for (int l=0;l<50;l++) p[l] = 0.f; return; }
  float s = 0.f;
  for (int l=0;l<50;l++){ float a = p[l]; float e = (a==0.f) ? 0.f : expf(a-m); p[l]=e; s+=e; }
  float inv = 1.f/s;
  for (int l=0;l<50;l++) p[l] *= inv;
}

// ---------------- fact separation combine (rows of 300), 1 wave per row ----------------
// NOTE: no __restrict__ — call 2 intentionally aliases simOut=scen, diffOut=circ.
__global__ void k_factsep(const float* circ, const float* scen,
                          float* simOut, float* diffOut, long nrows)
{
  int lane = threadIdx.x & 63;
  long row = (long)blockIdx.x*4 + (threadIdx.x >> 6);
  if (row >= nrows) return;
  const float* c = circ + row*300;
  const float* s = scen + row*300;
  float x3=0.f, x4=0.f;
  for (int d=lane; d<300; d+=64){ float sv=s[d]; x3 += c[d]*sv; x4 += sv*sv; }
  for (int o=32;o>0;o>>=1){ x3 += __shfl_down(x3,o); x4 += __shfl_down(x4,o); }
  x3 = __shfl(x3,0); x4 = __shfl(x4,0);
  float coef = x3 / (x4 + 1e-10f);
  for (int d=lane; d<300; d+=64){
    float sv = s[d]; float cv = c[d];
    float sim = coef*sv;
    simOut[row*300+d] = sim;
    diffOut[row*300+d] = cv - sim;
  }
}

// ---------------- assemblers ----------------
__global__ void k_factart(const float* __restrict__ DH, const float* __restrict__ dha,
                          const float* __restrict__ adc, const float* __restrict__ db,
                          float* __restrict__ out)
{
  long row = blockIdx.x; int b = (int)(row >> 9);
  for (int c=threadIdx.x; c<1200; c+=256){
    float v;
    if (c < 300) v = DH[row*300 + c];
    else if (c < 600) v = dha[(long)b*300 + (c-300)];
    else if (c < 900) v = adc[row*300 + (c-600)];
    else v = db[(long)b*300 + (c-900)];
    out[row*1200 + c] = v;
  }
}
__global__ void k_termcat(const float* __restrict__ DH, const float* __restrict__ ssc,
                          const float* __restrict__ dsc, float* __restrict__ out){
  long row = blockIdx.x;
  for (int c=threadIdx.x; c<900; c+=256){
    float v = (c<300) ? DH[row*300+c] : (c<600 ? ssc[row*300+(c-300)] : dsc[row*300+(c-600)]);
    out[row*900+c] = v;
  }
}

// ---------------- classifier: logits -> fp32 out, optional argmax ----------------
__global__ __launch_bounds__(256) void k_classify(
    const float* __restrict__ s0, const float* __restrict__ s1, const float* __restrict__ s2,
    int L, int Kf, float scale,
    const float* __restrict__ W, const float* __restrict__ bias, int N,
    float* __restrict__ out, int* __restrict__ amax)
{
  int b = blockIdx.x; int tid = threadIdx.x;
  __shared__ float feat[1200];
  __shared__ float logit[128];
  for (int i=tid; i<Kf; i+=256){
    int seg = i / L, c = i % L;
    const float* s = (seg==0) ? s0 : (seg==1 ? s1 : s2);
    feat[i] = s[(long)b*L + c] * scale;
  }
  __syncthreads();
  for (int n=tid; n<N; n+=256){
    float acc = bias[n];
    const float* w = W + (long)n*Kf;
    for (int k=0;k<Kf;k++) acc += feat[k]*w[k];
    out[(long)b*N + n] = acc;
    logit[n] = acc;
  }
  __syncthreads();
  if (amax && tid==0){
    float best = logit[0]; int bi=0;
    for (int n=1;n<N;n++) if (logit[n] > best){ best=logit[n]; bi=n; }
    amax[b] = bi;
  }
}

static inline int cdiv(long a, long b){ return (int)((a + b - 1)/b); }

extern "C" void kernel_launch(void* const* d_in, const int* in_sizes, int n_in,
                              void* d_out, int out_size, void* d_ws, size_t ws_size,
                              hipStream_t stream)
{
  (void)in_sizes; (void)n_in; (void)out_size;
  const float* emb     = (const float*)d_in[0];
  const float* encWih  = (const float*)d_in[1];
  const float* encWhh  = (const float*)d_in[2];
  const float* encbih  = (const float*)d_in[3];
  const float* encbhh  = (const float*)d_in[4];
  const float* cchWih  = (const float*)d_in[5];
  const float* cchWhh  = (const float*)d_in[6];
  const float* cchbih  = (const float*)d_in[7];
  const float* cchbhh  = (const float*)d_in[8];
  const float* termWih = (const float*)d_in[9];
  const float* termWhh = (const float*)d_in[10];
  const float* termbih = (const float*)d_in[11];
  const float* termbhh = (const float*)d_in[12];
  const float* artWih  = (const float*)d_in[13];
  const float* artWhh  = (const float*)d_in[14];
  const float* artbih  = (const float*)d_in[15];
  const float* artbhh  = (const float*)d_in[16];
  const float* Wc      = (const float*)d_in[17];
  const float* bc      = (const float*)d_in[18];
  const float* Wa      = (const float*)d_in[19];
  const float* ba      = (const float*)d_in[20];
  const float* Wt_     = (const float*)d_in[21];
  const float* bt_     = (const float*)d_in[22];
  const int* docs    = (const int*)d_in[23];
  const int* chtok   = (const int*)d_in[24];
  const int* artok   = (const int*)d_in[25];
  const int* chnb    = (const int*)d_in[26];
  const int* chnbm   = (const int*)d_in[27];
  const int* arnb    = (const int*)d_in[28];
  const int* arnbm   = (const int*)d_in[29];
  const int* vchtok  = (const int*)d_in[30];
  const int* vartok  = (const int*)d_in[31];
  float* ob = (float*)d_out;
  float* ws = (float*)d_ws;

  // -------- workspace layout (float elements) --------
  constexpr long O_WTENC = 0;                       // 2*150*450
  constexpr long O_WTCCH = O_WTENC + 135000;        // 2*150*450
  constexpr long O_WTART = O_WTCCH + 135000;        // (spare)
  constexpr long O_WTTERM= O_WTART + 2160000;       // (spare)
  constexpr long O_DH    = O_WTTERM + 1215000;      // 16384*300
  constexpr long O_DMEAN = O_DH + 4915200;          // 32*300
  constexpr long O_CHM   = O_DMEAN + 9600;          // 119*300
  constexpr long O_ARM   = O_CHM + 35700;           // 103*300
  constexpr long O_LAB   = O_ARM + 30900;           // 444*300
  constexpr long O_GDT   = O_LAB + 133200;          // 119*300 (barrier ints after decomp)
  constexpr long O_CWM   = O_GDT + 35700;           // 4*16384
  constexpr long O_CWA   = O_CWM + 65536;           // 4*32*512
  constexpr long O_CWO   = O_CWA + 65536;           // 4*32*300
  constexpr long O_CP    = O_CWO + 38400;           // 64 ints
  constexpr long O_VCH   = O_CP + 64;               // 32*50*300
  constexpr long O_VCHT  = O_VCH + 480000;          // 32*300*50
  constexpr long O_ATT   = O_VCHT + 480000;         // 32*512*50
  constexpr long O_SCEN  = O_ATT + 819200;          // 16384*300
  constexpr long O_ADC   = O_SCEN + 4915200;        // 16384*300
  constexpr long O_SEC   = O_ADC + 4915200;         // 16384*300
  constexpr long O_HBUF  = O_SEC + 4915200;         // h ping-pong 2*38400
  constexpr long O_YSUM  = O_HBUF + 76800;          // 32*1200
  constexpr long O_GATH  = O_YSUM + 38400;          // 16384*200
  constexpr long O_XSS   = O_GATH + 3276800;        // 2*6592*450
  constexpr long O_PF    = O_XSS + 5932800;         // 16384*1200
  constexpr long O_XB    = O_PF + 19660800;         // 2*16384*1800
  constexpr long TOTAL   = O_XB + 58982400;         // ~454 MB
  if (ws_size < (size_t)TOTAL * 4) return;

  float* WT_ENC = ws + O_WTENC;
  float* WT_CCH = ws + O_WTCCH;
  float* DH     = ws + O_DH;
  float* DMEAN  = ws + O_DMEAN;
  float* CHM    = ws + O_CHM;
  float* ARM    = ws + O_ARM;
  float* LAB    = ws + O_LAB;
  float* GDT    = ws + O_GDT;
  float* CWM    = ws + O_CWM;
  float* CWA    = ws + O_CWA;
  float* CWO    = ws + O_CWO;
  int*   CP     = (int*)(ws + O_CP);
  int*   AP     = CP + 32;
  float* VCH    = ws + O_VCH;
  float* VCHT   = ws + O_VCHT;
  float* ATT    = ws + O_ATT;
  float* SCEN   = ws + O_SCEN;
  float* ADC    = ws + O_ADC;
  float* SEC    = ws + O_SEC;
  float* HBUF   = ws + O_HBUF;
  float* YSUM   = ws + O_YSUM;
  float* GATH   = ws + O_GATH;
  float* XSS    = ws + O_XSS;
  float* PF     = ws + O_PF;
  float* XB     = ws + O_XB;
  int*   FLAGS  = (int*)GDT;       // free after graph decomposition

  // -------- transpose small Whh --------
  k_transpose<<<dim3(cdiv(450L*150,256),2),256,0,stream>>>(encWhh, WT_ENC, 450,150);
  k_transpose<<<dim3(cdiv(450L*150,256),2),256,0,stream>>>(cchWhh, WT_CCH, 450,150);

  // -------- charge token encoder (encch), mean only --------
  k_gather<<<3808,256,0,stream>>>(emb, chtok, GATH);
  k_gemm128<<<dim3(4,cdiv(3808,128),2),256,0,stream>>>(GATH, cchWih, cchbih, XSS,
      3808,450,200, 0, 450L*200, 3808L*450, 450);
  k_gru_small<<<dim3(119,2),512,0,stream>>>(XSS, 3808L*450, WT_CCH, cchbhh,
      nullptr,0, CHM,300, 32);

  // -------- article token encoder (encch), mean only --------
  k_gather<<<6592,256,0,stream>>>(emb, artok, GATH);
  k_gemm128<<<dim3(4,cdiv(6592,128),2),256,0,stream>>>(GATH, cchWih, cchbih, XSS,
      6592,450,200, 0, 450L*200, 6592L*450, 450);
  k_gru_small<<<dim3(103,2),512,0,stream>>>(XSS, 6592L*450, WT_CCH, cchbhh,
      nullptr,0, ARM,300, 64);

  // -------- originals + graph decomposition into label-cat --------
  k_copy<<<cdiv(35700,256),256,0,stream>>>(CHM, LAB + 119L*300, 35700);
  k_copy<<<cdiv(30900,256),256,0,stream>>>(ARM, LAB + 341L*300, 30900);
  k_graphdecomp<<<119,256,0,stream>>>(CHM, GDT, chnb, chnbm, 119);
  k_graphdecomp<<<119,256,0,stream>>>(GDT, LAB, chnb, chnbm, 119);
  k_graphdecomp<<<103,256,0,stream>>>(ARM, GDT, arnb, arnbm, 103);
  k_graphdecomp<<<103,256,0,stream>>>(GDT, LAB + 238L*300, arnb, arnbm, 103);

  // -------- document encoder (enc) -> d_hidden + doc_mean --------
  k_gather<<<16384,256,0,stream>>>(emb, docs, GATH);
  k_gemm128<<<dim3(4,128,2),256,0,stream>>>(GATH, encWih, encbih, PF,
      16384,450,200, 0, 450L*200, 16384L*450, 450);
  k_gru_small<<<dim3(32,2),512,0,stream>>>(PF, 16384L*450, WT_ENC, encbhh,
      DH,300, DMEAN,300, 512);

  // -------- code_wise (4 label sets at once) --------
  k_gemm128<<<dim3(4,128,1),256,0,stream>>>(DH, LAB, nullptr, PF,
      16384,444,300, 0,0,0, 0);
  k_cw_rowmax<<<dim3(64,4),256,0,stream>>>(PF, CWM);
  k_cw_softmax<<<dim3(32,4),256,0,stream>>>(CWM, CWA);
  k_cw_out<<<dim3(32,4),256,0,stream>>>(CWA, DH, CWO);

  // -------- charge classifier + argmax --------
  k_classify<<<32,256,0,stream>>>(DMEAN, CWO, CWO + 32L*300,
      300, 900, 1.f, Wc, bc, 119, ob, CP);

  // -------- verdict-charge GRU (enc) --------
  k_gather_sel<<<dim3(50,32),256,0,stream>>>(emb, vchtok, CP, GATH);
  k_gemm128<<<dim3(4,13,2),256,0,stream>>>(GATH, encWih, encbih, XSS,
      1600,450,200, 0, 450L*200, 1600L*450, 450);
  k_gru_small<<<dim3(32,2),512,0,stream>>>(XSS, 1600L*450, WT_ENC, encbhh,
      VCH,300, nullptr,0, 50);

  // -------- fact separation 1 (vch vs d_hidden) --------
  k_gemm128<<<dim3(1,4,32),256,0,stream>>>(DH, VCH, nullptr, ATT,
      512,50,300, 512L*300, 50L*300, 512L*50, 0);
  k_masksm<<<64,256,0,stream>>>(ATT, 16384);
  k_transpose<<<dim3(cdiv(15000,256),32),256,0,stream>>>(VCH, VCHT, 50, 300);
  k_gemm128<<<dim3(3,4,32),256,0,stream>>>(ATT, VCHT, nullptr, SCEN,
      512,300,50, 512L*50, 300L*50, 512L*300, 0);
  k_factsep<<<4096,256,0,stream>>>(DH, SCEN, ADC, SEC, 16384);

  // -------- fact_article + art bigru (persistent, relaxed-atomic barrier) --------
  k_factart<<<16384,256,0,stream>>>(DH, CWO + 2L*32*300, ADC, CWO + 3L*32*300, PF);
  k_gemm128<<<dim3(cdiv(1800,128),128,2),256,0,stream>>>(PF, artWih, artbih, XB,
      16384,1800,1200, 0, 1800L*1200, 16384L*1800, 1800);
  hipMemsetAsync(FLAGS, 0, 256*sizeof(int), stream);
  hipMemsetAsync(HBUF, 0, 38400*sizeof(float), stream);
  // art: H=600, KP=600, LDW=604, HPAD=604, KL=100, NCB=60 -> 240 wgs
  k_gru_persist<600,600,604,604,100,60><<<240,256,0,stream>>>(
      XB, 16384L*1800, artWhh, artbhh, HBUF, HBUF+38400, YSUM, 1200, 512, FLAGS);
  k_classify<<<32,256,0,stream>>>(YSUM, nullptr, nullptr,
      1200, 1200, 1.f/512.f, Wa, ba, 103, ob + 3808, AP);

  // -------- verdict-article GRU (enc) --------
  k_gather_sel<<<dim3(50,32),256,0,stream>>>(emb, vartok, AP, GATH);
  k_gemm128<<<dim3(4,13,2),256,0,stream>>>(GATH, encWih, encbih, XSS,
      1600,450,200, 0, 450L*200, 1600L*450, 450);
  k_gru_small<<<dim3(32,2),512,0,stream>>>(XSS, 1600L*450, WT_ENC, encbhh,
      VCH,300, nullptr,0, 50);

  // -------- fact separation 2 (var vs sec); ssc->SCEN, dsc->SEC in place --------
  k_gemm128<<<dim3(1,4,32),256,0,stream>>>(SEC, VCH, nullptr, ATT,
      512,50,300, 512L*300, 50L*300, 512L*50, 0);
  k_masksm<<<64,256,0,stream>>>(ATT, 16384);
  k_transpose<<<dim3(cdiv(15000,256),32),256,0,stream>>>(VCH, VCHT, 50, 300);
  k_gemm128<<<dim3(3,4,32),256,0,stream>>>(ATT, VCHT, nullptr, SCEN,
      512,300,50, 512L*50, 300L*50, 512L*300, 0);
  k_factsep<<<4096,256,0,stream>>>(SEC, SCEN, SCEN, SEC, 16384);

  // -------- term bigru (persistent, relaxed-atomic barrier) --------
  k_termcat<<<16384,256,0,stream>>>(DH, SCEN, SEC, PF);
  k_gemm128<<<dim3(cdiv(1350,128),128,2),256,0,stream>>>(PF, termWih, termbih, XB,
      16384,1350,900, 0, 1350L*900, 16384L*1350, 1350);
  hipMemsetAsync(FLAGS, 0, 256*sizeof(int), stream);
  hipMemsetAsync(HBUF, 0, 38400*sizeof(float), stream);
  // term: H=450, KP=456, LDW=460, HPAD=460, KL=76, NCB=45 -> 180 wgs
  k_gru_persist<450,456,460,460,76,45><<<180,256,0,stream>>>(
      XB, 16384L*1350, termWhh, termbhh, HBUF, HBUF+38400, YSUM, 900, 512, FLAGS);
  k_classify<<<32,256,0,stream>>>(YSUM, nullptr, nullptr,
      900, 900, 1.f/512.f, Wt_, bt_, 11, ob + 7104, nullptr);
}

// Round 7
// 18415.836 us; speedup vs baseline: 4.5905x; 1.2554x over previous
//
#include <hip/hip_runtime.h>
#include <hip/hip_bf16.h>

#define DEVI __device__ __forceinline__

DEVI float sigm(float x){ return 1.f/(1.f+expf(-x)); }

// ---------------- transpose: out[b][c][r] = in[b][r][c] ----------------
__global__ void k_transpose(const float* __restrict__ in, float* __restrict__ out, int R, int C){
  int b = blockIdx.y;
  long n = (long)R*C;
  long i = (long)blockIdx.x*256 + threadIdx.x;
  if (i < n){
    int r = (int)(i / C), c = (int)(i % C);
    out[(long)b*n + (long)c*R + r] = in[(long)b*n + i];
  }
}

// ---------------- embedding gathers (D=200) ----------------
__global__ void k_gather(const float* __restrict__ emb, const int* __restrict__ tok, float* __restrict__ out){
  int row = blockIdx.x; int c = threadIdx.x;
  if (c < 200) out[(long)row*200 + c] = emb[(long)tok[row]*200 + c];
}
__global__ void k_gather_sel(const float* __restrict__ emb, const int* __restrict__ tok, const int* __restrict__ sel, float* __restrict__ out){
  int t = blockIdx.x, b = blockIdx.y; int c = threadIdx.x;
  if (c < 200){
    int tk = tok[(long)sel[b]*50 + t];
    out[((long)b*50 + t)*200 + c] = emb[(long)tk*200 + c];
  }
}

// ---------------- fp32 GEMM 128x128 tile, 8x8 micro: C = A(M,K) @ W(N,K)^T + bias ----------------
__global__ __launch_bounds__(256) void k_gemm128(
    const float* __restrict__ A, const float* __restrict__ W,
    const float* __restrict__ bias, float* __restrict__ C,
    int M, int N, int K, long sA, long sW, long sC, long sBias)
{
  int bz = blockIdx.z;
  A += (long)bz*sA; W += (long)bz*sW; C += (long)bz*sC;
  if (bias) bias += (long)bz*sBias;
  int n0 = blockIdx.x*128, m0 = blockIdx.y*128;
  __shared__ float As[16][132];
  __shared__ float Bs[16][132];
  int tid = threadIdx.x;
  int tx = tid & 15, ty = tid >> 4;
  float acc[8][8] = {};
  const bool k4 = ((K & 3) == 0);
  for (int k0 = 0; k0 < K; k0 += 16){
    #pragma unroll
    for (int half = 0; half < 2; half++){
      int s = tid + half*256;
      int r = s >> 2;
      int kq = (s & 3) << 2;
      int k = k0 + kq;
      int m = m0 + r;
      float4 va = make_float4(0.f,0.f,0.f,0.f);
      if (m < M){
        if (k4 && k + 3 < K) va = *(const float4*)&A[(long)m*K + k];
        else {
          float* pv = (float*)&va;
          #pragma unroll
          for (int u=0; u<4; u++) if (k+u < K) pv[u] = A[(long)m*K + k + u];
        }
      }
      As[kq+0][r]=va.x; As[kq+1][r]=va.y; As[kq+2][r]=va.z; As[kq+3][r]=va.w;
      int n = n0 + r;
      float4 vb = make_float4(0.f,0.f,0.f,0.f);
      if (n < N){
        if (k4 && k + 3 < K) vb = *(const float4*)&W[(long)n*K + k];
        else {
          float* pv = (float*)&vb;
          #pragma unroll
          for (int u=0; u<4; u++) if (k+u < K) pv[u] = W[(long)n*K + k + u];
        }
      }
      Bs[kq+0][r]=vb.x; Bs[kq+1][r]=vb.y; Bs[kq+2][r]=vb.z; Bs[kq+3][r]=vb.w;
    }
    __syncthreads();
    #pragma unroll
    for (int kk=0;kk<16;kk++){
      float a[8], b[8];
      *(float4*)&a[0] = *(const float4*)&As[kk][ty*8];
      *(float4*)&a[4] = *(const float4*)&As[kk][ty*8+4];
      *(float4*)&b[0] = *(const float4*)&Bs[kk][tx*8];
      *(float4*)&b[4] = *(const float4*)&Bs[kk][tx*8+4];
      #pragma unroll
      for (int i=0;i<8;i++)
        #pragma unroll
        for (int j=0;j<8;j++)
          acc[i][j] += a[i]*b[j];
    }
    __syncthreads();
  }
  #pragma unroll
  for (int i=0;i<8;i++){
    int m = m0 + ty*8 + i;
    if (m >= M) continue;
    #pragma unroll
    for (int j=0;j<8;j++){
      int n = n0 + tx*8 + j;
      if (n < N) C[(long)m*N + n] = acc[i][j] + (bias ? bias[n] : 0.f);
    }
  }
}

// ---------------- small GRU (h=150, 3h=450), 1 wg per (item,dir) ----------------
__global__ __launch_bounds__(512) void k_gru_small(
    const float* __restrict__ xs, long xsDir,
    const float* __restrict__ Wt, const float* __restrict__ bhh,
    float* __restrict__ y, int yld,
    float* __restrict__ meanOut, int meanld,
    int T)
{
  int item = blockIdx.x, dir = blockIdx.y;
  const float* xsd = xs + (long)dir*xsDir + (long)item*T*450;
  const float* Wtd = Wt + (long)dir*150*450;
  int tid = threadIdx.x;
  float bh = (tid < 450) ? bhh[(long)dir*450 + tid] : 0.f;
  __shared__ float hs[152];
  __shared__ float gs[456];
  if (tid < 150) hs[tid] = 0.f;
  float hsum = 0.f;
  __syncthreads();
  for (int t=0;t<T;t++){
    int tt = dir ? (T-1-t) : t;
    if (tid < 450){
      float g = bh;
      const float* wp = Wtd + tid;
      #pragma unroll 5
      for (int k=0;k<150;k++) g += hs[k] * wp[(long)k*450];
      gs[tid] = g;
    }
    __syncthreads();
    if (tid < 150){
      const float* xr = xsd + (long)tt*450;
      float r = sigm(xr[tid]     + gs[tid]);
      float z = sigm(xr[150+tid] + gs[150+tid]);
      float nn = tanhf(xr[300+tid] + r*gs[300+tid]);
      float h = (1.f-z)*nn + z*hs[tid];
      hs[tid] = h;
      hsum += h;
      if (y) y[((long)item*T + tt)*yld + dir*150 + tid] = h;
    }
    __syncthreads();
  }
  if (meanOut && tid < 150)
    meanOut[(long)item*meanld + dir*150 + tid] = hsum / (float)T;
}

// ---------------- persistent big GRU, fence-free relaxed-atomic exchange ----------------
// wid -> (dir, bb of 16 items, cb of 10 h-cols). Weights LDS-resident (loaded once).
// Cross-wg h exchange: RELAXED agent-scope atomics (write-through, no wbl2/inv storms).
// Staging uses 8-byte relaxed atomic loads (half the transactions).
// Barrier: leader-go per (dir,bb) quadrant — wgs store flags; leader (cb==0) polls all
// NCB flags with one wave, publishes one monotonic go word; others poll ONE address with
// ONE thread (cuts uncached poll traffic ~60x). Next-step x loads issue before the
// barrier so their HBM latency hides under the wait.
#define GDOT(AC, W, A) AC += W.x*A.x + W.y*A.y + W.z*A.z + W.w*A.w;
template<int H, int KP, int LDW, int HPAD, int KL, int NCB>
__global__ __launch_bounds__(256) void k_gru_persist(
    const float* __restrict__ xs, long xsDir,
    const float* __restrict__ Whh, const float* __restrict__ bhh,
    float* hA, float* hB,
    float* __restrict__ ysum, int ysld,
    int T, int* flags, int* go)
{
  constexpr int H3 = 3*H;
  constexpr int KP2 = KP/2;
  int wid = blockIdx.x;
  int dir = wid / (2*NCB);
  int rem = wid % (2*NCB);
  int bb  = rem / NCB;
  int cb  = rem % NCB;
  int quad = dir*2 + bb;
  int qbase = quad*64;
  int c0  = cb*10;
  int tid = threadIdx.x;

  const float* xsd = xs + (long)dir*xsDir;
  const float* Wd  = Whh + (long)dir*(long)H*H3;   // [3H][H] row-major
  const float* bhd = bhh + (long)dir*H3;

  __shared__ float hs[16*HPAD];
  __shared__ float Wl[30*LDW];
  __shared__ float blds[32];
  __shared__ float gl[30*16];
  __shared__ float part[240*12];

  // ---- load this wg's 30 gate-row weights into LDS ONCE ----
  for (int u = tid; u < 30*KP; u += 256){
    int r = u / KP, k = u % KP;
    long row = (long)(r/10)*H + c0 + (r%10);
    Wl[r*LDW + k] = (k < H) ? Wd[row*H + k] : 0.f;
  }
  if (tid < 30) blds[tid] = bhd[(long)(tid/10)*H + (c0 + tid%10)];

  // compute mapping: tid = ks*40 + rg*4 + ig  (ks 0..5, rg 0..9, ig 0..3)
  int ks = tid / 40;
  int rem2 = tid % 40;
  int rg = rem2 / 4;
  int ig = rem2 % 4;
  bool alive = (tid < 240);
  int r0 = rg*3;
  int it0 = ig*4;
  int kbase = ks*KL;

  // update mapping (tid<160): item uit, col uci
  int uit = tid / 10, uci = tid % 10;
  int uc = c0 + uci;
  int ub = bb*16 + uit;
  float ysacc = 0.f;

  // ---- prologue: prefetch x for t=0 ----
  float xv0 = 0.f, xv1 = 0.f, xv2 = 0.f;
  if (tid < 160){
    int tt0 = dir ? (T-1) : 0;
    const float* xr = xsd + ((long)ub*T + tt0)*H3;
    xv0 = xr[uc]; xv1 = xr[H+uc]; xv2 = xr[2*H+uc];
  }

  __syncthreads();

  for (int t=0; t<T; t++){
    float* hp = ((t & 1) ? hB : hA) + (long)dir*32*H;
    float* hn = ((t & 1) ? hA : hB) + (long)dir*32*H;

    // ---- stage h slice [16][H] via 8-byte relaxed agent atomics ----
    #pragma unroll 4
    for (int u = tid; u < 16*KP2; u += 256){
      int bl = u / KP2;
      int k  = (u % KP2)*2;
      float2 v = make_float2(0.f, 0.f);
      if (k + 2 <= H){
        unsigned long long raw = __hip_atomic_load(
            (unsigned long long*)&hp[(long)(bb*16+bl)*H + k],
            __ATOMIC_RELAXED, __HIP_MEMORY_SCOPE_AGENT);
        v = *(float2*)&raw;
      }
      *(float2*)&hs[bl*HPAD + k] = v;
    }
    __syncthreads();

    // ---- gate GEMM partials: 3 rows x 4 items x KL ----
    if (alive){
      float acc[3][4];
      #pragma unroll
      for (int a=0;a<3;a++)
        #pragma unroll
        for (int b=0;b<4;b++) acc[a][b] = 0.f;
      const float* wr0 = &Wl[(r0+0)*LDW + kbase];
      const float* wr1 = &Wl[(r0+1)*LDW + kbase];
      const float* wr2 = &Wl[(r0+2)*LDW + kbase];
      const float* h0  = &hs[(it0+0)*HPAD + kbase];
      const float* h1  = &hs[(it0+1)*HPAD + kbase];
      const float* h2  = &hs[(it0+2)*HPAD + kbase];
      const float* h3  = &hs[(it0+3)*HPAD + kbase];
      for (int jq = 0; jq < KL; jq += 4){
        float4 w0 = *(const float4*)&wr0[jq];
        float4 w1 = *(const float4*)&wr1[jq];
        float4 w2 = *(const float4*)&wr2[jq];
        float4 a0 = *(const float4*)&h0[jq];
        float4 a1 = *(const float4*)&h1[jq];
        float4 a2 = *(const float4*)&h2[jq];
        float4 a3 = *(const float4*)&h3[jq];
        GDOT(acc[0][0], w0, a0) GDOT(acc[0][1], w0, a1) GDOT(acc[0][2], w0, a2) GDOT(acc[0][3], w0, a3)
        GDOT(acc[1][0], w1, a0) GDOT(acc[1][1], w1, a1) GDOT(acc[1][2], w1, a2) GDOT(acc[1][3], w1, a3)
        GDOT(acc[2][0], w2, a0) GDOT(acc[2][1], w2, a1) GDOT(acc[2][2], w2, a2) GDOT(acc[2][3], w2, a3)
      }
      #pragma unroll
      for (int a=0;a<3;a++)
        *(float4*)&part[tid*12 + a*4] = make_float4(acc[a][0],acc[a][1],acc[a][2],acc[a][3]);
    }
    __syncthreads();

    // ---- k-reduce 6 partials -> gl[30][16] ----
    if (alive){
      #pragma unroll
      for (int vv=0; vv<2; vv++){
        int v = tid + vv*240;               // 0..479
        int row = v >> 4, item = v & 15;
        int base = ((row/3)*4 + (item>>2))*12 + (row%3)*4 + (item&3);
        float sum = blds[row];
        #pragma unroll
        for (int s=0; s<6; s++) sum += part[s*480 + base];
        gl[row*16 + item] = sum;
      }
    }
    __syncthreads();

    // ---- GRU update; h stores are write-through relaxed atomics ----
    if (tid < 160){
      float r  = sigm(xv0 + gl[(uci)*16    + uit]);
      float z  = sigm(xv1 + gl[(10+uci)*16 + uit]);
      float nn = tanhf(xv2 + r*gl[(20+uci)*16 + uit]);
      float hv = hs[uit*HPAD + uc];
      float hne = (1.f-z)*nn + z*hv;
      __hip_atomic_store(&hn[(long)ub*H + uc], hne, __ATOMIC_RELAXED, __HIP_MEMORY_SCOPE_AGENT);
      ysacc += hne;
    }
    __syncthreads();   // drains vmcnt(0): hn write-through stores are globally visible

    // ---- prefetch next step's x (independent of h; hides under barrier) ----
    float nx0 = 0.f, nx1 = 0.f, nx2 = 0.f;
    if (tid < 160 && t+1 < T){
      int tt1 = dir ? (T-2-t) : (t+1);
      const float* xr = xsd + ((long)ub*T + tt1)*H3;
      nx0 = xr[uc]; nx1 = xr[H+uc]; nx2 = xr[2*H+uc];
    }

    // ---- leader-go quadrant barrier (monotonic, relaxed atomics only) ----
    if (t+1 < T){
      if (tid == 0)
        __hip_atomic_store(&flags[qbase + cb], t+1, __ATOMIC_RELAXED, __HIP_MEMORY_SCOPE_AGENT);
      if (cb == 0){
        if (tid < NCB){
          while (__hip_atomic_load(&flags[qbase + tid], __ATOMIC_RELAXED, __HIP_MEMORY_SCOPE_AGENT) < t+1)
            __builtin_amdgcn_s_sleep(2);
        }
        __syncthreads();
        if (tid == 0)
          __hip_atomic_store(&go[quad*32], t+1, __ATOMIC_RELAXED, __HIP_MEMORY_SCOPE_AGENT);
      } else {
        if (tid == 0){
          while (__hip_atomic_load(&go[quad*32], __ATOMIC_RELAXED, __HIP_MEMORY_SCOPE_AGENT) < t+1)
            __builtin_amdgcn_s_sleep(2);
        }
        __syncthreads();
      }
    }
    xv0 = nx0; xv1 = nx1; xv2 = nx2;
  }
  if (tid < 160)
    ysum[(long)ub*ysld + dir*H + uc] = ysacc;
}

// ---------------- graph decomposition layer (D=300, K=8) ----------------
__global__ __launch_bounds__(256) void k_graphdecomp(
   const float* __restrict__ labIn, float* __restrict__ labOut,
   const int* __restrict__ nb, const int* __restrict__ nbm, int N)
{
  int n = blockIdx.x; if (n >= N) return;
  int tid = threadIdx.x;
  __shared__ float ln[300];
  __shared__ float red[12];
  for (int d=tid; d<300; d+=256) ln[d] = labIn[(long)n*300+d];
  float deg = 0.f;
  for (int k=0;k<8;k++) deg += (float)nbm[n*8+k];
  float invdeg = 1.f / fmaxf(deg, 1.f);
  float acc0 = 0.f, acc1 = 0.f;
  __syncthreads();
  for (int k=0;k<8;k++){
    int j = nb[n*8+k];
    float mk = (float)nbm[n*8+k];
    const float* lj = labIn + (long)j*300;
    float p1=0.f, p2=0.f;
    for (int d=tid; d<300; d+=256){ float v = lj[d]; p1 += ln[d]*v; p2 += v*v; }
    for (int o=32;o>0;o>>=1){ p1 += __shfl_down(p1,o); p2 += __shfl_down(p2,o); }
    __syncthreads();
    int w = tid>>6, lane = tid&63;
    if (lane==0){ red[w]=p1; red[4+w]=p2; }
    __syncthreads();
    float x1 = red[0]+red[1]+red[2]+red[3];
    float x2 = red[4]+red[5]+red[6]+red[7];
    float coef = (x1 / (x2 + 1e-10f)) * mk * invdeg;
    acc0 += coef * lj[tid];
    if (tid + 256 < 300) acc1 += coef * lj[tid+256];
    __syncthreads();
  }
  bool pos = deg > 0.f;
  labOut[(long)n*300 + tid]                       = pos ? (ln[tid]     - acc0) : ln[tid];
  if (tid+256 < 300) labOut[(long)n*300 + tid+256] = pos ? (ln[tid+256] - acc1) : ln[tid+256];
}

// ---------------- copy ----------------
__global__ void k_copy(const float* __restrict__ src, float* __restrict__ dst, long n){
  long i = (long)blockIdx.x*256+threadIdx.x; if (i<n) dst[i]=src[i];
}

// ---------------- code_wise reductions ----------------
__global__ void k_cw_rowmax(const float* __restrict__ S, float* __restrict__ Mv){
  const int ofs[4]={0,119,238,341};
  const int wid[4]={119,119,103,103};
  int s = blockIdx.y; int row = blockIdx.x*256+threadIdx.x;
  if (row < 16384){
    const float* p = S + (long)row*444 + ofs[s];
    float m = -3.4e38f;
    int w = wid[s];
    for (int n=0;n<w;n++) m = fmaxf(m, p[n]);
    Mv[(long)s*16384+row] = m;
  }
}
__global__ void k_cw_softmax(const float* __restrict__ Mv, float* __restrict__ att){
  int b=blockIdx.x, s=blockIdx.y, tid=threadIdx.x;
  const float* src = Mv + (long)s*16384 + (long)b*512;
  __shared__ float red[256];
  float v0 = src[tid], v1 = src[tid+256];
  red[tid] = fmaxf(v0,v1); __syncthreads();
  for (int o=128;o>0;o>>=1){ if (tid<o) red[tid]=fmaxf(red[tid],red[tid+o]); __syncthreads(); }
  float m = red[0]; __syncthreads();
  float e0=expf(v0-m), e1=expf(v1-m);
  red[tid]=e0+e1; __syncthreads();
  for (int o=128;o>0;o>>=1){ if (tid<o) red[tid]+=red[tid+o]; __syncthreads(); }
  float inv = 1.f/red[0];
  float* dst = att + ((long)s*32 + b)*512;
  dst[tid]=e0*inv; dst[tid+256]=e1*inv;
}
__global__ void k_cw_out(const float* __restrict__ att, const float* __restrict__ DH, float* __restrict__ outp){
  int b=blockIdx.x, s=blockIdx.y, tid=threadIdx.x;
  __shared__ float a[512];
  for (int i=tid;i<512;i+=256) a[i]=att[((long)s*32+b)*512+i];
  __syncthreads();
  for (int d=tid; d<300; d+=256){
    float acc=0.f;
    for (int t=0;t<512;t++) acc += a[t]*DH[((long)b*512+t)*300+d];
    outp[((long)s*32+b)*300+d]=acc;
  }
}

// ---------------- masked softmax over l=50 (in place) ----------------
__global__ void k_masksm(float* __restrict__ att, long nrows){
  long row = (long)blockIdx.x*256 + threadIdx.x;
  if (row >= nrows) return;
  float* p = att + row*50;
  float m = -INFINITY;
  for (int l=0;l<50;l++){ float a = p[l]; if (a != 0.f && a > m) m = a; }
  if (m == -INFINITY){ for (int l=0;l<50;l++) p[l] = 0.f; return; }
  float s = 0.f;
  for (int l=0;l<50;l++){ float a = p[l]; float e = (a==0.f) ? 0.f : expf(a-m); p[l]=e; s+=e; }
  float inv = 1.f/s;
  for (int l=0;l<50;l++) p[l] *= inv;
}

// ---------------- fact separation combine (rows of 300), 1 wave per row ----------------
// NOTE: no __restrict__ — call 2 intentionally aliases simOut=scen, diffOut=circ.
__global__ void k_factsep(const float* circ, const float* scen,
                          float* simOut, float* diffOut, long nrows)
{
  int lane = threadIdx.x & 63;
  long row = (long)blockIdx.x*4 + (threadIdx.x >> 6);
  if (row >= nrows) return;
  const float* c = circ + row*300;
  const float* s = scen + row*300;
  float x3=0.f, x4=0.f;
  for (int d=lane; d<300; d+=64){ float sv=s[d]; x3 += c[d]*sv; x4 += sv*sv; }
  for (int o=32;o>0;o>>=1){ x3 += __shfl_down(x3,o); x4 += __shfl_down(x4,o); }
  x3 = __shfl(x3,0); x4 = __shfl(x4,0);
  float coef = x3 / (x4 + 1e-10f);
  for (int d=lane; d<300; d+=64){
    float sv = s[d]; float cv = c[d];
    float sim = coef*sv;
    simOut[row*300+d] = sim;
    diffOut[row*300+d] = cv - sim;
  }
}

// ---------------- assemblers ----------------
__global__ void k_factart(const float* __restrict__ DH, const float* __restrict__ dha,
                          const float* __restrict__ adc, const float* __restrict__ db,
                          float* __restrict__ out)
{
  long row = blockIdx.x; int b = (int)(row >> 9);
  for (int c=threadIdx.x; c<1200; c+=256){
    float v;
    if (c < 300) v = DH[row*300 + c];
    else if (c < 600) v = dha[(long)b*300 + (c-300)];
    else if (c < 900) v = adc[row*300 + (c-600)];
    else v = db[(long)b*300 + (c-900)];
    out[row*1200 + c] = v;
  }
}
__global__ void k_termcat(const float* __restrict__ DH, const float* __restrict__ ssc,
                          const float* __restrict__ dsc, float* __restrict__ out){
  long row = blockIdx.x;
  for (int c=threadIdx.x; c<900; c+=256){
    float v = (c<300) ? DH[row*300+c] : (c<600 ? ssc[row*300+(c-300)] : dsc[row*300+(c-600)]);
    out[row*900+c] = v;
  }
}

// ---------------- classifier: logits -> fp32 out, optional argmax ----------------
__global__ __launch_bounds__(256) void k_classify(
    const float* __restrict__ s0, const float* __restrict__ s1, const float* __restrict__ s2,
    int L, int Kf, float scale,
    const float* __restrict__ W, const float* __restrict__ bias, int N,
    float* __restrict__ out, int* __restrict__ amax)
{
  int b = blockIdx.x; int tid = threadIdx.x;
  __shared__ float feat[1200];
  __shared__ float logit[128];
  for (int i=tid; i<Kf; i+=256){
    int seg = i / L, c = i % L;
    const float* s = (seg==0) ? s0 : (seg==1 ? s1 : s2);
    feat[i] = s[(long)b*L + c] * scale;
  }
  __syncthreads();
  for (int n=tid; n<N; n+=256){
    float acc = bias[n];
    const float* w = W + (long)n*Kf;
    for (int k=0;k<Kf;k++) acc += feat[k]*w[k];
    out[(long)b*N + n] = acc;
    logit[n] = acc;
  }
  __syncthreads();
  if (amax && tid==0){
    float best = logit[0]; int bi=0;
    for (int n=1;n<N;n++) if (logit[n] > best){ best=logit[n]; bi=n; }
    amax[b] = bi;
  }
}

static inline int cdiv(long a, long b){ return (int)((a + b - 1)/b); }

extern "C" void kernel_launch(void* const* d_in, const int* in_sizes, int n_in,
                              void* d_out, int out_size, void* d_ws, size_t ws_size,
                              hipStream_t stream)
{
  (void)in_sizes; (void)n_in; (void)out_size;
  const float* emb     = (const float*)d_in[0];
  const float* encWih  = (const float*)d_in[1];
  const float* encWhh  = (const float*)d_in[2];
  const float* encbih  = (const float*)d_in[3];
  const float* encbhh  = (const float*)d_in[4];
  const float* cchWih  = (const float*)d_in[5];
  const float* cchWhh  = (const float*)d_in[6];
  const float* cchbih  = (const float*)d_in[7];
  const float* cchbhh  = (const float*)d_in[8];
  const float* termWih = (const float*)d_in[9];
  const float* termWhh = (const float*)d_in[10];
  const float* termbih = (const float*)d_in[11];
  const float* termbhh = (const float*)d_in[12];
  const float* artWih  = (const float*)d_in[13];
  const float* artWhh  = (const float*)d_in[14];
  const float* artbih  = (const float*)d_in[15];
  const float* artbhh  = (const float*)d_in[16];
  const float* Wc      = (const float*)d_in[17];
  const float* bc      = (const float*)d_in[18];
  const float* Wa      = (const float*)d_in[19];
  const float* ba      = (const float*)d_in[20];
  const float* Wt_     = (const float*)d_in[21];
  const float* bt_     = (const float*)d_in[22];
  const int* docs    = (const int*)d_in[23];
  const int* chtok   = (const int*)d_in[24];
  const int* artok   = (const int*)d_in[25];
  const int* chnb    = (const int*)d_in[26];
  const int* chnbm   = (const int*)d_in[27];
  const int* arnb    = (const int*)d_in[28];
  const int* arnbm   = (const int*)d_in[29];
  const int* vchtok  = (const int*)d_in[30];
  const int* vartok  = (const int*)d_in[31];
  float* ob = (float*)d_out;
  float* ws = (float*)d_ws;

  // -------- workspace layout (float elements) --------
  constexpr long O_WTENC = 0;                       // 2*150*450
  constexpr long O_WTCCH = O_WTENC + 135000;        // 2*150*450
  constexpr long O_WTART = O_WTCCH + 135000;        // (spare)
  constexpr long O_WTTERM= O_WTART + 2160000;       // (spare)
  constexpr long O_DH    = O_WTTERM + 1215000;      // 16384*300
  constexpr long O_DMEAN = O_DH + 4915200;          // 32*300
  constexpr long O_CHM   = O_DMEAN + 9600;          // 119*300
  constexpr long O_ARM   = O_CHM + 35700;           // 103*300
  constexpr long O_LAB   = O_ARM + 30900;           // 444*300
  constexpr long O_GDT   = O_LAB + 133200;          // 119*300 (barrier ints after decomp)
  constexpr long O_CWM   = O_GDT + 35700;           // 4*16384
  constexpr long O_CWA   = O_CWM + 65536;           // 4*32*512
  constexpr long O_CWO   = O_CWA + 65536;           // 4*32*300
  constexpr long O_CP    = O_CWO + 38400;           // 64 ints
  constexpr long O_VCH   = O_CP + 64;               // 32*50*300
  constexpr long O_VCHT  = O_VCH + 480000;          // 32*300*50
  constexpr long O_ATT   = O_VCHT + 480000;         // 32*512*50
  constexpr long O_SCEN  = O_ATT + 819200;          // 16384*300
  constexpr long O_ADC   = O_SCEN + 4915200;        // 16384*300
  constexpr long O_SEC   = O_ADC + 4915200;         // 16384*300
  constexpr long O_HBUF  = O_SEC + 4915200;         // h ping-pong 2*38400
  constexpr long O_YSUM  = O_HBUF + 76800;          // 32*1200
  constexpr long O_GATH  = O_YSUM + 38400;          // 16384*200
  constexpr long O_XSS   = O_GATH + 3276800;        // 2*6592*450
  constexpr long O_PF    = O_XSS + 5932800;         // 16384*1200
  constexpr long O_XB    = O_PF + 19660800;         // 2*16384*1800
  constexpr long TOTAL   = O_XB + 58982400;         // ~454 MB
  if (ws_size < (size_t)TOTAL * 4) return;

  float* WT_ENC = ws + O_WTENC;
  float* WT_CCH = ws + O_WTCCH;
  float* DH     = ws + O_DH;
  float* DMEAN  = ws + O_DMEAN;
  float* CHM    = ws + O_CHM;
  float* ARM    = ws + O_ARM;
  float* LAB    = ws + O_LAB;
  float* GDT    = ws + O_GDT;
  float* CWM    = ws + O_CWM;
  float* CWA    = ws + O_CWA;
  float* CWO    = ws + O_CWO;
  int*   CP     = (int*)(ws + O_CP);
  int*   AP     = CP + 32;
  float* VCH    = ws + O_VCH;
  float* VCHT   = ws + O_VCHT;
  float* ATT    = ws + O_ATT;
  float* SCEN   = ws + O_SCEN;
  float* ADC    = ws + O_ADC;
  float* SEC    = ws + O_SEC;
  float* HBUF   = ws + O_HBUF;
  float* YSUM   = ws + O_YSUM;
  float* GATH   = ws + O_GATH;
  float* XSS    = ws + O_XSS;
  float* PF     = ws + O_PF;
  float* XB     = ws + O_XB;
  int*   FLAGS  = (int*)GDT;       // free after graph decomposition
  int*   GO     = FLAGS + 256;     // 4 quadrant go-words on separate lines

  // -------- transpose small Whh --------
  k_transpose<<<dim3(cdiv(450L*150,256),2),256,0,stream>>>(encWhh, WT_ENC, 450,150);
  k_transpose<<<dim3(cdiv(450L*150,256),2),256,0,stream>>>(cchWhh, WT_CCH, 450,150);

  // -------- charge token encoder (encch), mean only --------
  k_gather<<<3808,256,0,stream>>>(emb, chtok, GATH);
  k_gemm128<<<dim3(4,cdiv(3808,128),2),256,0,stream>>>(GATH, cchWih, cchbih, XSS,
      3808,450,200, 0, 450L*200, 3808L*450, 450);
  k_gru_small<<<dim3(119,2),512,0,stream>>>(XSS, 3808L*450, WT_CCH, cchbhh,
      nullptr,0, CHM,300, 32);

  // -------- article token encoder (encch), mean only --------
  k_gather<<<6592,256,0,stream>>>(emb, artok, GATH);
  k_gemm128<<<dim3(4,cdiv(6592,128),2),256,0,stream>>>(GATH, cchWih, cchbih, XSS,
      6592,450,200, 0, 450L*200, 6592L*450, 450);
  k_gru_small<<<dim3(103,2),512,0,stream>>>(XSS, 6592L*450, WT_CCH, cchbhh,
      nullptr,0, ARM,300, 64);

  // -------- originals + graph decomposition into label-cat --------
  k_copy<<<cdiv(35700,256),256,0,stream>>>(CHM, LAB + 119L*300, 35700);
  k_copy<<<cdiv(30900,256),256,0,stream>>>(ARM, LAB + 341L*300, 30900);
  k_graphdecomp<<<119,256,0,stream>>>(CHM, GDT, chnb, chnbm, 119);
  k_graphdecomp<<<119,256,0,stream>>>(GDT, LAB, chnb, chnbm, 119);
  k_graphdecomp<<<103,256,0,stream>>>(ARM, GDT, arnb, arnbm, 103);
  k_graphdecomp<<<103,256,0,stream>>>(GDT, LAB + 238L*300, arnb, arnbm, 103);

  // -------- document encoder (enc) -> d_hidden + doc_mean --------
  k_gather<<<16384,256,0,stream>>>(emb, docs, GATH);
  k_gemm128<<<dim3(4,128,2),256,0,stream>>>(GATH, encWih, encbih, PF,
      16384,450,200, 0, 450L*200, 16384L*450, 450);
  k_gru_small<<<dim3(32,2),512,0,stream>>>(PF, 16384L*450, WT_ENC, encbhh,
      DH,300, DMEAN,300, 512);

  // -------- code_wise (4 label sets at once) --------
  k_gemm128<<<dim3(4,128,1),256,0,stream>>>(DH, LAB, nullptr, PF,
      16384,444,300, 0,0,0, 0);
  k_cw_rowmax<<<dim3(64,4),256,0,stream>>>(PF, CWM);
  k_cw_softmax<<<dim3(32,4),256,0,stream>>>(CWM, CWA);
  k_cw_out<<<dim3(32,4),256,0,stream>>>(CWA, DH, CWO);

  // -------- charge classifier + argmax --------
  k_classify<<<32,256,0,stream>>>(DMEAN, CWO, CWO + 32L*300,
      300, 900, 1.f, Wc, bc, 119, ob, CP);

  // -------- verdict-charge GRU (enc) --------
  k_gather_sel<<<dim3(50,32),256,0,stream>>>(emb, vchtok, CP, GATH);
  k_gemm128<<<dim3(4,13,2),256,0,stream>>>(GATH, encWih, encbih, XSS,
      1600,450,200, 0, 450L*200, 1600L*450, 450);
  k_gru_small<<<dim3(32,2),512,0,stream>>>(XSS, 1600L*450, WT_ENC, encbhh,
      VCH,300, nullptr,0, 50);

  // -------- fact separation 1 (vch vs d_hidden) --------
  k_gemm128<<<dim3(1,4,32),256,0,stream>>>(DH, VCH, nullptr, ATT,
      512,50,300, 512L*300, 50L*300, 512L*50, 0);
  k_masksm<<<64,256,0,stream>>>(ATT, 16384);
  k_transpose<<<dim3(cdiv(15000,256),32),256,0,stream>>>(VCH, VCHT, 50, 300);
  k_gemm128<<<dim3(3,4,32),256,0,stream>>>(ATT, VCHT, nullptr, SCEN,
      512,300,50, 512L*50, 300L*50, 512L*300, 0);
  k_factsep<<<4096,256,0,stream>>>(DH, SCEN, ADC, SEC, 16384);

  // -------- fact_article + art bigru (persistent, leader-go barrier) --------
  k_factart<<<16384,256,0,stream>>>(DH, CWO + 2L*32*300, ADC, CWO + 3L*32*300, PF);
  k_gemm128<<<dim3(cdiv(1800,128),128,2),256,0,stream>>>(PF, artWih, artbih, XB,
      16384,1800,1200, 0, 1800L*1200, 16384L*1800, 1800);
  hipMemsetAsync(FLAGS, 0, 512*sizeof(int), stream);
  hipMemsetAsync(HBUF, 0, 38400*sizeof(float), stream);
  // art: H=600, KP=600, LDW=604, HPAD=604, KL=100, NCB=60 -> 240 wgs
  k_gru_persist<600,600,604,604,100,60><<<240,256,0,stream>>>(
      XB, 16384L*1800, artWhh, artbhh, HBUF, HBUF+38400, YSUM, 1200, 512, FLAGS, GO);
  k_classify<<<32,256,0,stream>>>(YSUM, nullptr, nullptr,
      1200, 1200, 1.f/512.f, Wa, ba, 103, ob + 3808, AP);

  // -------- verdict-article GRU (enc) --------
  k_gather_sel<<<dim3(50,32),256,0,stream>>>(emb, vartok, AP, GATH);
  k_gemm128<<<dim3(4,13,2),256,0,stream>>>(GATH, encWih, encbih, XSS,
      1600,450,200, 0, 450L*200, 1600L*450, 450);
  k_gru_small<<<dim3(32,2),512,0,stream>>>(XSS, 1600L*450, WT_ENC, encbhh,
      VCH,300, nullptr,0, 50);

  // -------- fact separation 2 (var vs sec); ssc->SCEN, dsc->SEC in place --------
  k_gemm128<<<dim3(1,4,32),256,0,stream>>>(SEC, VCH, nullptr, ATT,
      512,50,300, 512L*300, 50L*300, 512L*50, 0);
  k_masksm<<<64,256,0,stream>>>(ATT, 16384);
  k_transpose<<<dim3(cdiv(15000,256),32),256,0,stream>>>(VCH, VCHT, 50, 300);
  k_gemm128<<<dim3(3,4,32),256,0,stream>>>(ATT, VCHT, nullptr, SCEN,
      512,300,50, 512L*50, 300L*50, 512L*300, 0);
  k_factsep<<<4096,256,0,stream>>>(SEC, SCEN, SCEN, SEC, 16384);

  // -------- term bigru (persistent, leader-go barrier) --------
  k_termcat<<<16384,256,0,stream>>>(DH, SCEN, SEC, PF);
  k_gemm128<<<dim3(cdiv(1350,128),128,2),256,0,stream>>>(PF, termWih, termbih, XB,
      16384,1350,900, 0, 1350L*900, 16384L*1350, 1350);
  hipMemsetAsync(FLAGS, 0, 512*sizeof(int), stream);
  hipMemsetAsync(HBUF, 0, 38400*sizeof(float), stream);
  // term: H=450, KP=456, LDW=460, HPAD=460, KL=76, NCB=45 -> 180 wgs
  k_gru_persist<450,456,460,460,76,45><<<180,256,0,stream>>>(
      XB, 16384L*1350, termWhh, termbhh, HBUF, HBUF+38400, YSUM, 900, 512, FLAGS, GO);
  k_classify<<<32,256,0,stream>>>(YSUM, nullptr, nullptr,
      900, 900, 1.f/512.f, Wt_, bt_, 11, ob + 7104, nullptr);
}

// Round 8
// 14996.645 us; speedup vs baseline: 5.6371x; 1.2280x over previous
//
#include <hip/hip_runtime.h>
#include <hip/hip_bf16.h>

#define DEVI __device__ __forceinline__

DEVI float sigm(float x){ return 1.f/(1.f+expf(-x)); }

typedef int v4i __attribute__((ext_vector_type(4)));
typedef float f4 __attribute__((ext_vector_type(4)));

// SRSRC for raw untyped dword access (stride=0, num_records=bytes)
DEVI v4i make_srsrc(const void* p, unsigned bytes){
  unsigned long long a = (unsigned long long)p;
  v4i r;
  r.x = (int)(a & 0xFFFFFFFFull);
  r.y = (int)((a >> 32) & 0xFFFFull);
  r.z = (int)bytes;
  r.w = 0x00020000;
  return r;
}

// ---------------- transpose: out[b][c][r] = in[b][r][c] ----------------
__global__ void k_transpose(const float* __restrict__ in, float* __restrict__ out, int R, int C){
  int b = blockIdx.y;
  long n = (long)R*C;
  long i = (long)blockIdx.x*256 + threadIdx.x;
  if (i < n){
    int r = (int)(i / C), c = (int)(i % C);
    out[(long)b*n + (long)c*R + r] = in[(long)b*n + i];
  }
}

// ---------------- embedding gathers (D=200) ----------------
__global__ void k_gather(const float* __restrict__ emb, const int* __restrict__ tok, float* __restrict__ out){
  int row = blockIdx.x; int c = threadIdx.x;
  if (c < 200) out[(long)row*200 + c] = emb[(long)tok[row]*200 + c];
}
__global__ void k_gather_sel(const float* __restrict__ emb, const int* __restrict__ tok, const int* __restrict__ sel, float* __restrict__ out){
  int t = blockIdx.x, b = blockIdx.y; int c = threadIdx.x;
  if (c < 200){
    int tk = tok[(long)sel[b]*50 + t];
    out[((long)b*50 + t)*200 + c] = emb[(long)tk*200 + c];
  }
}

// ---------------- fp32 GEMM 128x128 tile, 8x8 micro: C = A(M,K) @ W(N,K)^T + bias ----------------
__global__ __launch_bounds__(256) void k_gemm128(
    const float* __restrict__ A, const float* __restrict__ W,
    const float* __restrict__ bias, float* __restrict__ C,
    int M, int N, int K, long sA, long sW, long sC, long sBias)
{
  int bz = blockIdx.z;
  A += (long)bz*sA; W += (long)bz*sW; C += (long)bz*sC;
  if (bias) bias += (long)bz*sBias;
  int n0 = blockIdx.x*128, m0 = blockIdx.y*128;
  __shared__ float As[16][132];
  __shared__ float Bs[16][132];
  int tid = threadIdx.x;
  int tx = tid & 15, ty = tid >> 4;
  float acc[8][8] = {};
  const bool k4 = ((K & 3) == 0);
  for (int k0 = 0; k0 < K; k0 += 16){
    #pragma unroll
    for (int half = 0; half < 2; half++){
      int s = tid + half*256;
      int r = s >> 2;
      int kq = (s & 3) << 2;
      int k = k0 + kq;
      int m = m0 + r;
      float4 va = make_float4(0.f,0.f,0.f,0.f);
      if (m < M){
        if (k4 && k + 3 < K) va = *(const float4*)&A[(long)m*K + k];
        else {
          float* pv = (float*)&va;
          #pragma unroll
          for (int u=0; u<4; u++) if (k+u < K) pv[u] = A[(long)m*K + k + u];
        }
      }
      As[kq+0][r]=va.x; As[kq+1][r]=va.y; As[kq+2][r]=va.z; As[kq+3][r]=va.w;
      int n = n0 + r;
      float4 vb = make_float4(0.f,0.f,0.f,0.f);
      if (n < N){
        if (k4 && k + 3 < K) vb = *(const float4*)&W[(long)n*K + k];
        else {
          float* pv = (float*)&vb;
          #pragma unroll
          for (int u=0; u<4; u++) if (k+u < K) pv[u] = W[(long)n*K + k + u];
        }
      }
      Bs[kq+0][r]=vb.x; Bs[kq+1][r]=vb.y; Bs[kq+2][r]=vb.z; Bs[kq+3][r]=vb.w;
    }
    __syncthreads();
    #pragma unroll
    for (int kk=0;kk<16;kk++){
      float a[8], b[8];
      *(float4*)&a[0] = *(const float4*)&As[kk][ty*8];
      *(float4*)&a[4] = *(const float4*)&As[kk][ty*8+4];
      *(float4*)&b[0] = *(const float4*)&Bs[kk][tx*8];
      *(float4*)&b[4] = *(const float4*)&Bs[kk][tx*8+4];
      #pragma unroll
      for (int i=0;i<8;i++)
        #pragma unroll
        for (int j=0;j<8;j++)
          acc[i][j] += a[i]*b[j];
    }
    __syncthreads();
  }
  #pragma unroll
  for (int i=0;i<8;i++){
    int m = m0 + ty*8 + i;
    if (m >= M) continue;
    #pragma unroll
    for (int j=0;j<8;j++){
      int n = n0 + tx*8 + j;
      if (n < N) C[(long)m*N + n] = acc[i][j] + (bias ? bias[n] : 0.f);
    }
  }
}

// ---------------- small GRU (h=150, 3h=450), 1 wg per (item,dir) ----------------
__global__ __launch_bounds__(512) void k_gru_small(
    const float* __restrict__ xs, long xsDir,
    const float* __restrict__ Wt, const float* __restrict__ bhh,
    float* __restrict__ y, int yld,
    float* __restrict__ meanOut, int meanld,
    int T)
{
  int item = blockIdx.x, dir = blockIdx.y;
  const float* xsd = xs + (long)dir*xsDir + (long)item*T*450;
  const float* Wtd = Wt + (long)dir*150*450;
  int tid = threadIdx.x;
  float bh = (tid < 450) ? bhh[(long)dir*450 + tid] : 0.f;
  __shared__ float hs[152];
  __shared__ float gs[456];
  if (tid < 150) hs[tid] = 0.f;
  float hsum = 0.f;
  __syncthreads();
  for (int t=0;t<T;t++){
    int tt = dir ? (T-1-t) : t;
    if (tid < 450){
      float g = bh;
      const float* wp = Wtd + tid;
      #pragma unroll 5
      for (int k=0;k<150;k++) g += hs[k] * wp[(long)k*450];
      gs[tid] = g;
    }
    __syncthreads();
    if (tid < 150){
      const float* xr = xsd + (long)tt*450;
      float r = sigm(xr[tid]     + gs[tid]);
      float z = sigm(xr[150+tid] + gs[150+tid]);
      float nn = tanhf(xr[300+tid] + r*gs[300+tid]);
      float h = (1.f-z)*nn + z*hs[tid];
      hs[tid] = h;
      hsum += h;
      if (y) y[((long)item*T + tt)*yld + dir*150 + tid] = h;
    }
    __syncthreads();
  }
  if (meanOut && tid < 150)
    meanOut[(long)item*meanld + dir*150 + tid] = hsum / (float)T;
}

// ---------------- persistent big GRU, fence-free relaxed-atomic exchange ----------------
// wid -> (dir, bb of 16 items, cb of 10 h-cols). Weights LDS-resident (loaded once).
// h exchange: stores = 4B relaxed agent atomics (write-through); loads = 16B
// buffer_load_dwordx4 sc0 sc1 (cache-bypassing, system-scope-coherent) — halves the
// coherent-load transaction count vs 8B atomics. h buffers use row stride HS (>=H,
// 16B-aligned rows; pad zeroed once by host-side memset, matching zero-padded Wl).
// Barrier: leader-go per (dir,bb) quadrant, monotonic flags, relaxed atomics only.
#define GDOT(AC, W, A) AC += W.x*A.x + W.y*A.y + W.z*A.z + W.w*A.w;
template<int H, int HS, int LDW, int HPAD, int KL, int NCB>
__global__ __launch_bounds__(256) void k_gru_persist(
    const float* __restrict__ xs, long xsDir,
    const float* __restrict__ Whh, const float* __restrict__ bhh,
    float* hA, float* hB,
    float* __restrict__ ysum, int ysld,
    int T, int* flags, int* go)
{
  constexpr int H3 = 3*H;
  constexpr int CPR = HS/4;              // 16B chunks per item row
  constexpr int NCH = 16*CPR;            // chunks per step per wg
  constexpr int NIT = (NCH + 255)/256;   // chunks per thread (static)
  int wid = blockIdx.x;
  int dir = wid / (2*NCB);
  int rem = wid % (2*NCB);
  int bb  = rem / NCB;
  int cb  = rem % NCB;
  int quad = dir*2 + bb;
  int qbase = quad*64;
  int c0  = cb*10;
  int tid = threadIdx.x;

  const float* xsd = xs + (long)dir*xsDir;
  const float* Wd  = Whh + (long)dir*(long)H*H3;   // [3H][H] row-major
  const float* bhd = bhh + (long)dir*H3;

  __shared__ float hs[16*HPAD];
  __shared__ float Wl[30*LDW];
  __shared__ float blds[32];
  __shared__ float gl[30*16];
  __shared__ float part[240*12];

  // ---- load this wg's 30 gate-row weights into LDS ONCE (zero-pad k in [H,HS)) ----
  for (int u = tid; u < 30*HS; u += 256){
    int r = u / HS, k = u % HS;
    long row = (long)(r/10)*H + c0 + (r%10);
    Wl[r*LDW + k] = (k < H) ? Wd[row*H + k] : 0.f;
  }
  if (tid < 30) blds[tid] = bhd[(long)(tid/10)*H + (c0 + tid%10)];

  // compute mapping: tid = ks*40 + rg*4 + ig  (ks 0..5, rg 0..9, ig 0..3)
  int ks = tid / 40;
  int rem2 = tid % 40;
  int rg = rem2 / 4;
  int ig = rem2 % 4;
  bool alive = (tid < 240);
  int r0 = rg*3;
  int it0 = ig*4;
  int kbase = ks*KL;

  // update mapping (tid<160): item uit, col uci
  int uit = tid / 10, uci = tid % 10;
  int uc = c0 + uci;
  int ub = bb*16 + uit;
  float ysacc = 0.f;

  // ---- prologue: prefetch x for t=0 ----
  float xv0 = 0.f, xv1 = 0.f, xv2 = 0.f;
  if (tid < 160){
    int tt0 = dir ? (T-1) : 0;
    const float* xr = xsd + ((long)ub*T + tt0)*H3;
    xv0 = xr[uc]; xv1 = xr[H+uc]; xv2 = xr[2*H+uc];
  }

  __syncthreads();

  for (int t=0; t<T; t++){
    float* hp = ((t & 1) ? hB : hA) + (long)dir*32*HS;
    float* hn = ((t & 1) ? hA : hB) + (long)dir*32*HS;

    // ---- stage h slice [16][HS] via 16B cache-bypassing buffer loads ----
    {
      v4i srsrc = make_srsrc(hp, 32u*HS*4u);
      f4 sbuf[NIT];
      #pragma unroll
      for (int i = 0; i < NIT; i++){
        int u = tid + i*256;
        if (u < NCH){
          int voff = ((bb*16 + u/CPR)*HS + (u%CPR)*4)*4;
          asm volatile("buffer_load_dwordx4 %0, %1, %2, 0 offen sc0 sc1"
                       : "=v"(sbuf[i]) : "v"(voff), "s"(srsrc));
        }
      }
      asm volatile("s_waitcnt vmcnt(0)" ::: "memory");
      __builtin_amdgcn_sched_barrier(0);
      #pragma unroll
      for (int i = 0; i < NIT; i++){
        int u = tid + i*256;
        if (u < NCH)
          *(f4*)&hs[(u/CPR)*HPAD + (u%CPR)*4] = sbuf[i];
      }
    }
    __syncthreads();

    // ---- gate GEMM partials: 3 rows x 4 items x KL ----
    if (alive){
      float acc[3][4];
      #pragma unroll
      for (int a=0;a<3;a++)
        #pragma unroll
        for (int b=0;b<4;b++) acc[a][b] = 0.f;
      const float* wr0 = &Wl[(r0+0)*LDW + kbase];
      const float* wr1 = &Wl[(r0+1)*LDW + kbase];
      const float* wr2 = &Wl[(r0+2)*LDW + kbase];
      const float* h0  = &hs[(it0+0)*HPAD + kbase];
      const float* h1  = &hs[(it0+1)*HPAD + kbase];
      const float* h2  = &hs[(it0+2)*HPAD + kbase];
      const float* h3  = &hs[(it0+3)*HPAD + kbase];
      for (int jq = 0; jq < KL; jq += 4){
        float4 w0 = *(const float4*)&wr0[jq];
        float4 w1 = *(const float4*)&wr1[jq];
        float4 w2 = *(const float4*)&wr2[jq];
        float4 a0 = *(const float4*)&h0[jq];
        float4 a1 = *(const float4*)&h1[jq];
        float4 a2 = *(const float4*)&h2[jq];
        float4 a3 = *(const float4*)&h3[jq];
        GDOT(acc[0][0], w0, a0) GDOT(acc[0][1], w0, a1) GDOT(acc[0][2], w0, a2) GDOT(acc[0][3], w0, a3)
        GDOT(acc[1][0], w1, a0) GDOT(acc[1][1], w1, a1) GDOT(acc[1][2], w1, a2) GDOT(acc[1][3], w1, a3)
        GDOT(acc[2][0], w2, a0) GDOT(acc[2][1], w2, a1) GDOT(acc[2][2], w2, a2) GDOT(acc[2][3], w2, a3)
      }
      #pragma unroll
      for (int a=0;a<3;a++)
        *(float4*)&part[tid*12 + a*4] = make_float4(acc[a][0],acc[a][1],acc[a][2],acc[a][3]);
    }
    __syncthreads();

    // ---- k-reduce 6 partials -> gl[30][16] ----
    if (alive){
      #pragma unroll
      for (int vv=0; vv<2; vv++){
        int v = tid + vv*240;               // 0..479
        int row = v >> 4, item = v & 15;
        int base = ((row/3)*4 + (item>>2))*12 + (row%3)*4 + (item&3);
        float sum = blds[row];
        #pragma unroll
        for (int s=0; s<6; s++) sum += part[s*480 + base];
        gl[row*16 + item] = sum;
      }
    }
    __syncthreads();

    // ---- GRU update; h stores are write-through relaxed atomics ----
    if (tid < 160){
      float r  = sigm(xv0 + gl[(uci)*16    + uit]);
      float z  = sigm(xv1 + gl[(10+uci)*16 + uit]);
      float nn = tanhf(xv2 + r*gl[(20+uci)*16 + uit]);
      float hv = hs[uit*HPAD + uc];
      float hne = (1.f-z)*nn + z*hv;
      __hip_atomic_store(&hn[(long)ub*HS + uc], hne, __ATOMIC_RELAXED, __HIP_MEMORY_SCOPE_AGENT);
      ysacc += hne;
    }
    __syncthreads();   // drains vmcnt(0): hn write-through stores are globally visible

    // ---- prefetch next step's x (independent of h; hides under barrier) ----
    float nx0 = 0.f, nx1 = 0.f, nx2 = 0.f;
    if (tid < 160 && t+1 < T){
      int tt1 = dir ? (T-2-t) : (t+1);
      const float* xr = xsd + ((long)ub*T + tt1)*H3;
      nx0 = xr[uc]; nx1 = xr[H+uc]; nx2 = xr[2*H+uc];
    }

    // ---- leader-go quadrant barrier (monotonic, relaxed atomics only) ----
    if (t+1 < T){
      if (tid == 0)
        __hip_atomic_store(&flags[qbase + cb], t+1, __ATOMIC_RELAXED, __HIP_MEMORY_SCOPE_AGENT);
      if (cb == 0){
        if (tid < NCB){
          while (__hip_atomic_load(&flags[qbase + tid], __ATOMIC_RELAXED, __HIP_MEMORY_SCOPE_AGENT) < t+1)
            __builtin_amdgcn_s_sleep(2);
        }
        __syncthreads();
        if (tid == 0)
          __hip_atomic_store(&go[quad*32], t+1, __ATOMIC_RELAXED, __HIP_MEMORY_SCOPE_AGENT);
      } else {
        if (tid == 0){
          while (__hip_atomic_load(&go[quad*32], __ATOMIC_RELAXED, __HIP_MEMORY_SCOPE_AGENT) < t+1)
            __builtin_amdgcn_s_sleep(2);
        }
        __syncthreads();
      }
    }
    xv0 = nx0; xv1 = nx1; xv2 = nx2;
  }
  if (tid < 160)
    ysum[(long)ub*ysld + dir*H + uc] = ysacc;
}

// ---------------- graph decomposition layer (D=300, K=8) ----------------
__global__ __launch_bounds__(256) void k_graphdecomp(
   const float* __restrict__ labIn, float* __restrict__ labOut,
   const int* __restrict__ nb, const int* __restrict__ nbm, int N)
{
  int n = blockIdx.x; if (n >= N) return;
  int tid = threadIdx.x;
  __shared__ float ln[300];
  __shared__ float red[12];
  for (int d=tid; d<300; d+=256) ln[d] = labIn[(long)n*300+d];
  float deg = 0.f;
  for (int k=0;k<8;k++) deg += (float)nbm[n*8+k];
  float invdeg = 1.f / fmaxf(deg, 1.f);
  float acc0 = 0.f, acc1 = 0.f;
  __syncthreads();
  for (int k=0;k<8;k++){
    int j = nb[n*8+k];
    float mk = (float)nbm[n*8+k];
    const float* lj = labIn + (long)j*300;
    float p1=0.f, p2=0.f;
    for (int d=tid; d<300; d+=256){ float v = lj[d]; p1 += ln[d]*v; p2 += v*v; }
    for (int o=32;o>0;o>>=1){ p1 += __shfl_down(p1,o); p2 += __shfl_down(p2,o); }
    __syncthreads();
    int w = tid>>6, lane = tid&63;
    if (lane==0){ red[w]=p1; red[4+w]=p2; }
    __syncthreads();
    float x1 = red[0]+red[1]+red[2]+red[3];
    float x2 = red[4]+red[5]+red[6]+red[7];
    float coef = (x1 / (x2 + 1e-10f)) * mk * invdeg;
    acc0 += coef * lj[tid];
    if (tid + 256 < 300) acc1 += coef * lj[tid+256];
    __syncthreads();
  }
  bool pos = deg > 0.f;
  labOut[(long)n*300 + tid]                       = pos ? (ln[tid]     - acc0) : ln[tid];
  if (tid+256 < 300) labOut[(long)n*300 + tid+256] = pos ? (ln[tid+256] - acc1) : ln[tid+256];
}

// ---------------- copy ----------------
__global__ void k_copy(const float* __restrict__ src, float* __restrict__ dst, long n){
  long i = (long)blockIdx.x*256+threadIdx.x; if (i<n) dst[i]=src[i];
}

// ---------------- code_wise reductions ----------------
__global__ void k_cw_rowmax(const float* __restrict__ S, float* __restrict__ Mv){
  const int ofs[4]={0,119,238,341};
  const int wid[4]={119,119,103,103};
  int s = blockIdx.y; int row = blockIdx.x*256+threadIdx.x;
  if (row < 16384){
    const float* p = S + (long)row*444 + ofs[s];
    float m = -3.4e38f;
    int w = wid[s];
    for (int n=0;n<w;n++) m = fmaxf(m, p[n]);
    Mv[(long)s*16384+row] = m;
  }
}
__global__ void k_cw_softmax(const float* __restrict__ Mv, float* __restrict__ att){
  int b=blockIdx.x, s=blockIdx.y, tid=threadIdx.x;
  const float* src = Mv + (long)s*16384 + (long)b*512;
  __shared__ float red[256];
  float v0 = src[tid], v1 = src[tid+256];
  red[tid] = fmaxf(v0,v1); __syncthreads();
  for (int o=128;o>0;o>>=1){ if (tid<o) red[tid]=fmaxf(red[tid],red[tid+o]); __syncthreads(); }
  float m = red[0]; __syncthreads();
  float e0=expf(v0-m), e1=expf(v1-m);
  red[tid]=e0+e1; __syncthreads();
  for (int o=128;o>0;o>>=1){ if (tid<o) red[tid]+=red[tid+o]; __syncthreads(); }
  float inv = 1.f/red[0];
  float* dst = att + ((long)s*32 + b)*512;
  dst[tid]=e0*inv; dst[tid+256]=e1*inv;
}
__global__ void k_cw_out(const float* __restrict__ att, const float* __restrict__ DH, float* __restrict__ outp){
  int b=blockIdx.x, s=blockIdx.y, tid=threadIdx.x;
  __shared__ float a[512];
  for (int i=tid;i<512;i+=256) a[i]=att[((long)s*32+b)*512+i];
  __syncthreads();
  for (int d=tid; d<300; d+=256){
    float acc=0.f;
    for (int t=0;t<512;t++) acc += a[t]*DH[((long)b*512+t)*300+d];
    outp[((long)s*32+b)*300+d]=acc;
  }
}

// ---------------- masked softmax over l=50 (in place) ----------------
__global__ void k_masksm(float* __restrict__ att, long nrows){
  long row = (long)blockIdx.x*256 + threadIdx.x;
  if (row >= nrows) return;
  float* p = att + row*50;
  float m = -INFINITY;
  for (int l=0;l<50;l++){ float a = p[l]; if (a != 0.f && a > m) m = a; }
  if (m == -INFINITY){ for (int l=0;l<50;l++) p[l] = 0.f; return; }
  float s = 0.f;
  for (int l=0;l<50;l++){ float a = p[l]; float e = (a==0.f) ? 0.f : expf(a-m); p[l]=e; s+=e; }
  float inv = 1.f/s;
  for (int l=0;l<50;l++) p[l] *= inv;
}

// ---------------- fact separation combine (rows of 300), 1 wave per row ----------------
// NOTE: no __restrict__ — call 2 intentionally aliases simOut=scen, diffOut=circ.
__global__ void k_factsep(const float* circ, const float* scen,
                          float* simOut, float* diffOut, long nrows)
{
  int lane = threadIdx.x & 63;
  long row = (long)blockIdx.x*4 + (threadIdx.x >> 6);
  if (row >= nrows) return;
  const float* c = circ + row*300;
  const float* s = scen + row*300;
  float x3=0.f, x4=0.f;
  for (int d=lane; d<300; d+=64){ float sv=s[d]; x3 += c[d]*sv; x4 += sv*sv; }
  for (int o=32;o>0;o>>=1){ x3 += __shfl_down(x3,o); x4 += __shfl_down(x4,o); }
  x3 = __shfl(x3,0); x4 = __shfl(x4,0);
  float coef = x3 / (x4 + 1e-10f);
  for (int d=lane; d<300; d+=64){
    float sv = s[d]; float cv = c[d];
    float sim = coef*sv;
    simOut[row*300+d] = sim;
    diffOut[row*300+d] = cv - sim;
  }
}

// ---------------- assemblers ----------------
__global__ void k_factart(const float* __restrict__ DH, const float* __restrict__ dha,
                          const float* __restrict__ adc, const float* __restrict__ db,
                          float* __restrict__ out)
{
  long row = blockIdx.x; int b = (int)(row >> 9);
  for (int c=threadIdx.x; c<1200; c+=256){
    float v;
    if (c < 300) v = DH[row*300 + c];
    else if (c < 600) v = dha[(long)b*300 + (c-300)];
    else if (c < 900) v = adc[row*300 + (c-600)];
    else v = db[(long)b*300 + (c-900)];
    out[row*1200 + c] = v;
  }
}
__global__ void k_termcat(const float* __restrict__ DH, const float* __restrict__ ssc,
                          const float* __restrict__ dsc, float* __restrict__ out){
  long row = blockIdx.x;
  for (int c=threadIdx.x; c<900; c+=256){
    float v = (c<300) ? DH[row*300+c] : (c<600 ? ssc[row*300+(c-300)] : dsc[row*300+(c-600)]);
    out[row*900+c] = v;
  }
}

// ---------------- classifier: logits -> fp32 out, optional argmax ----------------
__global__ __launch_bounds__(256) void k_classify(
    const float* __restrict__ s0, const float* __restrict__ s1, const float* __restrict__ s2,
    int L, int Kf, float scale,
    const float* __restrict__ W, const float* __restrict__ bias, int N,
    float* __restrict__ out, int* __restrict__ amax)
{
  int b = blockIdx.x; int tid = threadIdx.x;
  __shared__ float feat[1200];
  __shared__ float logit[128];
  for (int i=tid; i<Kf; i+=256){
    int seg = i / L, c = i % L;
    const float* s = (seg==0) ? s0 : (seg==1 ? s1 : s2);
    feat[i] = s[(long)b*L + c] * scale;
  }
  __syncthreads();
  for (int n=tid; n<N; n+=256){
    float acc = bias[n];
    const float* w = W + (long)n*Kf;
    for (int k=0;k<Kf;k++) acc += feat[k]*w[k];
    out[(long)b*N + n] = acc;
    logit[n] = acc;
  }
  __syncthreads();
  if (amax && tid==0){
    float best = logit[0]; int bi=0;
    for (int n=1;n<N;n++) if (logit[n] > best){ best=logit[n]; bi=n; }
    amax[b] = bi;
  }
}

static inline int cdiv(long a, long b){ return (int)((a + b - 1)/b); }

extern "C" void kernel_launch(void* const* d_in, const int* in_sizes, int n_in,
                              void* d_out, int out_size, void* d_ws, size_t ws_size,
                              hipStream_t stream)
{
  (void)in_sizes; (void)n_in; (void)out_size;
  const float* emb     = (const float*)d_in[0];
  const float* encWih  = (const float*)d_in[1];
  const float* encWhh  = (const float*)d_in[2];
  const float* encbih  = (const float*)d_in[3];
  const float* encbhh  = (const float*)d_in[4];
  const float* cchWih  = (const float*)d_in[5];
  const float* cchWhh  = (const float*)d_in[6];
  const float* cchbih  = (const float*)d_in[7];
  const float* cchbhh  = (const float*)d_in[8];
  const float* termWih = (const float*)d_in[9];
  const float* termWhh = (const float*)d_in[10];
  const float* termbih = (const float*)d_in[11];
  const float* termbhh = (const float*)d_in[12];
  const float* artWih  = (const float*)d_in[13];
  const float* artWhh  = (const float*)d_in[14];
  const float* artbih  = (const float*)d_in[15];
  const float* artbhh  = (const float*)d_in[16];
  const float* Wc      = (const float*)d_in[17];
  const float* bc      = (const float*)d_in[18];
  const float* Wa      = (const float*)d_in[19];
  const float* ba      = (const float*)d_in[20];
  const float* Wt_     = (const float*)d_in[21];
  const float* bt_     = (const float*)d_in[22];
  const int* docs    = (const int*)d_in[23];
  const int* chtok   = (const int*)d_in[24];
  const int* artok   = (const int*)d_in[25];
  const int* chnb    = (const int*)d_in[26];
  const int* chnbm   = (const int*)d_in[27];
  const int* arnb    = (const int*)d_in[28];
  const int* arnbm   = (const int*)d_in[29];
  const int* vchtok  = (const int*)d_in[30];
  const int* vartok  = (const int*)d_in[31];
  float* ob = (float*)d_out;
  float* ws = (float*)d_ws;

  // -------- workspace layout (float elements) --------
  constexpr long O_WTENC = 0;                       // 2*150*450
  constexpr long O_WTCCH = O_WTENC + 135000;        // 2*150*450
  constexpr long O_WTART = O_WTCCH + 135000;        // (spare)
  constexpr long O_WTTERM= O_WTART + 2160000;       // (spare)
  constexpr long O_DH    = O_WTTERM + 1215000;      // 16384*300
  constexpr long O_DMEAN = O_DH + 4915200;          // 32*300
  constexpr long O_CHM   = O_DMEAN + 9600;          // 119*300
  constexpr long O_ARM   = O_CHM + 35700;           // 103*300
  constexpr long O_LAB   = O_ARM + 30900;           // 444*300
  constexpr long O_GDT   = O_LAB + 133200;          // 119*300 (barrier ints after decomp)
  constexpr long O_CWM   = O_GDT + 35700;           // 4*16384
  constexpr long O_CWA   = O_CWM + 65536;           // 4*32*512
  constexpr long O_CWO   = O_CWA + 65536;           // 4*32*300
  constexpr long O_CP    = O_CWO + 38400;           // 64 ints
  constexpr long O_VCH   = O_CP + 64;               // 32*50*300
  constexpr long O_VCHT  = O_VCH + 480000;          // 32*300*50
  constexpr long O_ATT   = O_VCHT + 480000;         // 32*512*50
  constexpr long O_SCEN  = O_ATT + 819200;          // 16384*300
  constexpr long O_ADC   = O_SCEN + 4915200;        // 16384*300
  constexpr long O_SEC   = O_ADC + 4915200;         // 16384*300
  constexpr long O_HBUF  = O_SEC + 4915200;         // h ping-pong (art 2*38400 / term 2*29184)
  constexpr long O_YSUM  = O_HBUF + 76800;          // 32*1200
  constexpr long O_GATH  = O_YSUM + 38400;          // 16384*200
  constexpr long O_XSS   = O_GATH + 3276800;        // 2*6592*450
  constexpr long O_PF    = O_XSS + 5932800;         // 16384*1200
  constexpr long O_XB    = O_PF + 19660800;         // 2*16384*1800
  constexpr long TOTAL   = O_XB + 58982400;         // ~454 MB
  if (ws_size < (size_t)TOTAL * 4) return;

  float* WT_ENC = ws + O_WTENC;
  float* WT_CCH = ws + O_WTCCH;
  float* DH     = ws + O_DH;
  float* DMEAN  = ws + O_DMEAN;
  float* CHM    = ws + O_CHM;
  float* ARM    = ws + O_ARM;
  float* LAB    = ws + O_LAB;
  float* GDT    = ws + O_GDT;
  float* CWM    = ws + O_CWM;
  float* CWA    = ws + O_CWA;
  float* CWO    = ws + O_CWO;
  int*   CP     = (int*)(ws + O_CP);
  int*   AP     = CP + 32;
  float* VCH    = ws + O_VCH;
  float* VCHT   = ws + O_VCHT;
  float* ATT    = ws + O_ATT;
  float* SCEN   = ws + O_SCEN;
  float* ADC    = ws + O_ADC;
  float* SEC    = ws + O_SEC;
  float* HBUF   = ws + O_HBUF;
  float* YSUM   = ws + O_YSUM;
  float* GATH   = ws + O_GATH;
  float* XSS    = ws + O_XSS;
  float* PF     = ws + O_PF;
  float* XB     = ws + O_XB;
  int*   FLAGS  = (int*)GDT;       // free after graph decomposition
  int*   GO     = FLAGS + 256;     // 4 quadrant go-words on separate lines

  // -------- transpose small Whh --------
  k_transpose<<<dim3(cdiv(450L*150,256),2),256,0,stream>>>(encWhh, WT_ENC, 450,150);
  k_transpose<<<dim3(cdiv(450L*150,256),2),256,0,stream>>>(cchWhh, WT_CCH, 450,150);

  // -------- charge token encoder (encch), mean only --------
  k_gather<<<3808,256,0,stream>>>(emb, chtok, GATH);
  k_gemm128<<<dim3(4,cdiv(3808,128),2),256,0,stream>>>(GATH, cchWih, cchbih, XSS,
      3808,450,200, 0, 450L*200, 3808L*450, 450);
  k_gru_small<<<dim3(119,2),512,0,stream>>>(XSS, 3808L*450, WT_CCH, cchbhh,
      nullptr,0, CHM,300, 32);

  // -------- article token encoder (encch), mean only --------
  k_gather<<<6592,256,0,stream>>>(emb, artok, GATH);
  k_gemm128<<<dim3(4,cdiv(6592,128),2),256,0,stream>>>(GATH, cchWih, cchbih, XSS,
      6592,450,200, 0, 450L*200, 6592L*450, 450);
  k_gru_small<<<dim3(103,2),512,0,stream>>>(XSS, 6592L*450, WT_CCH, cchbhh,
      nullptr,0, ARM,300, 64);

  // -------- originals + graph decomposition into label-cat --------
  k_copy<<<cdiv(35700,256),256,0,stream>>>(CHM, LAB + 119L*300, 35700);
  k_copy<<<cdiv(30900,256),256,0,stream>>>(ARM, LAB + 341L*300, 30900);
  k_graphdecomp<<<119,256,0,stream>>>(CHM, GDT, chnb, chnbm, 119);
  k_graphdecomp<<<119,256,0,stream>>>(GDT, LAB, chnb, chnbm, 119);
  k_graphdecomp<<<103,256,0,stream>>>(ARM, GDT, arnb, arnbm, 103);
  k_graphdecomp<<<103,256,0,stream>>>(GDT, LAB + 238L*300, arnb, arnbm, 103);

  // -------- document encoder (enc) -> d_hidden + doc_mean --------
  k_gather<<<16384,256,0,stream>>>(emb, docs, GATH);
  k_gemm128<<<dim3(4,128,2),256,0,stream>>>(GATH, encWih, encbih, PF,
      16384,450,200, 0, 450L*200, 16384L*450, 450);
  k_gru_small<<<dim3(32,2),512,0,stream>>>(PF, 16384L*450, WT_ENC, encbhh,
      DH,300, DMEAN,300, 512);

  // -------- code_wise (4 label sets at once) --------
  k_gemm128<<<dim3(4,128,1),256,0,stream>>>(DH, LAB, nullptr, PF,
      16384,444,300, 0,0,0, 0);
  k_cw_rowmax<<<dim3(64,4),256,0,stream>>>(PF, CWM);
  k_cw_softmax<<<dim3(32,4),256,0,stream>>>(CWM, CWA);
  k_cw_out<<<dim3(32,4),256,0,stream>>>(CWA, DH, CWO);

  // -------- charge classifier + argmax --------
  k_classify<<<32,256,0,stream>>>(DMEAN, CWO, CWO + 32L*300,
      300, 900, 1.f, Wc, bc, 119, ob, CP);

  // -------- verdict-charge GRU (enc) --------
  k_gather_sel<<<dim3(50,32),256,0,stream>>>(emb, vchtok, CP, GATH);
  k_gemm128<<<dim3(4,13,2),256,0,stream>>>(GATH, encWih, encbih, XSS,
      1600,450,200, 0, 450L*200, 1600L*450, 450);
  k_gru_small<<<dim3(32,2),512,0,stream>>>(XSS, 1600L*450, WT_ENC, encbhh,
      VCH,300, nullptr,0, 50);

  // -------- fact separation 1 (vch vs d_hidden) --------
  k_gemm128<<<dim3(1,4,32),256,0,stream>>>(DH, VCH, nullptr, ATT,
      512,50,300, 512L*300, 50L*300, 512L*50, 0);
  k_masksm<<<64,256,0,stream>>>(ATT, 16384);
  k_transpose<<<dim3(cdiv(15000,256),32),256,0,stream>>>(VCH, VCHT, 50, 300);
  k_gemm128<<<dim3(3,4,32),256,0,stream>>>(ATT, VCHT, nullptr, SCEN,
      512,300,50, 512L*50, 300L*50, 512L*300, 0);
  k_factsep<<<4096,256,0,stream>>>(DH, SCEN, ADC, SEC, 16384);

  // -------- fact_article + art bigru (persistent, 16B coherent staging) --------
  k_factart<<<16384,256,0,stream>>>(DH, CWO + 2L*32*300, ADC, CWO + 3L*32*300, PF);
  k_gemm128<<<dim3(cdiv(1800,128),128,2),256,0,stream>>>(PF, artWih, artbih, XB,
      16384,1800,1200, 0, 1800L*1200, 16384L*1800, 1800);
  hipMemsetAsync(FLAGS, 0, 512*sizeof(int), stream);
  hipMemsetAsync(HBUF, 0, 76800*sizeof(float), stream);
  // art: H=600, HS=600, LDW=604, HPAD=604, KL=100, NCB=60 -> 240 wgs
  k_gru_persist<600,600,604,604,100,60><<<240,256,0,stream>>>(
      XB, 16384L*1800, artWhh, artbhh, HBUF, HBUF+38400, YSUM, 1200, 512, FLAGS, GO);
  k_classify<<<32,256,0,stream>>>(YSUM, nullptr, nullptr,
      1200, 1200, 1.f/512.f, Wa, ba, 103, ob + 3808, AP);

  // -------- verdict-article GRU (enc) --------
  k_gather_sel<<<dim3(50,32),256,0,stream>>>(emb, vartok, AP, GATH);
  k_gemm128<<<dim3(4,13,2),256,0,stream>>>(GATH, encWih, encbih, XSS,
      1600,450,200, 0, 450L*200, 1600L*450, 450);
  k_gru_small<<<dim3(32,2),512,0,stream>>>(XSS, 1600L*450, WT_ENC, encbhh,
      VCH,300, nullptr,0, 50);

  // -------- fact separation 2 (var vs sec); ssc->SCEN, dsc->SEC in place --------
  k_gemm128<<<dim3(1,4,32),256,0,stream>>>(SEC, VCH, nullptr, ATT,
      512,50,300, 512L*300, 50L*300, 512L*50, 0);
  k_masksm<<<64,256,0,stream>>>(ATT, 16384);
  k_transpose<<<dim3(cdiv(15000,256),32),256,0,stream>>>(VCH, VCHT, 50, 300);
  k_gemm128<<<dim3(3,4,32),256,0,stream>>>(ATT, VCHT, nullptr, SCEN,
      512,300,50, 512L*50, 300L*50, 512L*300, 0);
  k_factsep<<<4096,256,0,stream>>>(SEC, SCEN, SCEN, SEC, 16384);

  // -------- term bigru (persistent, 16B coherent staging, HS=456 padded rows) --------
  k_termcat<<<16384,256,0,stream>>>(DH, SCEN, SEC, PF);
  k_gemm128<<<dim3(cdiv(1350,128),128,2),256,0,stream>>>(PF, termWih, termbih, XB,
      16384,1350,900, 0, 1350L*900, 16384L*1350, 1350);
  hipMemsetAsync(FLAGS, 0, 512*sizeof(int), stream);
  hipMemsetAsync(HBUF, 0, 76800*sizeof(float), stream);   // zeroes both buffers incl. row pads
  // term: H=450, HS=456, LDW=460, HPAD=460, KL=76, NCB=45 -> 180 wgs
  k_gru_persist<450,456,460,460,76,45><<<180,256,0,stream>>>(
      XB, 16384L*1350, termWhh, termbhh, HBUF, HBUF+29184, YSUM, 900, 512, FLAGS, GO);
  k_classify<<<32,256,0,stream>>>(YSUM, nullptr, nullptr,
      900, 900, 1.f/512.f, Wt_, bt_, 11, ob + 7104, nullptr);
}

// Round 9
// 14404.080 us; speedup vs baseline: 5.8690x; 1.0411x over previous
//
#include <hip/hip_runtime.h>
#include <hip/hip_bf16.h>

#define DEVI __device__ __forceinline__

DEVI float sigm(float x){ return 1.f/(1.f+expf(-x)); }

typedef int v4i __attribute__((ext_vector_type(4)));
typedef float f4 __attribute__((ext_vector_type(4)));
using bf16x8 = __attribute__((ext_vector_type(8))) short;

// SRSRC for raw untyped dword access (stride=0, num_records=bytes)
DEVI v4i make_srsrc(const void* p, unsigned bytes){
  unsigned long long a = (unsigned long long)p;
  v4i r;
  r.x = (int)(a & 0xFFFFFFFFull);
  r.y = (int)((a >> 32) & 0xFFFFull);
  r.z = (int)bytes;
  r.w = 0x00020000;
  return r;
}

// split-bf16 pack: hi = bf16_rne(a) in top 16 bits, lo = bf16_rne(a - hi) in low 16
DEVI unsigned packsplit(float a){
  unsigned u = __float_as_uint(a);
  unsigned hi = (u + 0x7fffu + ((u >> 16) & 1u)) & 0xffff0000u;
  float res = a - __uint_as_float(hi);
  unsigned v = __float_as_uint(res);
  unsigned lo = ((v + 0x7fffu + ((v >> 16) & 1u)) >> 16) & 0xffffu;
  return hi | lo;
}

// ---------------- transpose: out[b][c][r] = in[b][r][c] ----------------
__global__ void k_transpose(const float* __restrict__ in, float* __restrict__ out, int R, int C){
  int b = blockIdx.y;
  long n = (long)R*C;
  long i = (long)blockIdx.x*256 + threadIdx.x;
  if (i < n){
    int r = (int)(i / C), c = (int)(i % C);
    out[(long)b*n + (long)c*R + r] = in[(long)b*n + i];
  }
}

// ---------------- embedding gathers (D=200) ----------------
__global__ void k_gather(const float* __restrict__ emb, const int* __restrict__ tok, float* __restrict__ out){
  int row = blockIdx.x; int c = threadIdx.x;
  if (c < 200) out[(long)row*200 + c] = emb[(long)tok[row]*200 + c];
}
__global__ void k_gather_sel(const float* __restrict__ emb, const int* __restrict__ tok, const int* __restrict__ sel, float* __restrict__ out){
  int t = blockIdx.x, b = blockIdx.y; int c = threadIdx.x;
  if (c < 200){
    int tk = tok[(long)sel[b]*50 + t];
    out[((long)b*50 + t)*200 + c] = emb[(long)tk*200 + c];
  }
}

// ---------------- split-bf16 pack kernels ----------------
__global__ void k_packA(float* __restrict__ x, long n){
  long i = (long)blockIdx.x*256 + threadIdx.x;
  if (i < n) x[i] = __uint_as_float(packsplit(x[i]));
}
__global__ void k_packW(const float* __restrict__ src, unsigned* __restrict__ dst, int R, int K, int KP){
  long i = (long)blockIdx.x*256 + threadIdx.x;
  if (i < (long)R*KP){
    int r = (int)(i / KP), k = (int)(i % KP);
    dst[i] = (k < K) ? packsplit(src[(long)r*K + k]) : 0u;
  }
}

// ---------------- split-bf16 MFMA NT-GEMM: C = A(M,K) @ W(N,K)^T + bias ----------------
// A packed u32 (hi bf16 | lo bf16) [M][K]; W packed [z][N][KP]. 128x128 tile, BK=64.
// a = ah + al, w = wh + wl; a*w ~ ah*wh + al*wh + ah*wl (drop al*wl ~ 2^-18).
__global__ __launch_bounds__(256) void k_gemm_bf3(
    const unsigned* __restrict__ Ap, const unsigned* __restrict__ Wp,
    const float* __restrict__ bias, float* __restrict__ C,
    int M, int N, int K, int KP, long sW, long sC, long sBias)
{
  int dir = blockIdx.z;
  Wp += (long)dir*sW; C += (long)dir*sC;
  if (bias) bias += (long)dir*sBias;
  int n0 = blockIdx.x*128, m0 = blockIdx.y*128;
  __shared__ unsigned short Ah[128*72], Al[128*72], Bh[128*72], Bl[128*72];
  int tid = threadIdx.x;
  int w = tid >> 6, lane = tid & 63;
  int l15 = lane & 15, lg = lane >> 4;
  f4 acc[2][8] = {};

  for (int k0 = 0; k0 < K; k0 += 64){
    __syncthreads();
    for (int u = tid; u < 2048; u += 256){
      int r = u >> 4, q = u & 15;
      int k = k0 + q*4;
      uint4 pa = make_uint4(0,0,0,0);
      if (k + 4 <= K) pa = *(const uint4*)&Ap[(long)(m0 + r)*K + k];
      ushort4 h4, s4;
      h4.x=(unsigned short)(pa.x>>16); s4.x=(unsigned short)(pa.x&0xffff);
      h4.y=(unsigned short)(pa.y>>16); s4.y=(unsigned short)(pa.y&0xffff);
      h4.z=(unsigned short)(pa.z>>16); s4.z=(unsigned short)(pa.z&0xffff);
      h4.w=(unsigned short)(pa.w>>16); s4.w=(unsigned short)(pa.w&0xffff);
      *(ushort4*)&Ah[r*72 + q*4] = h4;
      *(ushort4*)&Al[r*72 + q*4] = s4;
      int n = n0 + r;
      uint4 pw = make_uint4(0,0,0,0);
      if (n < N && k + 4 <= KP) pw = *(const uint4*)&Wp[(long)n*KP + k];
      ushort4 wh, wl;
      wh.x=(unsigned short)(pw.x>>16); wl.x=(unsigned short)(pw.x&0xffff);
      wh.y=(unsigned short)(pw.y>>16); wl.y=(unsigned short)(pw.y&0xffff);
      wh.z=(unsigned short)(pw.z>>16); wl.z=(unsigned short)(pw.z&0xffff);
      wh.w=(unsigned short)(pw.w>>16); wl.w=(unsigned short)(pw.w&0xffff);
      *(ushort4*)&Bh[r*72 + q*4] = wh;
      *(ushort4*)&Bl[r*72 + q*4] = wl;
    }
    __syncthreads();
    bf16x8 ah[2][2], al[2][2];
    #pragma unroll
    for (int fm=0; fm<2; fm++)
      #pragma unroll
      for (int ks=0; ks<2; ks++){
        int idx = (w*32 + fm*16 + l15)*72 + ks*32 + lg*8;
        ah[fm][ks] = *(const bf16x8*)&Ah[idx];
        al[fm][ks] = *(const bf16x8*)&Al[idx];
      }
    #pragma unroll
    for (int fn=0; fn<8; fn++){
      int bidx0 = (fn*16 + l15)*72 + lg*8;
      bf16x8 bh0 = *(const bf16x8*)&Bh[bidx0];
      bf16x8 bh1 = *(const bf16x8*)&Bh[bidx0 + 32];
      bf16x8 bl0 = *(const bf16x8*)&Bl[bidx0];
      bf16x8 bl1 = *(const bf16x8*)&Bl[bidx0 + 32];
      #pragma unroll
      for (int fm=0; fm<2; fm++){
        f4 a = acc[fm][fn];
        a = __builtin_amdgcn_mfma_f32_16x16x32_bf16(ah[fm][0], bh0, a, 0, 0, 0);
        a = __builtin_amdgcn_mfma_f32_16x16x32_bf16(al[fm][0], bh0, a, 0, 0, 0);
        a = __builtin_amdgcn_mfma_f32_16x16x32_bf16(ah[fm][0], bl0, a, 0, 0, 0);
        a = __builtin_amdgcn_mfma_f32_16x16x32_bf16(ah[fm][1], bh1, a, 0, 0, 0);
        a = __builtin_amdgcn_mfma_f32_16x16x32_bf16(al[fm][1], bh1, a, 0, 0, 0);
        a = __builtin_amdgcn_mfma_f32_16x16x32_bf16(ah[fm][1], bl1, a, 0, 0, 0);
        acc[fm][fn] = a;
      }
    }
  }
  #pragma unroll
  for (int fm=0; fm<2; fm++)
    #pragma unroll
    for (int fn=0; fn<8; fn++){
      int row = m0 + w*32 + fm*16 + lg*4;
      int col = n0 + fn*16 + l15;
      if (col < N){
        float bv = bias ? bias[col] : 0.f;
        #pragma unroll
        for (int r2=0; r2<4; r2++)
          C[(long)(row+r2)*N + col] = acc[fm][fn][r2] + bv;
      }
    }
}

// ---------------- fp32 GEMM 128x128 tile, 8x8 micro: C = A(M,K) @ W(N,K)^T + bias ----------------
__global__ __launch_bounds__(256) void k_gemm128(
    const float* __restrict__ A, const float* __restrict__ W,
    const float* __restrict__ bias, float* __restrict__ C,
    int M, int N, int K, long sA, long sW, long sC, long sBias)
{
  int bz = blockIdx.z;
  A += (long)bz*sA; W += (long)bz*sW; C += (long)bz*sC;
  if (bias) bias += (long)bz*sBias;
  int n0 = blockIdx.x*128, m0 = blockIdx.y*128;
  __shared__ float As[16][132];
  __shared__ float Bs[16][132];
  int tid = threadIdx.x;
  int tx = tid & 15, ty = tid >> 4;
  float acc[8][8] = {};
  const bool k4 = ((K & 3) == 0);
  for (int k0 = 0; k0 < K; k0 += 16){
    #pragma unroll
    for (int half = 0; half < 2; half++){
      int s = tid + half*256;
      int r = s >> 2;
      int kq = (s & 3) << 2;
      int k = k0 + kq;
      int m = m0 + r;
      float4 va = make_float4(0.f,0.f,0.f,0.f);
      if (m < M){
        if (k4 && k + 3 < K) va = *(const float4*)&A[(long)m*K + k];
        else {
          float* pv = (float*)&va;
          #pragma unroll
          for (int u=0; u<4; u++) if (k+u < K) pv[u] = A[(long)m*K + k + u];
        }
      }
      As[kq+0][r]=va.x; As[kq+1][r]=va.y; As[kq+2][r]=va.z; As[kq+3][r]=va.w;
      int n = n0 + r;
      float4 vb = make_float4(0.f,0.f,0.f,0.f);
      if (n < N){
        if (k4 && k + 3 < K) vb = *(const float4*)&W[(long)n*K + k];
        else {
          float* pv = (float*)&vb;
          #pragma unroll
          for (int u=0; u<4; u++) if (k+u < K) pv[u] = W[(long)n*K + k + u];
        }
      }
      Bs[kq+0][r]=vb.x; Bs[kq+1][r]=vb.y; Bs[kq+2][r]=vb.z; Bs[kq+3][r]=vb.w;
    }
    __syncthreads();
    #pragma unroll
    for (int kk=0;kk<16;kk++){
      float a[8], b[8];
      *(float4*)&a[0] = *(const float4*)&As[kk][ty*8];
      *(float4*)&a[4] = *(const float4*)&As[kk][ty*8+4];
      *(float4*)&b[0] = *(const float4*)&Bs[kk][tx*8];
      *(float4*)&b[4] = *(const float4*)&Bs[kk][tx*8+4];
      #pragma unroll
      for (int i=0;i<8;i++)
        #pragma unroll
        for (int j=0;j<8;j++)
          acc[i][j] += a[i]*b[j];
    }
    __syncthreads();
  }
  #pragma unroll
  for (int i=0;i<8;i++){
    int m = m0 + ty*8 + i;
    if (m >= M) continue;
    #pragma unroll
    for (int j=0;j<8;j++){
      int n = n0 + tx*8 + j;
      if (n < N) C[(long)m*N + n] = acc[i][j] + (bias ? bias[n] : 0.f);
    }
  }
}

// ---------------- small GRU (h=150, 3h=450), 1 wg per (item,dir) ----------------
__global__ __launch_bounds__(512) void k_gru_small(
    const float* __restrict__ xs, long xsDir,
    const float* __restrict__ Wt, const float* __restrict__ bhh,
    float* __restrict__ y, int yld,
    float* __restrict__ meanOut, int meanld,
    int T)
{
  int item = blockIdx.x, dir = blockIdx.y;
  const float* xsd = xs + (long)dir*xsDir + (long)item*T*450;
  const float* Wtd = Wt + (long)dir*150*450;
  int tid = threadIdx.x;
  float bh = (tid < 450) ? bhh[(long)dir*450 + tid] : 0.f;
  __shared__ float hs[152];
  __shared__ float gs[456];
  if (tid < 150) hs[tid] = 0.f;
  float hsum = 0.f;
  __syncthreads();
  for (int t=0;t<T;t++){
    int tt = dir ? (T-1-t) : t;
    if (tid < 450){
      float g = bh;
      const float* wp = Wtd + tid;
      #pragma unroll 5
      for (int k=0;k<150;k++) g += hs[k] * wp[(long)k*450];
      gs[tid] = g;
    }
    __syncthreads();
    if (tid < 150){
      const float* xr = xsd + (long)tt*450;
      float r = sigm(xr[tid]     + gs[tid]);
      float z = sigm(xr[150+tid] + gs[150+tid]);
      float nn = tanhf(xr[300+tid] + r*gs[300+tid]);
      float h = (1.f-z)*nn + z*hs[tid];
      hs[tid] = h;
      hsum += h;
      if (y) y[((long)item*T + tt)*yld + dir*150 + tid] = h;
    }
    __syncthreads();
  }
  if (meanOut && tid < 150)
    meanOut[(long)item*meanld + dir*150 + tid] = hsum / (float)T;
}

// ---------------- persistent big GRU, fence-free relaxed-atomic exchange ----------------
#define GDOT(AC, W, A) AC += W.x*A.x + W.y*A.y + W.z*A.z + W.w*A.w;
template<int H, int HS, int LDW, int HPAD, int KL, int NCB>
__global__ __launch_bounds__(256) void k_gru_persist(
    const float* __restrict__ xs, long xsDir,
    const float* __restrict__ Whh, const float* __restrict__ bhh,
    float* hA, float* hB,
    float* __restrict__ ysum, int ysld,
    int T, int* flags, int* go)
{
  constexpr int H3 = 3*H;
  constexpr int CPR = HS/4;              // 16B chunks per item row
  constexpr int NCH = 16*CPR;            // chunks per step per wg
  constexpr int NIT = (NCH + 255)/256;   // chunks per thread (static)
  int wid = blockIdx.x;
  int dir = wid / (2*NCB);
  int rem = wid % (2*NCB);
  int bb  = rem / NCB;
  int cb  = rem % NCB;
  int quad = dir*2 + bb;
  int qbase = quad*64;
  int c0  = cb*10;
  int tid = threadIdx.x;

  const float* xsd = xs + (long)dir*xsDir;
  const float* Wd  = Whh + (long)dir*(long)H*H3;   // [3H][H] row-major
  const float* bhd = bhh + (long)dir*H3;

  __shared__ float hs[16*HPAD];
  __shared__ float Wl[30*LDW];
  __shared__ float blds[32];
  __shared__ float gl[30*16];
  __shared__ float part[240*12];

  for (int u = tid; u < 30*HS; u += 256){
    int r = u / HS, k = u % HS;
    long row = (long)(r/10)*H + c0 + (r%10);
    Wl[r*LDW + k] = (k < H) ? Wd[row*H + k] : 0.f;
  }
  if (tid < 30) blds[tid] = bhd[(long)(tid/10)*H + (c0 + tid%10)];

  int ks = tid / 40;
  int rem2 = tid % 40;
  int rg = rem2 / 4;
  int ig = rem2 % 4;
  bool alive = (tid < 240);
  int r0 = rg*3;
  int it0 = ig*4;
  int kbase = ks*KL;

  int uit = tid / 10, uci = tid % 10;
  int uc = c0 + uci;
  int ub = bb*16 + uit;
  float ysacc = 0.f;

  float xv0 = 0.f, xv1 = 0.f, xv2 = 0.f;
  if (tid < 160){
    int tt0 = dir ? (T-1) : 0;
    const float* xr = xsd + ((long)ub*T + tt0)*H3;
    xv0 = xr[uc]; xv1 = xr[H+uc]; xv2 = xr[2*H+uc];
  }

  __syncthreads();

  for (int t=0; t<T; t++){
    float* hp = ((t & 1) ? hB : hA) + (long)dir*32*HS;
    float* hn = ((t & 1) ? hA : hB) + (long)dir*32*HS;

    {
      v4i srsrc = make_srsrc(hp, 32u*HS*4u);
      f4 sbuf[NIT];
      #pragma unroll
      for (int i = 0; i < NIT; i++){
        int u = tid + i*256;
        if (u < NCH){
          int voff = ((bb*16 + u/CPR)*HS + (u%CPR)*4)*4;
          asm volatile("buffer_load_dwordx4 %0, %1, %2, 0 offen sc0 sc1"
                       : "=v"(sbuf[i]) : "v"(voff), "s"(srsrc));
        }
      }
      asm volatile("s_waitcnt vmcnt(0)" ::: "memory");
      __builtin_amdgcn_sched_barrier(0);
      #pragma unroll
      for (int i = 0; i < NIT; i++){
        int u = tid + i*256;
        if (u < NCH)
          *(f4*)&hs[(u/CPR)*HPAD + (u%CPR)*4] = sbuf[i];
      }
    }
    __syncthreads();

    if (alive){
      float acc[3][4];
      #pragma unroll
      for (int a=0;a<3;a++)
        #pragma unroll
        for (int b=0;b<4;b++) acc[a][b] = 0.f;
      const float* wr0 = &Wl[(r0+0)*LDW + kbase];
      const float* wr1 = &Wl[(r0+1)*LDW + kbase];
      const float* wr2 = &Wl[(r0+2)*LDW + kbase];
      const float* h0  = &hs[(it0+0)*HPAD + kbase];
      const float* h1  = &hs[(it0+1)*HPAD + kbase];
      const float* h2  = &hs[(it0+2)*HPAD + kbase];
      const float* h3  = &hs[(it0+3)*HPAD + kbase];
      for (int jq = 0; jq < KL; jq += 4){
        float4 w0 = *(const float4*)&wr0[jq];
        float4 w1 = *(const float4*)&wr1[jq];
        float4 w2 = *(const float4*)&wr2[jq];
        float4 a0 = *(const float4*)&h0[jq];
        float4 a1 = *(const float4*)&h1[jq];
        float4 a2 = *(const float4*)&h2[jq];
        float4 a3 = *(const float4*)&h3[jq];
        GDOT(acc[0][0], w0, a0) GDOT(acc[0][1], w0, a1) GDOT(acc[0][2], w0, a2) GDOT(acc[0][3], w0, a3)
        GDOT(acc[1][0], w1, a0) GDOT(acc[1][1], w1, a1) GDOT(acc[1][2], w1, a2) GDOT(acc[1][3], w1, a3)
        GDOT(acc[2][0], w2, a0) GDOT(acc[2][1], w2, a1) GDOT(acc[2][2], w2, a2) GDOT(acc[2][3], w2, a3)
      }
      #pragma unroll
      for (int a=0;a<3;a++)
        *(float4*)&part[tid*12 + a*4] = make_float4(acc[a][0],acc[a][1],acc[a][2],acc[a][3]);
    }
    __syncthreads();

    if (alive){
      #pragma unroll
      for (int vv=0; vv<2; vv++){
        int v = tid + vv*240;
        int row = v >> 4, item = v & 15;
        int base = ((row/3)*4 + (item>>2))*12 + (row%3)*4 + (item&3);
        float sum = blds[row];
        #pragma unroll
        for (int s=0; s<6; s++) sum += part[s*480 + base];
        gl[row*16 + item] = sum;
      }
    }
    __syncthreads();

    if (tid < 160){
      float r  = sigm(xv0 + gl[(uci)*16    + uit]);
      float z  = sigm(xv1 + gl[(10+uci)*16 + uit]);
      float nn = tanhf(xv2 + r*gl[(20+uci)*16 + uit]);
      float hv = hs[uit*HPAD + uc];
      float hne = (1.f-z)*nn + z*hv;
      __hip_atomic_store(&hn[(long)ub*HS + uc], hne, __ATOMIC_RELAXED, __HIP_MEMORY_SCOPE_AGENT);
      ysacc += hne;
    }
    __syncthreads();

    float nx0 = 0.f, nx1 = 0.f, nx2 = 0.f;
    if (tid < 160 && t+1 < T){
      int tt1 = dir ? (T-2-t) : (t+1);
      const float* xr = xsd + ((long)ub*T + tt1)*H3;
      nx0 = xr[uc]; nx1 = xr[H+uc]; nx2 = xr[2*H+uc];
    }

    if (t+1 < T){
      if (tid == 0)
        __hip_atomic_store(&flags[qbase + cb], t+1, __ATOMIC_RELAXED, __HIP_MEMORY_SCOPE_AGENT);
      if (cb == 0){
        if (tid < NCB){
          while (__hip_atomic_load(&flags[qbase + tid], __ATOMIC_RELAXED, __HIP_MEMORY_SCOPE_AGENT) < t+1)
            __builtin_amdgcn_s_sleep(2);
        }
        __syncthreads();
        if (tid == 0)
          __hip_atomic_store(&go[quad*32], t+1, __ATOMIC_RELAXED, __HIP_MEMORY_SCOPE_AGENT);
      } else {
        if (tid == 0){
          while (__hip_atomic_load(&go[quad*32], __ATOMIC_RELAXED, __HIP_MEMORY_SCOPE_AGENT) < t+1)
            __builtin_amdgcn_s_sleep(2);
        }
        __syncthreads();
      }
    }
    xv0 = nx0; xv1 = nx1; xv2 = nx2;
  }
  if (tid < 160)
    ysum[(long)ub*ysld + dir*H + uc] = ysacc;
}

// ---------------- graph decomposition layer (D=300, K=8) ----------------
__global__ __launch_bounds__(256) void k_graphdecomp(
   const float* __restrict__ labIn, float* __restrict__ labOut,
   const int* __restrict__ nb, const int* __restrict__ nbm, int N)
{
  int n = blockIdx.x; if (n >= N) return;
  int tid = threadIdx.x;
  __shared__ float ln[300];
  __shared__ float red[12];
  for (int d=tid; d<300; d+=256) ln[d] = labIn[(long)n*300+d];
  float deg = 0.f;
  for (int k=0;k<8;k++) deg += (float)nbm[n*8+k];
  float invdeg = 1.f / fmaxf(deg, 1.f);
  float acc0 = 0.f, acc1 = 0.f;
  __syncthreads();
  for (int k=0;k<8;k++){
    int j = nb[n*8+k];
    float mk = (float)nbm[n*8+k];
    const float* lj = labIn + (long)j*300;
    float p1=0.f, p2=0.f;
    for (int d=tid; d<300; d+=256){ float v = lj[d]; p1 += ln[d]*v; p2 += v*v; }
    for (int o=32;o>0;o>>=1){ p1 += __shfl_down(p1,o); p2 += __shfl_down(p2,o); }
    __syncthreads();
    int w = tid>>6, lane = tid&63;
    if (lane==0){ red[w]=p1; red[4+w]=p2; }
    __syncthreads();
    float x1 = red[0]+red[1]+red[2]+red[3];
    float x2 = red[4]+red[5]+red[6]+red[7];
    float coef = (x1 / (x2 + 1e-10f)) * mk * invdeg;
    acc0 += coef * lj[tid];
    if (tid + 256 < 300) acc1 += coef * lj[tid+256];
    __syncthreads();
  }
  bool pos = deg > 0.f;
  labOut[(long)n*300 + tid]                       = pos ? (ln[tid]     - acc0) : ln[tid];
  if (tid+256 < 300) labOut[(long)n*300 + tid+256] = pos ? (ln[tid+256] - acc1) : ln[tid+256];
}

// ---------------- copy ----------------
__global__ void k_copy(const float* __restrict__ src, float* __restrict__ dst, long n){
  long i = (long)blockIdx.x*256+threadIdx.x; if (i<n) dst[i]=src[i];
}

// ---------------- code_wise reductions ----------------
__global__ void k_cw_rowmax(const float* __restrict__ S, float* __restrict__ Mv){
  const int ofs[4]={0,119,238,341};
  const int wid[4]={119,119,103,103};
  int s = blockIdx.y; int row = blockIdx.x*256+threadIdx.x;
  if (row < 16384){
    const float* p = S + (long)row*444 + ofs[s];
    float m = -3.4e38f;
    int w = wid[s];
    for (int n=0;n<w;n++) m = fmaxf(m, p[n]);
    Mv[(long)s*16384+row] = m;
  }
}
__global__ void k_cw_softmax(const float* __restrict__ Mv, float* __restrict__ att){
  int b=blockIdx.x, s=blockIdx.y, tid=threadIdx.x;
  const float* src = Mv + (long)s*16384 + (long)b*512;
  __shared__ float red[256];
  float v0 = src[tid], v1 = src[tid+256];
  red[tid] = fmaxf(v0,v1); __syncthreads();
  for (int o=128;o>0;o>>=1){ if (tid<o) red[tid]=fmaxf(red[tid],red[tid+o]); __syncthreads(); }
  float m = red[0]; __syncthreads();
  float e0=expf(v0-m), e1=expf(v1-m);
  red[tid]=e0+e1; __syncthreads();
  for (int o=128;o>0;o>>=1){ if (tid<o) red[tid]+=red[tid+o]; __syncthreads(); }
  float inv = 1.f/red[0];
  float* dst = att + ((long)s*32 + b)*512;
  dst[tid]=e0*inv; dst[tid+256]=e1*inv;
}
__global__ void k_cw_out(const float* __restrict__ att, const float* __restrict__ DH, float* __restrict__ outp){
  int b=blockIdx.x, s=blockIdx.y, tid=threadIdx.x;
  __shared__ float a[512];
  for (int i=tid;i<512;i+=256) a[i]=att[((long)s*32+b)*512+i];
  __syncthreads();
  for (int d=tid; d<300; d+=256){
    float acc=0.f;
    for (int t=0;t<512;t++) acc += a[t]*DH[((long)b*512+t)*300+d];
    outp[((long)s*32+b)*300+d]=acc;
  }
}

// ---------------- masked softmax over l=50 (in place) ----------------
__global__ void k_masksm(float* __restrict__ att, long nrows){
  long row = (long)blockIdx.x*256 + threadIdx.x;
  if (row >= nrows) return;
  float* p = att + row*50;
  float m = -INFINITY;
  for (int l=0;l<50;l++){ float a = p[l]; if (a != 0.f && a > m) m = a; }
  if (m == -INFINITY){ for (int l=0;l<50;l++) p[l] = 0.f; return; }
  float s = 0.f;
  for (int l=0;l<50;l++){ float a = p[l]; float e = (a==0.f) ? 0.f : expf(a-m); p[l]=e; s+=e; }
  float inv = 1.f/s;
  for (int l=0;l<50;l++) p[l] *= inv;
}

// ---------------- fact separation combine (rows of 300), 1 wave per row ----------------
// NOTE: no __restrict__ — call 2 intentionally aliases simOut=scen, diffOut=circ.
__global__ void k_factsep(const float* circ, const float* scen,
                          float* simOut, float* diffOut, long nrows)
{
  int lane = threadIdx.x & 63;
  long row = (long)blockIdx.x*4 + (threadIdx.x >> 6);
  if (row >= nrows) return;
  const float* c = circ + row*300;
  const float* s = scen + row*300;
  float x3=0.f, x4=0.f;
  for (int d=lane; d<300; d+=64){ float sv=s[d]; x3 += c[d]*sv; x4 += sv*sv; }
  for (int o=32;o>0;o>>=1){ x3 += __shfl_down(x3,o); x4 += __shfl_down(x4,o); }
  x3 = __shfl(x3,0); x4 = __shfl(x4,0);
  float coef = x3 / (x4 + 1e-10f);
  for (int d=lane; d<300; d+=64){
    float sv = s[d]; float cv = c[d];
    float sim = coef*sv;
    simOut[row*300+d] = sim;
    diffOut[row*300+d] = cv - sim;
  }
}

// ---------------- assemblers ----------------
__global__ void k_factart(const float* __restrict__ DH, const float* __restrict__ dha,
                          const float* __restrict__ adc, const float* __restrict__ db,
                          float* __restrict__ out)
{
  long row = blockIdx.x; int b = (int)(row >> 9);
  for (int c=threadIdx.x; c<1200; c+=256){
    float v;
    if (c < 300) v = DH[row*300 + c];
    else if (c < 600) v = dha[(long)b*300 + (c-300)];
    else if (c < 900) v = adc[row*300 + (c-600)];
    else v = db[(long)b*300 + (c-900)];
    out[row*1200 + c] = v;
  }
}
__global__ void k_termcat(const float* __restrict__ DH, const float* __restrict__ ssc,
                          const float* __restrict__ dsc, float* __restrict__ out){
  long row = blockIdx.x;
  for (int c=threadIdx.x; c<900; c+=256){
    float v = (c<300) ? DH[row*300+c] : (c<600 ? ssc[row*300+(c-300)] : dsc[row*300+(c-600)]);
    out[row*900+c] = v;
  }
}

// ---------------- classifier: logits -> fp32 out, optional argmax ----------------
__global__ __launch_bounds__(256) void k_classify(
    const float* __restrict__ s0, const float* __restrict__ s1, const float* __restrict__ s2,
    int L, int Kf, float scale,
    const float* __restrict__ W, const float* __restrict__ bias, int N,
    float* __restrict__ out, int* __restrict__ amax)
{
  int b = blockIdx.x; int tid = threadIdx.x;
  __shared__ float feat[1200];
  __shared__ float logit[128];
  for (int i=tid; i<Kf; i+=256){
    int seg = i / L, c = i % L;
    const float* s = (seg==0) ? s0 : (seg==1 ? s1 : s2);
    feat[i] = s[(long)b*L + c] * scale;
  }
  __syncthreads();
  for (int n=tid; n<N; n+=256){
    float acc = bias[n];
    const float* w = W + (long)n*Kf;
    for (int k=0;k<Kf;k++) acc += feat[k]*w[k];
    out[(long)b*N + n] = acc;
    logit[n] = acc;
  }
  __syncthreads();
  if (amax && tid==0){
    float best = logit[0]; int bi=0;
    for (int n=1;n<N;n++) if (logit[n] > best){ best=logit[n]; bi=n; }
    amax[b] = bi;
  }
}

static inline int cdiv(long a, long b){ return (int)((a + b - 1)/b); }

extern "C" void kernel_launch(void* const* d_in, const int* in_sizes, int n_in,
                              void* d_out, int out_size, void* d_ws, size_t ws_size,
                              hipStream_t stream)
{
  (void)in_sizes; (void)n_in; (void)out_size;
  const float* emb     = (const float*)d_in[0];
  const float* encWih  = (const float*)d_in[1];
  const float* encWhh  = (const float*)d_in[2];
  const float* encbih  = (const float*)d_in[3];
  const float* encbhh  = (const float*)d_in[4];
  const float* cchWih  = (const float*)d_in[5];
  const float* cchWhh  = (const float*)d_in[6];
  const float* cchbih  = (const float*)d_in[7];
  const float* cchbhh  = (const float*)d_in[8];
  const float* termWih = (const float*)d_in[9];
  const float* termWhh = (const float*)d_in[10];
  const float* termbih = (const float*)d_in[11];
  const float* termbhh = (const float*)d_in[12];
  const float* artWih  = (const float*)d_in[13];
  const float* artWhh  = (const float*)d_in[14];
  const float* artbih  = (const float*)d_in[15];
  const float* artbhh  = (const float*)d_in[16];
  const float* Wc      = (const float*)d_in[17];
  const float* bc      = (const float*)d_in[18];
  const float* Wa      = (const float*)d_in[19];
  const float* ba      = (const float*)d_in[20];
  const float* Wt_     = (const float*)d_in[21];
  const float* bt_     = (const float*)d_in[22];
  const int* docs    = (const int*)d_in[23];
  const int* chtok   = (const int*)d_in[24];
  const int* artok   = (const int*)d_in[25];
  const int* chnb    = (const int*)d_in[26];
  const int* chnbm   = (const int*)d_in[27];
  const int* arnb    = (const int*)d_in[28];
  const int* arnbm   = (const int*)d_in[29];
  const int* vchtok  = (const int*)d_in[30];
  const int* vartok  = (const int*)d_in[31];
  float* ob = (float*)d_out;
  float* ws = (float*)d_ws;

  // -------- workspace layout (float elements) --------
  constexpr long O_WTENC = 0;                       // 2*150*450
  constexpr long O_WTCCH = O_WTENC + 135000;        // 2*150*450
  constexpr long O_WTART = O_WTCCH + 135000;        // (spare)
  constexpr long O_WTTERM= O_WTART + 2160000;       // (spare)
  constexpr long O_DH    = O_WTTERM + 1215000;      // 16384*300
  constexpr long O_DMEAN = O_DH + 4915200;          // 32*300
  constexpr long O_CHM   = O_DMEAN + 9600;          // 119*300
  constexpr long O_ARM   = O_CHM + 35700;           // 103*300
  constexpr long O_LAB   = O_ARM + 30900;           // 444*300
  constexpr long O_GDT   = O_LAB + 133200;          // 119*300 (barrier ints after decomp)
  constexpr long O_CWM   = O_GDT + 35700;           // 4*16384
  constexpr long O_CWA   = O_CWM + 65536;           // 4*32*512
  constexpr long O_CWO   = O_CWA + 65536;           // 4*32*300
  constexpr long O_CP    = O_CWO + 38400;           // 64 ints
  constexpr long O_VCH   = O_CP + 64;               // 32*50*300
  constexpr long O_VCHT  = O_VCH + 480000;          // 32*300*50
  constexpr long O_ATT   = O_VCHT + 480000;         // 32*512*50
  constexpr long O_SCEN  = O_ATT + 819200;          // 16384*300
  constexpr long O_ADC   = O_SCEN + 4915200;        // 16384*300
  constexpr long O_SEC   = O_ADC + 4915200;         // 16384*300
  constexpr long O_HBUF  = O_SEC + 4915200;         // h ping-pong
  constexpr long O_YSUM  = O_HBUF + 76800;          // 32*1200
  constexpr long O_GATH  = O_YSUM + 38400;          // 16384*200
  constexpr long O_XSS   = O_GATH + 3276800;        // 2*6592*450
  constexpr long O_PF    = O_XSS + 5932800;         // 16384*1200
  constexpr long O_XB    = O_PF + 19660800;         // 2*16384*1800
  constexpr long TOTAL   = O_XB + 58982400;         // ~454 MB
  if (ws_size < (size_t)TOTAL * 4) return;

  float* WT_ENC = ws + O_WTENC;
  float* WT_CCH = ws + O_WTCCH;
  float* DH     = ws + O_DH;
  float* DMEAN  = ws + O_DMEAN;
  float* CHM    = ws + O_CHM;
  float* ARM    = ws + O_ARM;
  float* LAB    = ws + O_LAB;
  float* GDT    = ws + O_GDT;
  float* CWM    = ws + O_CWM;
  float* CWA    = ws + O_CWA;
  float* CWO    = ws + O_CWO;
  int*   CP     = (int*)(ws + O_CP);
  int*   AP     = CP + 32;
  float* VCH    = ws + O_VCH;
  float* VCHT   = ws + O_VCHT;
  float* ATT    = ws + O_ATT;
  float* SCEN   = ws + O_SCEN;
  float* ADC    = ws + O_ADC;
  float* SEC    = ws + O_SEC;
  float* HBUF   = ws + O_HBUF;
  float* YSUM   = ws + O_YSUM;
  float* GATH   = ws + O_GATH;
  float* XSS    = ws + O_XSS;
  float* PF     = ws + O_PF;
  float* XB     = ws + O_XB;
  int*   FLAGS  = (int*)GDT;       // free after graph decomposition
  int*   GO     = FLAGS + 256;     // 4 quadrant go-words on separate lines

  // -------- transpose small Whh --------
  k_transpose<<<dim3(cdiv(450L*150,256),2),256,0,stream>>>(encWhh, WT_ENC, 450,150);
  k_transpose<<<dim3(cdiv(450L*150,256),2),256,0,stream>>>(cchWhh, WT_CCH, 450,150);

  // -------- charge token encoder (encch), mean only --------
  k_gather<<<3808,256,0,stream>>>(emb, chtok, GATH);
  k_gemm128<<<dim3(4,cdiv(3808,128),2),256,0,stream>>>(GATH, cchWih, cchbih, XSS,
      3808,450,200, 0, 450L*200, 3808L*450, 450);
  k_gru_small<<<dim3(119,2),512,0,stream>>>(XSS, 3808L*450, WT_CCH, cchbhh,
      nullptr,0, CHM,300, 32);

  // -------- article token encoder (encch), mean only --------
  k_gather<<<6592,256,0,stream>>>(emb, artok, GATH);
  k_gemm128<<<dim3(4,cdiv(6592,128),2),256,0,stream>>>(GATH, cchWih, cchbih, XSS,
      6592,450,200, 0, 450L*200, 6592L*450, 450);
  k_gru_small<<<dim3(103,2),512,0,stream>>>(XSS, 6592L*450, WT_CCH, cchbhh,
      nullptr,0, ARM,300, 64);

  // -------- originals + graph decomposition into label-cat --------
  k_copy<<<cdiv(35700,256),256,0,stream>>>(CHM, LAB + 119L*300, 35700);
  k_copy<<<cdiv(30900,256),256,0,stream>>>(ARM, LAB + 341L*300, 30900);
  k_graphdecomp<<<119,256,0,stream>>>(CHM, GDT, chnb, chnbm, 119);
  k_graphdecomp<<<119,256,0,stream>>>(GDT, LAB, chnb, chnbm, 119);
  k_graphdecomp<<<103,256,0,stream>>>(ARM, GDT, arnb, arnbm, 103);
  k_graphdecomp<<<103,256,0,stream>>>(GDT, LAB + 238L*300, arnb, arnbm, 103);

  // -------- document encoder (enc) -> d_hidden + doc_mean --------
  k_gather<<<16384,256,0,stream>>>(emb, docs, GATH);
  k_gemm128<<<dim3(4,128,2),256,0,stream>>>(GATH, encWih, encbih, PF,
      16384,450,200, 0, 450L*200, 16384L*450, 450);
  k_gru_small<<<dim3(32,2),512,0,stream>>>(PF, 16384L*450, WT_ENC, encbhh,
      DH,300, DMEAN,300, 512);

  // -------- code_wise (4 label sets at once) --------
  k_gemm128<<<dim3(4,128,1),256,0,stream>>>(DH, LAB, nullptr, PF,
      16384,444,300, 0,0,0, 0);
  k_cw_rowmax<<<dim3(64,4),256,0,stream>>>(PF, CWM);
  k_cw_softmax<<<dim3(32,4),256,0,stream>>>(CWM, CWA);
  k_cw_out<<<dim3(32,4),256,0,stream>>>(CWA, DH, CWO);

  // -------- charge classifier + argmax --------
  k_classify<<<32,256,0,stream>>>(DMEAN, CWO, CWO + 32L*300,
      300, 900, 1.f, Wc, bc, 119, ob, CP);

  // -------- verdict-charge GRU (enc) --------
  k_gather_sel<<<dim3(50,32),256,0,stream>>>(emb, vchtok, CP, GATH);
  k_gemm128<<<dim3(4,13,2),256,0,stream>>>(GATH, encWih, encbih, XSS,
      1600,450,200, 0, 450L*200, 1600L*450, 450);
  k_gru_small<<<dim3(32,2),512,0,stream>>>(XSS, 1600L*450, WT_ENC, encbhh,
      VCH,300, nullptr,0, 50);

  // -------- fact separation 1 (vch vs d_hidden) --------
  k_gemm128<<<dim3(1,4,32),256,0,stream>>>(DH, VCH, nullptr, ATT,
      512,50,300, 512L*300, 50L*300, 512L*50, 0);
  k_masksm<<<64,256,0,stream>>>(ATT, 16384);
  k_transpose<<<dim3(cdiv(15000,256),32),256,0,stream>>>(VCH, VCHT, 50, 300);
  k_gemm128<<<dim3(3,4,32),256,0,stream>>>(ATT, VCHT, nullptr, SCEN,
      512,300,50, 512L*50, 300L*50, 512L*300, 0);
  k_factsep<<<4096,256,0,stream>>>(DH, SCEN, ADC, SEC, 16384);

  // -------- fact_article + art bigru (persistent) --------
  k_factart<<<16384,256,0,stream>>>(DH, CWO + 2L*32*300, ADC, CWO + 3L*32*300, PF);
  k_gemm128<<<dim3(cdiv(1800,128),128,2),256,0,stream>>>(PF, artWih, artbih, XB,
      16384,1800,1200, 0, 1800L*1200, 16384L*1800, 1800);
  hipMemsetAsync(FLAGS, 0, 512*sizeof(int), stream);
  hipMemsetAsync(HBUF, 0, 76800*sizeof(float), stream);
  k_gru_persist<600,600,604,604,100,60><<<240,256,0,stream>>>(
      XB, 16384L*1800, artWhh, artbhh, HBUF, HBUF+38400, YSUM, 1200, 512, FLAGS, GO);
  k_classify<<<32,256,0,stream>>>(YSUM, nullptr, nullptr,
      1200, 1200, 1.f/512.f, Wa, ba, 103, ob + 3808, AP);

  // -------- verdict-article GRU (enc) --------
  k_gather_sel<<<dim3(50,32),256,0,stream>>>(emb, vartok, AP, GATH);
  k_gemm128<<<dim3(4,13,2),256,0,stream>>>(GATH, encWih, encbih, XSS,
      1600,450,200, 0, 450L*200, 1600L*450, 450);
  k_gru_small<<<dim3(32,2),512,0,stream>>>(XSS, 1600L*450, WT_ENC, encbhh,
      VCH,300, nullptr,0, 50);

  // -------- fact separation 2 (var vs sec); ssc->SCEN, dsc->SEC in place --------
  k_gemm128<<<dim3(1,4,32),256,0,stream>>>(SEC, VCH, nullptr, ATT,
      512,50,300, 512L*300, 50L*300, 512L*50, 0);
  k_masksm<<<64,256,0,stream>>>(ATT, 16384);
  k_transpose<<<dim3(cdiv(15000,256),32),256,0,stream>>>(VCH, VCHT, 50, 300);
  k_gemm128<<<dim3(3,4,32),256,0,stream>>>(ATT, VCHT, nullptr, SCEN,
      512,300,50, 512L*50, 300L*50, 512L*300, 0);
  k_factsep<<<4096,256,0,stream>>>(SEC, SCEN, SCEN, SEC, 16384);

  // -------- term bigru: split-bf16 MFMA projection + persistent GRU --------
  k_termcat<<<16384,256,0,stream>>>(DH, SCEN, SEC, PF);
  // pack A (PF, in place) and W (termWih -> GATH, padded K 900->912)
  k_packA<<<cdiv(16384L*900,256),256,0,stream>>>(PF, 16384L*900);
  k_packW<<<cdiv(2L*1350*912,256),256,0,stream>>>(termWih, (unsigned*)GATH, 2*1350, 900, 912);
  k_gemm_bf3<<<dim3(11,128,2),256,0,stream>>>((const unsigned*)PF, (const unsigned*)GATH,
      termbih, XB, 16384, 1350, 900, 912, 1350L*912, 16384L*1350, 1350);
  hipMemsetAsync(FLAGS, 0, 512*sizeof(int), stream);
  hipMemsetAsync(HBUF, 0, 76800*sizeof(float), stream);   // zero both buffers incl. row pads
  k_gru_persist<450,456,460,460,76,45><<<180,256,0,stream>>>(
      XB, 16384L*1350, termWhh, termbhh, HBUF, HBUF+29184, YSUM, 900, 512, FLAGS, GO);
  k_classify<<<32,256,0,stream>>>(YSUM, nullptr, nullptr,
      900, 900, 1.f/512.f, Wt_, bt_, 11, ob + 7104, nullptr);
}

// Round 10
// 13428.560 us; speedup vs baseline: 6.2954x; 1.0726x over previous
//
#include <hip/hip_runtime.h>
#include <hip/hip_bf16.h>

#define DEVI __device__ __forceinline__

DEVI float sigm(float x){ return 1.f/(1.f+expf(-x)); }

typedef int v4i __attribute__((ext_vector_type(4)));
typedef float f4 __attribute__((ext_vector_type(4)));
using bf16x8 = __attribute__((ext_vector_type(8))) short;

// SRSRC for raw untyped dword access (stride=0, num_records=bytes)
DEVI v4i make_srsrc(const void* p, unsigned bytes){
  unsigned long long a = (unsigned long long)p;
  v4i r;
  r.x = (int)(a & 0xFFFFFFFFull);
  r.y = (int)((a >> 32) & 0xFFFFull);
  r.z = (int)bytes;
  r.w = 0x00020000;
  return r;
}

// split-bf16 pack: hi = bf16_rne(a) in top 16 bits, lo = bf16_rne(a - hi) in low 16
DEVI unsigned packsplit(float a){
  unsigned u = __float_as_uint(a);
  unsigned hi = (u + 0x7fffu + ((u >> 16) & 1u)) & 0xffff0000u;
  float res = a - __uint_as_float(hi);
  unsigned v = __float_as_uint(res);
  unsigned lo = ((v + 0x7fffu + ((v >> 16) & 1u)) >> 16) & 0xffffu;
  return hi | lo;
}

// ---------------- transpose: out[b][c][r] = in[b][r][c] ----------------
__global__ void k_transpose(const float* __restrict__ in, float* __restrict__ out, int R, int C){
  int b = blockIdx.y;
  long n = (long)R*C;
  long i = (long)blockIdx.x*256 + threadIdx.x;
  if (i < n){
    int r = (int)(i / C), c = (int)(i % C);
    out[(long)b*n + (long)c*R + r] = in[(long)b*n + i];
  }
}

// ---------------- embedding gathers (D=200) ----------------
__global__ void k_gather(const float* __restrict__ emb, const int* __restrict__ tok, float* __restrict__ out){
  int row = blockIdx.x; int c = threadIdx.x;
  if (c < 200) out[(long)row*200 + c] = emb[(long)tok[row]*200 + c];
}
__global__ void k_gather_sel(const float* __restrict__ emb, const int* __restrict__ tok, const int* __restrict__ sel, float* __restrict__ out){
  int t = blockIdx.x, b = blockIdx.y; int c = threadIdx.x;
  if (c < 200){
    int tk = tok[(long)sel[b]*50 + t];
    out[((long)b*50 + t)*200 + c] = emb[(long)tk*200 + c];
  }
}

// ---------------- split-bf16 pack kernels ----------------
__global__ void k_packA(float* __restrict__ x, long n){
  long i = (long)blockIdx.x*256 + threadIdx.x;
  if (i < n) x[i] = __uint_as_float(packsplit(x[i]));
}
__global__ void k_packW(const float* __restrict__ src, unsigned* __restrict__ dst, int R, int K, int KP){
  long i = (long)blockIdx.x*256 + threadIdx.x;
  if (i < (long)R*KP){
    int r = (int)(i / KP), k = (int)(i % KP);
    dst[i] = (k < K) ? packsplit(src[(long)r*K + k]) : 0u;
  }
}

// ---------------- split-bf16 MFMA NT-GEMM: C = A(M,K) @ W(N,K)^T + bias ----------------
// A packed u32 (hi bf16 | lo bf16) [M][K]; W packed [z][N][KP]. 128x128 tile, BK=64.
// a = ah + al, w = wh + wl; a*w ~ ah*wh + al*wh + ah*wl (drop al*wl ~ 2^-18).
__global__ __launch_bounds__(256) void k_gemm_bf3(
    const unsigned* __restrict__ Ap, const unsigned* __restrict__ Wp,
    const float* __restrict__ bias, float* __restrict__ C,
    int M, int N, int K, int KP, long sW, long sC, long sBias)
{
  int dir = blockIdx.z;
  Wp += (long)dir*sW; C += (long)dir*sC;
  if (bias) bias += (long)dir*sBias;
  int n0 = blockIdx.x*128, m0 = blockIdx.y*128;
  __shared__ unsigned short Ah[128*72], Al[128*72], Bh[128*72], Bl[128*72];
  int tid = threadIdx.x;
  int w = tid >> 6, lane = tid & 63;
  int l15 = lane & 15, lg = lane >> 4;
  f4 acc[2][8] = {};

  for (int k0 = 0; k0 < K; k0 += 64){
    __syncthreads();
    for (int u = tid; u < 2048; u += 256){
      int r = u >> 4, q = u & 15;
      int k = k0 + q*4;
      uint4 pa = make_uint4(0,0,0,0);
      if (k + 4 <= K) pa = *(const uint4*)&Ap[(long)(m0 + r)*K + k];
      ushort4 h4, s4;
      h4.x=(unsigned short)(pa.x>>16); s4.x=(unsigned short)(pa.x&0xffff);
      h4.y=(unsigned short)(pa.y>>16); s4.y=(unsigned short)(pa.y&0xffff);
      h4.z=(unsigned short)(pa.z>>16); s4.z=(unsigned short)(pa.z&0xffff);
      h4.w=(unsigned short)(pa.w>>16); s4.w=(unsigned short)(pa.w&0xffff);
      *(ushort4*)&Ah[r*72 + q*4] = h4;
      *(ushort4*)&Al[r*72 + q*4] = s4;
      int n = n0 + r;
      uint4 pw = make_uint4(0,0,0,0);
      if (n < N && k + 4 <= KP) pw = *(const uint4*)&Wp[(long)n*KP + k];
      ushort4 wh, wl;
      wh.x=(unsigned short)(pw.x>>16); wl.x=(unsigned short)(pw.x&0xffff);
      wh.y=(unsigned short)(pw.y>>16); wl.y=(unsigned short)(pw.y&0xffff);
      wh.z=(unsigned short)(pw.z>>16); wl.z=(unsigned short)(pw.z&0xffff);
      wh.w=(unsigned short)(pw.w>>16); wl.w=(unsigned short)(pw.w&0xffff);
      *(ushort4*)&Bh[r*72 + q*4] = wh;
      *(ushort4*)&Bl[r*72 + q*4] = wl;
    }
    __syncthreads();
    bf16x8 ah[2][2], al[2][2];
    #pragma unroll
    for (int fm=0; fm<2; fm++)
      #pragma unroll
      for (int ks=0; ks<2; ks++){
        int idx = (w*32 + fm*16 + l15)*72 + ks*32 + lg*8;
        ah[fm][ks] = *(const bf16x8*)&Ah[idx];
        al[fm][ks] = *(const bf16x8*)&Al[idx];
      }
    #pragma unroll
    for (int fn=0; fn<8; fn++){
      int bidx0 = (fn*16 + l15)*72 + lg*8;
      bf16x8 bh0 = *(const bf16x8*)&Bh[bidx0];
      bf16x8 bh1 = *(const bf16x8*)&Bh[bidx0 + 32];
      bf16x8 bl0 = *(const bf16x8*)&Bl[bidx0];
      bf16x8 bl1 = *(const bf16x8*)&Bl[bidx0 + 32];
      #pragma unroll
      for (int fm=0; fm<2; fm++){
        f4 a = acc[fm][fn];
        a = __builtin_amdgcn_mfma_f32_16x16x32_bf16(ah[fm][0], bh0, a, 0, 0, 0);
        a = __builtin_amdgcn_mfma_f32_16x16x32_bf16(al[fm][0], bh0, a, 0, 0, 0);
        a = __builtin_amdgcn_mfma_f32_16x16x32_bf16(ah[fm][0], bl0, a, 0, 0, 0);
        a = __builtin_amdgcn_mfma_f32_16x16x32_bf16(ah[fm][1], bh1, a, 0, 0, 0);
        a = __builtin_amdgcn_mfma_f32_16x16x32_bf16(al[fm][1], bh1, a, 0, 0, 0);
        a = __builtin_amdgcn_mfma_f32_16x16x32_bf16(ah[fm][1], bl1, a, 0, 0, 0);
        acc[fm][fn] = a;
      }
    }
  }
  #pragma unroll
  for (int fm=0; fm<2; fm++)
    #pragma unroll
    for (int fn=0; fn<8; fn++){
      int row = m0 + w*32 + fm*16 + lg*4;
      int col = n0 + fn*16 + l15;
      if (col < N){
        float bv = bias ? bias[col] : 0.f;
        #pragma unroll
        for (int r2=0; r2<4; r2++)
          C[(long)(row+r2)*N + col] = acc[fm][fn][r2] + bv;
      }
    }
}

// ---------------- fp32 GEMM 128x128 tile, 8x8 micro: C = A(M,K) @ W(N,K)^T + bias ----------------
__global__ __launch_bounds__(256) void k_gemm128(
    const float* __restrict__ A, const float* __restrict__ W,
    const float* __restrict__ bias, float* __restrict__ C,
    int M, int N, int K, long sA, long sW, long sC, long sBias)
{
  int bz = blockIdx.z;
  A += (long)bz*sA; W += (long)bz*sW; C += (long)bz*sC;
  if (bias) bias += (long)bz*sBias;
  int n0 = blockIdx.x*128, m0 = blockIdx.y*128;
  __shared__ float As[16][132];
  __shared__ float Bs[16][132];
  int tid = threadIdx.x;
  int tx = tid & 15, ty = tid >> 4;
  float acc[8][8] = {};
  const bool k4 = ((K & 3) == 0);
  for (int k0 = 0; k0 < K; k0 += 16){
    #pragma unroll
    for (int half = 0; half < 2; half++){
      int s = tid + half*256;
      int r = s >> 2;
      int kq = (s & 3) << 2;
      int k = k0 + kq;
      int m = m0 + r;
      float4 va = make_float4(0.f,0.f,0.f,0.f);
      if (m < M){
        if (k4 && k + 3 < K) va = *(const float4*)&A[(long)m*K + k];
        else {
          float* pv = (float*)&va;
          #pragma unroll
          for (int u=0; u<4; u++) if (k+u < K) pv[u] = A[(long)m*K + k + u];
        }
      }
      As[kq+0][r]=va.x; As[kq+1][r]=va.y; As[kq+2][r]=va.z; As[kq+3][r]=va.w;
      int n = n0 + r;
      float4 vb = make_float4(0.f,0.f,0.f,0.f);
      if (n < N){
        if (k4 && k + 3 < K) vb = *(const float4*)&W[(long)n*K + k];
        else {
          float* pv = (float*)&vb;
          #pragma unroll
          for (int u=0; u<4; u++) if (k+u < K) pv[u] = W[(long)n*K + k + u];
        }
      }
      Bs[kq+0][r]=vb.x; Bs[kq+1][r]=vb.y; Bs[kq+2][r]=vb.z; Bs[kq+3][r]=vb.w;
    }
    __syncthreads();
    #pragma unroll
    for (int kk=0;kk<16;kk++){
      float a[8], b[8];
      *(float4*)&a[0] = *(const float4*)&As[kk][ty*8];
      *(float4*)&a[4] = *(const float4*)&As[kk][ty*8+4];
      *(float4*)&b[0] = *(const float4*)&Bs[kk][tx*8];
      *(float4*)&b[4] = *(const float4*)&Bs[kk][tx*8+4];
      #pragma unroll
      for (int i=0;i<8;i++)
        #pragma unroll
        for (int j=0;j<8;j++)
          acc[i][j] += a[i]*b[j];
    }
    __syncthreads();
  }
  #pragma unroll
  for (int i=0;i<8;i++){
    int m = m0 + ty*8 + i;
    if (m >= M) continue;
    #pragma unroll
    for (int j=0;j<8;j++){
      int n = n0 + tx*8 + j;
      if (n < N) C[(long)m*N + n] = acc[i][j] + (bias ? bias[n] : 0.f);
    }
  }
}

// ---------------- small GRU (h=150, 3h=450), 1 wg per (item,dir) ----------------
__global__ __launch_bounds__(512) void k_gru_small(
    const float* __restrict__ xs, long xsDir,
    const float* __restrict__ Wt, const float* __restrict__ bhh,
    float* __restrict__ y, int yld,
    float* __restrict__ meanOut, int meanld,
    int T)
{
  int item = blockIdx.x, dir = blockIdx.y;
  const float* xsd = xs + (long)dir*xsDir + (long)item*T*450;
  const float* Wtd = Wt + (long)dir*150*450;
  int tid = threadIdx.x;
  float bh = (tid < 450) ? bhh[(long)dir*450 + tid] : 0.f;
  __shared__ float hs[152];
  __shared__ float gs[456];
  if (tid < 150) hs[tid] = 0.f;
  float hsum = 0.f;
  __syncthreads();
  for (int t=0;t<T;t++){
    int tt = dir ? (T-1-t) : t;
    if (tid < 450){
      float g = bh;
      const float* wp = Wtd + tid;
      #pragma unroll 5
      for (int k=0;k<150;k++) g += hs[k] * wp[(long)k*450];
      gs[tid] = g;
    }
    __syncthreads();
    if (tid < 150){
      const float* xr = xsd + (long)tt*450;
      float r = sigm(xr[tid]     + gs[tid]);
      float z = sigm(xr[150+tid] + gs[150+tid]);
      float nn = tanhf(xr[300+tid] + r*gs[300+tid]);
      float h = (1.f-z)*nn + z*hs[tid];
      hs[tid] = h;
      hsum += h;
      if (y) y[((long)item*T + tt)*yld + dir*150 + tid] = h;
    }
    __syncthreads();
  }
  if (meanOut && tid < 150)
    meanOut[(long)item*meanld + dir*150 + tid] = hsum / (float)T;
}

// ---------------- persistent big GRU, fence-free relaxed-atomic exchange ----------------
#define GDOT(AC, W, A) AC += W.x*A.x + W.y*A.y + W.z*A.z + W.w*A.w;
template<int H, int HS, int LDW, int HPAD, int KL, int NCB>
__global__ __launch_bounds__(256) void k_gru_persist(
    const float* __restrict__ xs, long xsDir,
    const float* __restrict__ Whh, const float* __restrict__ bhh,
    float* hA, float* hB,
    float* __restrict__ ysum, int ysld,
    int T, int* flags, int* go)
{
  constexpr int H3 = 3*H;
  constexpr int CPR = HS/4;              // 16B chunks per item row
  constexpr int NCH = 16*CPR;            // chunks per step per wg
  constexpr int NIT = (NCH + 255)/256;   // chunks per thread (static)
  int wid = blockIdx.x;
  int dir = wid / (2*NCB);
  int rem = wid % (2*NCB);
  int bb  = rem / NCB;
  int cb  = rem % NCB;
  int quad = dir*2 + bb;
  int qbase = quad*64;
  int c0  = cb*10;
  int tid = threadIdx.x;

  const float* xsd = xs + (long)dir*xsDir;
  const float* Wd  = Whh + (long)dir*(long)H*H3;   // [3H][H] row-major
  const float* bhd = bhh + (long)dir*H3;

  __shared__ float hs[16*HPAD];
  __shared__ float Wl[30*LDW];
  __shared__ float blds[32];
  __shared__ float gl[30*16];
  __shared__ float part[240*12];

  for (int u = tid; u < 30*HS; u += 256){
    int r = u / HS, k = u % HS;
    long row = (long)(r/10)*H + c0 + (r%10);
    Wl[r*LDW + k] = (k < H) ? Wd[row*H + k] : 0.f;
  }
  if (tid < 30) blds[tid] = bhd[(long)(tid/10)*H + (c0 + tid%10)];

  int ks = tid / 40;
  int rem2 = tid % 40;
  int rg = rem2 / 4;
  int ig = rem2 % 4;
  bool alive = (tid < 240);
  int r0 = rg*3;
  int it0 = ig*4;
  int kbase = ks*KL;

  int uit = tid / 10, uci = tid % 10;
  int uc = c0 + uci;
  int ub = bb*16 + uit;
  float ysacc = 0.f;

  float xv0 = 0.f, xv1 = 0.f, xv2 = 0.f;
  if (tid < 160){
    int tt0 = dir ? (T-1) : 0;
    const float* xr = xsd + ((long)ub*T + tt0)*H3;
    xv0 = xr[uc]; xv1 = xr[H+uc]; xv2 = xr[2*H+uc];
  }

  __syncthreads();

  for (int t=0; t<T; t++){
    float* hp = ((t & 1) ? hB : hA) + (long)dir*32*HS;
    float* hn = ((t & 1) ? hA : hB) + (long)dir*32*HS;

    {
      v4i srsrc = make_srsrc(hp, 32u*HS*4u);
      f4 sbuf[NIT];
      #pragma unroll
      for (int i = 0; i < NIT; i++){
        int u = tid + i*256;
        if (u < NCH){
          int voff = ((bb*16 + u/CPR)*HS + (u%CPR)*4)*4;
          asm volatile("buffer_load_dwordx4 %0, %1, %2, 0 offen sc0 sc1"
                       : "=v"(sbuf[i]) : "v"(voff), "s"(srsrc));
        }
      }
      asm volatile("s_waitcnt vmcnt(0)" ::: "memory");
      __builtin_amdgcn_sched_barrier(0);
      #pragma unroll
      for (int i = 0; i < NIT; i++){
        int u = tid + i*256;
        if (u < NCH)
          *(f4*)&hs[(u/CPR)*HPAD + (u%CPR)*4] = sbuf[i];
      }
    }
    __syncthreads();

    if (alive){
      float acc[3][4];
      #pragma unroll
      for (int a=0;a<3;a++)
        #pragma unroll
        for (int b=0;b<4;b++) acc[a][b] = 0.f;
      const float* wr0 = &Wl[(r0+0)*LDW + kbase];
      const float* wr1 = &Wl[(r0+1)*LDW + kbase];
      const float* wr2 = &Wl[(r0+2)*LDW + kbase];
      const float* h0  = &hs[(it0+0)*HPAD + kbase];
      const float* h1  = &hs[(it0+1)*HPAD + kbase];
      const float* h2  = &hs[(it0+2)*HPAD + kbase];
      const float* h3  = &hs[(it0+3)*HPAD + kbase];
      for (int jq = 0; jq < KL; jq += 4){
        float4 w0 = *(const float4*)&wr0[jq];
        float4 w1 = *(const float4*)&wr1[jq];
        float4 w2 = *(const float4*)&wr2[jq];
        float4 a0 = *(const float4*)&h0[jq];
        float4 a1 = *(const float4*)&h1[jq];
        float4 a2 = *(const float4*)&h2[jq];
        float4 a3 = *(const float4*)&h3[jq];
        GDOT(acc[0][0], w0, a0) GDOT(acc[0][1], w0, a1) GDOT(acc[0][2], w0, a2) GDOT(acc[0][3], w0, a3)
        GDOT(acc[1][0], w1, a0) GDOT(acc[1][1], w1, a1) GDOT(acc[1][2], w1, a2) GDOT(acc[1][3], w1, a3)
        GDOT(acc[2][0], w2, a0) GDOT(acc[2][1], w2, a1) GDOT(acc[2][2], w2, a2) GDOT(acc[2][3], w2, a3)
      }
      #pragma unroll
      for (int a=0;a<3;a++)
        *(float4*)&part[tid*12 + a*4] = make_float4(acc[a][0],acc[a][1],acc[a][2],acc[a][3]);
    }
    __syncthreads();

    if (alive){
      #pragma unroll
      for (int vv=0; vv<2; vv++){
        int v = tid + vv*240;
        int row = v >> 4, item = v & 15;
        int base = ((row/3)*4 + (item>>2))*12 + (row%3)*4 + (item&3);
        float sum = blds[row];
        #pragma unroll
        for (int s=0; s<6; s++) sum += part[s*480 + base];
        gl[row*16 + item] = sum;
      }
    }
    __syncthreads();

    if (tid < 160){
      float r  = sigm(xv0 + gl[(uci)*16    + uit]);
      float z  = sigm(xv1 + gl[(10+uci)*16 + uit]);
      float nn = tanhf(xv2 + r*gl[(20+uci)*16 + uit]);
      float hv = hs[uit*HPAD + uc];
      float hne = (1.f-z)*nn + z*hv;
      __hip_atomic_store(&hn[(long)ub*HS + uc], hne, __ATOMIC_RELAXED, __HIP_MEMORY_SCOPE_AGENT);
      ysacc += hne;
    }
    __syncthreads();

    float nx0 = 0.f, nx1 = 0.f, nx2 = 0.f;
    if (tid < 160 && t+1 < T){
      int tt1 = dir ? (T-2-t) : (t+1);
      const float* xr = xsd + ((long)ub*T + tt1)*H3;
      nx0 = xr[uc]; nx1 = xr[H+uc]; nx2 = xr[2*H+uc];
    }

    if (t+1 < T){
      if (tid == 0)
        __hip_atomic_store(&flags[qbase + cb], t+1, __ATOMIC_RELAXED, __HIP_MEMORY_SCOPE_AGENT);
      if (cb == 0){
        if (tid < NCB){
          while (__hip_atomic_load(&flags[qbase + tid], __ATOMIC_RELAXED, __HIP_MEMORY_SCOPE_AGENT) < t+1)
            __builtin_amdgcn_s_sleep(2);
        }
        __syncthreads();
        if (tid == 0)
          __hip_atomic_store(&go[quad*32], t+1, __ATOMIC_RELAXED, __HIP_MEMORY_SCOPE_AGENT);
      } else {
        if (tid == 0){
          while (__hip_atomic_load(&go[quad*32], __ATOMIC_RELAXED, __HIP_MEMORY_SCOPE_AGENT) < t+1)
            __builtin_amdgcn_s_sleep(2);
        }
        __syncthreads();
      }
    }
    xv0 = nx0; xv1 = nx1; xv2 = nx2;
  }
  if (tid < 160)
    ysum[(long)ub*ysld + dir*H + uc] = ysacc;
}

// ---------------- graph decomposition layer (D=300, K=8) ----------------
__global__ __launch_bounds__(256) void k_graphdecomp(
   const float* __restrict__ labIn, float* __restrict__ labOut,
   const int* __restrict__ nb, const int* __restrict__ nbm, int N)
{
  int n = blockIdx.x; if (n >= N) return;
  int tid = threadIdx.x;
  __shared__ float ln[300];
  __shared__ float red[12];
  for (int d=tid; d<300; d+=256) ln[d] = labIn[(long)n*300+d];
  float deg = 0.f;
  for (int k=0;k<8;k++) deg += (float)nbm[n*8+k];
  float invdeg = 1.f / fmaxf(deg, 1.f);
  float acc0 = 0.f, acc1 = 0.f;
  __syncthreads();
  for (int k=0;k<8;k++){
    int j = nb[n*8+k];
    float mk = (float)nbm[n*8+k];
    const float* lj = labIn + (long)j*300;
    float p1=0.f, p2=0.f;
    for (int d=tid; d<300; d+=256){ float v = lj[d]; p1 += ln[d]*v; p2 += v*v; }
    for (int o=32;o>0;o>>=1){ p1 += __shfl_down(p1,o); p2 += __shfl_down(p2,o); }
    __syncthreads();
    int w = tid>>6, lane = tid&63;
    if (lane==0){ red[w]=p1; red[4+w]=p2; }
    __syncthreads();
    float x1 = red[0]+red[1]+red[2]+red[3];
    float x2 = red[4]+red[5]+red[6]+red[7];
    float coef = (x1 / (x2 + 1e-10f)) * mk * invdeg;
    acc0 += coef * lj[tid];
    if (tid + 256 < 300) acc1 += coef * lj[tid+256];
    __syncthreads();
  }
  bool pos = deg > 0.f;
  labOut[(long)n*300 + tid]                       = pos ? (ln[tid]     - acc0) : ln[tid];
  if (tid+256 < 300) labOut[(long)n*300 + tid+256] = pos ? (ln[tid+256] - acc1) : ln[tid+256];
}

// ---------------- copy ----------------
__global__ void k_copy(const float* __restrict__ src, float* __restrict__ dst, long n){
  long i = (long)blockIdx.x*256+threadIdx.x; if (i<n) dst[i]=src[i];
}

// ---------------- code_wise reductions ----------------
__global__ void k_cw_rowmax(const float* __restrict__ S, float* __restrict__ Mv){
  const int ofs[4]={0,119,238,341};
  const int wid[4]={119,119,103,103};
  int s = blockIdx.y; int row = blockIdx.x*256+threadIdx.x;
  if (row < 16384){
    const float* p = S + (long)row*444 + ofs[s];
    float m = -3.4e38f;
    int w = wid[s];
    for (int n=0;n<w;n++) m = fmaxf(m, p[n]);
    Mv[(long)s*16384+row] = m;
  }
}
__global__ void k_cw_softmax(const float* __restrict__ Mv, float* __restrict__ att){
  int b=blockIdx.x, s=blockIdx.y, tid=threadIdx.x;
  const float* src = Mv + (long)s*16384 + (long)b*512;
  __shared__ float red[256];
  float v0 = src[tid], v1 = src[tid+256];
  red[tid] = fmaxf(v0,v1); __syncthreads();
  for (int o=128;o>0;o>>=1){ if (tid<o) red[tid]=fmaxf(red[tid],red[tid+o]); __syncthreads(); }
  float m = red[0]; __syncthreads();
  float e0=expf(v0-m), e1=expf(v1-m);
  red[tid]=e0+e1; __syncthreads();
  for (int o=128;o>0;o>>=1){ if (tid<o) red[tid]+=red[tid+o]; __syncthreads(); }
  float inv = 1.f/red[0];
  float* dst = att + ((long)s*32 + b)*512;
  dst[tid]=e0*inv; dst[tid+256]=e1*inv;
}
__global__ void k_cw_out(const float* __restrict__ att, const float* __restrict__ DH, float* __restrict__ outp){
  int b=blockIdx.x, s=blockIdx.y, tid=threadIdx.x;
  __shared__ float a[512];
  for (int i=tid;i<512;i+=256) a[i]=att[((long)s*32+b)*512+i];
  __syncthreads();
  for (int d=tid; d<300; d+=256){
    float acc=0.f;
    for (int t=0;t<512;t++) acc += a[t]*DH[((long)b*512+t)*300+d];
    outp[((long)s*32+b)*300+d]=acc;
  }
}

// ---------------- masked softmax over l=50 (in place) ----------------
__global__ void k_masksm(float* __restrict__ att, long nrows){
  long row = (long)blockIdx.x*256 + threadIdx.x;
  if (row >= nrows) return;
  float* p = att + row*50;
  float m = -INFINITY;
  for (int l=0;l<50;l++){ float a = p[l]; if (a != 0.f && a > m) m = a; }
  if (m == -INFINITY){ for (int l=0;l<50;l++) p[l] = 0.f; return; }
  float s = 0.f;
  for (int l=0;l<50;l++){ float a = p[l]; float e = (a==0.f) ? 0.f : expf(a-m); p[l]=e; s+=e; }
  float inv = 1.f/s;
  for (int l=0;l<50;l++) p[l] *= inv;
}

// ---------------- fact separation combine (rows of 300), 1 wave per row ----------------
// NOTE: no __restrict__ — call 2 intentionally aliases simOut=scen, diffOut=circ.
__global__ void k_factsep(const float* circ, const float* scen,
                          float* simOut, float* diffOut, long nrows)
{
  int lane = threadIdx.x & 63;
  long row = (long)blockIdx.x*4 + (threadIdx.x >> 6);
  if (row >= nrows) return;
  const float* c = circ + row*300;
  const float* s = scen + row*300;
  float x3=0.f, x4=0.f;
  for (int d=lane; d<300; d+=64){ float sv=s[d]; x3 += c[d]*sv; x4 += sv*sv; }
  for (int o=32;o>0;o>>=1){ x3 += __shfl_down(x3,o); x4 += __shfl_down(x4,o); }
  x3 = __shfl(x3,0); x4 = __shfl(x4,0);
  float coef = x3 / (x4 + 1e-10f);
  for (int d=lane; d<300; d+=64){
    float sv = s[d]; float cv = c[d];
    float sim = coef*sv;
    simOut[row*300+d] = sim;
    diffOut[row*300+d] = cv - sim;
  }
}

// ---------------- assemblers ----------------
__global__ void k_factart(const float* __restrict__ DH, const float* __restrict__ dha,
                          const float* __restrict__ adc, const float* __restrict__ db,
                          float* __restrict__ out)
{
  long row = blockIdx.x; int b = (int)(row >> 9);
  for (int c=threadIdx.x; c<1200; c+=256){
    float v;
    if (c < 300) v = DH[row*300 + c];
    else if (c < 600) v = dha[(long)b*300 + (c-300)];
    else if (c < 900) v = adc[row*300 + (c-600)];
    else v = db[(long)b*300 + (c-900)];
    out[row*1200 + c] = v;
  }
}
__global__ void k_termcat(const float* __restrict__ DH, const float* __restrict__ ssc,
                          const float* __restrict__ dsc, float* __restrict__ out){
  long row = blockIdx.x;
  for (int c=threadIdx.x; c<900; c+=256){
    float v = (c<300) ? DH[row*300+c] : (c<600 ? ssc[row*300+(c-300)] : dsc[row*300+(c-600)]);
    out[row*900+c] = v;
  }
}

// ---------------- classifier: logits -> fp32 out, optional argmax ----------------
__global__ __launch_bounds__(256) void k_classify(
    const float* __restrict__ s0, const float* __restrict__ s1, const float* __restrict__ s2,
    int L, int Kf, float scale,
    const float* __restrict__ W, const float* __restrict__ bias, int N,
    float* __restrict__ out, int* __restrict__ amax)
{
  int b = blockIdx.x; int tid = threadIdx.x;
  __shared__ float feat[1200];
  __shared__ float logit[128];
  for (int i=tid; i<Kf; i+=256){
    int seg = i / L, c = i % L;
    const float* s = (seg==0) ? s0 : (seg==1 ? s1 : s2);
    feat[i] = s[(long)b*L + c] * scale;
  }
  __syncthreads();
  for (int n=tid; n<N; n+=256){
    float acc = bias[n];
    const float* w = W + (long)n*Kf;
    for (int k=0;k<Kf;k++) acc += feat[k]*w[k];
    out[(long)b*N + n] = acc;
    logit[n] = acc;
  }
  __syncthreads();
  if (amax && tid==0){
    float best = logit[0]; int bi=0;
    for (int n=1;n<N;n++) if (logit[n] > best){ best=logit[n]; bi=n; }
    amax[b] = bi;
  }
}

static inline int cdiv(long a, long b){ return (int)((a + b - 1)/b); }

extern "C" void kernel_launch(void* const* d_in, const int* in_sizes, int n_in,
                              void* d_out, int out_size, void* d_ws, size_t ws_size,
                              hipStream_t stream)
{
  (void)in_sizes; (void)n_in; (void)out_size;
  const float* emb     = (const float*)d_in[0];
  const float* encWih  = (const float*)d_in[1];
  const float* encWhh  = (const float*)d_in[2];
  const float* encbih  = (const float*)d_in[3];
  const float* encbhh  = (const float*)d_in[4];
  const float* cchWih  = (const float*)d_in[5];
  const float* cchWhh  = (const float*)d_in[6];
  const float* cchbih  = (const float*)d_in[7];
  const float* cchbhh  = (const float*)d_in[8];
  const float* termWih = (const float*)d_in[9];
  const float* termWhh = (const float*)d_in[10];
  const float* termbih = (const float*)d_in[11];
  const float* termbhh = (const float*)d_in[12];
  const float* artWih  = (const float*)d_in[13];
  const float* artWhh  = (const float*)d_in[14];
  const float* artbih  = (const float*)d_in[15];
  const float* artbhh  = (const float*)d_in[16];
  const float* Wc      = (const float*)d_in[17];
  const float* bc      = (const float*)d_in[18];
  const float* Wa      = (const float*)d_in[19];
  const float* ba      = (const float*)d_in[20];
  const float* Wt_     = (const float*)d_in[21];
  const float* bt_     = (const float*)d_in[22];
  const int* docs    = (const int*)d_in[23];
  const int* chtok   = (const int*)d_in[24];
  const int* artok   = (const int*)d_in[25];
  const int* chnb    = (const int*)d_in[26];
  const int* chnbm   = (const int*)d_in[27];
  const int* arnb    = (const int*)d_in[28];
  const int* arnbm   = (const int*)d_in[29];
  const int* vchtok  = (const int*)d_in[30];
  const int* vartok  = (const int*)d_in[31];
  float* ob = (float*)d_out;
  float* ws = (float*)d_ws;

  // -------- workspace layout (float elements) --------
  constexpr long O_WTENC = 0;                       // 2*150*450
  constexpr long O_WTCCH = O_WTENC + 135000;        // 2*150*450
  constexpr long O_WTART = O_WTCCH + 135000;        // (spare)
  constexpr long O_WTTERM= O_WTART + 2160000;       // (spare)
  constexpr long O_DH    = O_WTTERM + 1215000;      // 16384*300
  constexpr long O_DMEAN = O_DH + 4915200;          // 32*300
  constexpr long O_CHM   = O_DMEAN + 9600;          // 119*300
  constexpr long O_ARM   = O_CHM + 35700;           // 103*300
  constexpr long O_LAB   = O_ARM + 30900;           // 444*300
  constexpr long O_GDT   = O_LAB + 133200;          // 119*300 (barrier ints after decomp)
  constexpr long O_CWM   = O_GDT + 35700;           // 4*16384
  constexpr long O_CWA   = O_CWM + 65536;           // 4*32*512
  constexpr long O_CWO   = O_CWA + 65536;           // 4*32*300
  constexpr long O_CP    = O_CWO + 38400;           // 64 ints
  constexpr long O_VCH   = O_CP + 64;               // 32*50*300
  constexpr long O_VCHT  = O_VCH + 480000;          // 32*300*50
  constexpr long O_ATT   = O_VCHT + 480000;         // 32*512*50
  constexpr long O_SCEN  = O_ATT + 819200;          // 16384*300
  constexpr long O_ADC   = O_SCEN + 4915200;        // 16384*300
  constexpr long O_SEC   = O_ADC + 4915200;         // 16384*300
  constexpr long O_HBUF  = O_SEC + 4915200;         // h ping-pong
  constexpr long O_YSUM  = O_HBUF + 76800;          // 32*1200
  constexpr long O_GATH  = O_YSUM + 38400;          // 16384*200
  constexpr long O_XSS   = O_GATH + 3276800;        // 2*6592*450
  constexpr long O_PF    = O_XSS + 5932800;         // 16384*1200
  constexpr long O_XB    = O_PF + 19660800;         // 2*16384*1800
  constexpr long TOTAL   = O_XB + 58982400;         // ~454 MB
  if (ws_size < (size_t)TOTAL * 4) return;

  float* WT_ENC = ws + O_WTENC;
  float* WT_CCH = ws + O_WTCCH;
  float* DH     = ws + O_DH;
  float* DMEAN  = ws + O_DMEAN;
  float* CHM    = ws + O_CHM;
  float* ARM    = ws + O_ARM;
  float* LAB    = ws + O_LAB;
  float* GDT    = ws + O_GDT;
  float* CWM    = ws + O_CWM;
  float* CWA    = ws + O_CWA;
  float* CWO    = ws + O_CWO;
  int*   CP     = (int*)(ws + O_CP);
  int*   AP     = CP + 32;
  float* VCH    = ws + O_VCH;
  float* VCHT   = ws + O_VCHT;
  float* ATT    = ws + O_ATT;
  float* SCEN   = ws + O_SCEN;
  float* ADC    = ws + O_ADC;
  float* SEC    = ws + O_SEC;
  float* HBUF   = ws + O_HBUF;
  float* YSUM   = ws + O_YSUM;
  float* GATH   = ws + O_GATH;
  float* XSS    = ws + O_XSS;
  float* PF     = ws + O_PF;
  float* XB     = ws + O_XB;
  int*   FLAGS  = (int*)GDT;       // free after graph decomposition
  int*   GO     = FLAGS + 256;     // 4 quadrant go-words on separate lines

  // -------- transpose small Whh --------
  k_transpose<<<dim3(cdiv(450L*150,256),2),256,0,stream>>>(encWhh, WT_ENC, 450,150);
  k_transpose<<<dim3(cdiv(450L*150,256),2),256,0,stream>>>(cchWhh, WT_CCH, 450,150);

  // -------- charge token encoder (encch), mean only --------
  k_gather<<<3808,256,0,stream>>>(emb, chtok, GATH);
  k_gemm128<<<dim3(4,cdiv(3808,128),2),256,0,stream>>>(GATH, cchWih, cchbih, XSS,
      3808,450,200, 0, 450L*200, 3808L*450, 450);
  k_gru_small<<<dim3(119,2),512,0,stream>>>(XSS, 3808L*450, WT_CCH, cchbhh,
      nullptr,0, CHM,300, 32);

  // -------- article token encoder (encch), mean only --------
  k_gather<<<6592,256,0,stream>>>(emb, artok, GATH);
  k_gemm128<<<dim3(4,cdiv(6592,128),2),256,0,stream>>>(GATH, cchWih, cchbih, XSS,
      6592,450,200, 0, 450L*200, 6592L*450, 450);
  k_gru_small<<<dim3(103,2),512,0,stream>>>(XSS, 6592L*450, WT_CCH, cchbhh,
      nullptr,0, ARM,300, 64);

  // -------- originals + graph decomposition into label-cat --------
  k_copy<<<cdiv(35700,256),256,0,stream>>>(CHM, LAB + 119L*300, 35700);
  k_copy<<<cdiv(30900,256),256,0,stream>>>(ARM, LAB + 341L*300, 30900);
  k_graphdecomp<<<119,256,0,stream>>>(CHM, GDT, chnb, chnbm, 119);
  k_graphdecomp<<<119,256,0,stream>>>(GDT, LAB, chnb, chnbm, 119);
  k_graphdecomp<<<103,256,0,stream>>>(ARM, GDT, arnb, arnbm, 103);
  k_graphdecomp<<<103,256,0,stream>>>(GDT, LAB + 238L*300, arnb, arnbm, 103);

  // -------- document encoder (enc) -> d_hidden + doc_mean --------
  k_gather<<<16384,256,0,stream>>>(emb, docs, GATH);
  k_gemm128<<<dim3(4,128,2),256,0,stream>>>(GATH, encWih, encbih, PF,
      16384,450,200, 0, 450L*200, 16384L*450, 450);
  k_gru_small<<<dim3(32,2),512,0,stream>>>(PF, 16384L*450, WT_ENC, encbhh,
      DH,300, DMEAN,300, 512);

  // -------- code_wise (4 label sets at once) --------
  k_gemm128<<<dim3(4,128,1),256,0,stream>>>(DH, LAB, nullptr, PF,
      16384,444,300, 0,0,0, 0);
  k_cw_rowmax<<<dim3(64,4),256,0,stream>>>(PF, CWM);
  k_cw_softmax<<<dim3(32,4),256,0,stream>>>(CWM, CWA);
  k_cw_out<<<dim3(32,4),256,0,stream>>>(CWA, DH, CWO);

  // -------- charge classifier + argmax --------
  k_classify<<<32,256,0,stream>>>(DMEAN, CWO, CWO + 32L*300,
      300, 900, 1.f, Wc, bc, 119, ob, CP);

  // -------- verdict-charge GRU (enc) --------
  k_gather_sel<<<dim3(50,32),256,0,stream>>>(emb, vchtok, CP, GATH);
  k_gemm128<<<dim3(4,13,2),256,0,stream>>>(GATH, encWih, encbih, XSS,
      1600,450,200, 0, 450L*200, 1600L*450, 450);
  k_gru_small<<<dim3(32,2),512,0,stream>>>(XSS, 1600L*450, WT_ENC, encbhh,
      VCH,300, nullptr,0, 50);

  // -------- fact separation 1 (vch vs d_hidden) --------
  k_gemm128<<<dim3(1,4,32),256,0,stream>>>(DH, VCH, nullptr, ATT,
      512,50,300, 512L*300, 50L*300, 512L*50, 0);
  k_masksm<<<64,256,0,stream>>>(ATT, 16384);
  k_transpose<<<dim3(cdiv(15000,256),32),256,0,stream>>>(VCH, VCHT, 50, 300);
  k_gemm128<<<dim3(3,4,32),256,0,stream>>>(ATT, VCHT, nullptr, SCEN,
      512,300,50, 512L*50, 300L*50, 512L*300, 0);
  k_factsep<<<4096,256,0,stream>>>(DH, SCEN, ADC, SEC, 16384);

  // -------- fact_article: split-bf16 MFMA projection + persistent art GRU --------
  k_factart<<<16384,256,0,stream>>>(DH, CWO + 2L*32*300, ADC, CWO + 3L*32*300, PF);
  // pack A (PF in place, 16384x1200) and W (artWih -> XSS u32, K 1200 -> KP 1216)
  k_packA<<<cdiv(16384L*1200,256),256,0,stream>>>(PF, 16384L*1200);
  k_packW<<<cdiv(2L*1800*1216,256),256,0,stream>>>(artWih, (unsigned*)XSS, 2*1800, 1200, 1216);
  k_gemm_bf3<<<dim3(15,128,2),256,0,stream>>>((const unsigned*)PF, (const unsigned*)XSS,
      artbih, XB, 16384, 1800, 1200, 1216, 1800L*1216, 16384L*1800, 1800);
  hipMemsetAsync(FLAGS, 0, 512*sizeof(int), stream);
  hipMemsetAsync(HBUF, 0, 76800*sizeof(float), stream);
  k_gru_persist<600,600,604,604,100,60><<<240,256,0,stream>>>(
      XB, 16384L*1800, artWhh, artbhh, HBUF, HBUF+38400, YSUM, 1200, 512, FLAGS, GO);
  k_classify<<<32,256,0,stream>>>(YSUM, nullptr, nullptr,
      1200, 1200, 1.f/512.f, Wa, ba, 103, ob + 3808, AP);

  // -------- verdict-article GRU (enc) --------
  k_gather_sel<<<dim3(50,32),256,0,stream>>>(emb, vartok, AP, GATH);
  k_gemm128<<<dim3(4,13,2),256,0,stream>>>(GATH, encWih, encbih, XSS,
      1600,450,200, 0, 450L*200, 1600L*450, 450);
  k_gru_small<<<dim3(32,2),512,0,stream>>>(XSS, 1600L*450, WT_ENC, encbhh,
      VCH,300, nullptr,0, 50);

  // -------- fact separation 2 (var vs sec); ssc->SCEN, dsc->SEC in place --------
  k_gemm128<<<dim3(1,4,32),256,0,stream>>>(SEC, VCH, nullptr, ATT,
      512,50,300, 512L*300, 50L*300, 512L*50, 0);
  k_masksm<<<64,256,0,stream>>>(ATT, 16384);
  k_transpose<<<dim3(cdiv(15000,256),32),256,0,stream>>>(VCH, VCHT, 50, 300);
  k_gemm128<<<dim3(3,4,32),256,0,stream>>>(ATT, VCHT, nullptr, SCEN,
      512,300,50, 512L*50, 300L*50, 512L*300, 0);
  k_factsep<<<4096,256,0,stream>>>(SEC, SCEN, SCEN, SEC, 16384);

  // -------- term bigru: split-bf16 MFMA projection + persistent GRU --------
  k_termcat<<<16384,256,0,stream>>>(DH, SCEN, SEC, PF);
  // pack A (PF, in place) and W (termWih -> GATH, padded K 900->912)
  k_packA<<<cdiv(16384L*900,256),256,0,stream>>>(PF, 16384L*900);
  k_packW<<<cdiv(2L*1350*912,256),256,0,stream>>>(termWih, (unsigned*)GATH, 2*1350, 900, 912);
  k_gemm_bf3<<<dim3(11,128,2),256,0,stream>>>((const unsigned*)PF, (const unsigned*)GATH,
      termbih, XB, 16384, 1350, 900, 912, 1350L*912, 16384L*1350, 1350);
  hipMemsetAsync(FLAGS, 0, 512*sizeof(int), stream);
  hipMemsetAsync(HBUF, 0, 76800*sizeof(float), stream);   // zero both buffers incl. row pads
  k_gru_persist<450,456,460,460,76,45><<<180,256,0,stream>>>(
      XB, 16384L*1350, termWhh, termbhh, HBUF, HBUF+29184, YSUM, 900, 512, FLAGS, GO);
  k_classify<<<32,256,0,stream>>>(YSUM, nullptr, nullptr,
      900, 900, 1.f/512.f, Wt_, bt_, 11, ob + 7104, nullptr);
}

// Round 11
// 13288.420 us; speedup vs baseline: 6.3618x; 1.0105x over previous
//
#include <hip/hip_runtime.h>
#include <hip/hip_bf16.h>

#define DEVI __device__ __forceinline__

DEVI float sigm(float x){ return 1.f/(1.f+expf(-x)); }

typedef int v4i __attribute__((ext_vector_type(4)));
typedef float f4 __attribute__((ext_vector_type(4)));
using bf16x8 = __attribute__((ext_vector_type(8))) short;

// SRSRC for raw untyped dword access (stride=0, num_records=bytes)
DEVI v4i make_srsrc(const void* p, unsigned bytes){
  unsigned long long a = (unsigned long long)p;
  v4i r;
  r.x = (int)(a & 0xFFFFFFFFull);
  r.y = (int)((a >> 32) & 0xFFFFull);
  r.z = (int)bytes;
  r.w = 0x00020000;
  return r;
}

// split-bf16 pack: hi = bf16_rne(a) in top 16 bits, lo = bf16_rne(a - hi) in low 16
DEVI unsigned packsplit(float a){
  unsigned u = __float_as_uint(a);
  unsigned hi = (u + 0x7fffu + ((u >> 16) & 1u)) & 0xffff0000u;
  float res = a - __uint_as_float(hi);
  unsigned v = __float_as_uint(res);
  unsigned lo = ((v + 0x7fffu + ((v >> 16) & 1u)) >> 16) & 0xffffu;
  return hi | lo;
}

// ---------------- transpose: out[b][c][r] = in[b][r][c] ----------------
__global__ void k_transpose(const float* __restrict__ in, float* __restrict__ out, int R, int C){
  int b = blockIdx.y;
  long n = (long)R*C;
  long i = (long)blockIdx.x*256 + threadIdx.x;
  if (i < n){
    int r = (int)(i / C), c = (int)(i % C);
    out[(long)b*n + (long)c*R + r] = in[(long)b*n + i];
  }
}

// ---------------- embedding gathers (D=200) ----------------
__global__ void k_gather(const float* __restrict__ emb, const int* __restrict__ tok, float* __restrict__ out){
  int row = blockIdx.x; int c = threadIdx.x;
  if (c < 200) out[(long)row*200 + c] = emb[(long)tok[row]*200 + c];
}
__global__ void k_gather_sel(const float* __restrict__ emb, const int* __restrict__ tok, const int* __restrict__ sel, float* __restrict__ out){
  int t = blockIdx.x, b = blockIdx.y; int c = threadIdx.x;
  if (c < 200){
    int tk = tok[(long)sel[b]*50 + t];
    out[((long)b*50 + t)*200 + c] = emb[(long)tk*200 + c];
  }
}

// ---------------- split-bf16 pack kernels ----------------
__global__ void k_packA(float* __restrict__ x, long n){
  long i = (long)blockIdx.x*256 + threadIdx.x;
  if (i < n) x[i] = __uint_as_float(packsplit(x[i]));
}
// pack with copy (src preserved): dst[i] = packsplit(src[i])
__global__ void k_packAc(const float* __restrict__ src, unsigned* __restrict__ dst, long n){
  long i = (long)blockIdx.x*256 + threadIdx.x;
  if (i < n) dst[i] = packsplit(src[i]);
}
__global__ void k_packW(const float* __restrict__ src, unsigned* __restrict__ dst, int R, int K, int KP){
  long i = (long)blockIdx.x*256 + threadIdx.x;
  if (i < (long)R*KP){
    int r = (int)(i / KP), k = (int)(i % KP);
    dst[i] = (k < K) ? packsplit(src[(long)r*K + k]) : 0u;
  }
}

// ---------------- split-bf16 MFMA NT-GEMM: C = A(M,K) @ W(N,K)^T + bias ----------------
// A packed u32 (hi bf16 | lo bf16) [M][K]; W packed [z][N][KP]. 128x128 tile, BK=64.
// a = ah + al, w = wh + wl; a*w ~ ah*wh + al*wh + ah*wl (drop al*wl ~ 2^-18).
__global__ __launch_bounds__(256) void k_gemm_bf3(
    const unsigned* __restrict__ Ap, const unsigned* __restrict__ Wp,
    const float* __restrict__ bias, float* __restrict__ C,
    int M, int N, int K, int KP, long sW, long sC, long sBias)
{
  int dir = blockIdx.z;
  Wp += (long)dir*sW; C += (long)dir*sC;
  if (bias) bias += (long)dir*sBias;
  int n0 = blockIdx.x*128, m0 = blockIdx.y*128;
  __shared__ unsigned short Ah[128*72], Al[128*72], Bh[128*72], Bl[128*72];
  int tid = threadIdx.x;
  int w = tid >> 6, lane = tid & 63;
  int l15 = lane & 15, lg = lane >> 4;
  f4 acc[2][8] = {};

  for (int k0 = 0; k0 < K; k0 += 64){
    __syncthreads();
    for (int u = tid; u < 2048; u += 256){
      int r = u >> 4, q = u & 15;
      int k = k0 + q*4;
      uint4 pa = make_uint4(0,0,0,0);
      if (k + 4 <= K) pa = *(const uint4*)&Ap[(long)(m0 + r)*K + k];
      ushort4 h4, s4;
      h4.x=(unsigned short)(pa.x>>16); s4.x=(unsigned short)(pa.x&0xffff);
      h4.y=(unsigned short)(pa.y>>16); s4.y=(unsigned short)(pa.y&0xffff);
      h4.z=(unsigned short)(pa.z>>16); s4.z=(unsigned short)(pa.z&0xffff);
      h4.w=(unsigned short)(pa.w>>16); s4.w=(unsigned short)(pa.w&0xffff);
      *(ushort4*)&Ah[r*72 + q*4] = h4;
      *(ushort4*)&Al[r*72 + q*4] = s4;
      int n = n0 + r;
      uint4 pw = make_uint4(0,0,0,0);
      if (n < N && k + 4 <= KP) pw = *(const uint4*)&Wp[(long)n*KP + k];
      ushort4 wh, wl;
      wh.x=(unsigned short)(pw.x>>16); wl.x=(unsigned short)(pw.x&0xffff);
      wh.y=(unsigned short)(pw.y>>16); wl.y=(unsigned short)(pw.y&0xffff);
      wh.z=(unsigned short)(pw.z>>16); wl.z=(unsigned short)(pw.z&0xffff);
      wh.w=(unsigned short)(pw.w>>16); wl.w=(unsigned short)(pw.w&0xffff);
      *(ushort4*)&Bh[r*72 + q*4] = wh;
      *(ushort4*)&Bl[r*72 + q*4] = wl;
    }
    __syncthreads();
    bf16x8 ah[2][2], al[2][2];
    #pragma unroll
    for (int fm=0; fm<2; fm++)
      #pragma unroll
      for (int ks=0; ks<2; ks++){
        int idx = (w*32 + fm*16 + l15)*72 + ks*32 + lg*8;
        ah[fm][ks] = *(const bf16x8*)&Ah[idx];
        al[fm][ks] = *(const bf16x8*)&Al[idx];
      }
    #pragma unroll
    for (int fn=0; fn<8; fn++){
      int bidx0 = (fn*16 + l15)*72 + lg*8;
      bf16x8 bh0 = *(const bf16x8*)&Bh[bidx0];
      bf16x8 bh1 = *(const bf16x8*)&Bh[bidx0 + 32];
      bf16x8 bl0 = *(const bf16x8*)&Bl[bidx0];
      bf16x8 bl1 = *(const bf16x8*)&Bl[bidx0 + 32];
      #pragma unroll
      for (int fm=0; fm<2; fm++){
        f4 a = acc[fm][fn];
        a = __builtin_amdgcn_mfma_f32_16x16x32_bf16(ah[fm][0], bh0, a, 0, 0, 0);
        a = __builtin_amdgcn_mfma_f32_16x16x32_bf16(al[fm][0], bh0, a, 0, 0, 0);
        a = __builtin_amdgcn_mfma_f32_16x16x32_bf16(ah[fm][0], bl0, a, 0, 0, 0);
        a = __builtin_amdgcn_mfma_f32_16x16x32_bf16(ah[fm][1], bh1, a, 0, 0, 0);
        a = __builtin_amdgcn_mfma_f32_16x16x32_bf16(al[fm][1], bh1, a, 0, 0, 0);
        a = __builtin_amdgcn_mfma_f32_16x16x32_bf16(ah[fm][1], bl1, a, 0, 0, 0);
        acc[fm][fn] = a;
      }
    }
  }
  #pragma unroll
  for (int fm=0; fm<2; fm++)
    #pragma unroll
    for (int fn=0; fn<8; fn++){
      int row = m0 + w*32 + fm*16 + lg*4;
      int col = n0 + fn*16 + l15;
      if (col < N){
        float bv = bias ? bias[col] : 0.f;
        #pragma unroll
        for (int r2=0; r2<4; r2++)
          if (row + r2 < M)                       // tail-M guard: z-blocks race otherwise
            C[(long)(row+r2)*N + col] = acc[fm][fn][r2] + bv;
      }
    }
}

// ---------------- fp32 GEMM 128x128 tile, 8x8 micro (small/argmax-adjacent GEMMs) ----------------
__global__ __launch_bounds__(256) void k_gemm128(
    const float* __restrict__ A, const float* __restrict__ W,
    const float* __restrict__ bias, float* __restrict__ C,
    int M, int N, int K, long sA, long sW, long sC, long sBias)
{
  int bz = blockIdx.z;
  A += (long)bz*sA; W += (long)bz*sW; C += (long)bz*sC;
  if (bias) bias += (long)bz*sBias;
  int n0 = blockIdx.x*128, m0 = blockIdx.y*128;
  __shared__ float As[16][132];
  __shared__ float Bs[16][132];
  int tid = threadIdx.x;
  int tx = tid & 15, ty = tid >> 4;
  float acc[8][8] = {};
  const bool k4 = ((K & 3) == 0);
  for (int k0 = 0; k0 < K; k0 += 16){
    #pragma unroll
    for (int half = 0; half < 2; half++){
      int s = tid + half*256;
      int r = s >> 2;
      int kq = (s & 3) << 2;
      int k = k0 + kq;
      int m = m0 + r;
      float4 va = make_float4(0.f,0.f,0.f,0.f);
      if (m < M){
        if (k4 && k + 3 < K) va = *(const float4*)&A[(long)m*K + k];
        else {
          float* pv = (float*)&va;
          #pragma unroll
          for (int u=0; u<4; u++) if (k+u < K) pv[u] = A[(long)m*K + k + u];
        }
      }
      As[kq+0][r]=va.x; As[kq+1][r]=va.y; As[kq+2][r]=va.z; As[kq+3][r]=va.w;
      int n = n0 + r;
      float4 vb = make_float4(0.f,0.f,0.f,0.f);
      if (n < N){
        if (k4 && k + 3 < K) vb = *(const float4*)&W[(long)n*K + k];
        else {
          float* pv = (float*)&vb;
          #pragma unroll
          for (int u=0; u<4; u++) if (k+u < K) pv[u] = W[(long)n*K + k + u];
        }
      }
      Bs[kq+0][r]=vb.x; Bs[kq+1][r]=vb.y; Bs[kq+2][r]=vb.z; Bs[kq+3][r]=vb.w;
    }
    __syncthreads();
    #pragma unroll
    for (int kk=0;kk<16;kk++){
      float a[8], b[8];
      *(float4*)&a[0] = *(const float4*)&As[kk][ty*8];
      *(float4*)&a[4] = *(const float4*)&As[kk][ty*8+4];
      *(float4*)&b[0] = *(const float4*)&Bs[kk][tx*8];
      *(float4*)&b[4] = *(const float4*)&Bs[kk][tx*8+4];
      #pragma unroll
      for (int i=0;i<8;i++)
        #pragma unroll
        for (int j=0;j<8;j++)
          acc[i][j] += a[i]*b[j];
    }
    __syncthreads();
  }
  #pragma unroll
  for (int i=0;i<8;i++){
    int m = m0 + ty*8 + i;
    if (m >= M) continue;
    #pragma unroll
    for (int j=0;j<8;j++){
      int n = n0 + tx*8 + j;
      if (n < N) C[(long)m*N + n] = acc[i][j] + (bias ? bias[n] : 0.f);
    }
  }
}

// ---------------- small GRU (h=150, 3h=450), 1 wg per (item,dir) ----------------
__global__ __launch_bounds__(512) void k_gru_small(
    const float* __restrict__ xs, long xsDir,
    const float* __restrict__ Wt, const float* __restrict__ bhh,
    float* __restrict__ y, int yld,
    float* __restrict__ meanOut, int meanld,
    int T)
{
  int item = blockIdx.x, dir = blockIdx.y;
  const float* xsd = xs + (long)dir*xsDir + (long)item*T*450;
  const float* Wtd = Wt + (long)dir*150*450;
  int tid = threadIdx.x;
  float bh = (tid < 450) ? bhh[(long)dir*450 + tid] : 0.f;
  __shared__ float hs[152];
  __shared__ float gs[456];
  if (tid < 150) hs[tid] = 0.f;
  float hsum = 0.f;
  __syncthreads();
  for (int t=0;t<T;t++){
    int tt = dir ? (T-1-t) : t;
    if (tid < 450){
      float g = bh;
      const float* wp = Wtd + tid;
      #pragma unroll 5
      for (int k=0;k<150;k++) g += hs[k] * wp[(long)k*450];
      gs[tid] = g;
    }
    __syncthreads();
    if (tid < 150){
      const float* xr = xsd + (long)tt*450;
      float r = sigm(xr[tid]     + gs[tid]);
      float z = sigm(xr[150+tid] + gs[150+tid]);
      float nn = tanhf(xr[300+tid] + r*gs[300+tid]);
      float h = (1.f-z)*nn + z*hs[tid];
      hs[tid] = h;
      hsum += h;
      if (y) y[((long)item*T + tt)*yld + dir*150 + tid] = h;
    }
    __syncthreads();
  }
  if (meanOut && tid < 150)
    meanOut[(long)item*meanld + dir*150 + tid] = hsum / (float)T;
}

// ---------------- persistent big GRU, fence-free relaxed-atomic exchange ----------------
#define GDOT(AC, W, A) AC += W.x*A.x + W.y*A.y + W.z*A.z + W.w*A.w;
template<int H, int HS, int LDW, int HPAD, int KL, int NCB>
__global__ __launch_bounds__(256) void k_gru_persist(
    const float* __restrict__ xs, long xsDir,
    const float* __restrict__ Whh, const float* __restrict__ bhh,
    float* hA, float* hB,
    float* __restrict__ ysum, int ysld,
    int T, int* flags, int* go)
{
  constexpr int H3 = 3*H;
  constexpr int CPR = HS/4;              // 16B chunks per item row
  constexpr int NCH = 16*CPR;            // chunks per step per wg
  constexpr int NIT = (NCH + 255)/256;   // chunks per thread (static)
  int wid = blockIdx.x;
  int dir = wid / (2*NCB);
  int rem = wid % (2*NCB);
  int bb  = rem / NCB;
  int cb  = rem % NCB;
  int quad = dir*2 + bb;
  int qbase = quad*64;
  int c0  = cb*10;
  int tid = threadIdx.x;

  const float* xsd = xs + (long)dir*xsDir;
  const float* Wd  = Whh + (long)dir*(long)H*H3;   // [3H][H] row-major
  const float* bhd = bhh + (long)dir*H3;

  __shared__ float hs[16*HPAD];
  __shared__ float Wl[30*LDW];
  __shared__ float blds[32];
  __shared__ float gl[30*16];
  __shared__ float part[240*12];

  for (int u = tid; u < 30*HS; u += 256){
    int r = u / HS, k = u % HS;
    long row = (long)(r/10)*H + c0 + (r%10);
    Wl[r*LDW + k] = (k < H) ? Wd[row*H + k] : 0.f;
  }
  if (tid < 30) blds[tid] = bhd[(long)(tid/10)*H + (c0 + tid%10)];

  int ks = tid / 40;
  int rem2 = tid % 40;
  int rg = rem2 / 4;
  int ig = rem2 % 4;
  bool alive = (tid < 240);
  int r0 = rg*3;
  int it0 = ig*4;
  int kbase = ks*KL;

  int uit = tid / 10, uci = tid % 10;
  int uc = c0 + uci;
  int ub = bb*16 + uit;
  float ysacc = 0.f;

  float xv0 = 0.f, xv1 = 0.f, xv2 = 0.f;
  if (tid < 160){
    int tt0 = dir ? (T-1) : 0;
    const float* xr = xsd + ((long)ub*T + tt0)*H3;
    xv0 = xr[uc]; xv1 = xr[H+uc]; xv2 = xr[2*H+uc];
  }

  __syncthreads();

  for (int t=0; t<T; t++){
    float* hp = ((t & 1) ? hB : hA) + (long)dir*32*HS;
    float* hn = ((t & 1) ? hA : hB) + (long)dir*32*HS;

    {
      v4i srsrc = make_srsrc(hp, 32u*HS*4u);
      f4 sbuf[NIT];
      #pragma unroll
      for (int i = 0; i < NIT; i++){
        int u = tid + i*256;
        if (u < NCH){
          int voff = ((bb*16 + u/CPR)*HS + (u%CPR)*4)*4;
          asm volatile("buffer_load_dwordx4 %0, %1, %2, 0 offen sc0 sc1"
                       : "=v"(sbuf[i]) : "v"(voff), "s"(srsrc));
        }
      }
      asm volatile("s_waitcnt vmcnt(0)" ::: "memory");
      __builtin_amdgcn_sched_barrier(0);
      #pragma unroll
      for (int i = 0; i < NIT; i++){
        int u = tid + i*256;
        if (u < NCH)
          *(f4*)&hs[(u/CPR)*HPAD + (u%CPR)*4] = sbuf[i];
      }
    }
    __syncthreads();

    if (alive){
      float acc[3][4];
      #pragma unroll
      for (int a=0;a<3;a++)
        #pragma unroll
        for (int b=0;b<4;b++) acc[a][b] = 0.f;
      const float* wr0 = &Wl[(r0+0)*LDW + kbase];
      const float* wr1 = &Wl[(r0+1)*LDW + kbase];
      const float* wr2 = &Wl[(r0+2)*LDW + kbase];
      const float* h0  = &hs[(it0+0)*HPAD + kbase];
      const float* h1  = &hs[(it0+1)*HPAD + kbase];
      const float* h2  = &hs[(it0+2)*HPAD + kbase];
      const float* h3  = &hs[(it0+3)*HPAD + kbase];
      for (int jq = 0; jq < KL; jq += 4){
        float4 w0 = *(const float4*)&wr0[jq];
        float4 w1 = *(const float4*)&wr1[jq];
        float4 w2 = *(const float4*)&wr2[jq];
        float4 a0 = *(const float4*)&h0[jq];
        float4 a1 = *(const float4*)&h1[jq];
        float4 a2 = *(const float4*)&h2[jq];
        float4 a3 = *(const float4*)&h3[jq];
        GDOT(acc[0][0], w0, a0) GDOT(acc[0][1], w0, a1) GDOT(acc[0][2], w0, a2) GDOT(acc[0][3], w0, a3)
        GDOT(acc[1][0], w1, a0) GDOT(acc[1][1], w1, a1) GDOT(acc[1][2], w1, a2) GDOT(acc[1][3], w1, a3)
        GDOT(acc[2][0], w2, a0) GDOT(acc[2][1], w2, a1) GDOT(acc[2][2], w2, a2) GDOT(acc[2][3], w2, a3)
      }
      #pragma unroll
      for (int a=0;a<3;a++)
        *(float4*)&part[tid*12 + a*4] = make_float4(acc[a][0],acc[a][1],acc[a][2],acc[a][3]);
    }
    __syncthreads();

    if (alive){
      #pragma unroll
      for (int vv=0; vv<2; vv++){
        int v = tid + vv*240;
        int row = v >> 4, item = v & 15;
        int base = ((row/3)*4 + (item>>2))*12 + (row%3)*4 + (item&3);
        float sum = blds[row];
        #pragma unroll
        for (int s=0; s<6; s++) sum += part[s*480 + base];
        gl[row*16 + item] = sum;
      }
    }
    __syncthreads();

    if (tid < 160){
      float r  = sigm(xv0 + gl[(uci)*16    + uit]);
      float z  = sigm(xv1 + gl[(10+uci)*16 + uit]);
      float nn = tanhf(xv2 + r*gl[(20+uci)*16 + uit]);
      float hv = hs[uit*HPAD + uc];
      float hne = (1.f-z)*nn + z*hv;
      __hip_atomic_store(&hn[(long)ub*HS + uc], hne, __ATOMIC_RELAXED, __HIP_MEMORY_SCOPE_AGENT);
      ysacc += hne;
    }
    __syncthreads();

    float nx0 = 0.f, nx1 = 0.f, nx2 = 0.f;
    if (tid < 160 && t+1 < T){
      int tt1 = dir ? (T-2-t) : (t+1);
      const float* xr = xsd + ((long)ub*T + tt1)*H3;
      nx0 = xr[uc]; nx1 = xr[H+uc]; nx2 = xr[2*H+uc];
    }

    if (t+1 < T){
      if (tid == 0)
        __hip_atomic_store(&flags[qbase + cb], t+1, __ATOMIC_RELAXED, __HIP_MEMORY_SCOPE_AGENT);
      if (cb == 0){
        if (tid < NCB){
          while (__hip_atomic_load(&flags[qbase + tid], __ATOMIC_RELAXED, __HIP_MEMORY_SCOPE_AGENT) < t+1)
            __builtin_amdgcn_s_sleep(2);
        }
        __syncthreads();
        if (tid == 0)
          __hip_atomic_store(&go[quad*32], t+1, __ATOMIC_RELAXED, __HIP_MEMORY_SCOPE_AGENT);
      } else {
        if (tid == 0){
          while (__hip_atomic_load(&go[quad*32], __ATOMIC_RELAXED, __HIP_MEMORY_SCOPE_AGENT) < t+1)
            __builtin_amdgcn_s_sleep(2);
        }
        __syncthreads();
      }
    }
    xv0 = nx0; xv1 = nx1; xv2 = nx2;
  }
  if (tid < 160)
    ysum[(long)ub*ysld + dir*H + uc] = ysacc;
}

// ---------------- graph decomposition layer (D=300, K=8) ----------------
__global__ __launch_bounds__(256) void k_graphdecomp(
   const float* __restrict__ labIn, float* __restrict__ labOut,
   const int* __restrict__ nb, const int* __restrict__ nbm, int N)
{
  int n = blockIdx.x; if (n >= N) return;
  int tid = threadIdx.x;
  __shared__ float ln[300];
  __shared__ float red[12];
  for (int d=tid; d<300; d+=256) ln[d] = labIn[(long)n*300+d];
  float deg = 0.f;
  for (int k=0;k<8;k++) deg += (float)nbm[n*8+k];
  float invdeg = 1.f / fmaxf(deg, 1.f);
  float acc0 = 0.f, acc1 = 0.f;
  __syncthreads();
  for (int k=0;k<8;k++){
    int j = nb[n*8+k];
    float mk = (float)nbm[n*8+k];
    const float* lj = labIn + (long)j*300;
    float p1=0.f, p2=0.f;
    for (int d=tid; d<300; d+=256){ float v = lj[d]; p1 += ln[d]*v; p2 += v*v; }
    for (int o=32;o>0;o>>=1){ p1 += __shfl_down(p1,o); p2 += __shfl_down(p2,o); }
    __syncthreads();
    int w = tid>>6, lane = tid&63;
    if (lane==0){ red[w]=p1; red[4+w]=p2; }
    __syncthreads();
    float x1 = red[0]+red[1]+red[2]+red[3];
    float x2 = red[4]+red[5]+red[6]+red[7];
    float coef = (x1 / (x2 + 1e-10f)) * mk * invdeg;
    acc0 += coef * lj[tid];
    if (tid + 256 < 300) acc1 += coef * lj[tid+256];
    __syncthreads();
  }
  bool pos = deg > 0.f;
  labOut[(long)n*300 + tid]                       = pos ? (ln[tid]     - acc0) : ln[tid];
  if (tid+256 < 300) labOut[(long)n*300 + tid+256] = pos ? (ln[tid+256] - acc1) : ln[tid+256];
}

// ---------------- copy ----------------
__global__ void k_copy(const float* __restrict__ src, float* __restrict__ dst, long n){
  long i = (long)blockIdx.x*256+threadIdx.x; if (i<n) dst[i]=src[i];
}

// ---------------- code_wise reductions ----------------
__global__ void k_cw_rowmax(const float* __restrict__ S, float* __restrict__ Mv){
  const int ofs[4]={0,119,238,341};
  const int wid[4]={119,119,103,103};
  int s = blockIdx.y; int row = blockIdx.x*256+threadIdx.x;
  if (row < 16384){
    const float* p = S + (long)row*444 + ofs[s];
    float m = -3.4e38f;
    int w = wid[s];
    for (int n=0;n<w;n++) m = fmaxf(m, p[n]);
    Mv[(long)s*16384+row] = m;
  }
}
__global__ void k_cw_softmax(const float* __restrict__ Mv, float* __restrict__ att){
  int b=blockIdx.x, s=blockIdx.y, tid=threadIdx.x;
  const float* src = Mv + (long)s*16384 + (long)b*512;
  __shared__ float red[256];
  float v0 = src[tid], v1 = src[tid+256];
  red[tid] = fmaxf(v0,v1); __syncthreads();
  for (int o=128;o>0;o>>=1){ if (tid<o) red[tid]=fmaxf(red[tid],red[tid+o]); __syncthreads(); }
  float m = red[0]; __syncthreads();
  float e0=expf(v0-m), e1=expf(v1-m);
  red[tid]=e0+e1; __syncthreads();
  for (int o=128;o>0;o>>=1){ if (tid<o) red[tid]+=red[tid+o]; __syncthreads(); }
  float inv = 1.f/red[0];
  float* dst = att + ((long)s*32 + b)*512;
  dst[tid]=e0*inv; dst[tid+256]=e1*inv;
}
__global__ void k_cw_out(const float* __restrict__ att, const float* __restrict__ DH, float* __restrict__ outp){
  int b=blockIdx.x, s=blockIdx.y, tid=threadIdx.x;
  __shared__ float a[512];
  for (int i=tid;i<512;i+=256) a[i]=att[((long)s*32+b)*512+i];
  __syncthreads();
  for (int d=tid; d<300; d+=256){
    float acc=0.f;
    for (int t=0;t<512;t++) acc += a[t]*DH[((long)b*512+t)*300+d];
    outp[((long)s*32+b)*300+d]=acc;
  }
}

// ---------------- masked softmax over l=50 (in place) ----------------
__global__ void k_masksm(float* __restrict__ att, long nrows){
  long row = (long)blockIdx.x*256 + threadIdx.x;
  if (row >= nrows) return;
  float* p = att + row*50;
  float m = -INFINITY;
  for (int l=0;l<50;l++){ float a = p[l]; if (a != 0.f && a > m) m = a; }
  if (m == -INFINITY){ for (int l=0;l<50;l++) p[l] = 0.f; return; }
  float s = 0.f;
  for (int l=0;l<50;l++){ float a = p[l]; float e = (a==0.f) ? 0.f : expf(a-m); p[l]=e; s+=e; }
  float inv = 1.f/s;
  for (int l=0;l<50;l++) p[l] *= inv;
}

// ---------------- fact separation combine (rows of 300), 1 wave per row ----------------
// NOTE: no __restrict__ — call 2 intentionally aliases simOut=scen, diffOut=circ.
__global__ void k_factsep(const float* circ, const float* scen,
                          float* simOut, float* diffOut, long nrows)
{
  int lane = threadIdx.x & 63;
  long row = (long)blockIdx.x*4 + (threadIdx.x >> 6);
  if (row >= nrows) return;
  const float* c = circ + row*300;
  const float* s = scen + row*300;
  float x3=0.f, x4=0.f;
  for (int d=lane; d<300; d+=64){ float sv=s[d]; x3 += c[d]*sv; x4 += sv*sv; }
  for (int o=32;o>0;o>>=1){ x3 += __shfl_down(x3,o); x4 += __shfl_down(x4,o); }
  x3 = __shfl(x3,0); x4 = __shfl(x4,0);
  float coef = x3 / (x4 + 1e-10f);
  for (int d=lane; d<300; d+=64){
    float sv = s[d]; float cv = c[d];
    float sim = coef*sv;
    simOut[row*300+d] = sim;
    diffOut[row*300+d] = cv - sim;
  }
}

// ---------------- assemblers ----------------
__global__ void k_factart(const float* __restrict__ DH, const float* __restrict__ dha,
                          const float* __restrict__ adc, const float* __restrict__ db,
                          float* __restrict__ out)
{
  long row = blockIdx.x; int b = (int)(row >> 9);
  for (int c=threadIdx.x; c<1200; c+=256){
    float v;
    if (c < 300) v = DH[row*300 + c];
    else if (c < 600) v = dha[(long)b*300 + (c-300)];
    else if (c < 900) v = adc[row*300 + (c-600)];
    else v = db[(long)b*300 + (c-900)];
    out[row*1200 + c] = v;
  }
}
__global__ void k_termcat(const float* __restrict__ DH, const float* __restrict__ ssc,
                          const float* __restrict__ dsc, float* __restrict__ out){
  long row = blockIdx.x;
  for (int c=threadIdx.x; c<900; c+=256){
    float v = (c<300) ? DH[row*300+c] : (c<600 ? ssc[row*300+(c-300)] : dsc[row*300+(c-600)]);
    out[row*900+c] = v;
  }
}

// ---------------- classifier: logits -> fp32 out, optional argmax ----------------
__global__ __launch_bounds__(256) void k_classify(
    const float* __restrict__ s0, const float* __restrict__ s1, const float* __restrict__ s2,
    int L, int Kf, float scale,
    const float* __restrict__ W, const float* __restrict__ bias, int N,
    float* __restrict__ out, int* __restrict__ amax)
{
  int b = blockIdx.x; int tid = threadIdx.x;
  __shared__ float feat[1200];
  __shared__ float logit[128];
  for (int i=tid; i<Kf; i+=256){
    int seg = i / L, c = i % L;
    const float* s = (seg==0) ? s0 : (seg==1 ? s1 : s2);
    feat[i] = s[(long)b*L + c] * scale;
  }
  __syncthreads();
  for (int n=tid; n<N; n+=256){
    float acc = bias[n];
    const float* w = W + (long)n*Kf;
    for (int k=0;k<Kf;k++) acc += feat[k]*w[k];
    out[(long)b*N + n] = acc;
    logit[n] = acc;
  }
  __syncthreads();
  if (amax && tid==0){
    float best = logit[0]; int bi=0;
    for (int n=1;n<N;n++) if (logit[n] > best){ best=logit[n]; bi=n; }
    amax[b] = bi;
  }
}

static inline int cdiv(long a, long b){ return (int)((a + b - 1)/b); }

extern "C" void kernel_launch(void* const* d_in, const int* in_sizes, int n_in,
                              void* d_out, int out_size, void* d_ws, size_t ws_size,
                              hipStream_t stream)
{
  (void)in_sizes; (void)n_in; (void)out_size;
  const float* emb     = (const float*)d_in[0];
  const float* encWih  = (const float*)d_in[1];
  const float* encWhh  = (const float*)d_in[2];
  const float* encbih  = (const float*)d_in[3];
  const float* encbhh  = (const float*)d_in[4];
  const float* cchWih  = (const float*)d_in[5];
  const float* cchWhh  = (const float*)d_in[6];
  const float* cchbih  = (const float*)d_in[7];
  const float* cchbhh  = (const float*)d_in[8];
  const float* termWih = (const float*)d_in[9];
  const float* termWhh = (const float*)d_in[10];
  const float* termbih = (const float*)d_in[11];
  const float* termbhh = (const float*)d_in[12];
  const float* artWih  = (const float*)d_in[13];
  const float* artWhh  = (const float*)d_in[14];
  const float* artbih  = (const float*)d_in[15];
  const float* artbhh  = (const float*)d_in[16];
  const float* Wc      = (const float*)d_in[17];
  const float* bc      = (const float*)d_in[18];
  const float* Wa      = (const float*)d_in[19];
  const float* ba      = (const float*)d_in[20];
  const float* Wt_     = (const float*)d_in[21];
  const float* bt_     = (const float*)d_in[22];
  const int* docs    = (const int*)d_in[23];
  const int* chtok   = (const int*)d_in[24];
  const int* artok   = (const int*)d_in[25];
  const int* chnb    = (const int*)d_in[26];
  const int* chnbm   = (const int*)d_in[27];
  const int* arnb    = (const int*)d_in[28];
  const int* arnbm   = (const int*)d_in[29];
  const int* vchtok  = (const int*)d_in[30];
  const int* vartok  = (const int*)d_in[31];
  float* ob = (float*)d_out;
  float* ws = (float*)d_ws;

  // -------- workspace layout (float elements) --------
  constexpr long O_WTENC = 0;                       // 2*150*450
  constexpr long O_WTCCH = O_WTENC + 135000;        // 2*150*450
  constexpr long O_WTART = O_WTCCH + 135000;        // packed encWih (2*450*208 u32)
  constexpr long O_WTTERM= O_WTART + 2160000;       // packed cchWih (2*450*208 u32)
  constexpr long O_DH    = O_WTTERM + 1215000;      // 16384*300
  constexpr long O_DMEAN = O_DH + 4915200;          // 32*300
  constexpr long O_CHM   = O_DMEAN + 9600;          // 119*300
  constexpr long O_ARM   = O_CHM + 35700;           // 103*300
  constexpr long O_LAB   = O_ARM + 30900;           // 444*300
  constexpr long O_GDT   = O_LAB + 133200;          // 119*300 (barrier ints after decomp)
  constexpr long O_CWM   = O_GDT + 35700;           // 4*16384
  constexpr long O_CWA   = O_CWM + 65536;           // 4*32*512
  constexpr long O_CWO   = O_CWA + 65536;           // 4*32*300
  constexpr long O_CP    = O_CWO + 38400;           // 64 ints
  constexpr long O_VCH   = O_CP + 64;               // 32*50*300
  constexpr long O_VCHT  = O_VCH + 480000;          // 32*300*50
  constexpr long O_ATT   = O_VCHT + 480000;         // 32*512*50
  constexpr long O_SCEN  = O_ATT + 819200;          // 16384*300
  constexpr long O_ADC   = O_SCEN + 4915200;        // 16384*300
  constexpr long O_SEC   = O_ADC + 4915200;         // 16384*300
  constexpr long O_HBUF  = O_SEC + 4915200;         // h ping-pong
  constexpr long O_YSUM  = O_HBUF + 76800;          // 32*1200
  constexpr long O_GATH  = O_YSUM + 38400;          // 16384*200
  constexpr long O_XSS   = O_GATH + 3276800;        // 2*6592*450
  constexpr long O_PF    = O_XSS + 5932800;         // 16384*1200
  constexpr long O_XB    = O_PF + 19660800;         // 2*16384*1800
  constexpr long TOTAL   = O_XB + 58982400;         // ~454 MB
  if (ws_size < (size_t)TOTAL * 4) return;

  float* WT_ENC = ws + O_WTENC;
  float* WT_CCH = ws + O_WTCCH;
  unsigned* PWENC = (unsigned*)(ws + O_WTART);   // packed encWih [2][450][208]
  unsigned* PWCCH = (unsigned*)(ws + O_WTTERM);  // packed cchWih [2][450][208]
  float* DH     = ws + O_DH;
  float* DMEAN  = ws + O_DMEAN;
  float* CHM    = ws + O_CHM;
  float* ARM    = ws + O_ARM;
  float* LAB    = ws + O_LAB;
  float* GDT    = ws + O_GDT;
  float* CWM    = ws + O_CWM;
  float* CWA    = ws + O_CWA;
  float* CWO    = ws + O_CWO;
  int*   CP     = (int*)(ws + O_CP);
  int*   AP     = CP + 32;
  float* VCH    = ws + O_VCH;
  float* VCHT   = ws + O_VCHT;
  float* ATT    = ws + O_ATT;
  float* SCEN   = ws + O_SCEN;
  float* ADC    = ws + O_ADC;
  float* SEC    = ws + O_SEC;
  float* HBUF   = ws + O_HBUF;
  float* YSUM   = ws + O_YSUM;
  float* GATH   = ws + O_GATH;
  float* XSS    = ws + O_XSS;
  float* PF     = ws + O_PF;
  float* XB     = ws + O_XB;
  int*   FLAGS  = (int*)GDT;       // free after graph decomposition
  int*   GO     = FLAGS + 256;     // 4 quadrant go-words on separate lines

  // -------- transpose small Whh + pack input-proj weights (once) --------
  k_transpose<<<dim3(cdiv(450L*150,256),2),256,0,stream>>>(encWhh, WT_ENC, 450,150);
  k_transpose<<<dim3(cdiv(450L*150,256),2),256,0,stream>>>(cchWhh, WT_CCH, 450,150);
  k_packW<<<cdiv(900L*208,256),256,0,stream>>>(encWih, PWENC, 900, 200, 208);
  k_packW<<<cdiv(900L*208,256),256,0,stream>>>(cchWih, PWCCH, 900, 200, 208);

  // -------- charge token encoder (encch), mean only --------
  k_gather<<<3808,256,0,stream>>>(emb, chtok, GATH);
  k_packA<<<cdiv(3808L*200,256),256,0,stream>>>(GATH, 3808L*200);
  k_gemm_bf3<<<dim3(4,cdiv(3808,128),2),256,0,stream>>>((const unsigned*)GATH, PWCCH,
      cchbih, XSS, 3808, 450, 200, 208, 450L*208, 3808L*450, 450);
  k_gru_small<<<dim3(119,2),512,0,stream>>>(XSS, 3808L*450, WT_CCH, cchbhh,
      nullptr,0, CHM,300, 32);

  // -------- article token encoder (encch), mean only --------
  k_gather<<<6592,256,0,stream>>>(emb, artok, GATH);
  k_packA<<<cdiv(6592L*200,256),256,0,stream>>>(GATH, 6592L*200);
  k_gemm_bf3<<<dim3(4,cdiv(6592,128),2),256,0,stream>>>((const unsigned*)GATH, PWCCH,
      cchbih, XSS, 6592, 450, 200, 208, 450L*208, 6592L*450, 450);
  k_gru_small<<<dim3(103,2),512,0,stream>>>(XSS, 6592L*450, WT_CCH, cchbhh,
      nullptr,0, ARM,300, 64);

  // -------- originals + graph decomposition into label-cat --------
  k_copy<<<cdiv(35700,256),256,0,stream>>>(CHM, LAB + 119L*300, 35700);
  k_copy<<<cdiv(30900,256),256,0,stream>>>(ARM, LAB + 341L*300, 30900);
  k_graphdecomp<<<119,256,0,stream>>>(CHM, GDT, chnb, chnbm, 119);
  k_graphdecomp<<<119,256,0,stream>>>(GDT, LAB, chnb, chnbm, 119);
  k_graphdecomp<<<103,256,0,stream>>>(ARM, GDT, arnb, arnbm, 103);
  k_graphdecomp<<<103,256,0,stream>>>(GDT, LAB + 238L*300, arnb, arnbm, 103);

  // -------- document encoder (enc) -> d_hidden + doc_mean --------
  k_gather<<<16384,256,0,stream>>>(emb, docs, GATH);
  k_packA<<<cdiv(16384L*200,256),256,0,stream>>>(GATH, 16384L*200);
  k_gemm_bf3<<<dim3(4,128,2),256,0,stream>>>((const unsigned*)GATH, PWENC,
      encbih, PF, 16384, 450, 200, 208, 450L*208, 16384L*450, 450);
  k_gru_small<<<dim3(32,2),512,0,stream>>>(PF, 16384L*450, WT_ENC, encbhh,
      DH,300, DMEAN,300, 512);

  // -------- code_wise (4 label sets at once), split-bf16 --------
  k_packAc<<<cdiv(16384L*300,256),256,0,stream>>>(DH, (unsigned*)XB, 16384L*300);
  k_packW<<<cdiv(444L*304,256),256,0,stream>>>(LAB, (unsigned*)XB + 16384L*300, 444, 300, 304);
  k_gemm_bf3<<<dim3(4,128,1),256,0,stream>>>((const unsigned*)XB, (const unsigned*)XB + 16384L*300,
      nullptr, PF, 16384, 444, 300, 304, 0, 0, 0);
  k_cw_rowmax<<<dim3(64,4),256,0,stream>>>(PF, CWM);
  k_cw_softmax<<<dim3(32,4),256,0,stream>>>(CWM, CWA);
  k_cw_out<<<dim3(32,4),256,0,stream>>>(CWA, DH, CWO);

  // -------- charge classifier + argmax --------
  k_classify<<<32,256,0,stream>>>(DMEAN, CWO, CWO + 32L*300,
      300, 900, 1.f, Wc, bc, 119, ob, CP);

  // -------- verdict-charge GRU (enc) --------
  k_gather_sel<<<dim3(50,32),256,0,stream>>>(emb, vchtok, CP, GATH);
  k_packA<<<cdiv(1600L*200,256),256,0,stream>>>(GATH, 1600L*200);
  k_gemm_bf3<<<dim3(4,13,2),256,0,stream>>>((const unsigned*)GATH, PWENC,
      encbih, XSS, 1600, 450, 200, 208, 450L*208, 1600L*450, 450);
  k_gru_small<<<dim3(32,2),512,0,stream>>>(XSS, 1600L*450, WT_ENC, encbhh,
      VCH,300, nullptr,0, 50);

  // -------- fact separation 1 (vch vs d_hidden) --------
  k_gemm128<<<dim3(1,4,32),256,0,stream>>>(DH, VCH, nullptr, ATT,
      512,50,300, 512L*300, 50L*300, 512L*50, 0);
  k_masksm<<<64,256,0,stream>>>(ATT, 16384);
  k_transpose<<<dim3(cdiv(15000,256),32),256,0,stream>>>(VCH, VCHT, 50, 300);
  k_gemm128<<<dim3(3,4,32),256,0,stream>>>(ATT, VCHT, nullptr, SCEN,
      512,300,50, 512L*50, 300L*50, 512L*300, 0);
  k_factsep<<<4096,256,0,stream>>>(DH, SCEN, ADC, SEC, 16384);

  // -------- fact_article: split-bf16 MFMA projection + persistent art GRU --------
  k_factart<<<16384,256,0,stream>>>(DH, CWO + 2L*32*300, ADC, CWO + 3L*32*300, PF);
  k_packA<<<cdiv(16384L*1200,256),256,0,stream>>>(PF, 16384L*1200);
  k_packW<<<cdiv(2L*1800*1216,256),256,0,stream>>>(artWih, (unsigned*)XSS, 2*1800, 1200, 1216);
  k_gemm_bf3<<<dim3(15,128,2),256,0,stream>>>((const unsigned*)PF, (const unsigned*)XSS,
      artbih, XB, 16384, 1800, 1200, 1216, 1800L*1216, 16384L*1800, 1800);
  hipMemsetAsync(FLAGS, 0, 512*sizeof(int), stream);
  hipMemsetAsync(HBUF, 0, 76800*sizeof(float), stream);
  k_gru_persist<600,600,604,604,100,60><<<240,256,0,stream>>>(
      XB, 16384L*1800, artWhh, artbhh, HBUF, HBUF+38400, YSUM, 1200, 512, FLAGS, GO);
  k_classify<<<32,256,0,stream>>>(YSUM, nullptr, nullptr,
      1200, 1200, 1.f/512.f, Wa, ba, 103, ob + 3808, AP);

  // -------- verdict-article GRU (enc) --------
  k_gather_sel<<<dim3(50,32),256,0,stream>>>(emb, vartok, AP, GATH);
  k_packA<<<cdiv(1600L*200,256),256,0,stream>>>(GATH, 1600L*200);
  k_gemm_bf3<<<dim3(4,13,2),256,0,stream>>>((const unsigned*)GATH, PWENC,
      encbih, XSS, 1600, 450, 200, 208, 450L*208, 1600L*450, 450);
  k_gru_small<<<dim3(32,2),512,0,stream>>>(XSS, 1600L*450, WT_ENC, encbhh,
      VCH,300, nullptr,0, 50);

  // -------- fact separation 2 (var vs sec); ssc->SCEN, dsc->SEC in place --------
  k_gemm128<<<dim3(1,4,32),256,0,stream>>>(SEC, VCH, nullptr, ATT,
      512,50,300, 512L*300, 50L*300, 512L*50, 0);
  k_masksm<<<64,256,0,stream>>>(ATT, 16384);
  k_transpose<<<dim3(cdiv(15000,256),32),256,0,stream>>>(VCH, VCHT, 50, 300);
  k_gemm128<<<dim3(3,4,32),256,0,stream>>>(ATT, VCHT, nullptr, SCEN,
      512,300,50, 512L*50, 300L*50, 512L*300, 0);
  k_factsep<<<4096,256,0,stream>>>(SEC, SCEN, SCEN, SEC, 16384);

  // -------- term bigru: split-bf16 MFMA projection + persistent GRU --------
  k_termcat<<<16384,256,0,stream>>>(DH, SCEN, SEC, PF);
  k_packA<<<cdiv(16384L*900,256),256,0,stream>>>(PF, 16384L*900);
  k_packW<<<cdiv(2L*1350*912,256),256,0,stream>>>(termWih, (unsigned*)GATH, 2*1350, 900, 912);
  k_gemm_bf3<<<dim3(11,128,2),256,0,stream>>>((const unsigned*)PF, (const unsigned*)GATH,
      termbih, XB, 16384, 1350, 900, 912, 1350L*912, 16384L*1350, 1350);
  hipMemsetAsync(FLAGS, 0, 512*sizeof(int), stream);
  hipMemsetAsync(HBUF, 0, 76800*sizeof(float), stream);
  k_gru_persist<450,456,460,460,76,45><<<180,256,0,stream>>>(
      XB, 16384L*1350, termWhh, termbhh, HBUF, HBUF+29184, YSUM, 900, 512, FLAGS, GO);
  k_classify<<<32,256,0,stream>>>(YSUM, nullptr, nullptr,
      900, 900, 1.f/512.f, Wt_, bt_, 11, ob + 7104, nullptr);
}

// Round 12
// 12205.550 us; speedup vs baseline: 6.9262x; 1.0887x over previous
//
#include <hip/hip_runtime.h>
#include <hip/hip_bf16.h>

#define DEVI __device__ __forceinline__

DEVI float sigm(float x){ return 1.f/(1.f+expf(-x)); }

typedef int v4i __attribute__((ext_vector_type(4)));
typedef float f4 __attribute__((ext_vector_type(4)));
using bf16x8 = __attribute__((ext_vector_type(8))) short;

// SRSRC for raw untyped dword access (stride=0, num_records=bytes)
DEVI v4i make_srsrc(const void* p, unsigned bytes){
  unsigned long long a = (unsigned long long)p;
  v4i r;
  r.x = (int)(a & 0xFFFFFFFFull);
  r.y = (int)((a >> 32) & 0xFFFFull);
  r.z = (int)bytes;
  r.w = 0x00020000;
  return r;
}

// split-bf16 pack: hi = bf16_rne(a) in top 16 bits, lo = bf16_rne(a - hi) in low 16
DEVI unsigned packsplit(float a){
  unsigned u = __float_as_uint(a);
  unsigned hi = (u + 0x7fffu + ((u >> 16) & 1u)) & 0xffff0000u;
  float res = a - __uint_as_float(hi);
  unsigned v = __float_as_uint(res);
  unsigned lo = ((v + 0x7fffu + ((v >> 16) & 1u)) >> 16) & 0xffffu;
  return hi | lo;
}

// ---------------- transpose: out[b][c][r] = in[b][r][c] ----------------
__global__ void k_transpose(const float* __restrict__ in, float* __restrict__ out, int R, int C){
  int b = blockIdx.y;
  long n = (long)R*C;
  long i = (long)blockIdx.x*256 + threadIdx.x;
  if (i < n){
    int r = (int)(i / C), c = (int)(i % C);
    out[(long)b*n + (long)c*R + r] = in[(long)b*n + i];
  }
}

// ---------------- embedding gathers (D=200), write split-bf16 packed ----------------
__global__ void k_gather_p(const float* __restrict__ emb, const int* __restrict__ tok, unsigned* __restrict__ out){
  int row = blockIdx.x; int c = threadIdx.x;
  if (c < 200) out[(long)row*200 + c] = packsplit(emb[(long)tok[row]*200 + c]);
}
__global__ void k_gather_sel_p(const float* __restrict__ emb, const int* __restrict__ tok, const int* __restrict__ sel, unsigned* __restrict__ out){
  int t = blockIdx.x, b = blockIdx.y; int c = threadIdx.x;
  if (c < 200){
    int tk = tok[(long)sel[b]*50 + t];
    out[((long)b*50 + t)*200 + c] = packsplit(emb[(long)tk*200 + c]);
  }
}

// ---------------- split-bf16 pack kernels ----------------
// pack with copy (src preserved): dst[i] = packsplit(src[i])
__global__ void k_packAc(const float* __restrict__ src, unsigned* __restrict__ dst, long n){
  long i = (long)blockIdx.x*256 + threadIdx.x;
  if (i < n) dst[i] = packsplit(src[i]);
}
__global__ void k_packW(const float* __restrict__ src, unsigned* __restrict__ dst, int R, int K, int KP){
  long i = (long)blockIdx.x*256 + threadIdx.x;
  if (i < (long)R*KP){
    int r = (int)(i / KP), k = (int)(i % KP);
    dst[i] = (k < K) ? packsplit(src[(long)r*K + k]) : 0u;
  }
}

// ---------------- split-bf16 MFMA NT-GEMM: C = A(M,K) @ W(N,K)^T + bias ----------------
// A packed u32 (hi bf16 | lo bf16) [M][K]; W packed [z][N][KP]. 128x128 tile, BK=64.
// a = ah + al, w = wh + wl; a*w ~ ah*wh + al*wh + ah*wl (drop al*wl ~ 2^-18).
__global__ __launch_bounds__(256) void k_gemm_bf3(
    const unsigned* __restrict__ Ap, const unsigned* __restrict__ Wp,
    const float* __restrict__ bias, float* __restrict__ C,
    int M, int N, int K, int KP, long sW, long sC, long sBias)
{
  int dir = blockIdx.z;
  Wp += (long)dir*sW; C += (long)dir*sC;
  if (bias) bias += (long)dir*sBias;
  int n0 = blockIdx.x*128, m0 = blockIdx.y*128;
  __shared__ unsigned short Ah[128*72], Al[128*72], Bh[128*72], Bl[128*72];
  int tid = threadIdx.x;
  int w = tid >> 6, lane = tid & 63;
  int l15 = lane & 15, lg = lane >> 4;
  f4 acc[2][8] = {};

  for (int k0 = 0; k0 < K; k0 += 64){
    __syncthreads();
    for (int u = tid; u < 2048; u += 256){
      int r = u >> 4, q = u & 15;
      int k = k0 + q*4;
      uint4 pa = make_uint4(0,0,0,0);
      if (k + 4 <= K) pa = *(const uint4*)&Ap[(long)(m0 + r)*K + k];
      ushort4 h4, s4;
      h4.x=(unsigned short)(pa.x>>16); s4.x=(unsigned short)(pa.x&0xffff);
      h4.y=(unsigned short)(pa.y>>16); s4.y=(unsigned short)(pa.y&0xffff);
      h4.z=(unsigned short)(pa.z>>16); s4.z=(unsigned short)(pa.z&0xffff);
      h4.w=(unsigned short)(pa.w>>16); s4.w=(unsigned short)(pa.w&0xffff);
      *(ushort4*)&Ah[r*72 + q*4] = h4;
      *(ushort4*)&Al[r*72 + q*4] = s4;
      int n = n0 + r;
      uint4 pw = make_uint4(0,0,0,0);
      if (n < N && k + 4 <= KP) pw = *(const uint4*)&Wp[(long)n*KP + k];
      ushort4 wh, wl;
      wh.x=(unsigned short)(pw.x>>16); wl.x=(unsigned short)(pw.x&0xffff);
      wh.y=(unsigned short)(pw.y>>16); wl.y=(unsigned short)(pw.y&0xffff);
      wh.z=(unsigned short)(pw.z>>16); wl.z=(unsigned short)(pw.z&0xffff);
      wh.w=(unsigned short)(pw.w>>16); wl.w=(unsigned short)(pw.w&0xffff);
      *(ushort4*)&Bh[r*72 + q*4] = wh;
      *(ushort4*)&Bl[r*72 + q*4] = wl;
    }
    __syncthreads();
    bf16x8 ah[2][2], al[2][2];
    #pragma unroll
    for (int fm=0; fm<2; fm++)
      #pragma unroll
      for (int ks=0; ks<2; ks++){
        int idx = (w*32 + fm*16 + l15)*72 + ks*32 + lg*8;
        ah[fm][ks] = *(const bf16x8*)&Ah[idx];
        al[fm][ks] = *(const bf16x8*)&Al[idx];
      }
    #pragma unroll
    for (int fn=0; fn<8; fn++){
      int bidx0 = (fn*16 + l15)*72 + lg*8;
      bf16x8 bh0 = *(const bf16x8*)&Bh[bidx0];
      bf16x8 bh1 = *(const bf16x8*)&Bh[bidx0 + 32];
      bf16x8 bl0 = *(const bf16x8*)&Bl[bidx0];
      bf16x8 bl1 = *(const bf16x8*)&Bl[bidx0 + 32];
      #pragma unroll
      for (int fm=0; fm<2; fm++){
        f4 a = acc[fm][fn];
        a = __builtin_amdgcn_mfma_f32_16x16x32_bf16(ah[fm][0], bh0, a, 0, 0, 0);
        a = __builtin_amdgcn_mfma_f32_16x16x32_bf16(al[fm][0], bh0, a, 0, 0, 0);
        a = __builtin_amdgcn_mfma_f32_16x16x32_bf16(ah[fm][0], bl0, a, 0, 0, 0);
        a = __builtin_amdgcn_mfma_f32_16x16x32_bf16(ah[fm][1], bh1, a, 0, 0, 0);
        a = __builtin_amdgcn_mfma_f32_16x16x32_bf16(al[fm][1], bh1, a, 0, 0, 0);
        a = __builtin_amdgcn_mfma_f32_16x16x32_bf16(ah[fm][1], bl1, a, 0, 0, 0);
        acc[fm][fn] = a;
      }
    }
  }
  #pragma unroll
  for (int fm=0; fm<2; fm++)
    #pragma unroll
    for (int fn=0; fn<8; fn++){
      int row = m0 + w*32 + fm*16 + lg*4;
      int col = n0 + fn*16 + l15;
      if (col < N){
        float bv = bias ? bias[col] : 0.f;
        #pragma unroll
        for (int r2=0; r2<4; r2++)
          if (row + r2 < M)                       // tail-M guard: z-blocks race otherwise
            C[(long)(row+r2)*N + col] = acc[fm][fn][r2] + bv;
      }
    }
}

// ---------------- fp32 GEMM 128x128 tile, 8x8 micro (small fact-sep GEMMs) ----------------
__global__ __launch_bounds__(256) void k_gemm128(
    const float* __restrict__ A, const float* __restrict__ W,
    const float* __restrict__ bias, float* __restrict__ C,
    int M, int N, int K, long sA, long sW, long sC, long sBias)
{
  int bz = blockIdx.z;
  A += (long)bz*sA; W += (long)bz*sW; C += (long)bz*sC;
  if (bias) bias += (long)bz*sBias;
  int n0 = blockIdx.x*128, m0 = blockIdx.y*128;
  __shared__ float As[16][132];
  __shared__ float Bs[16][132];
  int tid = threadIdx.x;
  int tx = tid & 15, ty = tid >> 4;
  float acc[8][8] = {};
  const bool k4 = ((K & 3) == 0);
  for (int k0 = 0; k0 < K; k0 += 16){
    #pragma unroll
    for (int half = 0; half < 2; half++){
      int s = tid + half*256;
      int r = s >> 2;
      int kq = (s & 3) << 2;
      int k = k0 + kq;
      int m = m0 + r;
      float4 va = make_float4(0.f,0.f,0.f,0.f);
      if (m < M){
        if (k4 && k + 3 < K) va = *(const float4*)&A[(long)m*K + k];
        else {
          float* pv = (float*)&va;
          #pragma unroll
          for (int u=0; u<4; u++) if (k+u < K) pv[u] = A[(long)m*K + k + u];
        }
      }
      As[kq+0][r]=va.x; As[kq+1][r]=va.y; As[kq+2][r]=va.z; As[kq+3][r]=va.w;
      int n = n0 + r;
      float4 vb = make_float4(0.f,0.f,0.f,0.f);
      if (n < N){
        if (k4 && k + 3 < K) vb = *(const float4*)&W[(long)n*K + k];
        else {
          float* pv = (float*)&vb;
          #pragma unroll
          for (int u=0; u<4; u++) if (k+u < K) pv[u] = W[(long)n*K + k + u];
        }
      }
      Bs[kq+0][r]=vb.x; Bs[kq+1][r]=vb.y; Bs[kq+2][r]=vb.z; Bs[kq+3][r]=vb.w;
    }
    __syncthreads();
    #pragma unroll
    for (int kk=0;kk<16;kk++){
      float a[8], b[8];
      *(float4*)&a[0] = *(const float4*)&As[kk][ty*8];
      *(float4*)&a[4] = *(const float4*)&As[kk][ty*8+4];
      *(float4*)&b[0] = *(const float4*)&Bs[kk][tx*8];
      *(float4*)&b[4] = *(const float4*)&Bs[kk][tx*8+4];
      #pragma unroll
      for (int i=0;i<8;i++)
        #pragma unroll
        for (int j=0;j<8;j++)
          acc[i][j] += a[i]*b[j];
    }
    __syncthreads();
  }
  #pragma unroll
  for (int i=0;i<8;i++){
    int m = m0 + ty*8 + i;
    if (m >= M) continue;
    #pragma unroll
    for (int j=0;j<8;j++){
      int n = n0 + tx*8 + j;
      if (n < N) C[(long)m*N + n] = acc[i][j] + (bias ? bias[n] : 0.f);
    }
  }
}

// ---------------- small GRU (h=150, 3h=450), 1 wg per (item,dir) ----------------
__global__ __launch_bounds__(512) void k_gru_small(
    const float* __restrict__ xs, long xsDir,
    const float* __restrict__ Wt, const float* __restrict__ bhh,
    float* __restrict__ y, int yld,
    float* __restrict__ meanOut, int meanld,
    int T)
{
  int item = blockIdx.x, dir = blockIdx.y;
  const float* xsd = xs + (long)dir*xsDir + (long)item*T*450;
  const float* Wtd = Wt + (long)dir*150*450;
  int tid = threadIdx.x;
  float bh = (tid < 450) ? bhh[(long)dir*450 + tid] : 0.f;
  __shared__ float hs[152];
  __shared__ float gs[456];
  if (tid < 150) hs[tid] = 0.f;
  float hsum = 0.f;
  __syncthreads();
  for (int t=0;t<T;t++){
    int tt = dir ? (T-1-t) : t;
    if (tid < 450){
      float g = bh;
      const float* wp = Wtd + tid;
      #pragma unroll 15
      for (int k=0;k<150;k++) g += hs[k] * wp[(long)k*450];
      gs[tid] = g;
    }
    __syncthreads();
    if (tid < 150){
      const float* xr = xsd + (long)tt*450;
      float r = sigm(xr[tid]     + gs[tid]);
      float z = sigm(xr[150+tid] + gs[150+tid]);
      float nn = tanhf(xr[300+tid] + r*gs[300+tid]);
      float h = (1.f-z)*nn + z*hs[tid];
      hs[tid] = h;
      hsum += h;
      if (y) y[((long)item*T + tt)*yld + dir*150 + tid] = h;
    }
    __syncthreads();
  }
  if (meanOut && tid < 150)
    meanOut[(long)item*meanld + dir*150 + tid] = hsum / (float)T;
}

// ---------------- persistent big GRU, fence-free relaxed-atomic exchange ----------------
#define GDOT(AC, W, A) AC += W.x*A.x + W.y*A.y + W.z*A.z + W.w*A.w;
template<int H, int HS, int LDW, int HPAD, int KL, int NCB>
__global__ __launch_bounds__(256) void k_gru_persist(
    const float* __restrict__ xs, long xsDir,
    const float* __restrict__ Whh, const float* __restrict__ bhh,
    float* hA, float* hB,
    float* __restrict__ ysum, int ysld,
    int T, int* flags, int* go)
{
  constexpr int H3 = 3*H;
  constexpr int CPR = HS/4;              // 16B chunks per item row
  constexpr int NCH = 16*CPR;            // chunks per step per wg
  constexpr int NIT = (NCH + 255)/256;   // chunks per thread (static)
  int wid = blockIdx.x;
  int dir = wid / (2*NCB);
  int rem = wid % (2*NCB);
  int bb  = rem / NCB;
  int cb  = rem % NCB;
  int quad = dir*2 + bb;
  int qbase = quad*64;
  int c0  = cb*10;
  int tid = threadIdx.x;

  const float* xsd = xs + (long)dir*xsDir;
  const float* Wd  = Whh + (long)dir*(long)H*H3;   // [3H][H] row-major
  const float* bhd = bhh + (long)dir*H3;

  __shared__ float hs[16*HPAD];
  __shared__ float Wl[30*LDW];
  __shared__ float blds[32];
  __shared__ float gl[30*16];
  __shared__ float part[240*12];

  for (int u = tid; u < 30*HS; u += 256){
    int r = u / HS, k = u % HS;
    long row = (long)(r/10)*H + c0 + (r%10);
    Wl[r*LDW + k] = (k < H) ? Wd[row*H + k] : 0.f;
  }
  if (tid < 30) blds[tid] = bhd[(long)(tid/10)*H + (c0 + tid%10)];

  int ks = tid / 40;
  int rem2 = tid % 40;
  int rg = rem2 / 4;
  int ig = rem2 % 4;
  bool alive = (tid < 240);
  int r0 = rg*3;
  int it0 = ig*4;
  int kbase = ks*KL;

  int uit = tid / 10, uci = tid % 10;
  int uc = c0 + uci;
  int ub = bb*16 + uit;
  float ysacc = 0.f;

  float xv0 = 0.f, xv1 = 0.f, xv2 = 0.f;
  if (tid < 160){
    int tt0 = dir ? (T-1) : 0;
    const float* xr = xsd + ((long)ub*T + tt0)*H3;
    xv0 = xr[uc]; xv1 = xr[H+uc]; xv2 = xr[2*H+uc];
  }

  __syncthreads();

  for (int t=0; t<T; t++){
    float* hp = ((t & 1) ? hB : hA) + (long)dir*32*HS;
    float* hn = ((t & 1) ? hA : hB) + (long)dir*32*HS;

    {
      v4i srsrc = make_srsrc(hp, 32u*HS*4u);
      f4 sbuf[NIT];
      #pragma unroll
      for (int i = 0; i < NIT; i++){
        int u = tid + i*256;
        if (u < NCH){
          int voff = ((bb*16 + u/CPR)*HS + (u%CPR)*4)*4;
          asm volatile("buffer_load_dwordx4 %0, %1, %2, 0 offen sc0 sc1"
                       : "=v"(sbuf[i]) : "v"(voff), "s"(srsrc));
        }
      }
      asm volatile("s_waitcnt vmcnt(0)" ::: "memory");
      __builtin_amdgcn_sched_barrier(0);
      #pragma unroll
      for (int i = 0; i < NIT; i++){
        int u = tid + i*256;
        if (u < NCH)
          *(f4*)&hs[(u/CPR)*HPAD + (u%CPR)*4] = sbuf[i];
      }
    }
    __syncthreads();

    if (alive){
      float acc[3][4];
      #pragma unroll
      for (int a=0;a<3;a++)
        #pragma unroll
        for (int b=0;b<4;b++) acc[a][b] = 0.f;
      const float* wr0 = &Wl[(r0+0)*LDW + kbase];
      const float* wr1 = &Wl[(r0+1)*LDW + kbase];
      const float* wr2 = &Wl[(r0+2)*LDW + kbase];
      const float* h0  = &hs[(it0+0)*HPAD + kbase];
      const float* h1  = &hs[(it0+1)*HPAD + kbase];
      const float* h2  = &hs[(it0+2)*HPAD + kbase];
      const float* h3  = &hs[(it0+3)*HPAD + kbase];
      for (int jq = 0; jq < KL; jq += 4){
        float4 w0 = *(const float4*)&wr0[jq];
        float4 w1 = *(const float4*)&wr1[jq];
        float4 w2 = *(const float4*)&wr2[jq];
        float4 a0 = *(const float4*)&h0[jq];
        float4 a1 = *(const float4*)&h1[jq];
        float4 a2 = *(const float4*)&h2[jq];
        float4 a3 = *(const float4*)&h3[jq];
        GDOT(acc[0][0], w0, a0) GDOT(acc[0][1], w0, a1) GDOT(acc[0][2], w0, a2) GDOT(acc[0][3], w0, a3)
        GDOT(acc[1][0], w1, a0) GDOT(acc[1][1], w1, a1) GDOT(acc[1][2], w1, a2) GDOT(acc[1][3], w1, a3)
        GDOT(acc[2][0], w2, a0) GDOT(acc[2][1], w2, a1) GDOT(acc[2][2], w2, a2) GDOT(acc[2][3], w2, a3)
      }
      #pragma unroll
      for (int a=0;a<3;a++)
        *(float4*)&part[tid*12 + a*4] = make_float4(acc[a][0],acc[a][1],acc[a][2],acc[a][3]);
    }
    __syncthreads();

    if (alive){
      #pragma unroll
      for (int vv=0; vv<2; vv++){
        int v = tid + vv*240;
        int row = v >> 4, item = v & 15;
        int base = ((row/3)*4 + (item>>2))*12 + (row%3)*4 + (item&3);
        float sum = blds[row];
        #pragma unroll
        for (int s=0; s<6; s++) sum += part[s*480 + base];
        gl[row*16 + item] = sum;
      }
    }
    __syncthreads();

    if (tid < 160){
      float r  = sigm(xv0 + gl[(uci)*16    + uit]);
      float z  = sigm(xv1 + gl[(10+uci)*16 + uit]);
      float nn = tanhf(xv2 + r*gl[(20+uci)*16 + uit]);
      float hv = hs[uit*HPAD + uc];
      float hne = (1.f-z)*nn + z*hv;
      __hip_atomic_store(&hn[(long)ub*HS + uc], hne, __ATOMIC_RELAXED, __HIP_MEMORY_SCOPE_AGENT);
      ysacc += hne;
    }
    __syncthreads();

    float nx0 = 0.f, nx1 = 0.f, nx2 = 0.f;
    if (tid < 160 && t+1 < T){
      int tt1 = dir ? (T-2-t) : (t+1);
      const float* xr = xsd + ((long)ub*T + tt1)*H3;
      nx0 = xr[uc]; nx1 = xr[H+uc]; nx2 = xr[2*H+uc];
    }

    if (t+1 < T){
      if (tid == 0)
        __hip_atomic_store(&flags[qbase + cb], t+1, __ATOMIC_RELAXED, __HIP_MEMORY_SCOPE_AGENT);
      if (cb == 0){
        if (tid < NCB){
          while (__hip_atomic_load(&flags[qbase + tid], __ATOMIC_RELAXED, __HIP_MEMORY_SCOPE_AGENT) < t+1)
            __builtin_amdgcn_s_sleep(2);
        }
        __syncthreads();
        if (tid == 0)
          __hip_atomic_store(&go[quad*32], t+1, __ATOMIC_RELAXED, __HIP_MEMORY_SCOPE_AGENT);
      } else {
        if (tid == 0){
          while (__hip_atomic_load(&go[quad*32], __ATOMIC_RELAXED, __HIP_MEMORY_SCOPE_AGENT) < t+1)
            __builtin_amdgcn_s_sleep(2);
        }
        __syncthreads();
      }
    }
    xv0 = nx0; xv1 = nx1; xv2 = nx2;
  }
  if (tid < 160)
    ysum[(long)ub*ysld + dir*H + uc] = ysacc;
}

// ---------------- graph decomposition layer (D=300, K=8) ----------------
__global__ __launch_bounds__(256) void k_graphdecomp(
   const float* __restrict__ labIn, float* __restrict__ labOut,
   const int* __restrict__ nb, const int* __restrict__ nbm, int N)
{
  int n = blockIdx.x; if (n >= N) return;
  int tid = threadIdx.x;
  __shared__ float ln[300];
  __shared__ float red[12];
  for (int d=tid; d<300; d+=256) ln[d] = labIn[(long)n*300+d];
  float deg = 0.f;
  for (int k=0;k<8;k++) deg += (float)nbm[n*8+k];
  float invdeg = 1.f / fmaxf(deg, 1.f);
  float acc0 = 0.f, acc1 = 0.f;
  __syncthreads();
  for (int k=0;k<8;k++){
    int j = nb[n*8+k];
    float mk = (float)nbm[n*8+k];
    const float* lj = labIn + (long)j*300;
    float p1=0.f, p2=0.f;
    for (int d=tid; d<300; d+=256){ float v = lj[d]; p1 += ln[d]*v; p2 += v*v; }
    for (int o=32;o>0;o>>=1){ p1 += __shfl_down(p1,o); p2 += __shfl_down(p2,o); }
    __syncthreads();
    int w = tid>>6, lane = tid&63;
    if (lane==0){ red[w]=p1; red[4+w]=p2; }
    __syncthreads();
    float x1 = red[0]+red[1]+red[2]+red[3];
    float x2 = red[4]+red[5]+red[6]+red[7];
    float coef = (x1 / (x2 + 1e-10f)) * mk * invdeg;
    acc0 += coef * lj[tid];
    if (tid + 256 < 300) acc1 += coef * lj[tid+256];
    __syncthreads();
  }
  bool pos = deg > 0.f;
  labOut[(long)n*300 + tid]                       = pos ? (ln[tid]     - acc0) : ln[tid];
  if (tid+256 < 300) labOut[(long)n*300 + tid+256] = pos ? (ln[tid+256] - acc1) : ln[tid+256];
}

// ---------------- copy ----------------
__global__ void k_copy(const float* __restrict__ src, float* __restrict__ dst, long n){
  long i = (long)blockIdx.x*256+threadIdx.x; if (i<n) dst[i]=src[i];
}

// ---------------- code_wise reductions ----------------
__global__ void k_cw_rowmax(const float* __restrict__ S, float* __restrict__ Mv){
  const int ofs[4]={0,119,238,341};
  const int wid[4]={119,119,103,103};
  int s = blockIdx.y; int row = blockIdx.x*256+threadIdx.x;
  if (row < 16384){
    const float* p = S + (long)row*444 + ofs[s];
    float m = -3.4e38f;
    int w = wid[s];
    for (int n=0;n<w;n++) m = fmaxf(m, p[n]);
    Mv[(long)s*16384+row] = m;
  }
}
__global__ void k_cw_softmax(const float* __restrict__ Mv, float* __restrict__ att){
  int b=blockIdx.x, s=blockIdx.y, tid=threadIdx.x;
  const float* src = Mv + (long)s*16384 + (long)b*512;
  __shared__ float red[256];
  float v0 = src[tid], v1 = src[tid+256];
  red[tid] = fmaxf(v0,v1); __syncthreads();
  for (int o=128;o>0;o>>=1){ if (tid<o) red[tid]=fmaxf(red[tid],red[tid+o]); __syncthreads(); }
  float m = red[0]; __syncthreads();
  float e0=expf(v0-m), e1=expf(v1-m);
  red[tid]=e0+e1; __syncthreads();
  for (int o=128;o>0;o>>=1){ if (tid<o) red[tid]+=red[tid+o]; __syncthreads(); }
  float inv = 1.f/red[0];
  float* dst = att + ((long)s*32 + b)*512;
  dst[tid]=e0*inv; dst[tid+256]=e1*inv;
}
__global__ void k_cw_out(const float* __restrict__ att, const float* __restrict__ DH, float* __restrict__ outp){
  int b=blockIdx.x, s=blockIdx.y, tid=threadIdx.x;
  __shared__ float a[512];
  for (int i=tid;i<512;i+=256) a[i]=att[((long)s*32+b)*512+i];
  __syncthreads();
  for (int d=tid; d<300; d+=256){
    float acc=0.f;
    for (int t=0;t<512;t++) acc += a[t]*DH[((long)b*512+t)*300+d];
    outp[((long)s*32+b)*300+d]=acc;
  }
}

// ---------------- masked softmax over l=50 (in place) ----------------
__global__ void k_masksm(float* __restrict__ att, long nrows){
  long row = (long)blockIdx.x*256 + threadIdx.x;
  if (row >= nrows) return;
  float* p = att + row*50;
  float m = -INFINITY;
  for (int l=0;l<50;l++){ float a = p[l]; if (a != 0.f && a > m) m = a; }
  if (m == -INFINITY){ for (int l=0;l<50;l++) p[l] = 0.f; return; }
  float s = 0.f;
  for (int l=0;l<50;l++){ float a = p[l]; float e = (a==0.f) ? 0.f : expf(a-m); p[l]=e; s+=e; }
  float inv = 1.f/s;
  for (int l=0;l<50;l++) p[l] *= inv;
}

// ---------------- fact separation combine (rows of 300), 1 wave per row ----------------
// NOTE: no __restrict__ — call 2 intentionally aliases simOut=scen, diffOut=circ.
__global__ void k_factsep(const float* circ, const float* scen,
                          float* simOut, float* diffOut, long nrows)
{
  int lane = threadIdx.x & 63;
  long row = (long)blockIdx.x*4 + (threadIdx.x >> 6);
  if (row >= nrows) return;
  const float* c = circ + row*300;
  const float* s = scen + row*300;
  float x3=0.f, x4=0.f;
  for (int d=lane; d<300; d+=64){ float sv=s[d]; x3 += c[d]*sv; x4 += sv*sv; }
  for (int o=32;o>0;o>>=1){ x3 += __shfl_down(x3,o); x4 += __shfl_down(x4,o); }
  x3 = __shfl(x3,0); x4 = __shfl(x4,0);
  float coef = x3 / (x4 + 1e-10f);
  for (int d=lane; d<300; d+=64){
    float sv = s[d]; float cv = c[d];
    float sim = coef*sv;
    simOut[row*300+d] = sim;
    diffOut[row*300+d] = cv - sim;
  }
}

// ---------------- assemblers (emit split-bf16 packed directly) ----------------
__global__ void k_factart_p(const float* __restrict__ DH, const float* __restrict__ dha,
                            const float* __restrict__ adc, const float* __restrict__ db,
                            unsigned* __restrict__ out)
{
  long row = blockIdx.x; int b = (int)(row >> 9);
  for (int c=threadIdx.x; c<1200; c+=256){
    float v;
    if (c < 300) v = DH[row*300 + c];
    else if (c < 600) v = dha[(long)b*300 + (c-300)];
    else if (c < 900) v = adc[row*300 + (c-600)];
    else v = db[(long)b*300 + (c-900)];
    out[row*1200 + c] = packsplit(v);
  }
}
__global__ void k_termcat_p(const float* __restrict__ DH, const float* __restrict__ ssc,
                            const float* __restrict__ dsc, unsigned* __restrict__ out){
  long row = blockIdx.x;
  for (int c=threadIdx.x; c<900; c+=256){
    float v = (c<300) ? DH[row*300+c] : (c<600 ? ssc[row*300+(c-300)] : dsc[row*300+(c-600)]);
    out[row*900+c] = packsplit(v);
  }
}

// ---------------- classifier: logits -> fp32 out, optional argmax ----------------
__global__ __launch_bounds__(256) void k_classify(
    const float* __restrict__ s0, const float* __restrict__ s1, const float* __restrict__ s2,
    int L, int Kf, float scale,
    const float* __restrict__ W, const float* __restrict__ bias, int N,
    float* __restrict__ out, int* __restrict__ amax)
{
  int b = blockIdx.x; int tid = threadIdx.x;
  __shared__ float feat[1200];
  __shared__ float logit[128];
  for (int i=tid; i<Kf; i+=256){
    int seg = i / L, c = i % L;
    const float* s = (seg==0) ? s0 : (seg==1 ? s1 : s2);
    feat[i] = s[(long)b*L + c] * scale;
  }
  __syncthreads();
  for (int n=tid; n<N; n+=256){
    float acc = bias[n];
    const float* w = W + (long)n*Kf;
    for (int k=0;k<Kf;k++) acc += feat[k]*w[k];
    out[(long)b*N + n] = acc;
    logit[n] = acc;
  }
  __syncthreads();
  if (amax && tid==0){
    float best = logit[0]; int bi=0;
    for (int n=1;n<N;n++) if (logit[n] > best){ best=logit[n]; bi=n; }
    amax[b] = bi;
  }
}

static inline int cdiv(long a, long b){ return (int)((a + b - 1)/b); }

extern "C" void kernel_launch(void* const* d_in, const int* in_sizes, int n_in,
                              void* d_out, int out_size, void* d_ws, size_t ws_size,
                              hipStream_t stream)
{
  (void)in_sizes; (void)n_in; (void)out_size;
  const float* emb     = (const float*)d_in[0];
  const float* encWih  = (const float*)d_in[1];
  const float* encWhh  = (const float*)d_in[2];
  const float* encbih  = (const float*)d_in[3];
  const float* encbhh  = (const float*)d_in[4];
  const float* cchWih  = (const float*)d_in[5];
  const float* cchWhh  = (const float*)d_in[6];
  const float* cchbih  = (const float*)d_in[7];
  const float* cchbhh  = (const float*)d_in[8];
  const float* termWih = (const float*)d_in[9];
  const float* termWhh = (const float*)d_in[10];
  const float* termbih = (const float*)d_in[11];
  const float* termbhh = (const float*)d_in[12];
  const float* artWih  = (const float*)d_in[13];
  const float* artWhh  = (const float*)d_in[14];
  const float* artbih  = (const float*)d_in[15];
  const float* artbhh  = (const float*)d_in[16];
  const float* Wc      = (const float*)d_in[17];
  const float* bc      = (const float*)d_in[18];
  const float* Wa      = (const float*)d_in[19];
  const float* ba      = (const float*)d_in[20];
  const float* Wt_     = (const float*)d_in[21];
  const float* bt_     = (const float*)d_in[22];
  const int* docs    = (const int*)d_in[23];
  const int* chtok   = (const int*)d_in[24];
  const int* artok   = (const int*)d_in[25];
  const int* chnb    = (const int*)d_in[26];
  const int* chnbm   = (const int*)d_in[27];
  const int* arnb    = (const int*)d_in[28];
  const int* arnbm   = (const int*)d_in[29];
  const int* vchtok  = (const int*)d_in[30];
  const int* vartok  = (const int*)d_in[31];
  float* ob = (float*)d_out;
  float* ws = (float*)d_ws;

  // -------- workspace layout (float elements) --------
  constexpr long O_WTENC = 0;                       // 2*150*450
  constexpr long O_WTCCH = O_WTENC + 135000;        // 2*150*450
  constexpr long O_WTART = O_WTCCH + 135000;        // packed encWih (2*450*208 u32)
  constexpr long O_WTTERM= O_WTART + 2160000;       // packed cchWih (2*450*208 u32)
  constexpr long O_DH    = O_WTTERM + 1215000;      // 16384*300
  constexpr long O_DMEAN = O_DH + 4915200;          // 32*300
  constexpr long O_CHM   = O_DMEAN + 9600;          // 119*300
  constexpr long O_ARM   = O_CHM + 35700;           // 103*300
  constexpr long O_LAB   = O_ARM + 30900;           // 444*300
  constexpr long O_GDT   = O_LAB + 133200;          // 119*300 (barrier ints after decomp)
  constexpr long O_CWM   = O_GDT + 35700;           // 4*16384
  constexpr long O_CWA   = O_CWM + 65536;           // 4*32*512
  constexpr long O_CWO   = O_CWA + 65536;           // 4*32*300
  constexpr long O_CP    = O_CWO + 38400;           // 64 ints
  constexpr long O_VCH   = O_CP + 64;               // 32*50*300
  constexpr long O_VCHT  = O_VCH + 480000;          // 32*300*50
  constexpr long O_ATT   = O_VCHT + 480000;         // 32*512*50
  constexpr long O_SCEN  = O_ATT + 819200;          // 16384*300
  constexpr long O_ADC   = O_SCEN + 4915200;        // 16384*300
  constexpr long O_SEC   = O_ADC + 4915200;         // 16384*300
  constexpr long O_HBUF  = O_SEC + 4915200;         // h ping-pong
  constexpr long O_YSUM  = O_HBUF + 76800;          // 32*1200
  constexpr long O_GATH  = O_YSUM + 38400;          // 16384*200
  constexpr long O_XSS   = O_GATH + 3276800;        // 2*6592*450
  constexpr long O_PF    = O_XSS + 5932800;         // 16384*1200
  constexpr long O_XB    = O_PF + 19660800;         // 2*16384*1800
  constexpr long TOTAL   = O_XB + 58982400;         // ~454 MB
  if (ws_size < (size_t)TOTAL * 4) return;

  float* WT_ENC = ws + O_WTENC;
  float* WT_CCH = ws + O_WTCCH;
  unsigned* PWENC = (unsigned*)(ws + O_WTART);   // packed encWih [2][450][208]
  unsigned* PWCCH = (unsigned*)(ws + O_WTTERM);  // packed cchWih [2][450][208]
  float* DH     = ws + O_DH;
  float* DMEAN  = ws + O_DMEAN;
  float* CHM    = ws + O_CHM;
  float* ARM    = ws + O_ARM;
  float* LAB    = ws + O_LAB;
  float* GDT    = ws + O_GDT;
  float* CWM    = ws + O_CWM;
  float* CWA    = ws + O_CWA;
  float* CWO    = ws + O_CWO;
  int*   CP     = (int*)(ws + O_CP);
  int*   AP     = CP + 32;
  float* VCH    = ws + O_VCH;
  float* VCHT   = ws + O_VCHT;
  float* ATT    = ws + O_ATT;
  float* SCEN   = ws + O_SCEN;
  float* ADC    = ws + O_ADC;
  float* SEC    = ws + O_SEC;
  float* HBUF   = ws + O_HBUF;
  float* YSUM   = ws + O_YSUM;
  float* GATH   = ws + O_GATH;
  float* XSS    = ws + O_XSS;
  float* PF     = ws + O_PF;
  float* XB     = ws + O_XB;
  int*   FLAGS  = (int*)GDT;       // free after graph decomposition
  int*   GO     = FLAGS + 256;     // 4 quadrant go-words on separate lines

  // -------- transpose small Whh + pack input-proj weights (once) --------
  k_transpose<<<dim3(cdiv(450L*150,256),2),256,0,stream>>>(encWhh, WT_ENC, 450,150);
  k_transpose<<<dim3(cdiv(450L*150,256),2),256,0,stream>>>(cchWhh, WT_CCH, 450,150);
  k_packW<<<cdiv(900L*208,256),256,0,stream>>>(encWih, PWENC, 900, 200, 208);
  k_packW<<<cdiv(900L*208,256),256,0,stream>>>(cchWih, PWCCH, 900, 200, 208);

  // -------- charge token encoder (encch), mean only --------
  k_gather_p<<<3808,256,0,stream>>>(emb, chtok, (unsigned*)GATH);
  k_gemm_bf3<<<dim3(4,cdiv(3808,128),2),256,0,stream>>>((const unsigned*)GATH, PWCCH,
      cchbih, XSS, 3808, 450, 200, 208, 450L*208, 3808L*450, 450);
  k_gru_small<<<dim3(119,2),512,0,stream>>>(XSS, 3808L*450, WT_CCH, cchbhh,
      nullptr,0, CHM,300, 32);

  // -------- article token encoder (encch), mean only --------
  k_gather_p<<<6592,256,0,stream>>>(emb, artok, (unsigned*)GATH);
  k_gemm_bf3<<<dim3(4,cdiv(6592,128),2),256,0,stream>>>((const unsigned*)GATH, PWCCH,
      cchbih, XSS, 6592, 450, 200, 208, 450L*208, 6592L*450, 450);
  k_gru_small<<<dim3(103,2),512,0,stream>>>(XSS, 6592L*450, WT_CCH, cchbhh,
      nullptr,0, ARM,300, 64);

  // -------- originals + graph decomposition into label-cat --------
  k_copy<<<cdiv(35700,256),256,0,stream>>>(CHM, LAB + 119L*300, 35700);
  k_copy<<<cdiv(30900,256),256,0,stream>>>(ARM, LAB + 341L*300, 30900);
  k_graphdecomp<<<119,256,0,stream>>>(CHM, GDT, chnb, chnbm, 119);
  k_graphdecomp<<<119,256,0,stream>>>(GDT, LAB, chnb, chnbm, 119);
  k_graphdecomp<<<103,256,0,stream>>>(ARM, GDT, arnb, arnbm, 103);
  k_graphdecomp<<<103,256,0,stream>>>(GDT, LAB + 238L*300, arnb, arnbm, 103);

  // -------- document encoder (enc) -> d_hidden + doc_mean --------
  k_gather_p<<<16384,256,0,stream>>>(emb, docs, (unsigned*)GATH);
  k_gemm_bf3<<<dim3(4,128,2),256,0,stream>>>((const unsigned*)GATH, PWENC,
      encbih, PF, 16384, 450, 200, 208, 450L*208, 16384L*450, 450);
  k_gru_small<<<dim3(32,2),512,0,stream>>>(PF, 16384L*450, WT_ENC, encbhh,
      DH,300, DMEAN,300, 512);

  // -------- code_wise (4 label sets at once), split-bf16 --------
  k_packAc<<<cdiv(16384L*300,256),256,0,stream>>>(DH, (unsigned*)XB, 16384L*300);
  k_packW<<<cdiv(444L*304,256),256,0,stream>>>(LAB, (unsigned*)XB + 16384L*300, 444, 300, 304);
  k_gemm_bf3<<<dim3(4,128,1),256,0,stream>>>((const unsigned*)XB, (const unsigned*)XB + 16384L*300,
      nullptr, PF, 16384, 444, 300, 304, 0, 0, 0);
  k_cw_rowmax<<<dim3(64,4),256,0,stream>>>(PF, CWM);
  k_cw_softmax<<<dim3(32,4),256,0,stream>>>(CWM, CWA);
  k_cw_out<<<dim3(32,4),256,0,stream>>>(CWA, DH, CWO);

  // -------- charge classifier + argmax --------
  k_classify<<<32,256,0,stream>>>(DMEAN, CWO, CWO + 32L*300,
      300, 900, 1.f, Wc, bc, 119, ob, CP);

  // -------- verdict-charge GRU (enc) --------
  k_gather_sel_p<<<dim3(50,32),256,0,stream>>>(emb, vchtok, CP, (unsigned*)GATH);
  k_gemm_bf3<<<dim3(4,13,2),256,0,stream>>>((const unsigned*)GATH, PWENC,
      encbih, XSS, 1600, 450, 200, 208, 450L*208, 1600L*450, 450);
  k_gru_small<<<dim3(32,2),512,0,stream>>>(XSS, 1600L*450, WT_ENC, encbhh,
      VCH,300, nullptr,0, 50);

  // -------- fact separation 1 (vch vs d_hidden) --------
  k_gemm128<<<dim3(1,4,32),256,0,stream>>>(DH, VCH, nullptr, ATT,
      512,50,300, 512L*300, 50L*300, 512L*50, 0);
  k_masksm<<<64,256,0,stream>>>(ATT, 16384);
  k_transpose<<<dim3(cdiv(15000,256),32),256,0,stream>>>(VCH, VCHT, 50, 300);
  k_gemm128<<<dim3(3,4,32),256,0,stream>>>(ATT, VCHT, nullptr, SCEN,
      512,300,50, 512L*50, 300L*50, 512L*300, 0);
  k_factsep<<<4096,256,0,stream>>>(DH, SCEN, ADC, SEC, 16384);

  // -------- fact_article: packed assembler + split-bf16 MFMA proj + persistent art GRU --------
  k_factart_p<<<16384,256,0,stream>>>(DH, CWO + 2L*32*300, ADC, CWO + 3L*32*300, (unsigned*)PF);
  k_packW<<<cdiv(2L*1800*1216,256),256,0,stream>>>(artWih, (unsigned*)XSS, 2*1800, 1200, 1216);
  k_gemm_bf3<<<dim3(15,128,2),256,0,stream>>>((const unsigned*)PF, (const unsigned*)XSS,
      artbih, XB, 16384, 1800, 1200, 1216, 1800L*1216, 16384L*1800, 1800);
  hipMemsetAsync(FLAGS, 0, 512*sizeof(int), stream);
  hipMemsetAsync(HBUF, 0, 76800*sizeof(float), stream);
  k_gru_persist<600,600,604,604,100,60><<<240,256,0,stream>>>(
      XB, 16384L*1800, artWhh, artbhh, HBUF, HBUF+38400, YSUM, 1200, 512, FLAGS, GO);
  k_classify<<<32,256,0,stream>>>(YSUM, nullptr, nullptr,
      1200, 1200, 1.f/512.f, Wa, ba, 103, ob + 3808, AP);

  // -------- verdict-article GRU (enc) --------
  k_gather_sel_p<<<dim3(50,32),256,0,stream>>>(emb, vartok, AP, (unsigned*)GATH);
  k_gemm_bf3<<<dim3(4,13,2),256,0,stream>>>((const unsigned*)GATH, PWENC,
      encbih, XSS, 1600, 450, 200, 208, 450L*208, 1600L*450, 450);
  k_gru_small<<<dim3(32,2),512,0,stream>>>(XSS, 1600L*450, WT_ENC, encbhh,
      VCH,300, nullptr,0, 50);

  // -------- fact separation 2 (var vs sec); ssc->SCEN, dsc->SEC in place --------
  k_gemm128<<<dim3(1,4,32),256,0,stream>>>(SEC, VCH, nullptr, ATT,
      512,50,300, 512L*300, 50L*300, 512L*50, 0);
  k_masksm<<<64,256,0,stream>>>(ATT, 16384);
  k_transpose<<<dim3(cdiv(15000,256),32),256,0,stream>>>(VCH, VCHT, 50, 300);
  k_gemm128<<<dim3(3,4,32),256,0,stream>>>(ATT, VCHT, nullptr, SCEN,
      512,300,50, 512L*50, 300L*50, 512L*300, 0);
  k_factsep<<<4096,256,0,stream>>>(SEC, SCEN, SCEN, SEC, 16384);

  // -------- term bigru: packed assembler + split-bf16 MFMA proj + persistent GRU --------
  k_termcat_p<<<16384,256,0,stream>>>(DH, SCEN, SEC, (unsigned*)PF);
  k_packW<<<cdiv(2L*1350*912,256),256,0,stream>>>(termWih, (unsigned*)GATH, 2*1350, 900, 912);
  k_gemm_bf3<<<dim3(11,128,2),256,0,stream>>>((const unsigned*)PF, (const unsigned*)GATH,
      termbih, XB, 16384, 1350, 900, 912, 1350L*912, 16384L*1350, 1350);
  hipMemsetAsync(FLAGS, 0, 512*sizeof(int), stream);
  hipMemsetAsync(HBUF, 0, 76800*sizeof(float), stream);
  k_gru_persist<450,456,460,460,76,45><<<180,256,0,stream>>>(
      XB, 16384L*1350, termWhh, termbhh, HBUF, HBUF+29184, YSUM, 900, 512, FLAGS, GO);
  k_classify<<<32,256,0,stream>>>(YSUM, nullptr, nullptr,
      900, 900, 1.f/512.f, Wt_, bt_, 11, ob + 7104, nullptr);
}

// Round 13
// 9904.272 us; speedup vs baseline: 8.5355x; 1.2324x over previous
//
#include <hip/hip_runtime.h>
#include <hip/hip_bf16.h>

#define DEVI __device__ __forceinline__

DEVI float sigm(float x){ return 1.f/(1.f+expf(-x)); }

typedef int v4i __attribute__((ext_vector_type(4)));
typedef float f4 __attribute__((ext_vector_type(4)));
using bf16x8 = __attribute__((ext_vector_type(8))) short;

// SRSRC for raw untyped dword access (stride=0, num_records=bytes)
DEVI v4i make_srsrc(const void* p, unsigned bytes){
  unsigned long long a = (unsigned long long)p;
  v4i r;
  r.x = (int)(a & 0xFFFFFFFFull);
  r.y = (int)((a >> 32) & 0xFFFFull);
  r.z = (int)bytes;
  r.w = 0x00020000;
  return r;
}

// split-bf16 pack: hi = bf16_rne(a) in top 16 bits, lo = bf16_rne(a - hi) in low 16
DEVI unsigned packsplit(float a){
  unsigned u = __float_as_uint(a);
  unsigned hi = (u + 0x7fffu + ((u >> 16) & 1u)) & 0xffff0000u;
  float res = a - __uint_as_float(hi);
  unsigned v = __float_as_uint(res);
  unsigned lo = ((v + 0x7fffu + ((v >> 16) & 1u)) >> 16) & 0xffffu;
  return hi | lo;
}

// ---------------- transpose: out[b][c][r] = in[b][r][c] ----------------
__global__ void k_transpose(const float* __restrict__ in, float* __restrict__ out, int R, int C){
  int b = blockIdx.y;
  long n = (long)R*C;
  long i = (long)blockIdx.x*256 + threadIdx.x;
  if (i < n){
    int r = (int)(i / C), c = (int)(i % C);
    out[(long)b*n + (long)c*R + r] = in[(long)b*n + i];
  }
}

// ---------------- embedding gathers (D=200), write split-bf16 packed ----------------
__global__ void k_gather_p(const float* __restrict__ emb, const int* __restrict__ tok, unsigned* __restrict__ out){
  int row = blockIdx.x; int c = threadIdx.x;
  if (c < 200) out[(long)row*200 + c] = packsplit(emb[(long)tok[row]*200 + c]);
}
__global__ void k_gather_sel_p(const float* __restrict__ emb, const int* __restrict__ tok, const int* __restrict__ sel, unsigned* __restrict__ out){
  int t = blockIdx.x, b = blockIdx.y; int c = threadIdx.x;
  if (c < 200){
    int tk = tok[(long)sel[b]*50 + t];
    out[((long)b*50 + t)*200 + c] = packsplit(emb[(long)tk*200 + c]);
  }
}

// ---------------- split-bf16 pack kernels ----------------
__global__ void k_packAc(const float* __restrict__ src, unsigned* __restrict__ dst, long n){
  long i = (long)blockIdx.x*256 + threadIdx.x;
  if (i < n) dst[i] = packsplit(src[i]);
}
__global__ void k_packW(const float* __restrict__ src, unsigned* __restrict__ dst, int R, int K, int KP){
  long i = (long)blockIdx.x*256 + threadIdx.x;
  if (i < (long)R*KP){
    int r = (int)(i / KP), k = (int)(i % KP);
    dst[i] = (k < K) ? packsplit(src[(long)r*K + k]) : 0u;
  }
}

// ---------------- split-bf16 MFMA NT-GEMM: C = A(M,K) @ W(N,K)^T + bias ----------------
__global__ __launch_bounds__(256) void k_gemm_bf3(
    const unsigned* __restrict__ Ap, const unsigned* __restrict__ Wp,
    const float* __restrict__ bias, float* __restrict__ C,
    int M, int N, int K, int KP, long sW, long sC, long sBias)
{
  int dir = blockIdx.z;
  Wp += (long)dir*sW; C += (long)dir*sC;
  if (bias) bias += (long)dir*sBias;
  int n0 = blockIdx.x*128, m0 = blockIdx.y*128;
  __shared__ unsigned short Ah[128*72], Al[128*72], Bh[128*72], Bl[128*72];
  int tid = threadIdx.x;
  int w = tid >> 6, lane = tid & 63;
  int l15 = lane & 15, lg = lane >> 4;
  f4 acc[2][8] = {};

  for (int k0 = 0; k0 < K; k0 += 64){
    __syncthreads();
    for (int u = tid; u < 2048; u += 256){
      int r = u >> 4, q = u & 15;
      int k = k0 + q*4;
      uint4 pa = make_uint4(0,0,0,0);
      if (k + 4 <= K) pa = *(const uint4*)&Ap[(long)(m0 + r)*K + k];
      ushort4 h4, s4;
      h4.x=(unsigned short)(pa.x>>16); s4.x=(unsigned short)(pa.x&0xffff);
      h4.y=(unsigned short)(pa.y>>16); s4.y=(unsigned short)(pa.y&0xffff);
      h4.z=(unsigned short)(pa.z>>16); s4.z=(unsigned short)(pa.z&0xffff);
      h4.w=(unsigned short)(pa.w>>16); s4.w=(unsigned short)(pa.w&0xffff);
      *(ushort4*)&Ah[r*72 + q*4] = h4;
      *(ushort4*)&Al[r*72 + q*4] = s4;
      int n = n0 + r;
      uint4 pw = make_uint4(0,0,0,0);
      if (n < N && k + 4 <= KP) pw = *(const uint4*)&Wp[(long)n*KP + k];
      ushort4 wh, wl;
      wh.x=(unsigned short)(pw.x>>16); wl.x=(unsigned short)(pw.x&0xffff);
      wh.y=(unsigned short)(pw.y>>16); wl.y=(unsigned short)(pw.y&0xffff);
      wh.z=(unsigned short)(pw.z>>16); wl.z=(unsigned short)(pw.z&0xffff);
      wh.w=(unsigned short)(pw.w>>16); wl.w=(unsigned short)(pw.w&0xffff);
      *(ushort4*)&Bh[r*72 + q*4] = wh;
      *(ushort4*)&Bl[r*72 + q*4] = wl;
    }
    __syncthreads();
    bf16x8 ah[2][2], al[2][2];
    #pragma unroll
    for (int fm=0; fm<2; fm++)
      #pragma unroll
      for (int ks=0; ks<2; ks++){
        int idx = (w*32 + fm*16 + l15)*72 + ks*32 + lg*8;
        ah[fm][ks] = *(const bf16x8*)&Ah[idx];
        al[fm][ks] = *(const bf16x8*)&Al[idx];
      }
    #pragma unroll
    for (int fn=0; fn<8; fn++){
      int bidx0 = (fn*16 + l15)*72 + lg*8;
      bf16x8 bh0 = *(const bf16x8*)&Bh[bidx0];
      bf16x8 bh1 = *(const bf16x8*)&Bh[bidx0 + 32];
      bf16x8 bl0 = *(const bf16x8*)&Bl[bidx0];
      bf16x8 bl1 = *(const bf16x8*)&Bl[bidx0 + 32];
      #pragma unroll
      for (int fm=0; fm<2; fm++){
        f4 a = acc[fm][fn];
        a = __builtin_amdgcn_mfma_f32_16x16x32_bf16(ah[fm][0], bh0, a, 0, 0, 0);
        a = __builtin_amdgcn_mfma_f32_16x16x32_bf16(al[fm][0], bh0, a, 0, 0, 0);
        a = __builtin_amdgcn_mfma_f32_16x16x32_bf16(ah[fm][0], bl0, a, 0, 0, 0);
        a = __builtin_amdgcn_mfma_f32_16x16x32_bf16(ah[fm][1], bh1, a, 0, 0, 0);
        a = __builtin_amdgcn_mfma_f32_16x16x32_bf16(al[fm][1], bh1, a, 0, 0, 0);
        a = __builtin_amdgcn_mfma_f32_16x16x32_bf16(ah[fm][1], bl1, a, 0, 0, 0);
        acc[fm][fn] = a;
      }
    }
  }
  #pragma unroll
  for (int fm=0; fm<2; fm++)
    #pragma unroll
    for (int fn=0; fn<8; fn++){
      int row = m0 + w*32 + fm*16 + lg*4;
      int col = n0 + fn*16 + l15;
      if (col < N){
        float bv = bias ? bias[col] : 0.f;
        #pragma unroll
        for (int r2=0; r2<4; r2++)
          if (row + r2 < M)
            C[(long)(row+r2)*N + col] = acc[fm][fn][r2] + bv;
      }
    }
}

// ---------------- fp32 GEMM 128x128 tile, 8x8 micro (small fact-sep GEMMs) ----------------
__global__ __launch_bounds__(256) void k_gemm128(
    const float* __restrict__ A, const float* __restrict__ W,
    const float* __restrict__ bias, float* __restrict__ C,
    int M, int N, int K, long sA, long sW, long sC, long sBias)
{
  int bz = blockIdx.z;
  A += (long)bz*sA; W += (long)bz*sW; C += (long)bz*sC;
  if (bias) bias += (long)bz*sBias;
  int n0 = blockIdx.x*128, m0 = blockIdx.y*128;
  __shared__ float As[16][132];
  __shared__ float Bs[16][132];
  int tid = threadIdx.x;
  int tx = tid & 15, ty = tid >> 4;
  float acc[8][8] = {};
  const bool k4 = ((K & 3) == 0);
  for (int k0 = 0; k0 < K; k0 += 16){
    #pragma unroll
    for (int half = 0; half < 2; half++){
      int s = tid + half*256;
      int r = s >> 2;
      int kq = (s & 3) << 2;
      int k = k0 + kq;
      int m = m0 + r;
      float4 va = make_float4(0.f,0.f,0.f,0.f);
      if (m < M){
        if (k4 && k + 3 < K) va = *(const float4*)&A[(long)m*K + k];
        else {
          float* pv = (float*)&va;
          #pragma unroll
          for (int u=0; u<4; u++) if (k+u < K) pv[u] = A[(long)m*K + k + u];
        }
      }
      As[kq+0][r]=va.x; As[kq+1][r]=va.y; As[kq+2][r]=va.z; As[kq+3][r]=va.w;
      int n = n0 + r;
      float4 vb = make_float4(0.f,0.f,0.f,0.f);
      if (n < N){
        if (k4 && k + 3 < K) vb = *(const float4*)&W[(long)n*K + k];
        else {
          float* pv = (float*)&vb;
          #pragma unroll
          for (int u=0; u<4; u++) if (k+u < K) pv[u] = W[(long)n*K + k + u];
        }
      }
      Bs[kq+0][r]=vb.x; Bs[kq+1][r]=vb.y; Bs[kq+2][r]=vb.z; Bs[kq+3][r]=vb.w;
    }
    __syncthreads();
    #pragma unroll
    for (int kk=0;kk<16;kk++){
      float a[8], b[8];
      *(float4*)&a[0] = *(const float4*)&As[kk][ty*8];
      *(float4*)&a[4] = *(const float4*)&As[kk][ty*8+4];
      *(float4*)&b[0] = *(const float4*)&Bs[kk][tx*8];
      *(float4*)&b[4] = *(const float4*)&Bs[kk][tx*8+4];
      #pragma unroll
      for (int i=0;i<8;i++)
        #pragma unroll
        for (int j=0;j<8;j++)
          acc[i][j] += a[i]*b[j];
    }
    __syncthreads();
  }
  #pragma unroll
  for (int i=0;i<8;i++){
    int m = m0 + ty*8 + i;
    if (m >= M) continue;
    #pragma unroll
    for (int j=0;j<8;j++){
      int n = n0 + tx*8 + j;
      if (n < N) C[(long)m*N + n] = acc[i][j] + (bias ? bias[n] : 0.f);
    }
  }
}

// ---------------- small GRU (h=150, 3h=450), 1 wg per (item,dir) ----------------
__global__ __launch_bounds__(512) void k_gru_small(
    const float* __restrict__ xs, long xsDir,
    const float* __restrict__ Wt, const float* __restrict__ bhh,
    float* __restrict__ y, int yld,
    float* __restrict__ meanOut, int meanld,
    int T)
{
  int item = blockIdx.x, dir = blockIdx.y;
  const float* xsd = xs + (long)dir*xsDir + (long)item*T*450;
  const float* Wtd = Wt + (long)dir*150*450;
  int tid = threadIdx.x;
  float bh = (tid < 450) ? bhh[(long)dir*450 + tid] : 0.f;
  __shared__ float hs[152];
  __shared__ float gs[456];
  if (tid < 150) hs[tid] = 0.f;
  float hsum = 0.f;
  __syncthreads();
  for (int t=0;t<T;t++){
    int tt = dir ? (T-1-t) : t;
    if (tid < 450){
      float g = bh;
      const float* wp = Wtd + tid;
      #pragma unroll 15
      for (int k=0;k<150;k++) g += hs[k] * wp[(long)k*450];
      gs[tid] = g;
    }
    __syncthreads();
    if (tid < 150){
      const float* xr = xsd + (long)tt*450;
      float r = sigm(xr[tid]     + gs[tid]);
      float z = sigm(xr[150+tid] + gs[150+tid]);
      float nn = tanhf(xr[300+tid] + r*gs[300+tid]);
      float h = (1.f-z)*nn + z*hs[tid];
      hs[tid] = h;
      hsum += h;
      if (y) y[((long)item*T + tt)*yld + dir*150 + tid] = h;
    }
    __syncthreads();
  }
  if (meanOut && tid < 150)
    meanOut[(long)item*meanld + dir*150 + tid] = hsum / (float)T;
}

// ---------------- persistent big GRU: MFMA gate GEMM + relaxed-atomic exchange ----------------
// Gate dot via split-bf16 MFMA: W (hi/lo) packed in LDS once (32-row tile, K pad KM,
// row stride SW ushorts = 16B-aligned, 2-way bank alias). h packed hi/lo inline during
// staging. h_old kept in the update thread's REGISTER (exact). Waves 0/1 each compute
// one 16x16 tile (gate-rows x items) over K with 3 MFMA/kk. Bias re-added in update
// (n-gate bias inside the r-multiply, as reference). Barrier/staging chain unchanged.
template<int H, int HS, int KM, int SW, int NCB>
__global__ __launch_bounds__(256) void k_gru_persist(
    const float* __restrict__ xs, long xsDir,
    const float* __restrict__ Whh, const float* __restrict__ bhh,
    float* hA, float* hB,
    float* __restrict__ ysum, int ysld,
    int T, int* flags, int* go)
{
  constexpr int H3 = 3*H;
  constexpr int CPR = HS/4;              // 16B chunks per item row
  constexpr int NCH = 16*CPR;            // chunks per step per wg
  constexpr int NIT = (NCH + 255)/256;   // chunks per thread (static)
  constexpr int NK  = KM/32;             // MFMA k-steps
  int wid = blockIdx.x;
  int dir = wid / (2*NCB);
  int rem = wid % (2*NCB);
  int bb  = rem / NCB;
  int cb  = rem % NCB;
  int quad = dir*2 + bb;
  int qbase = quad*64;
  int c0  = cb*10;
  int tid = threadIdx.x;
  int w = tid >> 6, lane = tid & 63;
  int l15 = lane & 15, lg = lane >> 4;

  const float* xsd = xs + (long)dir*xsDir;
  const float* Wd  = Whh + (long)dir*(long)H*H3;   // [3H][H] row-major
  const float* bhd = bhh + (long)dir*H3;

  __shared__ unsigned short Wh[32*SW], Wlo[32*SW];
  __shared__ unsigned short Hh[16*SW], Hl[16*SW];
  __shared__ float blds[32];
  __shared__ float gl[30*16];

  // ---- pack this wg's 30 gate-row weights into LDS ONCE (rows 30,31 & k>=H zero) ----
  for (int u = tid; u < 32*KM; u += 256){
    int r = u / KM, k = u % KM;
    float val = 0.f;
    if (r < 30 && k < H) val = Wd[((long)(r/10)*H + c0 + (r%10))*H + k];
    unsigned ps = packsplit(val);
    Wh[r*SW + k]  = (unsigned short)(ps >> 16);
    Wlo[r*SW + k] = (unsigned short)(ps & 0xffffu);
  }
  if (tid < 30) blds[tid] = bhd[(long)(tid/10)*H + (c0 + tid%10)];
  // zero the h k-pad region [HS, KM)
  for (int u = tid; u < 16*(KM-HS); u += 256){
    int item = u / (KM-HS), k = HS + u % (KM-HS);
    Hh[item*SW + k] = 0; Hl[item*SW + k] = 0;
  }

  // update mapping (tid<160): item uit, col uci; own h kept in register
  int uit = tid / 10, uci = tid % 10;
  int uc = c0 + uci;
  int ub = bb*16 + uit;
  float hreg = 0.f;
  float ysacc = 0.f;

  // ---- prologue: prefetch x for t=0 ----
  float xv0 = 0.f, xv1 = 0.f, xv2 = 0.f;
  if (tid < 160){
    int tt0 = dir ? (T-1) : 0;
    const float* xr = xsd + ((long)ub*T + tt0)*H3;
    xv0 = xr[uc]; xv1 = xr[H+uc]; xv2 = xr[2*H+uc];
  }

  __syncthreads();

  for (int t=0; t<T; t++){
    float* hp = ((t & 1) ? hB : hA) + (long)dir*32*HS;
    float* hn = ((t & 1) ? hA : hB) + (long)dir*32*HS;

    // ---- stage h slice [16][HS] via 16B coherent loads; pack hi/lo into LDS ----
    {
      v4i srsrc = make_srsrc(hp, 32u*HS*4u);
      f4 sbuf[NIT];
      #pragma unroll
      for (int i = 0; i < NIT; i++){
        int u = tid + i*256;
        if (u < NCH){
          int voff = ((bb*16 + u/CPR)*HS + (u%CPR)*4)*4;
          asm volatile("buffer_load_dwordx4 %0, %1, %2, 0 offen sc0 sc1"
                       : "=v"(sbuf[i]) : "v"(voff), "s"(srsrc));
        }
      }
      asm volatile("s_waitcnt vmcnt(0)" ::: "memory");
      __builtin_amdgcn_sched_barrier(0);
      #pragma unroll
      for (int i = 0; i < NIT; i++){
        int u = tid + i*256;
        if (u < NCH){
          int item = u / CPR;
          int k = (u % CPR)*4;
          unsigned p0 = packsplit(sbuf[i][0]);
          unsigned p1 = packsplit(sbuf[i][1]);
          unsigned p2 = packsplit(sbuf[i][2]);
          unsigned p3 = packsplit(sbuf[i][3]);
          ushort4 h4 = make_ushort4((unsigned short)(p0>>16), (unsigned short)(p1>>16),
                                    (unsigned short)(p2>>16), (unsigned short)(p3>>16));
          ushort4 l4 = make_ushort4((unsigned short)(p0&0xffffu), (unsigned short)(p1&0xffffu),
                                    (unsigned short)(p2&0xffffu), (unsigned short)(p3&0xffffu));
          *(ushort4*)&Hh[item*SW + k] = h4;
          *(ushort4*)&Hl[item*SW + k] = l4;
        }
      }
    }
    __syncthreads();

    // ---- gate GEMM: waves 0/1, one 16x16 tile each, split-bf16 3-term MFMA ----
    if (w < 2){
      f4 acc = {0.f, 0.f, 0.f, 0.f};
      const int arow = (w*16 + l15)*SW;
      const int brow = l15*SW;
      #pragma unroll
      for (int kk = 0; kk < NK; kk++){
        int kb = kk*32 + lg*8;
        bf16x8 a_h = *(const bf16x8*)&Wh[arow + kb];
        bf16x8 a_l = *(const bf16x8*)&Wlo[arow + kb];
        bf16x8 b_h = *(const bf16x8*)&Hh[brow + kb];
        bf16x8 b_l = *(const bf16x8*)&Hl[brow + kb];
        acc = __builtin_amdgcn_mfma_f32_16x16x32_bf16(a_h, b_h, acc, 0, 0, 0);
        acc = __builtin_amdgcn_mfma_f32_16x16x32_bf16(a_l, b_h, acc, 0, 0, 0);
        acc = __builtin_amdgcn_mfma_f32_16x16x32_bf16(a_h, b_l, acc, 0, 0, 0);
      }
      #pragma unroll
      for (int r2 = 0; r2 < 4; r2++){
        int row = w*16 + lg*4 + r2;
        if (row < 30) gl[row*16 + l15] = acc[r2];
      }
    }
    __syncthreads();

    // ---- GRU update; h stores are write-through relaxed atomics ----
    if (tid < 160){
      float gr = gl[uci*16      + uit] + blds[uci];
      float gz = gl[(10+uci)*16 + uit] + blds[10+uci];
      float gn = gl[(20+uci)*16 + uit] + blds[20+uci];
      float r  = sigm(xv0 + gr);
      float z  = sigm(xv1 + gz);
      float nn = tanhf(xv2 + r*gn);
      float hne = (1.f-z)*nn + z*hreg;
      __hip_atomic_store(&hn[(long)ub*HS + uc], hne, __ATOMIC_RELAXED, __HIP_MEMORY_SCOPE_AGENT);
      hreg = hne;
      ysacc += hne;
    }
    __syncthreads();   // drains vmcnt(0): hn write-through stores are globally visible

    // ---- prefetch next step's x (independent of h; hides under barrier) ----
    float nx0 = 0.f, nx1 = 0.f, nx2 = 0.f;
    if (tid < 160 && t+1 < T){
      int tt1 = dir ? (T-2-t) : (t+1);
      const float* xr = xsd + ((long)ub*T + tt1)*H3;
      nx0 = xr[uc]; nx1 = xr[H+uc]; nx2 = xr[2*H+uc];
    }

    // ---- leader-go quadrant barrier (monotonic, relaxed atomics only) ----
    if (t+1 < T){
      if (tid == 0)
        __hip_atomic_store(&flags[qbase + cb], t+1, __ATOMIC_RELAXED, __HIP_MEMORY_SCOPE_AGENT);
      if (cb == 0){
        if (tid < NCB){
          while (__hip_atomic_load(&flags[qbase + tid], __ATOMIC_RELAXED, __HIP_MEMORY_SCOPE_AGENT) < t+1)
            __builtin_amdgcn_s_sleep(2);
        }
        __syncthreads();
        if (tid == 0)
          __hip_atomic_store(&go[quad*32], t+1, __ATOMIC_RELAXED, __HIP_MEMORY_SCOPE_AGENT);
      } else {
        if (tid == 0){
          while (__hip_atomic_load(&go[quad*32], __ATOMIC_RELAXED, __HIP_MEMORY_SCOPE_AGENT) < t+1)
            __builtin_amdgcn_s_sleep(2);
        }
        __syncthreads();
      }
    }
    xv0 = nx0; xv1 = nx1; xv2 = nx2;
  }
  if (tid < 160)
    ysum[(long)ub*ysld + dir*H + uc] = ysacc;
}

// ---------------- graph decomposition layer (D=300, K=8) ----------------
__global__ __launch_bounds__(256) void k_graphdecomp(
   const float* __restrict__ labIn, float* __restrict__ labOut,
   const int* __restrict__ nb, const int* __restrict__ nbm, int N)
{
  int n = blockIdx.x; if (n >= N) return;
  int tid = threadIdx.x;
  __shared__ float ln[300];
  __shared__ float red[12];
  for (int d=tid; d<300; d+=256) ln[d] = labIn[(long)n*300+d];
  float deg = 0.f;
  for (int k=0;k<8;k++) deg += (float)nbm[n*8+k];
  float invdeg = 1.f / fmaxf(deg, 1.f);
  float acc0 = 0.f, acc1 = 0.f;
  __syncthreads();
  for (int k=0;k<8;k++){
    int j = nb[n*8+k];
    float mk = (float)nbm[n*8+k];
    const float* lj = labIn + (long)j*300;
    float p1=0.f, p2=0.f;
    for (int d=tid; d<300; d+=256){ float v = lj[d]; p1 += ln[d]*v; p2 += v*v; }
    for (int o=32;o>0;o>>=1){ p1 += __shfl_down(p1,o); p2 += __shfl_down(p2,o); }
    __syncthreads();
    int w = tid>>6, lane = tid&63;
    if (lane==0){ red[w]=p1; red[4+w]=p2; }
    __syncthreads();
    float x1 = red[0]+red[1]+red[2]+red[3];
    float x2 = red[4]+red[5]+red[6]+red[7];
    float coef = (x1 / (x2 + 1e-10f)) * mk * invdeg;
    acc0 += coef * lj[tid];
    if (tid + 256 < 300) acc1 += coef * lj[tid+256];
    __syncthreads();
  }
  bool pos = deg > 0.f;
  labOut[(long)n*300 + tid]                       = pos ? (ln[tid]     - acc0) : ln[tid];
  if (tid+256 < 300) labOut[(long)n*300 + tid+256] = pos ? (ln[tid+256] - acc1) : ln[tid+256];
}

// ---------------- copy ----------------
__global__ void k_copy(const float* __restrict__ src, float* __restrict__ dst, long n){
  long i = (long)blockIdx.x*256+threadIdx.x; if (i<n) dst[i]=src[i];
}

// ---------------- code_wise reductions ----------------
__global__ void k_cw_rowmax(const float* __restrict__ S, float* __restrict__ Mv){
  const int ofs[4]={0,119,238,341};
  const int wid[4]={119,119,103,103};
  int s = blockIdx.y; int row = blockIdx.x*256+threadIdx.x;
  if (row < 16384){
    const float* p = S + (long)row*444 + ofs[s];
    float m = -3.4e38f;
    int w = wid[s];
    for (int n=0;n<w;n++) m = fmaxf(m, p[n]);
    Mv[(long)s*16384+row] = m;
  }
}
__global__ void k_cw_softmax(const float* __restrict__ Mv, float* __restrict__ att){
  int b=blockIdx.x, s=blockIdx.y, tid=threadIdx.x;
  const float* src = Mv + (long)s*16384 + (long)b*512;
  __shared__ float red[256];
  float v0 = src[tid], v1 = src[tid+256];
  red[tid] = fmaxf(v0,v1); __syncthreads();
  for (int o=128;o>0;o>>=1){ if (tid<o) red[tid]=fmaxf(red[tid],red[tid+o]); __syncthreads(); }
  float m = red[0]; __syncthreads();
  float e0=expf(v0-m), e1=expf(v1-m);
  red[tid]=e0+e1; __syncthreads();
  for (int o=128;o>0;o>>=1){ if (tid<o) red[tid]+=red[tid+o]; __syncthreads(); }
  float inv = 1.f/red[0];
  float* dst = att + ((long)s*32 + b)*512;
  dst[tid]=e0*inv; dst[tid+256]=e1*inv;
}
__global__ void k_cw_out(const float* __restrict__ att, const float* __restrict__ DH, float* __restrict__ outp){
  int b=blockIdx.x, s=blockIdx.y, tid=threadIdx.x;
  __shared__ float a[512];
  for (int i=tid;i<512;i+=256) a[i]=att[((long)s*32+b)*512+i];
  __syncthreads();
  for (int d=tid; d<300; d+=256){
    float acc=0.f;
    for (int t=0;t<512;t++) acc += a[t]*DH[((long)b*512+t)*300+d];
    outp[((long)s*32+b)*300+d]=acc;
  }
}

// ---------------- masked softmax over l=50 (in place) ----------------
__global__ void k_masksm(float* __restrict__ att, long nrows){
  long row = (long)blockIdx.x*256 + threadIdx.x;
  if (row >= nrows) return;
  float* p = att + row*50;
  float m = -INFINITY;
  for (int l=0;l<50;l++){ float a = p[l]; if (a != 0.f && a > m) m = a; }
  if (m == -INFINITY){ for (int l=0;l<50;l++) p[l] = 0.f; return; }
  float s = 0.f;
  for (int l=0;l<50;l++){ float a = p[l]; float e = (a==0.f) ? 0.f : expf(a-m); p[l]=e; s+=e; }
  float inv = 1.f/s;
  for (int l=0;l<50;l++) p[l] *= inv;
}

// ---------------- fact separation combine (rows of 300), 1 wave per row ----------------
// NOTE: no __restrict__ — call 2 intentionally aliases simOut=scen, diffOut=circ.
__global__ void k_factsep(const float* circ, const float* scen,
                          float* simOut, float* diffOut, long nrows)
{
  int lane = threadIdx.x & 63;
  long row = (long)blockIdx.x*4 + (threadIdx.x >> 6);
  if (row >= nrows) return;
  const float* c = circ + row*300;
  const float* s = scen + row*300;
  float x3=0.f, x4=0.f;
  for (int d=lane; d<300; d+=64){ float sv=s[d]; x3 += c[d]*sv; x4 += sv*sv; }
  for (int o=32;o>0;o>>=1){ x3 += __shfl_down(x3,o); x4 += __shfl_down(x4,o); }
  x3 = __shfl(x3,0); x4 = __shfl(x4,0);
  float coef = x3 / (x4 + 1e-10f);
  for (int d=lane; d<300; d+=64){
    float sv = s[d]; float cv = c[d];
    float sim = coef*sv;
    simOut[row*300+d] = sim;
    diffOut[row*300+d] = cv - sim;
  }
}

// ---------------- assemblers (emit split-bf16 packed directly) ----------------
__global__ void k_factart_p(const float* __restrict__ DH, const float* __restrict__ dha,
                            const float* __restrict__ adc, const float* __restrict__ db,
                            unsigned* __restrict__ out)
{
  long row = blockIdx.x; int b = (int)(row >> 9);
  for (int c=threadIdx.x; c<1200; c+=256){
    float v;
    if (c < 300) v = DH[row*300 + c];
    else if (c < 600) v = dha[(long)b*300 + (c-300)];
    else if (c < 900) v = adc[row*300 + (c-600)];
    else v = db[(long)b*300 + (c-900)];
    out[row*1200 + c] = packsplit(v);
  }
}
__global__ void k_termcat_p(const float* __restrict__ DH, const float* __restrict__ ssc,
                            const float* __restrict__ dsc, unsigned* __restrict__ out){
  long row = blockIdx.x;
  for (int c=threadIdx.x; c<900; c+=256){
    float v = (c<300) ? DH[row*300+c] : (c<600 ? ssc[row*300+(c-300)] : dsc[row*300+(c-600)]);
    out[row*900+c] = packsplit(v);
  }
}

// ---------------- classifier: logits -> fp32 out, optional argmax ----------------
__global__ __launch_bounds__(256) void k_classify(
    const float* __restrict__ s0, const float* __restrict__ s1, const float* __restrict__ s2,
    int L, int Kf, float scale,
    const float* __restrict__ W, const float* __restrict__ bias, int N,
    float* __restrict__ out, int* __restrict__ amax)
{
  int b = blockIdx.x; int tid = threadIdx.x;
  __shared__ float feat[1200];
  __shared__ float logit[128];
  for (int i=tid; i<Kf; i+=256){
    int seg = i / L, c = i % L;
    const float* s = (seg==0) ? s0 : (seg==1 ? s1 : s2);
    feat[i] = s[(long)b*L + c] * scale;
  }
  __syncthreads();
  for (int n=tid; n<N; n+=256){
    float acc = bias[n];
    const float* w = W + (long)n*Kf;
    for (int k=0;k<Kf;k++) acc += feat[k]*w[k];
    out[(long)b*N + n] = acc;
    logit[n] = acc;
  }
  __syncthreads();
  if (amax && tid==0){
    float best = logit[0]; int bi=0;
    for (int n=1;n<N;n++) if (logit[n] > best){ best=logit[n]; bi=n; }
    amax[b] = bi;
  }
}

static inline int cdiv(long a, long b){ return (int)((a + b - 1)/b); }

extern "C" void kernel_launch(void* const* d_in, const int* in_sizes, int n_in,
                              void* d_out, int out_size, void* d_ws, size_t ws_size,
                              hipStream_t stream)
{
  (void)in_sizes; (void)n_in; (void)out_size;
  const float* emb     = (const float*)d_in[0];
  const float* encWih  = (const float*)d_in[1];
  const float* encWhh  = (const float*)d_in[2];
  const float* encbih  = (const float*)d_in[3];
  const float* encbhh  = (const float*)d_in[4];
  const float* cchWih  = (const float*)d_in[5];
  const float* cchWhh  = (const float*)d_in[6];
  const float* cchbih  = (const float*)d_in[7];
  const float* cchbhh  = (const float*)d_in[8];
  const float* termWih = (const float*)d_in[9];
  const float* termWhh = (const float*)d_in[10];
  const float* termbih = (const float*)d_in[11];
  const float* termbhh = (const float*)d_in[12];
  const float* artWih  = (const float*)d_in[13];
  const float* artWhh  = (const float*)d_in[14];
  const float* artbih  = (const float*)d_in[15];
  const float* artbhh  = (const float*)d_in[16];
  const float* Wc      = (const float*)d_in[17];
  const float* bc      = (const float*)d_in[18];
  const float* Wa      = (const float*)d_in[19];
  const float* ba      = (const float*)d_in[20];
  const float* Wt_     = (const float*)d_in[21];
  const float* bt_     = (const float*)d_in[22];
  const int* docs    = (const int*)d_in[23];
  const int* chtok   = (const int*)d_in[24];
  const int* artok   = (const int*)d_in[25];
  const int* chnb    = (const int*)d_in[26];
  const int* chnbm   = (const int*)d_in[27];
  const int* arnb    = (const int*)d_in[28];
  const int* arnbm   = (const int*)d_in[29];
  const int* vchtok  = (const int*)d_in[30];
  const int* vartok  = (const int*)d_in[31];
  float* ob = (float*)d_out;
  float* ws = (float*)d_ws;

  // -------- workspace layout (float elements) --------
  constexpr long O_WTENC = 0;                       // 2*150*450
  constexpr long O_WTCCH = O_WTENC + 135000;        // 2*150*450
  constexpr long O_WTART = O_WTCCH + 135000;        // packed encWih (2*450*208 u32)
  constexpr long O_WTTERM= O_WTART + 2160000;       // packed cchWih (2*450*208 u32)
  constexpr long O_DH    = O_WTTERM + 1215000;      // 16384*300
  constexpr long O_DMEAN = O_DH + 4915200;          // 32*300
  constexpr long O_CHM   = O_DMEAN + 9600;          // 119*300
  constexpr long O_ARM   = O_CHM + 35700;           // 103*300
  constexpr long O_LAB   = O_ARM + 30900;           // 444*300
  constexpr long O_GDT   = O_LAB + 133200;          // 119*300 (barrier ints after decomp)
  constexpr long O_CWM   = O_GDT + 35700;           // 4*16384
  constexpr long O_CWA   = O_CWM + 65536;           // 4*32*512
  constexpr long O_CWO   = O_CWA + 65536;           // 4*32*300
  constexpr long O_CP    = O_CWO + 38400;           // 64 ints
  constexpr long O_VCH   = O_CP + 64;               // 32*50*300
  constexpr long O_VCHT  = O_VCH + 480000;          // 32*300*50
  constexpr long O_ATT   = O_VCHT + 480000;         // 32*512*50
  constexpr long O_SCEN  = O_ATT + 819200;          // 16384*300
  constexpr long O_ADC   = O_SCEN + 4915200;        // 16384*300
  constexpr long O_SEC   = O_ADC + 4915200;         // 16384*300
  constexpr long O_HBUF  = O_SEC + 4915200;         // h ping-pong
  constexpr long O_YSUM  = O_HBUF + 76800;          // 32*1200
  constexpr long O_GATH  = O_YSUM + 38400;          // 16384*200
  constexpr long O_XSS   = O_GATH + 3276800;        // 2*6592*450
  constexpr long O_PF    = O_XSS + 5932800;         // 16384*1200
  constexpr long O_XB    = O_PF + 19660800;         // 2*16384*1800
  constexpr long TOTAL   = O_XB + 58982400;         // ~454 MB
  if (ws_size < (size_t)TOTAL * 4) return;

  float* WT_ENC = ws + O_WTENC;
  float* WT_CCH = ws + O_WTCCH;
  unsigned* PWENC = (unsigned*)(ws + O_WTART);   // packed encWih [2][450][208]
  unsigned* PWCCH = (unsigned*)(ws + O_WTTERM);  // packed cchWih [2][450][208]
  float* DH     = ws + O_DH;
  float* DMEAN  = ws + O_DMEAN;
  float* CHM    = ws + O_CHM;
  float* ARM    = ws + O_ARM;
  float* LAB    = ws + O_LAB;
  float* GDT    = ws + O_GDT;
  float* CWM    = ws + O_CWM;
  float* CWA    = ws + O_CWA;
  float* CWO    = ws + O_CWO;
  int*   CP     = (int*)(ws + O_CP);
  int*   AP     = CP + 32;
  float* VCH    = ws + O_VCH;
  float* VCHT   = ws + O_VCHT;
  float* ATT    = ws + O_ATT;
  float* SCEN   = ws + O_SCEN;
  float* ADC    = ws + O_ADC;
  float* SEC    = ws + O_SEC;
  float* HBUF   = ws + O_HBUF;
  float* YSUM   = ws + O_YSUM;
  float* GATH   = ws + O_GATH;
  float* XSS    = ws + O_XSS;
  float* PF     = ws + O_PF;
  float* XB     = ws + O_XB;
  int*   FLAGS  = (int*)GDT;       // free after graph decomposition
  int*   GO     = FLAGS + 256;     // 4 quadrant go-words on separate lines

  // -------- transpose small Whh + pack input-proj weights (once) --------
  k_transpose<<<dim3(cdiv(450L*150,256),2),256,0,stream>>>(encWhh, WT_ENC, 450,150);
  k_transpose<<<dim3(cdiv(450L*150,256),2),256,0,stream>>>(cchWhh, WT_CCH, 450,150);
  k_packW<<<cdiv(900L*208,256),256,0,stream>>>(encWih, PWENC, 900, 200, 208);
  k_packW<<<cdiv(900L*208,256),256,0,stream>>>(cchWih, PWCCH, 900, 200, 208);

  // -------- charge token encoder (encch), mean only --------
  k_gather_p<<<3808,256,0,stream>>>(emb, chtok, (unsigned*)GATH);
  k_gemm_bf3<<<dim3(4,cdiv(3808,128),2),256,0,stream>>>((const unsigned*)GATH, PWCCH,
      cchbih, XSS, 3808, 450, 200, 208, 450L*208, 3808L*450, 450);
  k_gru_small<<<dim3(119,2),512,0,stream>>>(XSS, 3808L*450, WT_CCH, cchbhh,
      nullptr,0, CHM,300, 32);

  // -------- article token encoder (encch), mean only --------
  k_gather_p<<<6592,256,0,stream>>>(emb, artok, (unsigned*)GATH);
  k_gemm_bf3<<<dim3(4,cdiv(6592,128),2),256,0,stream>>>((const unsigned*)GATH, PWCCH,
      cchbih, XSS, 6592, 450, 200, 208, 450L*208, 6592L*450, 450);
  k_gru_small<<<dim3(103,2),512,0,stream>>>(XSS, 6592L*450, WT_CCH, cchbhh,
      nullptr,0, ARM,300, 64);

  // -------- originals + graph decomposition into label-cat --------
  k_copy<<<cdiv(35700,256),256,0,stream>>>(CHM, LAB + 119L*300, 35700);
  k_copy<<<cdiv(30900,256),256,0,stream>>>(ARM, LAB + 341L*300, 30900);
  k_graphdecomp<<<119,256,0,stream>>>(CHM, GDT, chnb, chnbm, 119);
  k_graphdecomp<<<119,256,0,stream>>>(GDT, LAB, chnb, chnbm, 119);
  k_graphdecomp<<<103,256,0,stream>>>(ARM, GDT, arnb, arnbm, 103);
  k_graphdecomp<<<103,256,0,stream>>>(GDT, LAB + 238L*300, arnb, arnbm, 103);

  // -------- document encoder (enc) -> d_hidden + doc_mean --------
  k_gather_p<<<16384,256,0,stream>>>(emb, docs, (unsigned*)GATH);
  k_gemm_bf3<<<dim3(4,128,2),256,0,stream>>>((const unsigned*)GATH, PWENC,
      encbih, PF, 16384, 450, 200, 208, 450L*208, 16384L*450, 450);
  k_gru_small<<<dim3(32,2),512,0,stream>>>(PF, 16384L*450, WT_ENC, encbhh,
      DH,300, DMEAN,300, 512);

  // -------- code_wise (4 label sets at once), split-bf16 --------
  k_packAc<<<cdiv(16384L*300,256),256,0,stream>>>(DH, (unsigned*)XB, 16384L*300);
  k_packW<<<cdiv(444L*304,256),256,0,stream>>>(LAB, (unsigned*)XB + 16384L*300, 444, 300, 304);
  k_gemm_bf3<<<dim3(4,128,1),256,0,stream>>>((const unsigned*)XB, (const unsigned*)XB + 16384L*300,
      nullptr, PF, 16384, 444, 300, 304, 0, 0, 0);
  k_cw_rowmax<<<dim3(64,4),256,0,stream>>>(PF, CWM);
  k_cw_softmax<<<dim3(32,4),256,0,stream>>>(CWM, CWA);
  k_cw_out<<<dim3(32,4),256,0,stream>>>(CWA, DH, CWO);

  // -------- charge classifier + argmax --------
  k_classify<<<32,256,0,stream>>>(DMEAN, CWO, CWO + 32L*300,
      300, 900, 1.f, Wc, bc, 119, ob, CP);

  // -------- verdict-charge GRU (enc) --------
  k_gather_sel_p<<<dim3(50,32),256,0,stream>>>(emb, vchtok, CP, (unsigned*)GATH);
  k_gemm_bf3<<<dim3(4,13,2),256,0,stream>>>((const unsigned*)GATH, PWENC,
      encbih, XSS, 1600, 450, 200, 208, 450L*208, 1600L*450, 450);
  k_gru_small<<<dim3(32,2),512,0,stream>>>(XSS, 1600L*450, WT_ENC, encbhh,
      VCH,300, nullptr,0, 50);

  // -------- fact separation 1 (vch vs d_hidden) --------
  k_gemm128<<<dim3(1,4,32),256,0,stream>>>(DH, VCH, nullptr, ATT,
      512,50,300, 512L*300, 50L*300, 512L*50, 0);
  k_masksm<<<64,256,0,stream>>>(ATT, 16384);
  k_transpose<<<dim3(cdiv(15000,256),32),256,0,stream>>>(VCH, VCHT, 50, 300);
  k_gemm128<<<dim3(3,4,32),256,0,stream>>>(ATT, VCHT, nullptr, SCEN,
      512,300,50, 512L*50, 300L*50, 512L*300, 0);
  k_factsep<<<4096,256,0,stream>>>(DH, SCEN, ADC, SEC, 16384);

  // -------- fact_article: packed assembler + split-bf16 MFMA proj + persistent art GRU --------
  k_factart_p<<<16384,256,0,stream>>>(DH, CWO + 2L*32*300, ADC, CWO + 3L*32*300, (unsigned*)PF);
  k_packW<<<cdiv(2L*1800*1216,256),256,0,stream>>>(artWih, (unsigned*)XSS, 2*1800, 1200, 1216);
  k_gemm_bf3<<<dim3(15,128,2),256,0,stream>>>((const unsigned*)PF, (const unsigned*)XSS,
      artbih, XB, 16384, 1800, 1200, 1216, 1800L*1216, 16384L*1800, 1800);
  hipMemsetAsync(FLAGS, 0, 512*sizeof(int), stream);
  hipMemsetAsync(HBUF, 0, 76800*sizeof(float), stream);
  // art: H=600, HS=600, KM=608, SW=616, NCB=60 -> 240 wgs
  k_gru_persist<600,600,608,616,60><<<240,256,0,stream>>>(
      XB, 16384L*1800, artWhh, artbhh, HBUF, HBUF+38400, YSUM, 1200, 512, FLAGS, GO);
  k_classify<<<32,256,0,stream>>>(YSUM, nullptr, nullptr,
      1200, 1200, 1.f/512.f, Wa, ba, 103, ob + 3808, AP);

  // -------- verdict-article GRU (enc) --------
  k_gather_sel_p<<<dim3(50,32),256,0,stream>>>(emb, vartok, AP, (unsigned*)GATH);
  k_gemm_bf3<<<dim3(4,13,2),256,0,stream>>>((const unsigned*)GATH, PWENC,
      encbih, XSS, 1600, 450, 200, 208, 450L*208, 1600L*450, 450);
  k_gru_small<<<dim3(32,2),512,0,stream>>>(XSS, 1600L*450, WT_ENC, encbhh,
      VCH,300, nullptr,0, 50);

  // -------- fact separation 2 (var vs sec); ssc->SCEN, dsc->SEC in place --------
  k_gemm128<<<dim3(1,4,32),256,0,stream>>>(SEC, VCH, nullptr, ATT,
      512,50,300, 512L*300, 50L*300, 512L*50, 0);
  k_masksm<<<64,256,0,stream>>>(ATT, 16384);
  k_transpose<<<dim3(cdiv(15000,256),32),256,0,stream>>>(VCH, VCHT, 50, 300);
  k_gemm128<<<dim3(3,4,32),256,0,stream>>>(ATT, VCHT, nullptr, SCEN,
      512,300,50, 512L*50, 300L*50, 512L*300, 0);
  k_factsep<<<4096,256,0,stream>>>(SEC, SCEN, SCEN, SEC, 16384);

  // -------- term bigru: packed assembler + split-bf16 MFMA proj + persistent GRU --------
  k_termcat_p<<<16384,256,0,stream>>>(DH, SCEN, SEC, (unsigned*)PF);
  k_packW<<<cdiv(2L*1350*912,256),256,0,stream>>>(termWih, (unsigned*)GATH, 2*1350, 900, 912);
  k_gemm_bf3<<<dim3(11,128,2),256,0,stream>>>((const unsigned*)PF, (const unsigned*)GATH,
      termbih, XB, 16384, 1350, 900, 912, 1350L*912, 16384L*1350, 1350);
  hipMemsetAsync(FLAGS, 0, 512*sizeof(int), stream);
  hipMemsetAsync(HBUF, 0, 76800*sizeof(float), stream);
  // term: H=450, HS=456, KM=480, SW=488, NCB=45 -> 180 wgs
  k_gru_persist<450,456,480,488,45><<<180,256,0,stream>>>(
      XB, 16384L*1350, termWhh, termbhh, HBUF, HBUF+29184, YSUM, 900, 512, FLAGS, GO);
  k_classify<<<32,256,0,stream>>>(YSUM, nullptr, nullptr,
      900, 900, 1.f/512.f, Wt_, bt_, 11, ob + 7104, nullptr);
}

// Round 14
// 9860.069 us; speedup vs baseline: 8.5737x; 1.0045x over previous
//
#include <hip/hip_runtime.h>
#include <hip/hip_bf16.h>

#define DEVI __device__ __forceinline__

DEVI float sigm(float x){ return 1.f/(1.f+expf(-x)); }

typedef int v4i __attribute__((ext_vector_type(4)));
typedef float f4 __attribute__((ext_vector_type(4)));
using bf16x8 = __attribute__((ext_vector_type(8))) short;

// SRSRC for raw untyped dword access (stride=0, num_records=bytes)
DEVI v4i make_srsrc(const void* p, unsigned bytes){
  unsigned long long a = (unsigned long long)p;
  v4i r;
  r.x = (int)(a & 0xFFFFFFFFull);
  r.y = (int)((a >> 32) & 0xFFFFull);
  r.z = (int)bytes;
  r.w = 0x00020000;
  return r;
}

// split-bf16 pack: hi = bf16_rne(a) in top 16 bits, lo = bf16_rne(a - hi) in low 16
DEVI unsigned packsplit(float a){
  unsigned u = __float_as_uint(a);
  unsigned hi = (u + 0x7fffu + ((u >> 16) & 1u)) & 0xffff0000u;
  float res = a - __uint_as_float(hi);
  unsigned v = __float_as_uint(res);
  unsigned lo = ((v + 0x7fffu + ((v >> 16) & 1u)) >> 16) & 0xffffu;
  return hi | lo;
}

// ---------------- transpose: out[b][c][r] = in[b][r][c] ----------------
__global__ void k_transpose(const float* __restrict__ in, float* __restrict__ out, int R, int C){
  int b = blockIdx.y;
  long n = (long)R*C;
  long i = (long)blockIdx.x*256 + threadIdx.x;
  if (i < n){
    int r = (int)(i / C), c = (int)(i % C);
    out[(long)b*n + (long)c*R + r] = in[(long)b*n + i];
  }
}

// ---------------- embedding gathers (D=200), write split-bf16 packed ----------------
__global__ void k_gather_p(const float* __restrict__ emb, const int* __restrict__ tok, unsigned* __restrict__ out){
  int row = blockIdx.x; int c = threadIdx.x;
  if (c < 200) out[(long)row*200 + c] = packsplit(emb[(long)tok[row]*200 + c]);
}
__global__ void k_gather_sel_p(const float* __restrict__ emb, const int* __restrict__ tok, const int* __restrict__ sel, unsigned* __restrict__ out){
  int t = blockIdx.x, b = blockIdx.y; int c = threadIdx.x;
  if (c < 200){
    int tk = tok[(long)sel[b]*50 + t];
    out[((long)b*50 + t)*200 + c] = packsplit(emb[(long)tk*200 + c]);
  }
}

// ---------------- split-bf16 pack kernels ----------------
__global__ void k_packAc(const float* __restrict__ src, unsigned* __restrict__ dst, long n){
  long i = (long)blockIdx.x*256 + threadIdx.x;
  if (i < n) dst[i] = packsplit(src[i]);
}
__global__ void k_packW(const float* __restrict__ src, unsigned* __restrict__ dst, int R, int K, int KP){
  long i = (long)blockIdx.x*256 + threadIdx.x;
  if (i < (long)R*KP){
    int r = (int)(i / KP), k = (int)(i % KP);
    dst[i] = (k < K) ? packsplit(src[(long)r*K + k]) : 0u;
  }
}

// ---------------- split-bf16 MFMA NT-GEMM: C = A(M,K) @ W(N,K)^T + bias ----------------
__global__ __launch_bounds__(256) void k_gemm_bf3(
    const unsigned* __restrict__ Ap, const unsigned* __restrict__ Wp,
    const float* __restrict__ bias, float* __restrict__ C,
    int M, int N, int K, int KP, long sW, long sC, long sBias)
{
  int dir = blockIdx.z;
  Wp += (long)dir*sW; C += (long)dir*sC;
  if (bias) bias += (long)dir*sBias;
  int n0 = blockIdx.x*128, m0 = blockIdx.y*128;
  __shared__ unsigned short Ah[128*72], Al[128*72], Bh[128*72], Bl[128*72];
  int tid = threadIdx.x;
  int w = tid >> 6, lane = tid & 63;
  int l15 = lane & 15, lg = lane >> 4;
  f4 acc[2][8] = {};

  for (int k0 = 0; k0 < K; k0 += 64){
    __syncthreads();
    for (int u = tid; u < 2048; u += 256){
      int r = u >> 4, q = u & 15;
      int k = k0 + q*4;
      uint4 pa = make_uint4(0,0,0,0);
      if (k + 4 <= K) pa = *(const uint4*)&Ap[(long)(m0 + r)*K + k];
      ushort4 h4, s4;
      h4.x=(unsigned short)(pa.x>>16); s4.x=(unsigned short)(pa.x&0xffff);
      h4.y=(unsigned short)(pa.y>>16); s4.y=(unsigned short)(pa.y&0xffff);
      h4.z=(unsigned short)(pa.z>>16); s4.z=(unsigned short)(pa.z&0xffff);
      h4.w=(unsigned short)(pa.w>>16); s4.w=(unsigned short)(pa.w&0xffff);
      *(ushort4*)&Ah[r*72 + q*4] = h4;
      *(ushort4*)&Al[r*72 + q*4] = s4;
      int n = n0 + r;
      uint4 pw = make_uint4(0,0,0,0);
      if (n < N && k + 4 <= KP) pw = *(const uint4*)&Wp[(long)n*KP + k];
      ushort4 wh, wl;
      wh.x=(unsigned short)(pw.x>>16); wl.x=(unsigned short)(pw.x&0xffff);
      wh.y=(unsigned short)(pw.y>>16); wl.y=(unsigned short)(pw.y&0xffff);
      wh.z=(unsigned short)(pw.z>>16); wl.z=(unsigned short)(pw.z&0xffff);
      wh.w=(unsigned short)(pw.w>>16); wl.w=(unsigned short)(pw.w&0xffff);
      *(ushort4*)&Bh[r*72 + q*4] = wh;
      *(ushort4*)&Bl[r*72 + q*4] = wl;
    }
    __syncthreads();
    bf16x8 ah[2][2], al[2][2];
    #pragma unroll
    for (int fm=0; fm<2; fm++)
      #pragma unroll
      for (int ks=0; ks<2; ks++){
        int idx = (w*32 + fm*16 + l15)*72 + ks*32 + lg*8;
        ah[fm][ks] = *(const bf16x8*)&Ah[idx];
        al[fm][ks] = *(const bf16x8*)&Al[idx];
      }
    #pragma unroll
    for (int fn=0; fn<8; fn++){
      int bidx0 = (fn*16 + l15)*72 + lg*8;
      bf16x8 bh0 = *(const bf16x8*)&Bh[bidx0];
      bf16x8 bh1 = *(const bf16x8*)&Bh[bidx0 + 32];
      bf16x8 bl0 = *(const bf16x8*)&Bl[bidx0];
      bf16x8 bl1 = *(const bf16x8*)&Bl[bidx0 + 32];
      #pragma unroll
      for (int fm=0; fm<2; fm++){
        f4 a = acc[fm][fn];
        a = __builtin_amdgcn_mfma_f32_16x16x32_bf16(ah[fm][0], bh0, a, 0, 0, 0);
        a = __builtin_amdgcn_mfma_f32_16x16x32_bf16(al[fm][0], bh0, a, 0, 0, 0);
        a = __builtin_amdgcn_mfma_f32_16x16x32_bf16(ah[fm][0], bl0, a, 0, 0, 0);
        a = __builtin_amdgcn_mfma_f32_16x16x32_bf16(ah[fm][1], bh1, a, 0, 0, 0);
        a = __builtin_amdgcn_mfma_f32_16x16x32_bf16(al[fm][1], bh1, a, 0, 0, 0);
        a = __builtin_amdgcn_mfma_f32_16x16x32_bf16(ah[fm][1], bl1, a, 0, 0, 0);
        acc[fm][fn] = a;
      }
    }
  }
  #pragma unroll
  for (int fm=0; fm<2; fm++)
    #pragma unroll
    for (int fn=0; fn<8; fn++){
      int row = m0 + w*32 + fm*16 + lg*4;
      int col = n0 + fn*16 + l15;
      if (col < N){
        float bv = bias ? bias[col] : 0.f;
        #pragma unroll
        for (int r2=0; r2<4; r2++)
          if (row + r2 < M)
            C[(long)(row+r2)*N + col] = acc[fm][fn][r2] + bv;
      }
    }
}

// ---------------- fp32 GEMM 128x128 tile, 8x8 micro (small fact-sep GEMMs) ----------------
__global__ __launch_bounds__(256) void k_gemm128(
    const float* __restrict__ A, const float* __restrict__ W,
    const float* __restrict__ bias, float* __restrict__ C,
    int M, int N, int K, long sA, long sW, long sC, long sBias)
{
  int bz = blockIdx.z;
  A += (long)bz*sA; W += (long)bz*sW; C += (long)bz*sC;
  if (bias) bias += (long)bz*sBias;
  int n0 = blockIdx.x*128, m0 = blockIdx.y*128;
  __shared__ float As[16][132];
  __shared__ float Bs[16][132];
  int tid = threadIdx.x;
  int tx = tid & 15, ty = tid >> 4;
  float acc[8][8] = {};
  const bool k4 = ((K & 3) == 0);
  for (int k0 = 0; k0 < K; k0 += 16){
    #pragma unroll
    for (int half = 0; half < 2; half++){
      int s = tid + half*256;
      int r = s >> 2;
      int kq = (s & 3) << 2;
      int k = k0 + kq;
      int m = m0 + r;
      float4 va = make_float4(0.f,0.f,0.f,0.f);
      if (m < M){
        if (k4 && k + 3 < K) va = *(const float4*)&A[(long)m*K + k];
        else {
          float* pv = (float*)&va;
          #pragma unroll
          for (int u=0; u<4; u++) if (k+u < K) pv[u] = A[(long)m*K + k + u];
        }
      }
      As[kq+0][r]=va.x; As[kq+1][r]=va.y; As[kq+2][r]=va.z; As[kq+3][r]=va.w;
      int n = n0 + r;
      float4 vb = make_float4(0.f,0.f,0.f,0.f);
      if (n < N){
        if (k4 && k + 3 < K) vb = *(const float4*)&W[(long)n*K + k];
        else {
          float* pv = (float*)&vb;
          #pragma unroll
          for (int u=0; u<4; u++) if (k+u < K) pv[u] = W[(long)n*K + k + u];
        }
      }
      Bs[kq+0][r]=vb.x; Bs[kq+1][r]=vb.y; Bs[kq+2][r]=vb.z; Bs[kq+3][r]=vb.w;
    }
    __syncthreads();
    #pragma unroll
    for (int kk=0;kk<16;kk++){
      float a[8], b[8];
      *(float4*)&a[0] = *(const float4*)&As[kk][ty*8];
      *(float4*)&a[4] = *(const float4*)&As[kk][ty*8+4];
      *(float4*)&b[0] = *(const float4*)&Bs[kk][tx*8];
      *(float4*)&b[4] = *(const float4*)&Bs[kk][tx*8+4];
      #pragma unroll
      for (int i=0;i<8;i++)
        #pragma unroll
        for (int j=0;j<8;j++)
          acc[i][j] += a[i]*b[j];
    }
    __syncthreads();
  }
  #pragma unroll
  for (int i=0;i<8;i++){
    int m = m0 + ty*8 + i;
    if (m >= M) continue;
    #pragma unroll
    for (int j=0;j<8;j++){
      int n = n0 + tx*8 + j;
      if (n < N) C[(long)m*N + n] = acc[i][j] + (bias ? bias[n] : 0.f);
    }
  }
}

// ---------------- small GRU (h=150, 3h=450), 1 wg per (item,dir) ----------------
__global__ __launch_bounds__(512) void k_gru_small(
    const float* __restrict__ xs, long xsDir,
    const float* __restrict__ Wt, const float* __restrict__ bhh,
    float* __restrict__ y, int yld,
    float* __restrict__ meanOut, int meanld,
    int T)
{
  int item = blockIdx.x, dir = blockIdx.y;
  const float* xsd = xs + (long)dir*xsDir + (long)item*T*450;
  const float* Wtd = Wt + (long)dir*150*450;
  int tid = threadIdx.x;
  float bh = (tid < 450) ? bhh[(long)dir*450 + tid] : 0.f;
  __shared__ float hs[152];
  __shared__ float gs[456];
  if (tid < 150) hs[tid] = 0.f;
  float hsum = 0.f;
  __syncthreads();
  for (int t=0;t<T;t++){
    int tt = dir ? (T-1-t) : t;
    if (tid < 450){
      float g = bh;
      const float* wp = Wtd + tid;
      #pragma unroll 15
      for (int k=0;k<150;k++) g += hs[k] * wp[(long)k*450];
      gs[tid] = g;
    }
    __syncthreads();
    if (tid < 150){
      const float* xr = xsd + (long)tt*450;
      float r = sigm(xr[tid]     + gs[tid]);
      float z = sigm(xr[150+tid] + gs[150+tid]);
      float nn = tanhf(xr[300+tid] + r*gs[300+tid]);
      float h = (1.f-z)*nn + z*hs[tid];
      hs[tid] = h;
      hsum += h;
      if (y) y[((long)item*T + tt)*yld + dir*150 + tid] = h;
    }
    __syncthreads();
  }
  if (meanOut && tid < 150)
    meanOut[(long)item*meanld + dir*150 + tid] = hsum / (float)T;
}

// ---------------- persistent big GRU: MFMA gate GEMM, 15 cols/wg (less h duplication) ----
// wid -> (dir, bb of 16 items, cb of 15 h-cols). 45 gate rows/wg -> 3 MFMA tiles (waves
// 0-2). W split-bf16 in LDS once; single SH block with manual offsets so wave-2 A-frag
// over-reads (rows 45-47, results discarded by row<45 guard) stay inside the allocation.
// h_old in update thread's register. Coherence chain unchanged (R6/R7-proven).
template<int H, int HS, int KM, int SW, int NCB>
__global__ __launch_bounds__(256) void k_gru_persist(
    const float* __restrict__ xs, long xsDir,
    const float* __restrict__ Whh, const float* __restrict__ bhh,
    float* hA, float* hB,
    float* __restrict__ ysum, int ysld,
    int T, int* flags, int* go)
{
  constexpr int H3 = 3*H;
  constexpr int CPR = HS/4;              // 16B chunks per item row
  constexpr int NCH = 16*CPR;            // chunks per step per wg
  constexpr int NIT = (NCH + 255)/256;   // chunks per thread (static)
  constexpr int NK  = KM/32;             // MFMA k-steps
  int wid = blockIdx.x;
  int dir = wid / (2*NCB);
  int rem = wid % (2*NCB);
  int bb  = rem / NCB;
  int cb  = rem % NCB;
  int quad = dir*2 + bb;
  int qbase = quad*64;
  int c0  = cb*15;
  int tid = threadIdx.x;
  int w = tid >> 6, lane = tid & 63;
  int l15 = lane & 15, lg = lane >> 4;

  const float* xsd = xs + (long)dir*xsDir;
  const float* Wd  = Whh + (long)dir*(long)H*H3;   // [3H][H] row-major
  const float* bhd = bhh + (long)dir*H3;

  // single LDS block: [Wh 45*SW][Wlo 45*SW][Hh 16*SW][Hl 16*SW]
  __shared__ unsigned short SH[122*SW];
  unsigned short* Wh  = SH;
  unsigned short* Wlo = SH + 45*SW;
  unsigned short* Hh  = SH + 90*SW;
  unsigned short* Hl  = SH + 106*SW;
  __shared__ float blds[48];
  __shared__ float gl[45*16];

  // ---- pack this wg's 45 gate-row weights into LDS ONCE (k>=H zero) ----
  for (int u = tid; u < 45*KM; u += 256){
    int r = u / KM, k = u % KM;
    float val = (k < H) ? Wd[((long)(r/15)*H + c0 + (r%15))*H + k] : 0.f;
    unsigned ps = packsplit(val);
    Wh[r*SW + k]  = (unsigned short)(ps >> 16);
    Wlo[r*SW + k] = (unsigned short)(ps & 0xffffu);
  }
  if (tid < 45) blds[tid] = bhd[(long)(tid/15)*H + (c0 + tid%15)];
  // zero the h k-pad region [HS, KM)
  for (int u = tid; u < 16*(KM-HS); u += 256){
    int item = u / (KM-HS), k = HS + u % (KM-HS);
    Hh[item*SW + k] = 0; Hl[item*SW + k] = 0;
  }

  // update mapping (tid<240): item uit, col uci; own h kept in register
  int uit = tid / 15, uci = tid % 15;
  int uc = c0 + uci;
  int ub = bb*16 + uit;
  float hreg = 0.f;
  float ysacc = 0.f;

  // ---- prologue: prefetch x for t=0 ----
  float xv0 = 0.f, xv1 = 0.f, xv2 = 0.f;
  if (tid < 240){
    int tt0 = dir ? (T-1) : 0;
    const float* xr = xsd + ((long)ub*T + tt0)*H3;
    xv0 = xr[uc]; xv1 = xr[H+uc]; xv2 = xr[2*H+uc];
  }

  __syncthreads();

  for (int t=0; t<T; t++){
    float* hp = ((t & 1) ? hB : hA) + (long)dir*32*HS;
    float* hn = ((t & 1) ? hA : hB) + (long)dir*32*HS;

    // ---- stage h slice [16][HS] via 16B coherent loads; pack hi/lo into LDS ----
    {
      v4i srsrc = make_srsrc(hp, 32u*HS*4u);
      f4 sbuf[NIT];
      #pragma unroll
      for (int i = 0; i < NIT; i++){
        int u = tid + i*256;
        if (u < NCH){
          int voff = ((bb*16 + u/CPR)*HS + (u%CPR)*4)*4;
          asm volatile("buffer_load_dwordx4 %0, %1, %2, 0 offen sc0 sc1"
                       : "=v"(sbuf[i]) : "v"(voff), "s"(srsrc));
        }
      }
      asm volatile("s_waitcnt vmcnt(0)" ::: "memory");
      __builtin_amdgcn_sched_barrier(0);
      #pragma unroll
      for (int i = 0; i < NIT; i++){
        int u = tid + i*256;
        if (u < NCH){
          int item = u / CPR;
          int k = (u % CPR)*4;
          unsigned p0 = packsplit(sbuf[i][0]);
          unsigned p1 = packsplit(sbuf[i][1]);
          unsigned p2 = packsplit(sbuf[i][2]);
          unsigned p3 = packsplit(sbuf[i][3]);
          ushort4 h4 = make_ushort4((unsigned short)(p0>>16), (unsigned short)(p1>>16),
                                    (unsigned short)(p2>>16), (unsigned short)(p3>>16));
          ushort4 l4 = make_ushort4((unsigned short)(p0&0xffffu), (unsigned short)(p1&0xffffu),
                                    (unsigned short)(p2&0xffffu), (unsigned short)(p3&0xffffu));
          *(ushort4*)&Hh[item*SW + k] = h4;
          *(ushort4*)&Hl[item*SW + k] = l4;
        }
      }
    }
    __syncthreads();

    // ---- gate GEMM: waves 0-2, one 16x16 tile each, split-bf16 3-term MFMA ----
    if (w < 3){
      f4 acc = {0.f, 0.f, 0.f, 0.f};
      const int arow = (w*16 + l15)*SW;
      const int brow = l15*SW;
      #pragma unroll
      for (int kk = 0; kk < NK; kk++){
        int kb = kk*32 + lg*8;
        bf16x8 a_h = *(const bf16x8*)&Wh[arow + kb];
        bf16x8 a_l = *(const bf16x8*)&Wlo[arow + kb];
        bf16x8 b_h = *(const bf16x8*)&Hh[brow + kb];
        bf16x8 b_l = *(const bf16x8*)&Hl[brow + kb];
        acc = __builtin_amdgcn_mfma_f32_16x16x32_bf16(a_h, b_h, acc, 0, 0, 0);
        acc = __builtin_amdgcn_mfma_f32_16x16x32_bf16(a_l, b_h, acc, 0, 0, 0);
        acc = __builtin_amdgcn_mfma_f32_16x16x32_bf16(a_h, b_l, acc, 0, 0, 0);
      }
      #pragma unroll
      for (int r2 = 0; r2 < 4; r2++){
        int row = w*16 + lg*4 + r2;
        if (row < 45) gl[row*16 + l15] = acc[r2];
      }
    }
    __syncthreads();

    // ---- GRU update; h stores are write-through relaxed atomics ----
    if (tid < 240){
      float gr = gl[uci*16      + uit] + blds[uci];
      float gz = gl[(15+uci)*16 + uit] + blds[15+uci];
      float gn = gl[(30+uci)*16 + uit] + blds[30+uci];
      float r  = sigm(xv0 + gr);
      float z  = sigm(xv1 + gz);
      float nn = tanhf(xv2 + r*gn);
      float hne = (1.f-z)*nn + z*hreg;
      __hip_atomic_store(&hn[(long)ub*HS + uc], hne, __ATOMIC_RELAXED, __HIP_MEMORY_SCOPE_AGENT);
      hreg = hne;
      ysacc += hne;
    }
    __syncthreads();   // drains vmcnt(0): hn write-through stores are globally visible

    // ---- prefetch next step's x (independent of h; hides under barrier) ----
    float nx0 = 0.f, nx1 = 0.f, nx2 = 0.f;
    if (tid < 240 && t+1 < T){
      int tt1 = dir ? (T-2-t) : (t+1);
      const float* xr = xsd + ((long)ub*T + tt1)*H3;
      nx0 = xr[uc]; nx1 = xr[H+uc]; nx2 = xr[2*H+uc];
    }

    // ---- leader-go quadrant barrier (monotonic, relaxed atomics only) ----
    if (t+1 < T){
      if (tid == 0)
        __hip_atomic_store(&flags[qbase + cb], t+1, __ATOMIC_RELAXED, __HIP_MEMORY_SCOPE_AGENT);
      if (cb == 0){
        if (tid < NCB){
          while (__hip_atomic_load(&flags[qbase + tid], __ATOMIC_RELAXED, __HIP_MEMORY_SCOPE_AGENT) < t+1)
            __builtin_amdgcn_s_sleep(2);
        }
        __syncthreads();
        if (tid == 0)
          __hip_atomic_store(&go[quad*32], t+1, __ATOMIC_RELAXED, __HIP_MEMORY_SCOPE_AGENT);
      } else {
        if (tid == 0){
          while (__hip_atomic_load(&go[quad*32], __ATOMIC_RELAXED, __HIP_MEMORY_SCOPE_AGENT) < t+1)
            __builtin_amdgcn_s_sleep(2);
        }
        __syncthreads();
      }
    }
    xv0 = nx0; xv1 = nx1; xv2 = nx2;
  }
  if (tid < 240)
    ysum[(long)ub*ysld + dir*H + uc] = ysacc;
}

// ---------------- graph decomposition layer (D=300, K=8) ----------------
__global__ __launch_bounds__(256) void k_graphdecomp(
   const float* __restrict__ labIn, float* __restrict__ labOut,
   const int* __restrict__ nb, const int* __restrict__ nbm, int N)
{
  int n = blockIdx.x; if (n >= N) return;
  int tid = threadIdx.x;
  __shared__ float ln[300];
  __shared__ float red[12];
  for (int d=tid; d<300; d+=256) ln[d] = labIn[(long)n*300+d];
  float deg = 0.f;
  for (int k=0;k<8;k++) deg += (float)nbm[n*8+k];
  float invdeg = 1.f / fmaxf(deg, 1.f);
  float acc0 = 0.f, acc1 = 0.f;
  __syncthreads();
  for (int k=0;k<8;k++){
    int j = nb[n*8+k];
    float mk = (float)nbm[n*8+k];
    const float* lj = labIn + (long)j*300;
    float p1=0.f, p2=0.f;
    for (int d=tid; d<300; d+=256){ float v = lj[d]; p1 += ln[d]*v; p2 += v*v; }
    for (int o=32;o>0;o>>=1){ p1 += __shfl_down(p1,o); p2 += __shfl_down(p2,o); }
    __syncthreads();
    int w = tid>>6, lane = tid&63;
    if (lane==0){ red[w]=p1; red[4+w]=p2; }
    __syncthreads();
    float x1 = red[0]+red[1]+red[2]+red[3];
    float x2 = red[4]+red[5]+red[6]+red[7];
    float coef = (x1 / (x2 + 1e-10f)) * mk * invdeg;
    acc0 += coef * lj[tid];
    if (tid + 256 < 300) acc1 += coef * lj[tid+256];
    __syncthreads();
  }
  bool pos = deg > 0.f;
  labOut[(long)n*300 + tid]                       = pos ? (ln[tid]     - acc0) : ln[tid];
  if (tid+256 < 300) labOut[(long)n*300 + tid+256] = pos ? (ln[tid+256] - acc1) : ln[tid+256];
}

// ---------------- copy ----------------
__global__ void k_copy(const float* __restrict__ src, float* __restrict__ dst, long n){
  long i = (long)blockIdx.x*256+threadIdx.x; if (i<n) dst[i]=src[i];
}

// ---------------- code_wise reductions ----------------
__global__ void k_cw_rowmax(const float* __restrict__ S, float* __restrict__ Mv){
  const int ofs[4]={0,119,238,341};
  const int wid[4]={119,119,103,103};
  int s = blockIdx.y; int row = blockIdx.x*256+threadIdx.x;
  if (row < 16384){
    const float* p = S + (long)row*444 + ofs[s];
    float m = -3.4e38f;
    int w = wid[s];
    for (int n=0;n<w;n++) m = fmaxf(m, p[n]);
    Mv[(long)s*16384+row] = m;
  }
}
__global__ void k_cw_softmax(const float* __restrict__ Mv, float* __restrict__ att){
  int b=blockIdx.x, s=blockIdx.y, tid=threadIdx.x;
  const float* src = Mv + (long)s*16384 + (long)b*512;
  __shared__ float red[256];
  float v0 = src[tid], v1 = src[tid+256];
  red[tid] = fmaxf(v0,v1); __syncthreads();
  for (int o=128;o>0;o>>=1){ if (tid<o) red[tid]=fmaxf(red[tid],red[tid+o]); __syncthreads(); }
  float m = red[0]; __syncthreads();
  float e0=expf(v0-m), e1=expf(v1-m);
  red[tid]=e0+e1; __syncthreads();
  for (int o=128;o>0;o>>=1){ if (tid<o) red[tid]+=red[tid+o]; __syncthreads(); }
  float inv = 1.f/red[0];
  float* dst = att + ((long)s*32 + b)*512;
  dst[tid]=e0*inv; dst[tid+256]=e1*inv;
}
__global__ void k_cw_out(const float* __restrict__ att, const float* __restrict__ DH, float* __restrict__ outp){
  int b=blockIdx.x, s=blockIdx.y, tid=threadIdx.x;
  __shared__ float a[512];
  for (int i=tid;i<512;i+=256) a[i]=att[((long)s*32+b)*512+i];
  __syncthreads();
  for (int d=tid; d<300; d+=256){
    float acc=0.f;
    for (int t=0;t<512;t++) acc += a[t]*DH[((long)b*512+t)*300+d];
    outp[((long)s*32+b)*300+d]=acc;
  }
}

// ---------------- masked softmax over l=50 (in place) ----------------
__global__ void k_masksm(float* __restrict__ att, long nrows){
  long row = (long)blockIdx.x*256 + threadIdx.x;
  if (row >= nrows) return;
  float* p = att + row*50;
  float m = -INFINITY;
  for (int l=0;l<50;l++){ float a = p[l]; if (a != 0.f && a > m) m = a; }
  if (m == -INFINITY){ for (int l=0;l<50;l++) p[l] = 0.f; return; }
  float s = 0.f;
  for (int l=0;l<50;l++){ float a = p[l]; float e = (a==0.f) ? 0.f : expf(a-m); p[l]=e; s+=e; }
  float inv = 1.f/s;
  for (int l=0;l<50;l++) p[l] *= inv;
}

// ---------------- fact separation combine (rows of 300), 1 wave per row ----------------
// NOTE: no __restrict__ — call 2 intentionally aliases simOut=scen, diffOut=circ.
__global__ void k_factsep(const float* circ, const float* scen,
                          float* simOut, float* diffOut, long nrows)
{
  int lane = threadIdx.x & 63;
  long row = (long)blockIdx.x*4 + (threadIdx.x >> 6);
  if (row >= nrows) return;
  const float* c = circ + row*300;
  const float* s = scen + row*300;
  float x3=0.f, x4=0.f;
  for (int d=lane; d<300; d+=64){ float sv=s[d]; x3 += c[d]*sv; x4 += sv*sv; }
  for (int o=32;o>0;o>>=1){ x3 += __shfl_down(x3,o); x4 += __shfl_down(x4,o); }
  x3 = __shfl(x3,0); x4 = __shfl(x4,0);
  float coef = x3 / (x4 + 1e-10f);
  for (int d=lane; d<300; d+=64){
    float sv = s[d]; float cv = c[d];
    float sim = coef*sv;
    simOut[row*300+d] = sim;
    diffOut[row*300+d] = cv - sim;
  }
}

// ---------------- assemblers (emit split-bf16 packed directly) ----------------
__global__ void k_factart_p(const float* __restrict__ DH, const float* __restrict__ dha,
                            const float* __restrict__ adc, const float* __restrict__ db,
                            unsigned* __restrict__ out)
{
  long row = blockIdx.x; int b = (int)(row >> 9);
  for (int c=threadIdx.x; c<1200; c+=256){
    float v;
    if (c < 300) v = DH[row*300 + c];
    else if (c < 600) v = dha[(long)b*300 + (c-300)];
    else if (c < 900) v = adc[row*300 + (c-600)];
    else v = db[(long)b*300 + (c-900)];
    out[row*1200 + c] = packsplit(v);
  }
}
__global__ void k_termcat_p(const float* __restrict__ DH, const float* __restrict__ ssc,
                            const float* __restrict__ dsc, unsigned* __restrict__ out){
  long row = blockIdx.x;
  for (int c=threadIdx.x; c<900; c+=256){
    float v = (c<300) ? DH[row*300+c] : (c<600 ? ssc[row*300+(c-300)] : dsc[row*300+(c-600)]);
    out[row*900+c] = packsplit(v);
  }
}

// ---------------- classifier: logits -> fp32 out, optional argmax ----------------
__global__ __launch_bounds__(256) void k_classify(
    const float* __restrict__ s0, const float* __restrict__ s1, const float* __restrict__ s2,
    int L, int Kf, float scale,
    const float* __restrict__ W, const float* __restrict__ bias, int N,
    float* __restrict__ out, int* __restrict__ amax)
{
  int b = blockIdx.x; int tid = threadIdx.x;
  __shared__ float feat[1200];
  __shared__ float logit[128];
  for (int i=tid; i<Kf; i+=256){
    int seg = i / L, c = i % L;
    const float* s = (seg==0) ? s0 : (seg==1 ? s1 : s2);
    feat[i] = s[(long)b*L + c] * scale;
  }
  __syncthreads();
  for (int n=tid; n<N; n+=256){
    float acc = bias[n];
    const float* w = W + (long)n*Kf;
    for (int k=0;k<Kf;k++) acc += feat[k]*w[k];
    out[(long)b*N + n] = acc;
    logit[n] = acc;
  }
  __syncthreads();
  if (amax && tid==0){
    float best = logit[0]; int bi=0;
    for (int n=1;n<N;n++) if (logit[n] > best){ best=logit[n]; bi=n; }
    amax[b] = bi;
  }
}

static inline int cdiv(long a, long b){ return (int)((a + b - 1)/b); }

extern "C" void kernel_launch(void* const* d_in, const int* in_sizes, int n_in,
                              void* d_out, int out_size, void* d_ws, size_t ws_size,
                              hipStream_t stream)
{
  (void)in_sizes; (void)n_in; (void)out_size;
  const float* emb     = (const float*)d_in[0];
  const float* encWih  = (const float*)d_in[1];
  const float* encWhh  = (const float*)d_in[2];
  const float* encbih  = (const float*)d_in[3];
  const float* encbhh  = (const float*)d_in[4];
  const float* cchWih  = (const float*)d_in[5];
  const float* cchWhh  = (const float*)d_in[6];
  const float* cchbih  = (const float*)d_in[7];
  const float* cchbhh  = (const float*)d_in[8];
  const float* termWih = (const float*)d_in[9];
  const float* termWhh = (const float*)d_in[10];
  const float* termbih = (const float*)d_in[11];
  const float* termbhh = (const float*)d_in[12];
  const float* artWih  = (const float*)d_in[13];
  const float* artWhh  = (const float*)d_in[14];
  const float* artbih  = (const float*)d_in[15];
  const float* artbhh  = (const float*)d_in[16];
  const float* Wc      = (const float*)d_in[17];
  const float* bc      = (const float*)d_in[18];
  const float* Wa      = (const float*)d_in[19];
  const float* ba      = (const float*)d_in[20];
  const float* Wt_     = (const float*)d_in[21];
  const float* bt_     = (const float*)d_in[22];
  const int* docs    = (const int*)d_in[23];
  const int* chtok   = (const int*)d_in[24];
  const int* artok   = (const int*)d_in[25];
  const int* chnb    = (const int*)d_in[26];
  const int* chnbm   = (const int*)d_in[27];
  const int* arnb    = (const int*)d_in[28];
  const int* arnbm   = (const int*)d_in[29];
  const int* vchtok  = (const int*)d_in[30];
  const int* vartok  = (const int*)d_in[31];
  float* ob = (float*)d_out;
  float* ws = (float*)d_ws;

  // -------- workspace layout (float elements) --------
  constexpr long O_WTENC = 0;                       // 2*150*450
  constexpr long O_WTCCH = O_WTENC + 135000;        // 2*150*450
  constexpr long O_WTART = O_WTCCH + 135000;        // packed encWih (2*450*208 u32)
  constexpr long O_WTTERM= O_WTART + 2160000;       // packed cchWih (2*450*208 u32)
  constexpr long O_DH    = O_WTTERM + 1215000;      // 16384*300
  constexpr long O_DMEAN = O_DH + 4915200;          // 32*300
  constexpr long O_CHM   = O_DMEAN + 9600;          // 119*300
  constexpr long O_ARM   = O_CHM + 35700;           // 103*300
  constexpr long O_LAB   = O_ARM + 30900;           // 444*300
  constexpr long O_GDT   = O_LAB + 133200;          // 119*300 (barrier ints after decomp)
  constexpr long O_CWM   = O_GDT + 35700;           // 4*16384
  constexpr long O_CWA   = O_CWM + 65536;           // 4*32*512
  constexpr long O_CWO   = O_CWA + 65536;           // 4*32*300
  constexpr long O_CP    = O_CWO + 38400;           // 64 ints
  constexpr long O_VCH   = O_CP + 64;               // 32*50*300
  constexpr long O_VCHT  = O_VCH + 480000;          // 32*300*50
  constexpr long O_ATT   = O_VCHT + 480000;         // 32*512*50
  constexpr long O_SCEN  = O_ATT + 819200;          // 16384*300
  constexpr long O_ADC   = O_SCEN + 4915200;        // 16384*300
  constexpr long O_SEC   = O_ADC + 4915200;         // 16384*300
  constexpr long O_HBUF  = O_SEC + 4915200;         // h ping-pong
  constexpr long O_YSUM  = O_HBUF + 76800;          // 32*1200
  constexpr long O_GATH  = O_YSUM + 38400;          // 16384*200
  constexpr long O_XSS   = O_GATH + 3276800;        // 2*6592*450
  constexpr long O_PF    = O_XSS + 5932800;         // 16384*1200
  constexpr long O_XB    = O_PF + 19660800;         // 2*16384*1800
  constexpr long TOTAL   = O_XB + 58982400;         // ~454 MB
  if (ws_size < (size_t)TOTAL * 4) return;

  float* WT_ENC = ws + O_WTENC;
  float* WT_CCH = ws + O_WTCCH;
  unsigned* PWENC = (unsigned*)(ws + O_WTART);   // packed encWih [2][450][208]
  unsigned* PWCCH = (unsigned*)(ws + O_WTTERM);  // packed cchWih [2][450][208]
  float* DH     = ws + O_DH;
  float* DMEAN  = ws + O_DMEAN;
  float* CHM    = ws + O_CHM;
  float* ARM    = ws + O_ARM;
  float* LAB    = ws + O_LAB;
  float* GDT    = ws + O_GDT;
  float* CWM    = ws + O_CWM;
  float* CWA    = ws + O_CWA;
  float* CWO    = ws + O_CWO;
  int*   CP     = (int*)(ws + O_CP);
  int*   AP     = CP + 32;
  float* VCH    = ws + O_VCH;
  float* VCHT   = ws + O_VCHT;
  float* ATT    = ws + O_ATT;
  float* SCEN   = ws + O_SCEN;
  float* ADC    = ws + O_ADC;
  float* SEC    = ws + O_SEC;
  float* HBUF   = ws + O_HBUF;
  float* YSUM   = ws + O_YSUM;
  float* GATH   = ws + O_GATH;
  float* XSS    = ws + O_XSS;
  float* PF     = ws + O_PF;
  float* XB     = ws + O_XB;
  int*   FLAGS  = (int*)GDT;       // free after graph decomposition
  int*   GO     = FLAGS + 256;     // 4 quadrant go-words on separate lines

  // -------- transpose small Whh + pack input-proj weights (once) --------
  k_transpose<<<dim3(cdiv(450L*150,256),2),256,0,stream>>>(encWhh, WT_ENC, 450,150);
  k_transpose<<<dim3(cdiv(450L*150,256),2),256,0,stream>>>(cchWhh, WT_CCH, 450,150);
  k_packW<<<cdiv(900L*208,256),256,0,stream>>>(encWih, PWENC, 900, 200, 208);
  k_packW<<<cdiv(900L*208,256),256,0,stream>>>(cchWih, PWCCH, 900, 200, 208);

  // -------- charge token encoder (encch), mean only --------
  k_gather_p<<<3808,256,0,stream>>>(emb, chtok, (unsigned*)GATH);
  k_gemm_bf3<<<dim3(4,cdiv(3808,128),2),256,0,stream>>>((const unsigned*)GATH, PWCCH,
      cchbih, XSS, 3808, 450, 200, 208, 450L*208, 3808L*450, 450);
  k_gru_small<<<dim3(119,2),512,0,stream>>>(XSS, 3808L*450, WT_CCH, cchbhh,
      nullptr,0, CHM,300, 32);

  // -------- article token encoder (encch), mean only --------
  k_gather_p<<<6592,256,0,stream>>>(emb, artok, (unsigned*)GATH);
  k_gemm_bf3<<<dim3(4,cdiv(6592,128),2),256,0,stream>>>((const unsigned*)GATH, PWCCH,
      cchbih, XSS, 6592, 450, 200, 208, 450L*208, 6592L*450, 450);
  k_gru_small<<<dim3(103,2),512,0,stream>>>(XSS, 6592L*450, WT_CCH, cchbhh,
      nullptr,0, ARM,300, 64);

  // -------- originals + graph decomposition into label-cat --------
  k_copy<<<cdiv(35700,256),256,0,stream>>>(CHM, LAB + 119L*300, 35700);
  k_copy<<<cdiv(30900,256),256,0,stream>>>(ARM, LAB + 341L*300, 30900);
  k_graphdecomp<<<119,256,0,stream>>>(CHM, GDT, chnb, chnbm, 119);
  k_graphdecomp<<<119,256,0,stream>>>(GDT, LAB, chnb, chnbm, 119);
  k_graphdecomp<<<103,256,0,stream>>>(ARM, GDT, arnb, arnbm, 103);
  k_graphdecomp<<<103,256,0,stream>>>(GDT, LAB + 238L*300, arnb, arnbm, 103);

  // -------- document encoder (enc) -> d_hidden + doc_mean --------
  k_gather_p<<<16384,256,0,stream>>>(emb, docs, (unsigned*)GATH);
  k_gemm_bf3<<<dim3(4,128,2),256,0,stream>>>((const unsigned*)GATH, PWENC,
      encbih, PF, 16384, 450, 200, 208, 450L*208, 16384L*450, 450);
  k_gru_small<<<dim3(32,2),512,0,stream>>>(PF, 16384L*450, WT_ENC, encbhh,
      DH,300, DMEAN,300, 512);

  // -------- code_wise (4 label sets at once), split-bf16 --------
  k_packAc<<<cdiv(16384L*300,256),256,0,stream>>>(DH, (unsigned*)XB, 16384L*300);
  k_packW<<<cdiv(444L*304,256),256,0,stream>>>(LAB, (unsigned*)XB + 16384L*300, 444, 300, 304);
  k_gemm_bf3<<<dim3(4,128,1),256,0,stream>>>((const unsigned*)XB, (const unsigned*)XB + 16384L*300,
      nullptr, PF, 16384, 444, 300, 304, 0, 0, 0);
  k_cw_rowmax<<<dim3(64,4),256,0,stream>>>(PF, CWM);
  k_cw_softmax<<<dim3(32,4),256,0,stream>>>(CWM, CWA);
  k_cw_out<<<dim3(32,4),256,0,stream>>>(CWA, DH, CWO);

  // -------- charge classifier + argmax --------
  k_classify<<<32,256,0,stream>>>(DMEAN, CWO, CWO + 32L*300,
      300, 900, 1.f, Wc, bc, 119, ob, CP);

  // -------- verdict-charge GRU (enc) --------
  k_gather_sel_p<<<dim3(50,32),256,0,stream>>>(emb, vchtok, CP, (unsigned*)GATH);
  k_gemm_bf3<<<dim3(4,13,2),256,0,stream>>>((const unsigned*)GATH, PWENC,
      encbih, XSS, 1600, 450, 200, 208, 450L*208, 1600L*450, 450);
  k_gru_small<<<dim3(32,2),512,0,stream>>>(XSS, 1600L*450, WT_ENC, encbhh,
      VCH,300, nullptr,0, 50);

  // -------- fact separation 1 (vch vs d_hidden) --------
  k_gemm128<<<dim3(1,4,32),256,0,stream>>>(DH, VCH, nullptr, ATT,
      512,50,300, 512L*300, 50L*300, 512L*50, 0);
  k_masksm<<<64,256,0,stream>>>(ATT, 16384);
  k_transpose<<<dim3(cdiv(15000,256),32),256,0,stream>>>(VCH, VCHT, 50, 300);
  k_gemm128<<<dim3(3,4,32),256,0,stream>>>(ATT, VCHT, nullptr, SCEN,
      512,300,50, 512L*50, 300L*50, 512L*300, 0);
  k_factsep<<<4096,256,0,stream>>>(DH, SCEN, ADC, SEC, 16384);

  // -------- fact_article: packed assembler + split-bf16 MFMA proj + persistent art GRU --------
  k_factart_p<<<16384,256,0,stream>>>(DH, CWO + 2L*32*300, ADC, CWO + 3L*32*300, (unsigned*)PF);
  k_packW<<<cdiv(2L*1800*1216,256),256,0,stream>>>(artWih, (unsigned*)XSS, 2*1800, 1200, 1216);
  k_gemm_bf3<<<dim3(15,128,2),256,0,stream>>>((const unsigned*)PF, (const unsigned*)XSS,
      artbih, XB, 16384, 1800, 1200, 1216, 1800L*1216, 16384L*1800, 1800);
  hipMemsetAsync(FLAGS, 0, 512*sizeof(int), stream);
  hipMemsetAsync(HBUF, 0, 76800*sizeof(float), stream);
  // art: H=600, HS=600, KM=608, SW=616, NCB=40 -> 160 wgs
  k_gru_persist<600,600,608,616,40><<<160,256,0,stream>>>(
      XB, 16384L*1800, artWhh, artbhh, HBUF, HBUF+38400, YSUM, 1200, 512, FLAGS, GO);
  k_classify<<<32,256,0,stream>>>(YSUM, nullptr, nullptr,
      1200, 1200, 1.f/512.f, Wa, ba, 103, ob + 3808, AP);

  // -------- verdict-article GRU (enc) --------
  k_gather_sel_p<<<dim3(50,32),256,0,stream>>>(emb, vartok, AP, (unsigned*)GATH);
  k_gemm_bf3<<<dim3(4,13,2),256,0,stream>>>((const unsigned*)GATH, PWENC,
      encbih, XSS, 1600, 450, 200, 208, 450L*208, 1600L*450, 450);
  k_gru_small<<<dim3(32,2),512,0,stream>>>(XSS, 1600L*450, WT_ENC, encbhh,
      VCH,300, nullptr,0, 50);

  // -------- fact separation 2 (var vs sec); ssc->SCEN, dsc->SEC in place --------
  k_gemm128<<<dim3(1,4,32),256,0,stream>>>(SEC, VCH, nullptr, ATT,
      512,50,300, 512L*300, 50L*300, 512L*50, 0);
  k_masksm<<<64,256,0,stream>>>(ATT, 16384);
  k_transpose<<<dim3(cdiv(15000,256),32),256,0,stream>>>(VCH, VCHT, 50, 300);
  k_gemm128<<<dim3(3,4,32),256,0,stream>>>(ATT, VCHT, nullptr, SCEN,
      512,300,50, 512L*50, 300L*50, 512L*300, 0);
  k_factsep<<<4096,256,0,stream>>>(SEC, SCEN, SCEN, SEC, 16384);

  // -------- term bigru: packed assembler + split-bf16 MFMA proj + persistent GRU --------
  k_termcat_p<<<16384,256,0,stream>>>(DH, SCEN, SEC, (unsigned*)PF);
  k_packW<<<cdiv(2L*1350*912,256),256,0,stream>>>(termWih, (unsigned*)GATH, 2*1350, 900, 912);
  k_gemm_bf3<<<dim3(11,128,2),256,0,stream>>>((const unsigned*)PF, (const unsigned*)GATH,
      termbih, XB, 16384, 1350, 900, 912, 1350L*912, 16384L*1350, 1350);
  hipMemsetAsync(FLAGS, 0, 512*sizeof(int), stream);
  hipMemsetAsync(HBUF, 0, 76800*sizeof(float), stream);
  // term: H=450, HS=456, KM=480, SW=488, NCB=30 -> 120 wgs
  k_gru_persist<450,456,480,488,30><<<120,256,0,stream>>>(
      XB, 16384L*1350, termWhh, termbhh, HBUF, HBUF+29184, YSUM, 900, 512, FLAGS, GO);
  k_classify<<<32,256,0,stream>>>(YSUM, nullptr, nullptr,
      900, 900, 1.f/512.f, Wt_, bt_, 11, ob + 7104, nullptr);
}